// Round 17
// baseline (690.686 us; speedup 1.0000x reference)
//
#include <hip/hip_runtime.h>
#include <hip/hip_bf16.h>

// ============================================================================
// HWNet-SPP forward, MFMA bf16 implicit-GEMM with selective hi/lo precision.
// conv2: A-resident kernel; conv3/4/5: 128x128 LDS-staged template; FC1/FC2:
// packed fragment-order operands, zero LDS/barriers. Pooled layers (conv2,
// conv4) fuse the 2x2 pool into the GEMM epilogue as (window-max, window-min)
// dual fp32 writes -> exact under BN for either scale sign, 2x less C traffic.
// prep uses LDS-transpose for conv weights (coalesced both sides); conv1
// processes 16 channels/block-group (halves x re-reads), wave-shfl stats.
// Pass config (error budget vs absmax threshold 0.098):
//   conv2: Ah*Bh (1-pass)  conv3: +Al*Bh (2-pass)  conv4: 1-pass
//   conv5: full 3-pass hi/lo (split-K=2)  FC1/FC2: 2-pass (split-K=16)
// BN stats fused into GEMM epilogue / split-K reducer; bn_finalize is
// one-block-per-channel wave butterfly. conv1 reads x with edge clamping.
// SPP reads conv5 fp32 out with inline BN. Biases skipped (BN cancels).
// ============================================================================

typedef __bf16 bf16;
using bf16x4 = __attribute__((ext_vector_type(4))) __bf16;
using bf16x8 = __attribute__((ext_vector_type(8))) __bf16;
using f32x4  = __attribute__((ext_vector_type(4))) float;

__device__ __forceinline__ void split2(float v, bf16& h, bf16& l) {
  bf16 hb = (bf16)v;
  h = hb;
  l = (bf16)(v - (float)hb);
}

__device__ __forceinline__ int iclamp(int v, int lo, int hi) {
  return v < lo ? lo : (v > hi ? hi : v);
}

__device__ __forceinline__ size_t pk_off(int row, int k, int Kd64) {
  return ((size_t)(row >> 4) * Kd64 + (k >> 6)) * 1024 +
         (size_t)(((k >> 5) & 1) * 512 + ((k >> 3) & 3) * 128 + ((row & 15) << 3) + (k & 7));
}

__device__ __forceinline__ void gld_lds16(const bf16* g, void* lds) {
  __builtin_amdgcn_global_load_lds(
      (const __attribute__((address_space(1))) unsigned int*)g,
      (__attribute__((address_space(3))) unsigned int*)lds, 16, 0, 0);
}

// ---------------- fused weight/input transforms (one kernel) ----------------
// conv weights: one block per co; coalesced read of [CI][KK] row into LDS,
// coalesced write of [KK][CI] order. FC weights / phoc: packed fragment order.
__global__ __launch_bounds__(256) void prep_k(const float* __restrict__ c2w,
                                              const float* __restrict__ c3w,
                                              const float* __restrict__ c4w,
                                              const float* __restrict__ c5w,
                                              const float* __restrict__ f1w,
                                              const float* __restrict__ f2w,
                                              const float* __restrict__ phoc,
                                              bf16* __restrict__ Wc2h,
                                              bf16* __restrict__ Wc3h,
                                              bf16* __restrict__ Wc4h,
                                              bf16* __restrict__ Wc5h,
                                              bf16* __restrict__ Wc5l,
                                              bf16* __restrict__ Wf1,
                                              bf16* __restrict__ Wf2,
                                              bf16* __restrict__ cch,
                                              bf16* __restrict__ ccl) {
  __shared__ float buf[4608];
  int b = blockIdx.x;
  int tid = threadIdx.x;
  // conv-weight transpose branches: (src, dsth, dstl, CI, KK, co)
  const float* src = nullptr;
  bf16 *dsth = nullptr, *dstl = nullptr;
  int CI = 0, KK = 0, co = 0;
  if (b < 128)        { src = c2w; dsth = Wc2h; CI = 64;  KK = 25; co = b; }
  else if (b < 384)   { src = c3w; dsth = Wc3h; CI = 128; KK = 9;  co = b - 128; }
  else if (b < 896)   { src = c4w; dsth = Wc4h; CI = 256; KK = 9;  co = b - 384; }
  else if (b < 1408)  { src = c5w; dsth = Wc5h; dstl = Wc5l; CI = 512; KK = 9; co = b - 896; }
  if (src) {
    const int n = CI * KK;
    const float* sp = src + (size_t)co * n;
    for (int i = tid; i < n; i += 256) buf[i] = sp[i];
    __syncthreads();
    bf16* oh = dsth + (size_t)co * n;
    bf16* ol = dstl ? dstl + (size_t)co * n : nullptr;
    for (int o = tid; o < n; o += 256) {
      int ci = o & (CI - 1), kk = o / CI;
      float v = buf[ci * KK + kk];
      bf16 h, l; split2(v, h, l);
      oh[o] = h;
      if (ol) ol[o] = l;
    }
    return;
  }
  b -= 1408;
  if (b < 6144) {  // f1w [2048][3072] -> packed hi, 4 elems/thread
    int i = b * 256 + tid;
    int k0 = (i % 768) * 4, n = i / 768;
    const float4 v = *(const float4*)(f1w + (size_t)n * 3072 + k0);
    bf16x4 o = { (bf16)v.x, (bf16)v.y, (bf16)v.z, (bf16)v.w };
    *(bf16x4*)(Wf1 + pk_off(n, k0, 48)) = o;
    return;
  }
  b -= 6144;
  if (b < 16384) {  // f2w [2048][7901] -> packed hi [2048][8192], 4/thread
    int i = b * 256 + tid;
    int k0 = (i & 2047) * 4, n = i >> 11;
    const float* xp = f2w + (size_t)n * 7901 + k0;
    bf16x4 o;
#pragma unroll
    for (int j = 0; j < 4; j++) o[j] = (bf16)((k0 + j < 7901) ? xp[j] : 0.f);
    *(bf16x4*)(Wf2 + pk_off(n, k0, 128)) = o;
    return;
  }
  b -= 16384;
  {  // phoc -> packed CC cols [2048,8192) hi/lo
    int i = b * 256 + tid;
    if (i >= 256 * 6144) return;
    int k = i % 6144, r = i / 6144;
    int col = 2048 + k;
    float v = (col < 7901) ? phoc[(size_t)r * 5853 + (col - 2048)] : 0.f;
    bf16 h, l; split2(v, h, l);
    size_t o = pk_off(r, col, 128);
    cch[o] = h;
    ccl[o] = l;
  }
}

// ---------------- conv1 pass 1: BN stats, 16 ch/group, wave-shfl reduce ----
__global__ __launch_bounds__(256) void conv1_stats_k(const float* __restrict__ x,
                                                     const float* __restrict__ wt,
                                                     float* __restrict__ part) {
  int co0 = blockIdx.y * 16;
  float sums[16] = {0.f}, sqs[16] = {0.f};
  for (int r = 0; r < 16; r++) {
    int pix = blockIdx.x * 4096 + r * 256 + threadIdx.x;  // 0..393215
    int w = pix & 127; int t = pix >> 7; int h = t % 48; int n = t / 48;
    const float* ip = x + (size_t)n * 48 * 128;
    int ihs[5], iws[5];
#pragma unroll
    for (int k = 0; k < 5; k++) {
      ihs[k] = iclamp(h + k - 2, 0, 47);
      iws[k] = iclamp(w + k - 2, 0, 127);
    }
    float win[25];
#pragma unroll
    for (int kh = 0; kh < 5; kh++)
#pragma unroll
      for (int kw = 0; kw < 5; kw++) win[kh * 5 + kw] = ip[ihs[kh] * 128 + iws[kw]];
#pragma unroll
    for (int j = 0; j < 16; j++) {
      const float* wp = wt + (size_t)(co0 + j) * 25;
      float acc = 0.f;
#pragma unroll
      for (int k = 0; k < 25; k++) acc += win[k] * wp[k];
      sums[j] += acc; sqs[j] += acc * acc;
    }
  }
  __shared__ float wsum[4][16][2];
  const int lane = threadIdx.x & 63, w4 = threadIdx.x >> 6;
#pragma unroll
  for (int j = 0; j < 16; j++) {
    float s = sums[j], q = sqs[j];
#pragma unroll
    for (int o = 32; o > 0; o >>= 1) { s += __shfl_xor(s, o); q += __shfl_xor(q, o); }
    if (lane == 0) { wsum[w4][j][0] = s; wsum[w4][j][1] = q; }
  }
  __syncthreads();
  if (threadIdx.x < 16) {
    int j = threadIdx.x;
    float s = wsum[0][j][0] + wsum[1][j][0] + wsum[2][j][0] + wsum[3][j][0];
    float q = wsum[0][j][1] + wsum[1][j][1] + wsum[2][j][1] + wsum[3][j][1];
    int c = co0 + j;
    part[((size_t)c * 96 + blockIdx.x) * 2 + 0] = s;
    part[((size_t)c * 96 + blockIdx.x) * 2 + 1] = q;
  }
}

// ---------------- conv1 pass 2: conv+BN+ReLU+pool+pad, 16 ch/group ---------
__global__ __launch_bounds__(256) void conv1_apply_k(const float* __restrict__ x,
                                                     const float* __restrict__ wt,
                                                     const float* __restrict__ scale,
                                                     const float* __restrict__ shift,
                                                     bf16* __restrict__ yh,
                                                     bf16* __restrict__ yl) {
  int i = blockIdx.x * 256 + threadIdx.x;  // padded pixel slots
  if (i >= 64 * 28 * 68) return;
  int owp = i % 68; int t = i / 68; int ohp = t % 28; int n = t / 28;
  int co0 = blockIdx.y * 16;
  int oh = ohp - 2, ow = owp - 2;
  bf16x8 hv0, lv0, hv1, lv1;
#pragma unroll
  for (int j = 0; j < 8; j++) {
    hv0[j] = (bf16)0.f; lv0[j] = (bf16)0.f;
    hv1[j] = (bf16)0.f; lv1[j] = (bf16)0.f;
  }
  if (oh >= 0 && oh < 24 && ow >= 0 && ow < 64) {
    const float* ip = x + (size_t)n * 48 * 128;
    int shr[6], swc[6];
#pragma unroll
    for (int k = 0; k < 6; k++) {
      shr[k] = iclamp(2 * oh + k - 2, 0, 47);
      swc[k] = iclamp(2 * ow + k - 2, 0, 127);
    }
    float win[36];
#pragma unroll
    for (int r = 0; r < 6; r++)
#pragma unroll
      for (int c = 0; c < 6; c++) win[r * 6 + c] = ip[shr[r] * 128 + swc[c]];
#pragma unroll
    for (int j = 0; j < 16; j++) {
      const float* wp = wt + (size_t)(co0 + j) * 25;
      float sc = scale[co0 + j], sh = shift[co0 + j];
      float m = -1e30f;
#pragma unroll
      for (int dy = 0; dy < 2; dy++)
#pragma unroll
        for (int dx = 0; dx < 2; dx++) {
          float acc = 0.f;
#pragma unroll
          for (int kh = 0; kh < 5; kh++)
#pragma unroll
            for (int kw = 0; kw < 5; kw++)
              acc += win[(kh + dy) * 6 + kw + dx] * wp[kh * 5 + kw];
          m = fmaxf(m, acc * sc + sh);
        }
      float v = fmaxf(m, 0.f);
      bf16 h, l; split2(v, h, l);
      if (j < 8) { hv0[j] = h; lv0[j] = l; }
      else       { hv1[j - 8] = h; lv1[j - 8] = l; }
    }
  }
  size_t o = (size_t)i * 64 + co0;
  *(bf16x8*)(yh + o)     = hv0;
  *(bf16x8*)(yl + o)     = lv0;
  *(bf16x8*)(yh + o + 8) = hv1;
  *(bf16x8*)(yl + o + 8) = lv1;
}

// ---------------- conv2 specialized: A-resident + fused pool (max/min) -----
__global__ __launch_bounds__(256) void conv2_gemm_k(const bf16* __restrict__ Ahi,
                                                    const bf16* __restrict__ Bhi,
                                                    float* __restrict__ Wmax,
                                                    float* __restrict__ Wmin,
                                                    float* __restrict__ part) {
  __shared__ bf16 Ash[416 * 64];      // 52 KB (reused as exchange post-loop)
  __shared__ bf16 Bsh[128 * 64];      // 16 KB
  __shared__ float red[2][128][8];    // 8 KB
  const int t = threadIdx.x;
  const int lane = t & 63, w = t >> 6;
  const int m0 = blockIdx.x * 128;
  const int img = m0 / 1536;
  const int oh0 = (m0 % 1536) >> 6;   // even
  const size_t abase = ((size_t)(img * 28 + oh0) * 68) * 64;

#pragma unroll
  for (int i = 0; i < 13; i++) {
    int f = i * 256 + t;
    int p = f >> 3; if (p > 407) p = 407;
    int s = f & 7;
    int ss = s ^ (p & 7);
    gld_lds16(Ahi + abase + (size_t)p * 64 + ss * 8,
              (char*)Ash + (size_t)(i * 256 + w * 64) * 16);
  }

  size_t boff[4];
#pragma unroll
  for (int i = 0; i < 4; i++) {
    int f = (i * 4 + w) * 64 + lane;
    int row = f >> 3, slot = f & 7;
    int ss = slot ^ (row & 7);
    boff[i] = (size_t)row * 1600 + ss * 8;
  }

  const int wrow = w >> 1, wcol = w & 1;
  const int kg = lane >> 4, l15 = lane & 15;
  int pixb[4];
#pragma unroll
  for (int q = 0; q < 4; q++) pixb[q] = wrow * 68 + q * 16 + l15;
  int brb[4], bmk[4];
#pragma unroll
  for (int q = 0; q < 4; q++) {
    int rb = wcol * 64 + q * 16 + l15;
    brb[q] = rb * 128; bmk[q] = rb & 7;
  }
  const char* Ashb = (const char*)Ash;
  const char* Bshb = (const char*)Bsh;

  f32x4 acc[4][4] = {};
  for (int kc = 0; kc < 25; ++kc) {
    const int kh = kc / 5, kw = kc % 5;
    const int kofs = kh * 68 + kw;
    const int k0 = kc * 64;
#pragma unroll
    for (int i = 0; i < 4; i++)
      gld_lds16(Bhi + boff[i] + k0, (char*)Bsh + (i * 4 + w) * 1024);
    __syncthreads();
#pragma unroll
    for (int ks = 0; ks < 2; ks++) {
      const int slot = ks * 4 + kg;
      bf16x8 ah[4], bh[4];
#pragma unroll
      for (int q = 0; q < 4; q++) {
        int pix = pixb[q] + kofs;
        ah[q] = *(const bf16x8*)(Ashb + pix * 128 + ((slot ^ (pix & 7)) << 4));
        bh[q] = *(const bf16x8*)(Bshb + brb[q] + ((slot ^ bmk[q]) << 4));
      }
#pragma unroll
      for (int mi = 0; mi < 4; mi++)
#pragma unroll
        for (int ni = 0; ni < 4; ni++)
          acc[mi][ni] = __builtin_amdgcn_mfma_f32_16x16x32_bf16(ah[mi], bh[ni], acc[mi][ni], 0, 0, 0);
    }
    __syncthreads();  // after this, Ash/Bsh free for reuse
  }

  const int ccol = l15;
  float hmx[4][4][2], hmn[4][4][2];
#pragma unroll
  for (int mi = 0; mi < 4; mi++)
#pragma unroll
    for (int ni = 0; ni < 4; ni++)
#pragma unroll
      for (int jp = 0; jp < 2; jp++) {
        float a = acc[mi][ni][2 * jp], b = acc[mi][ni][2 * jp + 1];
        hmx[mi][ni][jp] = fmaxf(a, b);
        hmn[mi][ni][jp] = fminf(a, b);
      }
  const int contrib = kg * 2 + wrow;
#pragma unroll
  for (int ni = 0; ni < 4; ni++) {
    float s = 0.f, q = 0.f;
#pragma unroll
    for (int mi = 0; mi < 4; mi++)
#pragma unroll
      for (int jj = 0; jj < 4; jj++) {
        float v = acc[mi][ni][jj];
        s += v; q += v * v;
      }
    int coll = wcol * 64 + ni * 16 + ccol;
    red[0][coll][contrib] = s;
    red[1][coll][contrib] = q;
  }
  float* exch = (float*)Ash;
  if (wrow == 1) {
    float* ep = exch + (size_t)(wcol * 64 + lane) * 64;
#pragma unroll
    for (int mi = 0; mi < 4; mi++)
#pragma unroll
      for (int ni = 0; ni < 4; ni++)
#pragma unroll
        for (int jp = 0; jp < 2; jp++) {
          int s = (mi * 8 + ni * 2 + jp) * 2;
          ep[s + 0] = hmx[mi][ni][jp];
          ep[s + 1] = hmn[mi][ni][jp];
        }
  }
  __syncthreads();
  if (wrow == 0) {
    const float* ep = exch + (size_t)(wcol * 64 + lane) * 64;
    const int pmb = img * 384 + (oh0 >> 1) * 32;
#pragma unroll
    for (int mi = 0; mi < 4; mi++)
#pragma unroll
      for (int ni = 0; ni < 4; ni++)
#pragma unroll
        for (int jp = 0; jp < 2; jp++) {
          int s = (mi * 8 + ni * 2 + jp) * 2;
          float mx = fmaxf(hmx[mi][ni][jp], ep[s + 0]);
          float mn = fminf(hmn[mi][ni][jp], ep[s + 1]);
          int pm = pmb + mi * 8 + kg * 2 + jp;
          int ch = wcol * 64 + ni * 16 + ccol;
          Wmax[(size_t)pm * 128 + ch] = mx;
          Wmin[(size_t)pm * 128 + ch] = mn;
        }
  }
  if (t < 128) {
    float s = 0.f, q = 0.f;
#pragma unroll
    for (int j = 0; j < 8; j++) { s += red[0][t][j]; q += red[1][t][j]; }
    size_t c = t;
    part[(c * gridDim.x + blockIdx.x) * 2 + 0] = s;
    part[(c * gridDim.x + blockIdx.x) * 2 + 1] = q;
  }
}

// ---------------- MFMA implicit-GEMM, LDS-staged, optional split-K/pool ----
template<int CI, int KS, int OH, int OW, int CO, bool ALO, bool BLO, int SPLIT, bool FUSEPOOL>
__global__ __launch_bounds__(256) void conv_gemm_k(const bf16* __restrict__ Ahi,
                                                   const bf16* __restrict__ Alo,
                                                   const bf16* __restrict__ Bhi,
                                                   const bf16* __restrict__ Blo,
                                                   float* __restrict__ Cout,
                                                   float* __restrict__ Cmin,
                                                   float* __restrict__ part) {
  static_assert(CI % 64 == 0, "chunk must not straddle ci segments");
  static_assert(!FUSEPOOL || (OW == 32 && SPLIT == 1), "fusepool needs OW=32");
  constexpr int K = KS * KS * CI;
  constexpr int IWP = OW + KS - 1;
  constexpr int NCH = K / 64;
  static_assert(NCH % SPLIT == 0, "split must divide chunk count");
  constexpr int NCHS = NCH / SPLIT;
  constexpr int M = 64 * OH * OW;
  __shared__ bf16 Ash[128 * 64];
  __shared__ bf16 Asl[ALO ? 128 * 64 : 64];
  __shared__ bf16 Bsh[128 * 64];
  __shared__ bf16 Bsl[BLO ? 128 * 64 : 64];
  __shared__ float red[2][128][8];
  const int t = threadIdx.x;
  const int lane = t & 63, w = t >> 6;
  const int m0 = blockIdx.x * 128, n0 = blockIdx.y * 128;
  const int z = (SPLIT > 1) ? blockIdx.z : 0;

  int apix[4]; size_t boff[4];
#pragma unroll
  for (int i = 0; i < 4; i++) {
    int f = (i * 4 + w) * 64 + lane;
    int row = f >> 3, slot = f & 7;
    int ss = slot ^ (row & 7);
    int m = m0 + row;
    int n = m / (OH * OW); int rem = m % (OH * OW);
    int oh = rem / OW, ow_ = rem % OW;
    apix[i] = ((n * (OH + KS - 1) + oh) * IWP + ow_) * CI + ss * 8;
    boff[i] = (size_t)(n0 + row) * K + ss * 8;
  }

  const int wrow = w >> 1, wcol = w & 1;
  const int kg = lane >> 4, l15 = lane & 15;
  int arb[4], amk[4], brb[4], bmk[4];
#pragma unroll
  for (int q = 0; q < 4; q++) {
    int ra = wrow * 64 + q * 16 + l15;
    arb[q] = ra * 128; amk[q] = ra & 7;
    int rb = wcol * 64 + q * 16 + l15;
    brb[q] = rb * 128; bmk[q] = rb & 7;
  }
  const char* Ashb = (const char*)Ash;
  const char* Aslb = (const char*)Asl;
  const char* Bshb = (const char*)Bsh;
  const char* Bslb = (const char*)Bsl;

  f32x4 acc[4][4] = {};
  for (int kc = z * NCHS; kc < (z + 1) * NCHS; ++kc) {
    const int k0 = kc * 64;
    const int seg = k0 / CI;
    const int ci0 = k0 % CI;
    const int kh = seg / KS, kw = seg % KS;
    const int aoff = (kh * IWP + kw) * CI + ci0;   // wave-uniform
#pragma unroll
    for (int i = 0; i < 4; i++) {
      gld_lds16(Ahi + (size_t)apix[i] + aoff, (char*)Ash + (i * 4 + w) * 1024);
      if (ALO)
        gld_lds16(Alo + (size_t)apix[i] + aoff, (char*)Asl + (i * 4 + w) * 1024);
      gld_lds16(Bhi + boff[i] + k0,   (char*)Bsh + (i * 4 + w) * 1024);
      if (BLO)
        gld_lds16(Blo + boff[i] + k0, (char*)Bsl + (i * 4 + w) * 1024);
    }
    __syncthreads();
#pragma unroll
    for (int ks = 0; ks < 2; ks++) {
      const int slot = ks * 4 + kg;
      bf16x8 ah[4], bh[4];
#pragma unroll
      for (int q = 0; q < 4; q++) {
        ah[q] = *(const bf16x8*)(Ashb + arb[q] + ((slot ^ amk[q]) << 4));
        bh[q] = *(const bf16x8*)(Bshb + brb[q] + ((slot ^ bmk[q]) << 4));
      }
#pragma unroll
      for (int mi = 0; mi < 4; mi++)
#pragma unroll
        for (int ni = 0; ni < 4; ni++)
          acc[mi][ni] = __builtin_amdgcn_mfma_f32_16x16x32_bf16(ah[mi], bh[ni], acc[mi][ni], 0, 0, 0);
      if (ALO) {
        bf16x8 al[4];
#pragma unroll
        for (int q = 0; q < 4; q++)
          al[q] = *(const bf16x8*)(Aslb + arb[q] + ((slot ^ amk[q]) << 4));
#pragma unroll
        for (int mi = 0; mi < 4; mi++)
#pragma unroll
          for (int ni = 0; ni < 4; ni++)
            acc[mi][ni] = __builtin_amdgcn_mfma_f32_16x16x32_bf16(al[mi], bh[ni], acc[mi][ni], 0, 0, 0);
      }
      if (BLO) {
        bf16x8 bl[4];
#pragma unroll
        for (int q = 0; q < 4; q++)
          bl[q] = *(const bf16x8*)(Bslb + brb[q] + ((slot ^ bmk[q]) << 4));
#pragma unroll
        for (int mi = 0; mi < 4; mi++)
#pragma unroll
          for (int ni = 0; ni < 4; ni++)
            acc[mi][ni] = __builtin_amdgcn_mfma_f32_16x16x32_bf16(ah[mi], bl[ni], acc[mi][ni], 0, 0, 0);
      }
    }
    __syncthreads();
  }

  const int crow0 = kg * 4, ccol = l15;
  if constexpr (FUSEPOOL) {
    const int n_img = m0 / (OH * OW);
    const int oh0 = (m0 % (OH * OW)) / OW;          // multiple of 4
    const int pmb = n_img * (OH / 2) * (OW / 2) + (oh0 / 2 + wrow) * (OW / 2);
#pragma unroll
    for (int mi = 0; mi < 2; mi++)
#pragma unroll
      for (int ni = 0; ni < 4; ni++)
#pragma unroll
        for (int jp = 0; jp < 2; jp++) {
          float a0 = acc[mi][ni][2 * jp],     a1 = acc[mi][ni][2 * jp + 1];
          float b0 = acc[mi + 2][ni][2 * jp], b1 = acc[mi + 2][ni][2 * jp + 1];
          float mx = fmaxf(fmaxf(a0, a1), fmaxf(b0, b1));
          float mn = fminf(fminf(a0, a1), fminf(b0, b1));
          int pm = pmb + mi * 8 + kg * 2 + jp;
          int ch = n0 + wcol * 64 + ni * 16 + ccol;
          Cout[(size_t)pm * CO + ch] = mx;
          Cmin[(size_t)pm * CO + ch] = mn;
        }
  } else {
    float* Cz = Cout + (size_t)z * M * CO;
#pragma unroll
    for (int mi = 0; mi < 4; mi++) {
      int m = m0 + wrow * 64 + mi * 16 + crow0;
#pragma unroll
      for (int ni = 0; ni < 4; ni++) {
        int nn = n0 + wcol * 64 + ni * 16 + ccol;
        float* cp = Cz + (size_t)m * CO + nn;
#pragma unroll
        for (int jj = 0; jj < 4; jj++) cp[(size_t)jj * CO] = acc[mi][ni][jj];
      }
    }
  }
  if constexpr (SPLIT == 1) {
    const int contrib = kg * 2 + wrow;
#pragma unroll
    for (int ni = 0; ni < 4; ni++) {
      float s = 0.f, q = 0.f;
#pragma unroll
      for (int mi = 0; mi < 4; mi++)
#pragma unroll
        for (int jj = 0; jj < 4; jj++) {
          float v = acc[mi][ni][jj];
          s += v; q += v * v;
        }
      int coll = wcol * 64 + ni * 16 + ccol;
      red[0][coll][contrib] = s;
      red[1][coll][contrib] = q;
    }
    __syncthreads();
    if (t < 128) {
      float s = 0.f, q = 0.f;
#pragma unroll
      for (int j = 0; j < 8; j++) { s += red[0][t][j]; q += red[1][t][j]; }
      size_t c = n0 + t;
      part[(c * gridDim.x + blockIdx.x) * 2 + 0] = s;
      part[(c * gridDim.x + blockIdx.x) * 2 + 1] = q;
    }
  }
}

// ---------------- FC GEMM: packed A (hi/lo) + packed B, zero LDS/barriers --
template<int K, int SPLIT>
__global__ __launch_bounds__(256) void fc_gemm_k(const bf16* __restrict__ Ahp,
                                                 const bf16* __restrict__ Alp,
                                                 const bf16* __restrict__ Bhp,
                                                 float* __restrict__ Cout) {
  constexpr int Kd64 = K / 64;
  constexpr int NCHS = Kd64 / SPLIT;
  constexpr int M = 256, N = 2048;
  const int t = threadIdx.x;
  const int lane = t & 63, w = t >> 6;
  const int m0 = blockIdx.x * 128, n0 = blockIdx.y * 128;
  const int z = blockIdx.z;
  const int wrow = w >> 1, wcol = w & 1;
  const int kg = lane >> 4, l15 = lane & 15;

  size_t ab[4], bb[4];
#pragma unroll
  for (int q = 0; q < 4; q++) {
    int rbA = (m0 >> 4) + wrow * 4 + q;
    ab[q] = (size_t)rbA * Kd64 * 1024 + (size_t)lane * 8;
    int rbB = (n0 >> 4) + wcol * 4 + q;
    bb[q] = (size_t)rbB * Kd64 * 1024 + (size_t)lane * 8;
  }

  f32x4 acc[4][4] = {};
  for (int kc = z * NCHS; kc < (z + 1) * NCHS; ++kc) {
    const size_t bco = (size_t)kc * 1024;
#pragma unroll
    for (int ks = 0; ks < 2; ks++) {
      const size_t soff = bco + ks * 512;
      bf16x8 ah[4], al[4], bh[4];
#pragma unroll
      for (int q = 0; q < 4; q++) {
        ah[q] = *(const bf16x8*)(Ahp + ab[q] + soff);
        al[q] = *(const bf16x8*)(Alp + ab[q] + soff);
        bh[q] = *(const bf16x8*)(Bhp + bb[q] + soff);
      }
#pragma unroll
      for (int mi = 0; mi < 4; mi++)
#pragma unroll
        for (int ni = 0; ni < 4; ni++)
          acc[mi][ni] = __builtin_amdgcn_mfma_f32_16x16x32_bf16(ah[mi], bh[ni], acc[mi][ni], 0, 0, 0);
#pragma unroll
      for (int mi = 0; mi < 4; mi++)
#pragma unroll
        for (int ni = 0; ni < 4; ni++)
          acc[mi][ni] = __builtin_amdgcn_mfma_f32_16x16x32_bf16(al[mi], bh[ni], acc[mi][ni], 0, 0, 0);
    }
  }

  const int crow0 = kg * 4, ccol = l15;
  float* Cz = Cout + (size_t)z * M * N;
#pragma unroll
  for (int mi = 0; mi < 4; mi++) {
    int m = m0 + wrow * 64 + mi * 16 + crow0;
#pragma unroll
    for (int ni = 0; ni < 4; ni++) {
      int nn = n0 + wcol * 64 + ni * 16 + ccol;
      float* cp = Cz + (size_t)m * N + nn;
#pragma unroll
      for (int jj = 0; jj < 4; jj++) cp[(size_t)jj * N] = acc[mi][ni][jj];
    }
  }
}

// ---------------- split-K reduction + BN partials ----------------
template<int M, int CO, int SPLIT, int NS>
__global__ __launch_bounds__(256) void reduce_bn_k(const float* __restrict__ Cp,
                                                   float* __restrict__ Cf,
                                                   float* __restrict__ part) {
  int c = blockIdx.x * 64 + (threadIdx.x & 63);
  int rl = threadIdx.x >> 6;
  constexpr int ROWS = M / NS;
  int r0 = blockIdx.y * ROWS;
  float sum = 0.f, sq = 0.f;
  for (int r = r0 + rl; r < r0 + ROWS; r += 4) {
    float v = 0.f;
#pragma unroll
    for (int s = 0; s < SPLIT; s++) v += Cp[(size_t)s * M * CO + (size_t)r * CO + c];
    Cf[(size_t)r * CO + c] = v;
    sum += v; sq += v * v;
  }
  __shared__ float ls[256], lq[256];
  ls[threadIdx.x] = sum; lq[threadIdx.x] = sq;
  __syncthreads();
  if (threadIdx.x < 64) {
    sum = ls[threadIdx.x] + ls[threadIdx.x + 64] + ls[threadIdx.x + 128] + ls[threadIdx.x + 192];
    sq  = lq[threadIdx.x] + lq[threadIdx.x + 64] + lq[threadIdx.x + 128] + lq[threadIdx.x + 192];
    part[((size_t)c * NS + blockIdx.y) * 2 + 0] = sum;
    part[((size_t)c * NS + blockIdx.y) * 2 + 1] = sq;
  }
}

// ---------------- BN finalize: one block per channel, wave butterfly -------
__global__ __launch_bounds__(64) void bn_finalize(const float* __restrict__ part,
                                                  const float* __restrict__ g,
                                                  const float* __restrict__ b,
                                                  float* __restrict__ scale,
                                                  float* __restrict__ shift,
                                                  int S, float invCount) {
  int c = blockIdx.x;
  int lane = threadIdx.x;
  float sum = 0.f, sq = 0.f;
  for (int s = lane; s < S; s += 64) {
    sum += part[((size_t)c * S + s) * 2 + 0];
    sq  += part[((size_t)c * S + s) * 2 + 1];
  }
#pragma unroll
  for (int o = 32; o > 0; o >>= 1) {
    sum += __shfl_xor(sum, o);
    sq  += __shfl_xor(sq, o);
  }
  if (lane == 0) {
    float m = sum * invCount;
    float var = sq * invCount - m * m;
    float sc = g[c] * rsqrtf(var + 1e-5f);
    scale[c] = sc;
    shift[c] = b[c] - m * sc;
  }
}

// ---------------- fused BN + ReLU + pad (no pool), 8ch/thread --------------
template<int CO, int IH, int IW, int PADO>
__global__ __launch_bounds__(256) void bn_act_pad_k(const float* __restrict__ x,
                                                    const float* __restrict__ scale,
                                                    const float* __restrict__ shift,
                                                    bf16* __restrict__ yh,
                                                    bf16* __restrict__ yl) {
  constexpr int OHP = IH + 2 * PADO, OWP = IW + 2 * PADO;
  constexpr int CO8 = CO / 8;
  int i = blockIdx.x * 256 + threadIdx.x;
  if (i >= 64 * OHP * OWP * CO8) return;
  int c8 = i % CO8; int t = i / CO8; int owp = t % OWP; t /= OWP; int ohp = t % OHP; int n = t / OHP;
  int c0 = c8 * 8;
  int oh = ohp - PADO, ow = owp - PADO;
  bf16x8 hv, lv;
#pragma unroll
  for (int j = 0; j < 8; j++) { hv[j] = (bf16)0.f; lv[j] = (bf16)0.f; }
  if (oh >= 0 && oh < IH && ow >= 0 && ow < IW) {
    float sc[8], sh[8];
    *(f32x4*)(sc)     = *(const f32x4*)(scale + c0);
    *(f32x4*)(sc + 4) = *(const f32x4*)(scale + c0 + 4);
    *(f32x4*)(sh)     = *(const f32x4*)(shift + c0);
    *(f32x4*)(sh + 4) = *(const f32x4*)(shift + c0 + 4);
    const float* p = x + (((size_t)(n * IH) + oh) * IW + ow) * CO + c0;
    float ta[8];
    *(f32x4*)(ta) = *(const f32x4*)(p); *(f32x4*)(ta + 4) = *(const f32x4*)(p + 4);
#pragma unroll
    for (int j = 0; j < 8; j++) {
      float vv = fmaxf(ta[j] * sc[j] + sh[j], 0.f);
      bf16 h, l; split2(vv, h, l);
      hv[j] = h; lv[j] = l;
    }
  }
  size_t o = (size_t)i * 8;
  *(bf16x8*)(yh + o) = hv;
  *(bf16x8*)(yl + o) = lv;
}

// ---------------- BN + ReLU + pad from pooled (max,min), 8ch/thread --------
template<int CO, int PH, int PW, int PADO>
__global__ __launch_bounds__(256) void act_pool_pad_k(const float* __restrict__ wmax,
                                                      const float* __restrict__ wmin,
                                                      const float* __restrict__ scale,
                                                      const float* __restrict__ shift,
                                                      bf16* __restrict__ yh,
                                                      bf16* __restrict__ yl) {
  constexpr int OHP = PH + 2 * PADO, OWP = PW + 2 * PADO;
  constexpr int CO8 = CO / 8;
  int i = blockIdx.x * 256 + threadIdx.x;
  if (i >= 64 * OHP * OWP * CO8) return;
  int c8 = i % CO8; int t = i / CO8; int owp = t % OWP; t /= OWP; int ohp = t % OHP; int n = t / OHP;
  int c0 = c8 * 8;
  int oh = ohp - PADO, ow = owp - PADO;
  bf16x8 hv, lv;
#pragma unroll
  for (int j = 0; j < 8; j++) { hv[j] = (bf16)0.f; lv[j] = (bf16)0.f; }
  if (oh >= 0 && oh < PH && ow >= 0 && ow < PW) {
    float sc[8], sh[8], mx[8], mn[8];
    *(f32x4*)(sc)     = *(const f32x4*)(scale + c0);
    *(f32x4*)(sc + 4) = *(const f32x4*)(scale + c0 + 4);
    *(f32x4*)(sh)     = *(const f32x4*)(shift + c0);
    *(f32x4*)(sh + 4) = *(const f32x4*)(shift + c0 + 4);
    size_t off = (((size_t)(n * PH) + oh) * PW + ow) * CO + c0;
    *(f32x4*)(mx)     = *(const f32x4*)(wmax + off);
    *(f32x4*)(mx + 4) = *(const f32x4*)(wmax + off + 4);
    *(f32x4*)(mn)     = *(const f32x4*)(wmin + off);
    *(f32x4*)(mn + 4) = *(const f32x4*)(wmin + off + 4);
#pragma unroll
    for (int j = 0; j < 8; j++) {
      float sel = (sc[j] >= 0.f) ? mx[j] : mn[j];
      float vv = fmaxf(sel * sc[j] + sh[j], 0.f);
      bf16 h, l; split2(vv, h, l);
      hv[j] = h; lv[j] = l;
    }
  }
  size_t o = (size_t)i * 8;
  *(bf16x8*)(yh + o) = hv;
  *(bf16x8*)(yl + o) = lv;
}

// ---------------- ROI SPP: conv5 fp32 + inline BN -> PACKED S hi/lo --------
__global__ __launch_bounds__(256) void spp_k(const float* __restrict__ feat,
                                             const float* __restrict__ scale,
                                             const float* __restrict__ shift,
                                             const int* __restrict__ roi,
                                             bf16* __restrict__ oh_,
                                             bf16* __restrict__ ol_) {
  int c = blockIdx.x * 256 + threadIdx.x;  // 0..511
  int r = blockIdx.y;                      // 0..255
  const int* rp = roi + r * 5;
  int im = rp[0];
  int c1 = rp[1] >> 3, r1 = rp[2] >> 3, c2 = rp[3] >> 3, r2 = rp[4] >> 3;
  int w = c2 - c1 + 1;
  int lo[6], hi[6];
  int bi = 0;
#pragma unroll
  for (int l = 1; l <= 3; l++)
    for (int k = 0; k < l; k++) {
      lo[bi] = c1 + (k * w) / l;
      hi[bi] = c1 + ((k + 1) * w + l - 1) / l - 1;
      bi++;
    }
  float mx[6];
#pragma unroll
  for (int b = 0; b < 6; b++) mx[b] = -1e30f;
  float sc = scale[c], sh = shift[c];
  const float* fp = feat + (size_t)im * 96 * 512 + c;
  for (int row = r1; row <= r2; row++)
    for (int col = c1; col <= c2; col++) {
      float v = fp[(size_t)(row * 16 + col) * 512] * sc + sh;
#pragma unroll
      for (int b = 0; b < 6; b++)
        if (col >= lo[b] && col <= hi[b]) mx[b] = fmaxf(mx[b], v);
    }
  int idx[6] = {c, 512 + c * 2, 512 + c * 2 + 1, 1536 + c * 3, 1536 + c * 3 + 1, 1536 + c * 3 + 2};
#pragma unroll
  for (int b = 0; b < 6; b++) {
    float v = fmaxf(mx[b], 0.f);
    bf16 h, l; split2(v, h, l);
    size_t o = pk_off(r, idx[b], 48);
    oh_[o] = h;
    ol_[o] = l;
  }
}

// FC1: BN+ReLU, write hi/lo PACKED into CC[:, 0:2048] (K=8192)
__global__ __launch_bounds__(256) void bn1d_apply_cc_k(const float* __restrict__ x,
                                                       const float* __restrict__ scale,
                                                       const float* __restrict__ shift,
                                                       bf16* __restrict__ ch,
                                                       bf16* __restrict__ cl) {
  int i = blockIdx.x * 256 + threadIdx.x;
  if (i >= 256 * 256) return;
  int f8 = i & 255, r = i >> 8;
  int f0 = f8 * 8;
  float xv[8], sc[8], sh[8];
  *(f32x4*)(xv)     = *(const f32x4*)(x + (size_t)r * 2048 + f0);
  *(f32x4*)(xv + 4) = *(const f32x4*)(x + (size_t)r * 2048 + f0 + 4);
  *(f32x4*)(sc)     = *(const f32x4*)(scale + f0);
  *(f32x4*)(sc + 4) = *(const f32x4*)(scale + f0 + 4);
  *(f32x4*)(sh)     = *(const f32x4*)(shift + f0);
  *(f32x4*)(sh + 4) = *(const f32x4*)(shift + f0 + 4);
  bf16x8 hv, lv;
#pragma unroll
  for (int j = 0; j < 8; j++) {
    float v = fmaxf(xv[j] * sc[j] + sh[j], 0.f);
    bf16 h, l; split2(v, h, l);
    hv[j] = h; lv[j] = l;
  }
  size_t o = pk_off(r, f0, 128);
  *(bf16x8*)(ch + o) = hv;
  *(bf16x8*)(cl + o) = lv;
}

// FC2: BN+ReLU, fp32 out, 4 feat/thread
__global__ __launch_bounds__(256) void bn1d_apply_f32_k(const float* __restrict__ x,
                                                        const float* __restrict__ scale,
                                                        const float* __restrict__ shift,
                                                        float* __restrict__ y) {
  int i = blockIdx.x * 256 + threadIdx.x;
  if (i >= 256 * 512) return;
  int f4 = i & 511, r = i >> 9;
  int f0 = f4 * 4;
  f32x4 xv = *(const f32x4*)(x + (size_t)r * 2048 + f0);
  f32x4 sc = *(const f32x4*)(scale + f0);
  f32x4 sh = *(const f32x4*)(shift + f0);
  f32x4 o;
#pragma unroll
  for (int j = 0; j < 4; j++) o[j] = fmaxf(xv[j] * sc[j] + sh[j], 0.f);
  *(f32x4*)(y + (size_t)r * 2048 + f0) = o;
}

// ============================================================================
extern "C" void kernel_launch(void* const* d_in, const int* in_sizes, int n_in,
                              void* d_out, int out_size, void* d_ws, size_t ws_size,
                              hipStream_t stream) {
  (void)in_sizes; (void)n_in; (void)out_size; (void)ws_size;

  const float* x    = (const float*)d_in[0];
  const int*   roi  = (const int*)  d_in[1];
  const float* phoc = (const float*)d_in[2];
  const float* c1w  = (const float*)d_in[3];
  const float* g1   = (const float*)d_in[5];
  const float* b1   = (const float*)d_in[6];
  const float* c2w  = (const float*)d_in[7];
  const float* g2   = (const float*)d_in[9];
  const float* b2   = (const float*)d_in[10];
  const float* c3w  = (const float*)d_in[11];
  const float* g3   = (const float*)d_in[13];
  const float* b3   = (const float*)d_in[14];
  const float* c4w  = (const float*)d_in[15];
  const float* g4   = (const float*)d_in[17];
  const float* b4   = (const float*)d_in[18];
  const float* c5w  = (const float*)d_in[19];
  const float* g5   = (const float*)d_in[21];
  const float* b5   = (const float*)d_in[22];
  const float* f1w  = (const float*)d_in[23];
  const float* g6   = (const float*)d_in[25];
  const float* b6   = (const float*)d_in[26];
  const float* f2w  = (const float*)d_in[27];
  const float* g7   = (const float*)d_in[29];
  const float* b7   = (const float*)d_in[30];
  float* out = (float*)d_out;

  // ---- workspace layout (total ~168.4 MB) ----
  char* ws = (char*)d_ws;
  bf16*  Ahi  = (bf16*) (ws + 0x0200000);   // 16 MB (padded NHWC activations)
  bf16*  Alo  = (bf16*) (ws + 0x1200000);   // 16 MB
  float* C    = (float*)(ws + 0x2200000);   // GEMM out / split slabs / pooled max
  float* CMIN = (float*)(ws + 0x2E00000);   // pooled min
  float* C5F  = (float*)(ws + 0x4600000);   // conv5 final
  bf16*  Wc2h = (bf16*) (ws + 0x5500000);   // conv weights (row-major [CO][K])
  bf16*  Wc3h = (bf16*) (ws + 0x5570000);
  bf16*  Wc4h = (bf16*) (ws + 0x5600000);
  bf16*  Wc5h = (bf16*) (ws + 0x5840000);
  bf16*  Wf1  = (bf16*) (ws + 0x5CC0000);   // packed FC weights
  bf16*  Wf2  = (bf16*) (ws + 0x68C0000);   // packed [2048][8192] = 32 MB
  bf16*  Wc5l = (bf16*) (ws + 0x8C00000);
  bf16*  Shi  = (bf16*) (ws + 0x9080000);   // packed spp out [256][3072]
  bf16*  Slo  = (bf16*) (ws + 0x9200000);
  float* G6   = (float*)(ws + 0x9380000);   // fc1 out fp32 [256][2048]
  bf16*  CChi = (bf16*) (ws + 0x9580000);   // packed concat [256][8192] = 4 MB
  bf16*  CClo = (bf16*) (ws + 0x9980000);
  float* G7   = (float*)(ws + 0x9D80000);   // fc2 out fp32 [256][2048]
  float* PART = (float*)(ws + 0x9F80000);   // 768 KB
  float* SC   = (float*)(ws + 0xA040000);
  float* SH   = (float*)(ws + 0xA050000);

  // ---- all weight/input transforms in one dispatch (LDS-transposed convs) --
  prep_k<<<30080, 256, 0, stream>>>(c2w, c3w, c4w, c5w, f1w, f2w, phoc,
                                    Wc2h, Wc3h, Wc4h, Wc5h, Wc5l, Wf1, Wf2,
                                    CChi, CClo);

  // ---- conv1 (two-pass, clamped reads, 16 ch/group) ----
  conv1_stats_k<<<dim3(96, 4), 256, 0, stream>>>(x, c1w, PART);
  bn_finalize<<<64, 64, 0, stream>>>(PART, g1, b1, SC, SH, 96, 1.f / 393216.f);
  conv1_apply_k<<<dim3(476, 4), 256, 0, stream>>>(x, c1w, SC, SH, Ahi, Alo);

  // ---- conv2 (1-pass, A-resident, fused pool): -> pooled max/min [24576][128]
  conv2_gemm_k<<<768, 256, 0, stream>>>(Ahi, Wc2h, C, CMIN, PART);
  bn_finalize<<<128, 64, 0, stream>>>(PART, g2, b2, SC, SH, 768, 1.f / 98304.f);
  act_pool_pad_k<128, 12, 32, 1><<<1904, 256, 0, stream>>>(C, CMIN, SC, SH, Ahi, Alo);

  // ---- conv3 (2-pass: Ah.Bh + Al.Bh, no pool) ----
  conv_gemm_k<128, 3, 12, 32, 256, true, false, 1, false><<<dim3(192, 2), 256, 0, stream>>>(Ahi, Alo, Wc3h, nullptr, C, nullptr, PART);
  bn_finalize<<<256, 64, 0, stream>>>(PART, g3, b3, SC, SH, 192, 1.f / 24576.f);
  bn_act_pad_k<256, 12, 32, 1><<<3808, 256, 0, stream>>>(C, SC, SH, Ahi, Alo);

  // ---- conv4 (1-pass, fused pool): -> pooled max/min [6144][512] ----
  conv_gemm_k<256, 3, 12, 32, 512, false, false, 1, true><<<dim3(192, 4), 256, 0, stream>>>(Ahi, Alo, Wc4h, nullptr, C, CMIN, PART);
  bn_finalize<<<512, 64, 0, stream>>>(PART, g4, b4, SC, SH, 192, 1.f / 24576.f);
  act_pool_pad_k<512, 6, 16, 1><<<2304, 256, 0, stream>>>(C, CMIN, SC, SH, Ahi, Alo);

  // ---- conv5 (3-pass, split-K=2): slabs in C, final in C5F ----
  conv_gemm_k<512, 3, 6, 16, 512, true, true, 2, false><<<dim3(48, 4, 2), 256, 0, stream>>>(Ahi, Alo, Wc5h, Wc5l, C, nullptr, nullptr);
  reduce_bn_k<6144, 512, 2, 16><<<dim3(8, 16), 256, 0, stream>>>(C, C5F, PART);
  bn_finalize<<<512, 64, 0, stream>>>(PART, g5, b5, SC, SH, 16, 1.f / 6144.f);

  // ---- SPP (reads fp32 conv5 out + inline BN, packed output) ----
  spp_k<<<dim3(2, 256), 256, 0, stream>>>(C5F, SC, SH, roi, Shi, Slo);

  // ---- FC1 (packed, LDS-free, split-K=16): [256][3072] x [2048][3072] ----
  fc_gemm_k<3072, 16><<<dim3(2, 16, 16), 256, 0, stream>>>(Shi, Slo, Wf1, C);
  reduce_bn_k<256, 2048, 16, 4><<<dim3(32, 4), 256, 0, stream>>>(C, G6, PART);
  bn_finalize<<<2048, 64, 0, stream>>>(PART, g6, b6, SC, SH, 4, 1.f / 256.f);
  bn1d_apply_cc_k<<<256, 256, 0, stream>>>(G6, SC, SH, CChi, CClo);

  // ---- FC2 (packed, LDS-free, split-K=16): [256][8192] x [2048][8192] ----
  fc_gemm_k<8192, 16><<<dim3(2, 16, 16), 256, 0, stream>>>(CChi, CClo, Wf2, C);
  reduce_bn_k<256, 2048, 16, 4><<<dim3(32, 4), 256, 0, stream>>>(C, G7, PART);
  bn_finalize<<<2048, 64, 0, stream>>>(PART, g7, b7, SC, SH, 4, 1.f / 256.f);
  bn1d_apply_f32_k<<<512, 256, 0, stream>>>(G7, SC, SH, out);
}

// Round 18
// 568.988 us; speedup vs baseline: 1.2139x; 1.2139x over previous
//
#include <hip/hip_runtime.h>
#include <hip/hip_bf16.h>

// ============================================================================
// HWNet-SPP forward, MFMA bf16 implicit-GEMM with selective hi/lo precision.
// conv2: A-resident kernel; conv3/4/5: 128x128 LDS-staged template; FC1/FC2:
// packed fragment-order operands, zero LDS/barriers. Pooled layers (conv2,
// conv4) fuse the 2x2 pool into the GEMM epilogue as (window-max, window-min)
// dual fp32 writes. prep uses LDS-transpose for conv weights (coalesced both
// sides). conv1 is the proven 8-ch/group version (16-ch spilled to scratch).
// Pass config (error budget vs absmax threshold 0.098):
//   conv2: Ah*Bh (1-pass)  conv3: +Al*Bh (2-pass)  conv4: 1-pass
//   conv5: full 3-pass hi/lo (split-K=2)  FC1/FC2: 2-pass (split-K=16)
// BN stats fused into GEMM epilogue / split-K reducer; bn_finalize is
// one-block-per-channel wave butterfly. conv1 reads x with edge clamping.
// SPP reads conv5 fp32 out with inline BN. Biases skipped (BN cancels).
// ============================================================================

typedef __bf16 bf16;
using bf16x4 = __attribute__((ext_vector_type(4))) __bf16;
using bf16x8 = __attribute__((ext_vector_type(8))) __bf16;
using f32x4  = __attribute__((ext_vector_type(4))) float;

__device__ __forceinline__ void split2(float v, bf16& h, bf16& l) {
  bf16 hb = (bf16)v;
  h = hb;
  l = (bf16)(v - (float)hb);
}

__device__ __forceinline__ int iclamp(int v, int lo, int hi) {
  return v < lo ? lo : (v > hi ? hi : v);
}

__device__ __forceinline__ size_t pk_off(int row, int k, int Kd64) {
  return ((size_t)(row >> 4) * Kd64 + (k >> 6)) * 1024 +
         (size_t)(((k >> 5) & 1) * 512 + ((k >> 3) & 3) * 128 + ((row & 15) << 3) + (k & 7));
}

__device__ __forceinline__ void gld_lds16(const bf16* g, void* lds) {
  __builtin_amdgcn_global_load_lds(
      (const __attribute__((address_space(1))) unsigned int*)g,
      (__attribute__((address_space(3))) unsigned int*)lds, 16, 0, 0);
}

// ---------------- fused weight/input transforms (one kernel) ----------------
// conv weights: one block per co; coalesced read of [CI][KK] row into LDS,
// coalesced write of [KK][CI] order. FC weights / phoc: packed fragment order.
__global__ __launch_bounds__(256) void prep_k(const float* __restrict__ c2w,
                                              const float* __restrict__ c3w,
                                              const float* __restrict__ c4w,
                                              const float* __restrict__ c5w,
                                              const float* __restrict__ f1w,
                                              const float* __restrict__ f2w,
                                              const float* __restrict__ phoc,
                                              bf16* __restrict__ Wc2h,
                                              bf16* __restrict__ Wc3h,
                                              bf16* __restrict__ Wc4h,
                                              bf16* __restrict__ Wc5h,
                                              bf16* __restrict__ Wc5l,
                                              bf16* __restrict__ Wf1,
                                              bf16* __restrict__ Wf2,
                                              bf16* __restrict__ cch,
                                              bf16* __restrict__ ccl) {
  __shared__ float buf[4608];
  int b = blockIdx.x;
  int tid = threadIdx.x;
  const float* src = nullptr;
  bf16 *dsth = nullptr, *dstl = nullptr;
  int CI = 0, KK = 0, co = 0;
  if (b < 128)        { src = c2w; dsth = Wc2h; CI = 64;  KK = 25; co = b; }
  else if (b < 384)   { src = c3w; dsth = Wc3h; CI = 128; KK = 9;  co = b - 128; }
  else if (b < 896)   { src = c4w; dsth = Wc4h; CI = 256; KK = 9;  co = b - 384; }
  else if (b < 1408)  { src = c5w; dsth = Wc5h; dstl = Wc5l; CI = 512; KK = 9; co = b - 896; }
  if (src) {
    const int n = CI * KK;
    const float* sp = src + (size_t)co * n;
    for (int i = tid; i < n; i += 256) buf[i] = sp[i];
    __syncthreads();
    bf16* oh = dsth + (size_t)co * n;
    bf16* ol = dstl ? dstl + (size_t)co * n : nullptr;
    for (int o = tid; o < n; o += 256) {
      int ci = o & (CI - 1), kk = o / CI;
      float v = buf[ci * KK + kk];
      bf16 h, l; split2(v, h, l);
      oh[o] = h;
      if (ol) ol[o] = l;
    }
    return;
  }
  b -= 1408;
  if (b < 6144) {  // f1w [2048][3072] -> packed hi, 4 elems/thread
    int i = b * 256 + tid;
    int k0 = (i % 768) * 4, n = i / 768;
    const float4 v = *(const float4*)(f1w + (size_t)n * 3072 + k0);
    bf16x4 o = { (bf16)v.x, (bf16)v.y, (bf16)v.z, (bf16)v.w };
    *(bf16x4*)(Wf1 + pk_off(n, k0, 48)) = o;
    return;
  }
  b -= 6144;
  if (b < 16384) {  // f2w [2048][7901] -> packed hi [2048][8192], 4/thread
    int i = b * 256 + tid;
    int k0 = (i & 2047) * 4, n = i >> 11;
    const float* xp = f2w + (size_t)n * 7901 + k0;
    bf16x4 o;
#pragma unroll
    for (int j = 0; j < 4; j++) o[j] = (bf16)((k0 + j < 7901) ? xp[j] : 0.f);
    *(bf16x4*)(Wf2 + pk_off(n, k0, 128)) = o;
    return;
  }
  b -= 16384;
  {  // phoc -> packed CC cols [2048,8192) hi/lo
    int i = b * 256 + tid;
    if (i >= 256 * 6144) return;
    int k = i % 6144, r = i / 6144;
    int col = 2048 + k;
    float v = (col < 7901) ? phoc[(size_t)r * 5853 + (col - 2048)] : 0.f;
    bf16 h, l; split2(v, h, l);
    size_t o = pk_off(r, col, 128);
    cch[o] = h;
    ccl[o] = l;
  }
}

// ---------------- conv1 pass 1: BN stats (8 ch/group, LDS tree) ------------
__global__ __launch_bounds__(256) void conv1_stats_k(const float* __restrict__ x,
                                                     const float* __restrict__ wt,
                                                     float* __restrict__ part) {
  int co0 = blockIdx.y * 8;
  float sums[8] = {0.f}, sqs[8] = {0.f};
  for (int r = 0; r < 16; r++) {
    int pix = blockIdx.x * 4096 + r * 256 + threadIdx.x;  // 0..393215
    int w = pix & 127; int t = pix >> 7; int h = t % 48; int n = t / 48;
    const float* ip = x + (size_t)n * 48 * 128;
    int ihs[5], iws[5];
#pragma unroll
    for (int k = 0; k < 5; k++) {
      ihs[k] = iclamp(h + k - 2, 0, 47);
      iws[k] = iclamp(w + k - 2, 0, 127);
    }
    float win[25];
#pragma unroll
    for (int kh = 0; kh < 5; kh++)
#pragma unroll
      for (int kw = 0; kw < 5; kw++) win[kh * 5 + kw] = ip[ihs[kh] * 128 + iws[kw]];
#pragma unroll
    for (int j = 0; j < 8; j++) {
      const float* wp = wt + (size_t)(co0 + j) * 25;
      float acc = 0.f;
#pragma unroll
      for (int k = 0; k < 25; k++) acc += win[k] * wp[k];
      sums[j] += acc; sqs[j] += acc * acc;
    }
  }
  __shared__ float ls[256], lq[256];
  for (int j = 0; j < 8; j++) {
    ls[threadIdx.x] = sums[j]; lq[threadIdx.x] = sqs[j];
    __syncthreads();
    for (int o = 128; o > 0; o >>= 1) {
      if (threadIdx.x < o) { ls[threadIdx.x] += ls[threadIdx.x + o]; lq[threadIdx.x] += lq[threadIdx.x + o]; }
      __syncthreads();
    }
    if (threadIdx.x == 0) {
      int c = co0 + j;
      part[((size_t)c * 96 + blockIdx.x) * 2 + 0] = ls[0];
      part[((size_t)c * 96 + blockIdx.x) * 2 + 1] = lq[0];
    }
    __syncthreads();
  }
}

// ---------------- conv1 pass 2: conv+BN+ReLU+pool+pad (8 ch/group) ---------
__global__ __launch_bounds__(256) void conv1_apply_k(const float* __restrict__ x,
                                                     const float* __restrict__ wt,
                                                     const float* __restrict__ scale,
                                                     const float* __restrict__ shift,
                                                     bf16* __restrict__ yh,
                                                     bf16* __restrict__ yl) {
  int i = blockIdx.x * 256 + threadIdx.x;  // padded pixel slots
  if (i >= 64 * 28 * 68) return;
  int owp = i % 68; int t = i / 68; int ohp = t % 28; int n = t / 28;
  int co0 = blockIdx.y * 8;
  int oh = ohp - 2, ow = owp - 2;
  bf16x8 hv, lv;
#pragma unroll
  for (int j = 0; j < 8; j++) { hv[j] = (bf16)0.f; lv[j] = (bf16)0.f; }
  if (oh >= 0 && oh < 24 && ow >= 0 && ow < 64) {
    const float* ip = x + (size_t)n * 48 * 128;
    int shr[6], swc[6];
#pragma unroll
    for (int k = 0; k < 6; k++) {
      shr[k] = iclamp(2 * oh + k - 2, 0, 47);
      swc[k] = iclamp(2 * ow + k - 2, 0, 127);
    }
    float win[36];
#pragma unroll
    for (int r = 0; r < 6; r++)
#pragma unroll
      for (int c = 0; c < 6; c++) win[r * 6 + c] = ip[shr[r] * 128 + swc[c]];
#pragma unroll
    for (int j = 0; j < 8; j++) {
      const float* wp = wt + (size_t)(co0 + j) * 25;
      float sc = scale[co0 + j], sh = shift[co0 + j];
      float m = -1e30f;
#pragma unroll
      for (int dy = 0; dy < 2; dy++)
#pragma unroll
        for (int dx = 0; dx < 2; dx++) {
          float acc = 0.f;
#pragma unroll
          for (int kh = 0; kh < 5; kh++)
#pragma unroll
            for (int kw = 0; kw < 5; kw++)
              acc += win[(kh + dy) * 6 + kw + dx] * wp[kh * 5 + kw];
          m = fmaxf(m, acc * sc + sh);
        }
      float v = fmaxf(m, 0.f);
      bf16 h, l; split2(v, h, l);
      hv[j] = h; lv[j] = l;
    }
  }
  size_t o = (size_t)i * 64 + co0;
  *(bf16x8*)(yh + o) = hv;
  *(bf16x8*)(yl + o) = lv;
}

// ---------------- conv2 specialized: A-resident + fused pool (max/min) -----
__global__ __launch_bounds__(256) void conv2_gemm_k(const bf16* __restrict__ Ahi,
                                                    const bf16* __restrict__ Bhi,
                                                    float* __restrict__ Wmax,
                                                    float* __restrict__ Wmin,
                                                    float* __restrict__ part) {
  __shared__ bf16 Ash[416 * 64];      // 52 KB (reused as exchange post-loop)
  __shared__ bf16 Bsh[128 * 64];      // 16 KB
  __shared__ float red[2][128][8];    // 8 KB
  const int t = threadIdx.x;
  const int lane = t & 63, w = t >> 6;
  const int m0 = blockIdx.x * 128;
  const int img = m0 / 1536;
  const int oh0 = (m0 % 1536) >> 6;   // even
  const size_t abase = ((size_t)(img * 28 + oh0) * 68) * 64;

#pragma unroll
  for (int i = 0; i < 13; i++) {
    int f = i * 256 + t;
    int p = f >> 3; if (p > 407) p = 407;
    int s = f & 7;
    int ss = s ^ (p & 7);
    gld_lds16(Ahi + abase + (size_t)p * 64 + ss * 8,
              (char*)Ash + (size_t)(i * 256 + w * 64) * 16);
  }

  size_t boff[4];
#pragma unroll
  for (int i = 0; i < 4; i++) {
    int f = (i * 4 + w) * 64 + lane;
    int row = f >> 3, slot = f & 7;
    int ss = slot ^ (row & 7);
    boff[i] = (size_t)row * 1600 + ss * 8;
  }

  const int wrow = w >> 1, wcol = w & 1;
  const int kg = lane >> 4, l15 = lane & 15;
  int pixb[4];
#pragma unroll
  for (int q = 0; q < 4; q++) pixb[q] = wrow * 68 + q * 16 + l15;
  int brb[4], bmk[4];
#pragma unroll
  for (int q = 0; q < 4; q++) {
    int rb = wcol * 64 + q * 16 + l15;
    brb[q] = rb * 128; bmk[q] = rb & 7;
  }
  const char* Ashb = (const char*)Ash;
  const char* Bshb = (const char*)Bsh;

  f32x4 acc[4][4] = {};
  for (int kc = 0; kc < 25; ++kc) {
    const int kh = kc / 5, kw = kc % 5;
    const int kofs = kh * 68 + kw;
    const int k0 = kc * 64;
#pragma unroll
    for (int i = 0; i < 4; i++)
      gld_lds16(Bhi + boff[i] + k0, (char*)Bsh + (i * 4 + w) * 1024);
    __syncthreads();
#pragma unroll
    for (int ks = 0; ks < 2; ks++) {
      const int slot = ks * 4 + kg;
      bf16x8 ah[4], bh[4];
#pragma unroll
      for (int q = 0; q < 4; q++) {
        int pix = pixb[q] + kofs;
        ah[q] = *(const bf16x8*)(Ashb + pix * 128 + ((slot ^ (pix & 7)) << 4));
        bh[q] = *(const bf16x8*)(Bshb + brb[q] + ((slot ^ bmk[q]) << 4));
      }
#pragma unroll
      for (int mi = 0; mi < 4; mi++)
#pragma unroll
        for (int ni = 0; ni < 4; ni++)
          acc[mi][ni] = __builtin_amdgcn_mfma_f32_16x16x32_bf16(ah[mi], bh[ni], acc[mi][ni], 0, 0, 0);
    }
    __syncthreads();  // after this, Ash/Bsh free for reuse
  }

  const int ccol = l15;
  float hmx[4][4][2], hmn[4][4][2];
#pragma unroll
  for (int mi = 0; mi < 4; mi++)
#pragma unroll
    for (int ni = 0; ni < 4; ni++)
#pragma unroll
      for (int jp = 0; jp < 2; jp++) {
        float a = acc[mi][ni][2 * jp], b = acc[mi][ni][2 * jp + 1];
        hmx[mi][ni][jp] = fmaxf(a, b);
        hmn[mi][ni][jp] = fminf(a, b);
      }
  const int contrib = kg * 2 + wrow;
#pragma unroll
  for (int ni = 0; ni < 4; ni++) {
    float s = 0.f, q = 0.f;
#pragma unroll
    for (int mi = 0; mi < 4; mi++)
#pragma unroll
      for (int jj = 0; jj < 4; jj++) {
        float v = acc[mi][ni][jj];
        s += v; q += v * v;
      }
    int coll = wcol * 64 + ni * 16 + ccol;
    red[0][coll][contrib] = s;
    red[1][coll][contrib] = q;
  }
  float* exch = (float*)Ash;
  if (wrow == 1) {
    float* ep = exch + (size_t)(wcol * 64 + lane) * 64;
#pragma unroll
    for (int mi = 0; mi < 4; mi++)
#pragma unroll
      for (int ni = 0; ni < 4; ni++)
#pragma unroll
        for (int jp = 0; jp < 2; jp++) {
          int s = (mi * 8 + ni * 2 + jp) * 2;
          ep[s + 0] = hmx[mi][ni][jp];
          ep[s + 1] = hmn[mi][ni][jp];
        }
  }
  __syncthreads();
  if (wrow == 0) {
    const float* ep = exch + (size_t)(wcol * 64 + lane) * 64;
    const int pmb = img * 384 + (oh0 >> 1) * 32;
#pragma unroll
    for (int mi = 0; mi < 4; mi++)
#pragma unroll
      for (int ni = 0; ni < 4; ni++)
#pragma unroll
        for (int jp = 0; jp < 2; jp++) {
          int s = (mi * 8 + ni * 2 + jp) * 2;
          float mx = fmaxf(hmx[mi][ni][jp], ep[s + 0]);
          float mn = fminf(hmn[mi][ni][jp], ep[s + 1]);
          int pm = pmb + mi * 8 + kg * 2 + jp;
          int ch = wcol * 64 + ni * 16 + ccol;
          Wmax[(size_t)pm * 128 + ch] = mx;
          Wmin[(size_t)pm * 128 + ch] = mn;
        }
  }
  if (t < 128) {
    float s = 0.f, q = 0.f;
#pragma unroll
    for (int j = 0; j < 8; j++) { s += red[0][t][j]; q += red[1][t][j]; }
    size_t c = t;
    part[(c * gridDim.x + blockIdx.x) * 2 + 0] = s;
    part[(c * gridDim.x + blockIdx.x) * 2 + 1] = q;
  }
}

// ---------------- MFMA implicit-GEMM, LDS-staged, optional split-K/pool ----
template<int CI, int KS, int OH, int OW, int CO, bool ALO, bool BLO, int SPLIT, bool FUSEPOOL>
__global__ __launch_bounds__(256) void conv_gemm_k(const bf16* __restrict__ Ahi,
                                                   const bf16* __restrict__ Alo,
                                                   const bf16* __restrict__ Bhi,
                                                   const bf16* __restrict__ Blo,
                                                   float* __restrict__ Cout,
                                                   float* __restrict__ Cmin,
                                                   float* __restrict__ part) {
  static_assert(CI % 64 == 0, "chunk must not straddle ci segments");
  static_assert(!FUSEPOOL || (OW == 32 && SPLIT == 1), "fusepool needs OW=32");
  constexpr int K = KS * KS * CI;
  constexpr int IWP = OW + KS - 1;
  constexpr int NCH = K / 64;
  static_assert(NCH % SPLIT == 0, "split must divide chunk count");
  constexpr int NCHS = NCH / SPLIT;
  constexpr int M = 64 * OH * OW;
  __shared__ bf16 Ash[128 * 64];
  __shared__ bf16 Asl[ALO ? 128 * 64 : 64];
  __shared__ bf16 Bsh[128 * 64];
  __shared__ bf16 Bsl[BLO ? 128 * 64 : 64];
  __shared__ float red[2][128][8];
  const int t = threadIdx.x;
  const int lane = t & 63, w = t >> 6;
  const int m0 = blockIdx.x * 128, n0 = blockIdx.y * 128;
  const int z = (SPLIT > 1) ? blockIdx.z : 0;

  int apix[4]; size_t boff[4];
#pragma unroll
  for (int i = 0; i < 4; i++) {
    int f = (i * 4 + w) * 64 + lane;
    int row = f >> 3, slot = f & 7;
    int ss = slot ^ (row & 7);
    int m = m0 + row;
    int n = m / (OH * OW); int rem = m % (OH * OW);
    int oh = rem / OW, ow_ = rem % OW;
    apix[i] = ((n * (OH + KS - 1) + oh) * IWP + ow_) * CI + ss * 8;
    boff[i] = (size_t)(n0 + row) * K + ss * 8;
  }

  const int wrow = w >> 1, wcol = w & 1;
  const int kg = lane >> 4, l15 = lane & 15;
  int arb[4], amk[4], brb[4], bmk[4];
#pragma unroll
  for (int q = 0; q < 4; q++) {
    int ra = wrow * 64 + q * 16 + l15;
    arb[q] = ra * 128; amk[q] = ra & 7;
    int rb = wcol * 64 + q * 16 + l15;
    brb[q] = rb * 128; bmk[q] = rb & 7;
  }
  const char* Ashb = (const char*)Ash;
  const char* Aslb = (const char*)Asl;
  const char* Bshb = (const char*)Bsh;
  const char* Bslb = (const char*)Bsl;

  f32x4 acc[4][4] = {};
  for (int kc = z * NCHS; kc < (z + 1) * NCHS; ++kc) {
    const int k0 = kc * 64;
    const int seg = k0 / CI;
    const int ci0 = k0 % CI;
    const int kh = seg / KS, kw = seg % KS;
    const int aoff = (kh * IWP + kw) * CI + ci0;   // wave-uniform
#pragma unroll
    for (int i = 0; i < 4; i++) {
      gld_lds16(Ahi + (size_t)apix[i] + aoff, (char*)Ash + (i * 4 + w) * 1024);
      if (ALO)
        gld_lds16(Alo + (size_t)apix[i] + aoff, (char*)Asl + (i * 4 + w) * 1024);
      gld_lds16(Bhi + boff[i] + k0,   (char*)Bsh + (i * 4 + w) * 1024);
      if (BLO)
        gld_lds16(Blo + boff[i] + k0, (char*)Bsl + (i * 4 + w) * 1024);
    }
    __syncthreads();
#pragma unroll
    for (int ks = 0; ks < 2; ks++) {
      const int slot = ks * 4 + kg;
      bf16x8 ah[4], bh[4];
#pragma unroll
      for (int q = 0; q < 4; q++) {
        ah[q] = *(const bf16x8*)(Ashb + arb[q] + ((slot ^ amk[q]) << 4));
        bh[q] = *(const bf16x8*)(Bshb + brb[q] + ((slot ^ bmk[q]) << 4));
      }
#pragma unroll
      for (int mi = 0; mi < 4; mi++)
#pragma unroll
        for (int ni = 0; ni < 4; ni++)
          acc[mi][ni] = __builtin_amdgcn_mfma_f32_16x16x32_bf16(ah[mi], bh[ni], acc[mi][ni], 0, 0, 0);
      if (ALO) {
        bf16x8 al[4];
#pragma unroll
        for (int q = 0; q < 4; q++)
          al[q] = *(const bf16x8*)(Aslb + arb[q] + ((slot ^ amk[q]) << 4));
#pragma unroll
        for (int mi = 0; mi < 4; mi++)
#pragma unroll
          for (int ni = 0; ni < 4; ni++)
            acc[mi][ni] = __builtin_amdgcn_mfma_f32_16x16x32_bf16(al[mi], bh[ni], acc[mi][ni], 0, 0, 0);
      }
      if (BLO) {
        bf16x8 bl[4];
#pragma unroll
        for (int q = 0; q < 4; q++)
          bl[q] = *(const bf16x8*)(Bslb + brb[q] + ((slot ^ bmk[q]) << 4));
#pragma unroll
        for (int mi = 0; mi < 4; mi++)
#pragma unroll
          for (int ni = 0; ni < 4; ni++)
            acc[mi][ni] = __builtin_amdgcn_mfma_f32_16x16x32_bf16(ah[mi], bl[ni], acc[mi][ni], 0, 0, 0);
      }
    }
    __syncthreads();
  }

  const int crow0 = kg * 4, ccol = l15;
  if constexpr (FUSEPOOL) {
    const int n_img = m0 / (OH * OW);
    const int oh0 = (m0 % (OH * OW)) / OW;          // multiple of 4
    const int pmb = n_img * (OH / 2) * (OW / 2) + (oh0 / 2 + wrow) * (OW / 2);
#pragma unroll
    for (int mi = 0; mi < 2; mi++)
#pragma unroll
      for (int ni = 0; ni < 4; ni++)
#pragma unroll
        for (int jp = 0; jp < 2; jp++) {
          float a0 = acc[mi][ni][2 * jp],     a1 = acc[mi][ni][2 * jp + 1];
          float b0 = acc[mi + 2][ni][2 * jp], b1 = acc[mi + 2][ni][2 * jp + 1];
          float mx = fmaxf(fmaxf(a0, a1), fmaxf(b0, b1));
          float mn = fminf(fminf(a0, a1), fminf(b0, b1));
          int pm = pmb + mi * 8 + kg * 2 + jp;
          int ch = n0 + wcol * 64 + ni * 16 + ccol;
          Cout[(size_t)pm * CO + ch] = mx;
          Cmin[(size_t)pm * CO + ch] = mn;
        }
  } else {
    float* Cz = Cout + (size_t)z * M * CO;
#pragma unroll
    for (int mi = 0; mi < 4; mi++) {
      int m = m0 + wrow * 64 + mi * 16 + crow0;
#pragma unroll
      for (int ni = 0; ni < 4; ni++) {
        int nn = n0 + wcol * 64 + ni * 16 + ccol;
        float* cp = Cz + (size_t)m * CO + nn;
#pragma unroll
        for (int jj = 0; jj < 4; jj++) cp[(size_t)jj * CO] = acc[mi][ni][jj];
      }
    }
  }
  if constexpr (SPLIT == 1) {
    const int contrib = kg * 2 + wrow;
#pragma unroll
    for (int ni = 0; ni < 4; ni++) {
      float s = 0.f, q = 0.f;
#pragma unroll
      for (int mi = 0; mi < 4; mi++)
#pragma unroll
        for (int jj = 0; jj < 4; jj++) {
          float v = acc[mi][ni][jj];
          s += v; q += v * v;
        }
      int coll = wcol * 64 + ni * 16 + ccol;
      red[0][coll][contrib] = s;
      red[1][coll][contrib] = q;
    }
    __syncthreads();
    if (t < 128) {
      float s = 0.f, q = 0.f;
#pragma unroll
      for (int j = 0; j < 8; j++) { s += red[0][t][j]; q += red[1][t][j]; }
      size_t c = n0 + t;
      part[(c * gridDim.x + blockIdx.x) * 2 + 0] = s;
      part[(c * gridDim.x + blockIdx.x) * 2 + 1] = q;
    }
  }
}

// ---------------- FC GEMM: packed A (hi/lo) + packed B, zero LDS/barriers --
template<int K, int SPLIT>
__global__ __launch_bounds__(256) void fc_gemm_k(const bf16* __restrict__ Ahp,
                                                 const bf16* __restrict__ Alp,
                                                 const bf16* __restrict__ Bhp,
                                                 float* __restrict__ Cout) {
  constexpr int Kd64 = K / 64;
  constexpr int NCHS = Kd64 / SPLIT;
  constexpr int M = 256, N = 2048;
  const int t = threadIdx.x;
  const int lane = t & 63, w = t >> 6;
  const int m0 = blockIdx.x * 128, n0 = blockIdx.y * 128;
  const int z = blockIdx.z;
  const int wrow = w >> 1, wcol = w & 1;
  const int kg = lane >> 4, l15 = lane & 15;

  size_t ab[4], bb[4];
#pragma unroll
  for (int q = 0; q < 4; q++) {
    int rbA = (m0 >> 4) + wrow * 4 + q;
    ab[q] = (size_t)rbA * Kd64 * 1024 + (size_t)lane * 8;
    int rbB = (n0 >> 4) + wcol * 4 + q;
    bb[q] = (size_t)rbB * Kd64 * 1024 + (size_t)lane * 8;
  }

  f32x4 acc[4][4] = {};
  for (int kc = z * NCHS; kc < (z + 1) * NCHS; ++kc) {
    const size_t bco = (size_t)kc * 1024;
#pragma unroll
    for (int ks = 0; ks < 2; ks++) {
      const size_t soff = bco + ks * 512;
      bf16x8 ah[4], al[4], bh[4];
#pragma unroll
      for (int q = 0; q < 4; q++) {
        ah[q] = *(const bf16x8*)(Ahp + ab[q] + soff);
        al[q] = *(const bf16x8*)(Alp + ab[q] + soff);
        bh[q] = *(const bf16x8*)(Bhp + bb[q] + soff);
      }
#pragma unroll
      for (int mi = 0; mi < 4; mi++)
#pragma unroll
        for (int ni = 0; ni < 4; ni++)
          acc[mi][ni] = __builtin_amdgcn_mfma_f32_16x16x32_bf16(ah[mi], bh[ni], acc[mi][ni], 0, 0, 0);
#pragma unroll
      for (int mi = 0; mi < 4; mi++)
#pragma unroll
        for (int ni = 0; ni < 4; ni++)
          acc[mi][ni] = __builtin_amdgcn_mfma_f32_16x16x32_bf16(al[mi], bh[ni], acc[mi][ni], 0, 0, 0);
    }
  }

  const int crow0 = kg * 4, ccol = l15;
  float* Cz = Cout + (size_t)z * M * N;
#pragma unroll
  for (int mi = 0; mi < 4; mi++) {
    int m = m0 + wrow * 64 + mi * 16 + crow0;
#pragma unroll
    for (int ni = 0; ni < 4; ni++) {
      int nn = n0 + wcol * 64 + ni * 16 + ccol;
      float* cp = Cz + (size_t)m * N + nn;
#pragma unroll
      for (int jj = 0; jj < 4; jj++) cp[(size_t)jj * N] = acc[mi][ni][jj];
    }
  }
}

// ---------------- split-K reduction + BN partials ----------------
template<int M, int CO, int SPLIT, int NS>
__global__ __launch_bounds__(256) void reduce_bn_k(const float* __restrict__ Cp,
                                                   float* __restrict__ Cf,
                                                   float* __restrict__ part) {
  int c = blockIdx.x * 64 + (threadIdx.x & 63);
  int rl = threadIdx.x >> 6;
  constexpr int ROWS = M / NS;
  int r0 = blockIdx.y * ROWS;
  float sum = 0.f, sq = 0.f;
  for (int r = r0 + rl; r < r0 + ROWS; r += 4) {
    float v = 0.f;
#pragma unroll
    for (int s = 0; s < SPLIT; s++) v += Cp[(size_t)s * M * CO + (size_t)r * CO + c];
    Cf[(size_t)r * CO + c] = v;
    sum += v; sq += v * v;
  }
  __shared__ float ls[256], lq[256];
  ls[threadIdx.x] = sum; lq[threadIdx.x] = sq;
  __syncthreads();
  if (threadIdx.x < 64) {
    sum = ls[threadIdx.x] + ls[threadIdx.x + 64] + ls[threadIdx.x + 128] + ls[threadIdx.x + 192];
    sq  = lq[threadIdx.x] + lq[threadIdx.x + 64] + lq[threadIdx.x + 128] + lq[threadIdx.x + 192];
    part[((size_t)c * NS + blockIdx.y) * 2 + 0] = sum;
    part[((size_t)c * NS + blockIdx.y) * 2 + 1] = sq;
  }
}

// ---------------- BN finalize: one block per channel, wave butterfly -------
__global__ __launch_bounds__(64) void bn_finalize(const float* __restrict__ part,
                                                  const float* __restrict__ g,
                                                  const float* __restrict__ b,
                                                  float* __restrict__ scale,
                                                  float* __restrict__ shift,
                                                  int S, float invCount) {
  int c = blockIdx.x;
  int lane = threadIdx.x;
  float sum = 0.f, sq = 0.f;
  for (int s = lane; s < S; s += 64) {
    sum += part[((size_t)c * S + s) * 2 + 0];
    sq  += part[((size_t)c * S + s) * 2 + 1];
  }
#pragma unroll
  for (int o = 32; o > 0; o >>= 1) {
    sum += __shfl_xor(sum, o);
    sq  += __shfl_xor(sq, o);
  }
  if (lane == 0) {
    float m = sum * invCount;
    float var = sq * invCount - m * m;
    float sc = g[c] * rsqrtf(var + 1e-5f);
    scale[c] = sc;
    shift[c] = b[c] - m * sc;
  }
}

// ---------------- fused BN + ReLU + pad (no pool), 8ch/thread --------------
template<int CO, int IH, int IW, int PADO>
__global__ __launch_bounds__(256) void bn_act_pad_k(const float* __restrict__ x,
                                                    const float* __restrict__ scale,
                                                    const float* __restrict__ shift,
                                                    bf16* __restrict__ yh,
                                                    bf16* __restrict__ yl) {
  constexpr int OHP = IH + 2 * PADO, OWP = IW + 2 * PADO;
  constexpr int CO8 = CO / 8;
  int i = blockIdx.x * 256 + threadIdx.x;
  if (i >= 64 * OHP * OWP * CO8) return;
  int c8 = i % CO8; int t = i / CO8; int owp = t % OWP; t /= OWP; int ohp = t % OHP; int n = t / OHP;
  int c0 = c8 * 8;
  int oh = ohp - PADO, ow = owp - PADO;
  bf16x8 hv, lv;
#pragma unroll
  for (int j = 0; j < 8; j++) { hv[j] = (bf16)0.f; lv[j] = (bf16)0.f; }
  if (oh >= 0 && oh < IH && ow >= 0 && ow < IW) {
    float sc[8], sh[8];
    *(f32x4*)(sc)     = *(const f32x4*)(scale + c0);
    *(f32x4*)(sc + 4) = *(const f32x4*)(scale + c0 + 4);
    *(f32x4*)(sh)     = *(const f32x4*)(shift + c0);
    *(f32x4*)(sh + 4) = *(const f32x4*)(shift + c0 + 4);
    const float* p = x + (((size_t)(n * IH) + oh) * IW + ow) * CO + c0;
    float ta[8];
    *(f32x4*)(ta) = *(const f32x4*)(p); *(f32x4*)(ta + 4) = *(const f32x4*)(p + 4);
#pragma unroll
    for (int j = 0; j < 8; j++) {
      float vv = fmaxf(ta[j] * sc[j] + sh[j], 0.f);
      bf16 h, l; split2(vv, h, l);
      hv[j] = h; lv[j] = l;
    }
  }
  size_t o = (size_t)i * 8;
  *(bf16x8*)(yh + o) = hv;
  *(bf16x8*)(yl + o) = lv;
}

// ---------------- BN + ReLU + pad from pooled (max,min), 8ch/thread --------
template<int CO, int PH, int PW, int PADO>
__global__ __launch_bounds__(256) void act_pool_pad_k(const float* __restrict__ wmax,
                                                      const float* __restrict__ wmin,
                                                      const float* __restrict__ scale,
                                                      const float* __restrict__ shift,
                                                      bf16* __restrict__ yh,
                                                      bf16* __restrict__ yl) {
  constexpr int OHP = PH + 2 * PADO, OWP = PW + 2 * PADO;
  constexpr int CO8 = CO / 8;
  int i = blockIdx.x * 256 + threadIdx.x;
  if (i >= 64 * OHP * OWP * CO8) return;
  int c8 = i % CO8; int t = i / CO8; int owp = t % OWP; t /= OWP; int ohp = t % OHP; int n = t / OHP;
  int c0 = c8 * 8;
  int oh = ohp - PADO, ow = owp - PADO;
  bf16x8 hv, lv;
#pragma unroll
  for (int j = 0; j < 8; j++) { hv[j] = (bf16)0.f; lv[j] = (bf16)0.f; }
  if (oh >= 0 && oh < PH && ow >= 0 && ow < PW) {
    float sc[8], sh[8], mx[8], mn[8];
    *(f32x4*)(sc)     = *(const f32x4*)(scale + c0);
    *(f32x4*)(sc + 4) = *(const f32x4*)(scale + c0 + 4);
    *(f32x4*)(sh)     = *(const f32x4*)(shift + c0);
    *(f32x4*)(sh + 4) = *(const f32x4*)(shift + c0 + 4);
    size_t off = (((size_t)(n * PH) + oh) * PW + ow) * CO + c0;
    *(f32x4*)(mx)     = *(const f32x4*)(wmax + off);
    *(f32x4*)(mx + 4) = *(const f32x4*)(wmax + off + 4);
    *(f32x4*)(mn)     = *(const f32x4*)(wmin + off);
    *(f32x4*)(mn + 4) = *(const f32x4*)(wmin + off + 4);
#pragma unroll
    for (int j = 0; j < 8; j++) {
      float sel = (sc[j] >= 0.f) ? mx[j] : mn[j];
      float vv = fmaxf(sel * sc[j] + sh[j], 0.f);
      bf16 h, l; split2(vv, h, l);
      hv[j] = h; lv[j] = l;
    }
  }
  size_t o = (size_t)i * 8;
  *(bf16x8*)(yh + o) = hv;
  *(bf16x8*)(yl + o) = lv;
}

// ---------------- ROI SPP: conv5 fp32 + inline BN -> PACKED S hi/lo --------
__global__ __launch_bounds__(256) void spp_k(const float* __restrict__ feat,
                                             const float* __restrict__ scale,
                                             const float* __restrict__ shift,
                                             const int* __restrict__ roi,
                                             bf16* __restrict__ oh_,
                                             bf16* __restrict__ ol_) {
  int c = blockIdx.x * 256 + threadIdx.x;  // 0..511
  int r = blockIdx.y;                      // 0..255
  const int* rp = roi + r * 5;
  int im = rp[0];
  int c1 = rp[1] >> 3, r1 = rp[2] >> 3, c2 = rp[3] >> 3, r2 = rp[4] >> 3;
  int w = c2 - c1 + 1;
  int lo[6], hi[6];
  int bi = 0;
#pragma unroll
  for (int l = 1; l <= 3; l++)
    for (int k = 0; k < l; k++) {
      lo[bi] = c1 + (k * w) / l;
      hi[bi] = c1 + ((k + 1) * w + l - 1) / l - 1;
      bi++;
    }
  float mx[6];
#pragma unroll
  for (int b = 0; b < 6; b++) mx[b] = -1e30f;
  float sc = scale[c], sh = shift[c];
  const float* fp = feat + (size_t)im * 96 * 512 + c;
  for (int row = r1; row <= r2; row++)
    for (int col = c1; col <= c2; col++) {
      float v = fp[(size_t)(row * 16 + col) * 512] * sc + sh;
#pragma unroll
      for (int b = 0; b < 6; b++)
        if (col >= lo[b] && col <= hi[b]) mx[b] = fmaxf(mx[b], v);
    }
  int idx[6] = {c, 512 + c * 2, 512 + c * 2 + 1, 1536 + c * 3, 1536 + c * 3 + 1, 1536 + c * 3 + 2};
#pragma unroll
  for (int b = 0; b < 6; b++) {
    float v = fmaxf(mx[b], 0.f);
    bf16 h, l; split2(v, h, l);
    size_t o = pk_off(r, idx[b], 48);
    oh_[o] = h;
    ol_[o] = l;
  }
}

// FC1: BN+ReLU, write hi/lo PACKED into CC[:, 0:2048] (K=8192)
__global__ __launch_bounds__(256) void bn1d_apply_cc_k(const float* __restrict__ x,
                                                       const float* __restrict__ scale,
                                                       const float* __restrict__ shift,
                                                       bf16* __restrict__ ch,
                                                       bf16* __restrict__ cl) {
  int i = blockIdx.x * 256 + threadIdx.x;
  if (i >= 256 * 256) return;
  int f8 = i & 255, r = i >> 8;
  int f0 = f8 * 8;
  float xv[8], sc[8], sh[8];
  *(f32x4*)(xv)     = *(const f32x4*)(x + (size_t)r * 2048 + f0);
  *(f32x4*)(xv + 4) = *(const f32x4*)(x + (size_t)r * 2048 + f0 + 4);
  *(f32x4*)(sc)     = *(const f32x4*)(scale + f0);
  *(f32x4*)(sc + 4) = *(const f32x4*)(scale + f0 + 4);
  *(f32x4*)(sh)     = *(const f32x4*)(shift + f0);
  *(f32x4*)(sh + 4) = *(const f32x4*)(shift + f0 + 4);
  bf16x8 hv, lv;
#pragma unroll
  for (int j = 0; j < 8; j++) {
    float v = fmaxf(xv[j] * sc[j] + sh[j], 0.f);
    bf16 h, l; split2(v, h, l);
    hv[j] = h; lv[j] = l;
  }
  size_t o = pk_off(r, f0, 128);
  *(bf16x8*)(ch + o) = hv;
  *(bf16x8*)(cl + o) = lv;
}

// FC2: BN+ReLU, fp32 out, 4 feat/thread
__global__ __launch_bounds__(256) void bn1d_apply_f32_k(const float* __restrict__ x,
                                                        const float* __restrict__ scale,
                                                        const float* __restrict__ shift,
                                                        float* __restrict__ y) {
  int i = blockIdx.x * 256 + threadIdx.x;
  if (i >= 256 * 512) return;
  int f4 = i & 511, r = i >> 9;
  int f0 = f4 * 4;
  f32x4 xv = *(const f32x4*)(x + (size_t)r * 2048 + f0);
  f32x4 sc = *(const f32x4*)(scale + f0);
  f32x4 sh = *(const f32x4*)(shift + f0);
  f32x4 o;
#pragma unroll
  for (int j = 0; j < 4; j++) o[j] = fmaxf(xv[j] * sc[j] + sh[j], 0.f);
  *(f32x4*)(y + (size_t)r * 2048 + f0) = o;
}

// ============================================================================
extern "C" void kernel_launch(void* const* d_in, const int* in_sizes, int n_in,
                              void* d_out, int out_size, void* d_ws, size_t ws_size,
                              hipStream_t stream) {
  (void)in_sizes; (void)n_in; (void)out_size; (void)ws_size;

  const float* x    = (const float*)d_in[0];
  const int*   roi  = (const int*)  d_in[1];
  const float* phoc = (const float*)d_in[2];
  const float* c1w  = (const float*)d_in[3];
  const float* g1   = (const float*)d_in[5];
  const float* b1   = (const float*)d_in[6];
  const float* c2w  = (const float*)d_in[7];
  const float* g2   = (const float*)d_in[9];
  const float* b2   = (const float*)d_in[10];
  const float* c3w  = (const float*)d_in[11];
  const float* g3   = (const float*)d_in[13];
  const float* b3   = (const float*)d_in[14];
  const float* c4w  = (const float*)d_in[15];
  const float* g4   = (const float*)d_in[17];
  const float* b4   = (const float*)d_in[18];
  const float* c5w  = (const float*)d_in[19];
  const float* g5   = (const float*)d_in[21];
  const float* b5   = (const float*)d_in[22];
  const float* f1w  = (const float*)d_in[23];
  const float* g6   = (const float*)d_in[25];
  const float* b6   = (const float*)d_in[26];
  const float* f2w  = (const float*)d_in[27];
  const float* g7   = (const float*)d_in[29];
  const float* b7   = (const float*)d_in[30];
  float* out = (float*)d_out;

  // ---- workspace layout (total ~168.4 MB) ----
  char* ws = (char*)d_ws;
  bf16*  Ahi  = (bf16*) (ws + 0x0200000);   // 16 MB (padded NHWC activations)
  bf16*  Alo  = (bf16*) (ws + 0x1200000);   // 16 MB
  float* C    = (float*)(ws + 0x2200000);   // GEMM out / split slabs / pooled max
  float* CMIN = (float*)(ws + 0x2E00000);   // pooled min
  float* C5F  = (float*)(ws + 0x4600000);   // conv5 final
  bf16*  Wc2h = (bf16*) (ws + 0x5500000);   // conv weights (row-major [CO][K])
  bf16*  Wc3h = (bf16*) (ws + 0x5570000);
  bf16*  Wc4h = (bf16*) (ws + 0x5600000);
  bf16*  Wc5h = (bf16*) (ws + 0x5840000);
  bf16*  Wf1  = (bf16*) (ws + 0x5CC0000);   // packed FC weights
  bf16*  Wf2  = (bf16*) (ws + 0x68C0000);   // packed [2048][8192] = 32 MB
  bf16*  Wc5l = (bf16*) (ws + 0x8C00000);
  bf16*  Shi  = (bf16*) (ws + 0x9080000);   // packed spp out [256][3072]
  bf16*  Slo  = (bf16*) (ws + 0x9200000);
  float* G6   = (float*)(ws + 0x9380000);   // fc1 out fp32 [256][2048]
  bf16*  CChi = (bf16*) (ws + 0x9580000);   // packed concat [256][8192] = 4 MB
  bf16*  CClo = (bf16*) (ws + 0x9980000);
  float* G7   = (float*)(ws + 0x9D80000);   // fc2 out fp32 [256][2048]
  float* PART = (float*)(ws + 0x9F80000);   // 768 KB
  float* SC   = (float*)(ws + 0xA040000);
  float* SH   = (float*)(ws + 0xA050000);

  // ---- all weight/input transforms in one dispatch (LDS-transposed convs) --
  prep_k<<<30080, 256, 0, stream>>>(c2w, c3w, c4w, c5w, f1w, f2w, phoc,
                                    Wc2h, Wc3h, Wc4h, Wc5h, Wc5l, Wf1, Wf2,
                                    CChi, CClo);

  // ---- conv1 (two-pass, clamped reads, 8 ch/group) ----
  conv1_stats_k<<<dim3(96, 8), 256, 0, stream>>>(x, c1w, PART);
  bn_finalize<<<64, 64, 0, stream>>>(PART, g1, b1, SC, SH, 96, 1.f / 393216.f);
  conv1_apply_k<<<dim3(476, 8), 256, 0, stream>>>(x, c1w, SC, SH, Ahi, Alo);

  // ---- conv2 (1-pass, A-resident, fused pool): -> pooled max/min [24576][128]
  conv2_gemm_k<<<768, 256, 0, stream>>>(Ahi, Wc2h, C, CMIN, PART);
  bn_finalize<<<128, 64, 0, stream>>>(PART, g2, b2, SC, SH, 768, 1.f / 98304.f);
  act_pool_pad_k<128, 12, 32, 1><<<1904, 256, 0, stream>>>(C, CMIN, SC, SH, Ahi, Alo);

  // ---- conv3 (2-pass: Ah.Bh + Al.Bh, no pool) ----
  conv_gemm_k<128, 3, 12, 32, 256, true, false, 1, false><<<dim3(192, 2), 256, 0, stream>>>(Ahi, Alo, Wc3h, nullptr, C, nullptr, PART);
  bn_finalize<<<256, 64, 0, stream>>>(PART, g3, b3, SC, SH, 192, 1.f / 24576.f);
  bn_act_pad_k<256, 12, 32, 1><<<3808, 256, 0, stream>>>(C, SC, SH, Ahi, Alo);

  // ---- conv4 (1-pass, fused pool): -> pooled max/min [6144][512] ----
  conv_gemm_k<256, 3, 12, 32, 512, false, false, 1, true><<<dim3(192, 4), 256, 0, stream>>>(Ahi, Alo, Wc4h, nullptr, C, CMIN, PART);
  bn_finalize<<<512, 64, 0, stream>>>(PART, g4, b4, SC, SH, 192, 1.f / 24576.f);
  act_pool_pad_k<512, 6, 16, 1><<<2304, 256, 0, stream>>>(C, CMIN, SC, SH, Ahi, Alo);

  // ---- conv5 (3-pass, split-K=2): slabs in C, final in C5F ----
  conv_gemm_k<512, 3, 6, 16, 512, true, true, 2, false><<<dim3(48, 4, 2), 256, 0, stream>>>(Ahi, Alo, Wc5h, Wc5l, C, nullptr, nullptr);
  reduce_bn_k<6144, 512, 2, 16><<<dim3(8, 16), 256, 0, stream>>>(C, C5F, PART);
  bn_finalize<<<512, 64, 0, stream>>>(PART, g5, b5, SC, SH, 16, 1.f / 6144.f);

  // ---- SPP (reads fp32 conv5 out + inline BN, packed output) ----
  spp_k<<<dim3(2, 256), 256, 0, stream>>>(C5F, SC, SH, roi, Shi, Slo);

  // ---- FC1 (packed, LDS-free, split-K=16): [256][3072] x [2048][3072] ----
  fc_gemm_k<3072, 16><<<dim3(2, 16, 16), 256, 0, stream>>>(Shi, Slo, Wf1, C);
  reduce_bn_k<256, 2048, 16, 4><<<dim3(32, 4), 256, 0, stream>>>(C, G6, PART);
  bn_finalize<<<2048, 64, 0, stream>>>(PART, g6, b6, SC, SH, 4, 1.f / 256.f);
  bn1d_apply_cc_k<<<256, 256, 0, stream>>>(G6, SC, SH, CChi, CClo);

  // ---- FC2 (packed, LDS-free, split-K=16): [256][8192] x [2048][8192] ----
  fc_gemm_k<8192, 16><<<dim3(2, 16, 16), 256, 0, stream>>>(CChi, CClo, Wf2, C);
  reduce_bn_k<256, 2048, 16, 4><<<dim3(32, 4), 256, 0, stream>>>(C, G7, PART);
  bn_finalize<<<2048, 64, 0, stream>>>(PART, g7, b7, SC, SH, 4, 1.f / 256.f);
  bn1d_apply_f32_k<<<512, 256, 0, stream>>>(G7, SC, SH, out);
}

// Round 19
// 551.229 us; speedup vs baseline: 1.2530x; 1.0322x over previous
//
#include <hip/hip_runtime.h>
#include <hip/hip_bf16.h>

// ============================================================================
// HWNet-SPP forward, MFMA bf16 implicit-GEMM with selective hi/lo precision.
// conv2: A-resident kernel; conv3/4/5: 128x128 LDS-staged template; FC1/FC2:
// packed fragment-order operands, zero LDS/barriers. Pooled layers (conv2,
// conv4) fuse the 2x2 pool into the GEMM epilogue as (window-max, window-min)
// dual fp32 writes. prep does LDS-transposed conv weights AND conv1 BN stats
// (independent, overlapped: VALU-bound stats || BW-bound transforms).
// Pass config (error budget vs absmax threshold 0.098):
//   conv2: Ah*Bh (1-pass)  conv3: +Al*Bh (2-pass)  conv4: 1-pass
//   conv5: full 3-pass hi/lo (split-K=2)  FC1/FC2: 2-pass (split-K=16)
// BN stats fused into GEMM epilogue / split-K reducer; bn_finalize is
// one-block-per-channel wave butterfly. conv1 reads x with edge clamping.
// SPP reads conv5 fp32 out with inline BN. Biases skipped (BN cancels).
// ============================================================================

typedef __bf16 bf16;
using bf16x4 = __attribute__((ext_vector_type(4))) __bf16;
using bf16x8 = __attribute__((ext_vector_type(8))) __bf16;
using f32x4  = __attribute__((ext_vector_type(4))) float;

__device__ __forceinline__ void split2(float v, bf16& h, bf16& l) {
  bf16 hb = (bf16)v;
  h = hb;
  l = (bf16)(v - (float)hb);
}

__device__ __forceinline__ int iclamp(int v, int lo, int hi) {
  return v < lo ? lo : (v > hi ? hi : v);
}

__device__ __forceinline__ size_t pk_off(int row, int k, int Kd64) {
  return ((size_t)(row >> 4) * Kd64 + (k >> 6)) * 1024 +
         (size_t)(((k >> 5) & 1) * 512 + ((k >> 3) & 3) * 128 + ((row & 15) << 3) + (k & 7));
}

__device__ __forceinline__ void gld_lds16(const bf16* g, void* lds) {
  __builtin_amdgcn_global_load_lds(
      (const __attribute__((address_space(1))) unsigned int*)g,
      (__attribute__((address_space(3))) unsigned int*)lds, 16, 0, 0);
}

// ---------------- fused prep: conv1 BN stats + all weight/input transforms --
// blocks [0,768): conv1 stats (seg = b/8, ch-group = b%8), VALU-bound.
// blocks [768,...): LDS-transposed conv weights, packed FC weights, phoc.
__global__ __launch_bounds__(256) void prep_k(const float* __restrict__ x,
                                              const float* __restrict__ c1w,
                                              float* __restrict__ part,
                                              const float* __restrict__ c2w,
                                              const float* __restrict__ c3w,
                                              const float* __restrict__ c4w,
                                              const float* __restrict__ c5w,
                                              const float* __restrict__ f1w,
                                              const float* __restrict__ f2w,
                                              const float* __restrict__ phoc,
                                              bf16* __restrict__ Wc2h,
                                              bf16* __restrict__ Wc3h,
                                              bf16* __restrict__ Wc4h,
                                              bf16* __restrict__ Wc5h,
                                              bf16* __restrict__ Wc5l,
                                              bf16* __restrict__ Wf1,
                                              bf16* __restrict__ Wf2,
                                              bf16* __restrict__ cch,
                                              bf16* __restrict__ ccl) {
  __shared__ float buf[4608];
  __shared__ float ls[256], lq[256];
  int b = blockIdx.x;
  int tid = threadIdx.x;
  if (b < 768) {
    // ---- conv1 BN stats (8 ch/group, edge-clamped reads of x) ----
    int seg = b >> 3;          // 0..95
    int co0 = (b & 7) * 8;     // channel group
    float sums[8] = {0.f}, sqs[8] = {0.f};
    for (int r = 0; r < 16; r++) {
      int pix = seg * 4096 + r * 256 + tid;  // 0..393215
      int w = pix & 127; int t = pix >> 7; int h = t % 48; int n = t / 48;
      const float* ip = x + (size_t)n * 48 * 128;
      int ihs[5], iws[5];
#pragma unroll
      for (int k = 0; k < 5; k++) {
        ihs[k] = iclamp(h + k - 2, 0, 47);
        iws[k] = iclamp(w + k - 2, 0, 127);
      }
      float win[25];
#pragma unroll
      for (int kh = 0; kh < 5; kh++)
#pragma unroll
        for (int kw = 0; kw < 5; kw++) win[kh * 5 + kw] = ip[ihs[kh] * 128 + iws[kw]];
#pragma unroll
      for (int j = 0; j < 8; j++) {
        const float* wp = c1w + (size_t)(co0 + j) * 25;
        float acc = 0.f;
#pragma unroll
        for (int k = 0; k < 25; k++) acc += win[k] * wp[k];
        sums[j] += acc; sqs[j] += acc * acc;
      }
    }
    for (int j = 0; j < 8; j++) {
      ls[tid] = sums[j]; lq[tid] = sqs[j];
      __syncthreads();
      for (int o = 128; o > 0; o >>= 1) {
        if (tid < o) { ls[tid] += ls[tid + o]; lq[tid] += lq[tid + o]; }
        __syncthreads();
      }
      if (tid == 0) {
        int c = co0 + j;
        part[((size_t)c * 96 + seg) * 2 + 0] = ls[0];
        part[((size_t)c * 96 + seg) * 2 + 1] = lq[0];
      }
      __syncthreads();
    }
    return;
  }
  b -= 768;
  const float* src = nullptr;
  bf16 *dsth = nullptr, *dstl = nullptr;
  int CI = 0, KK = 0, co = 0;
  if (b < 128)        { src = c2w; dsth = Wc2h; CI = 64;  KK = 25; co = b; }
  else if (b < 384)   { src = c3w; dsth = Wc3h; CI = 128; KK = 9;  co = b - 128; }
  else if (b < 896)   { src = c4w; dsth = Wc4h; CI = 256; KK = 9;  co = b - 384; }
  else if (b < 1408)  { src = c5w; dsth = Wc5h; dstl = Wc5l; CI = 512; KK = 9; co = b - 896; }
  if (src) {
    const int n = CI * KK;
    const float* sp = src + (size_t)co * n;
    for (int i = tid; i < n; i += 256) buf[i] = sp[i];
    __syncthreads();
    bf16* oh = dsth + (size_t)co * n;
    bf16* ol = dstl ? dstl + (size_t)co * n : nullptr;
    for (int o = tid; o < n; o += 256) {
      int ci = o & (CI - 1), kk = o / CI;
      float v = buf[ci * KK + kk];
      bf16 h, l; split2(v, h, l);
      oh[o] = h;
      if (ol) ol[o] = l;
    }
    return;
  }
  b -= 1408;
  if (b < 6144) {  // f1w [2048][3072] -> packed hi, 4 elems/thread
    int i = b * 256 + tid;
    int k0 = (i % 768) * 4, n = i / 768;
    const float4 v = *(const float4*)(f1w + (size_t)n * 3072 + k0);
    bf16x4 o = { (bf16)v.x, (bf16)v.y, (bf16)v.z, (bf16)v.w };
    *(bf16x4*)(Wf1 + pk_off(n, k0, 48)) = o;
    return;
  }
  b -= 6144;
  if (b < 16384) {  // f2w [2048][7901] -> packed hi [2048][8192], 4/thread
    int i = b * 256 + tid;
    int k0 = (i & 2047) * 4, n = i >> 11;
    const float* xp = f2w + (size_t)n * 7901 + k0;
    bf16x4 o;
#pragma unroll
    for (int j = 0; j < 4; j++) o[j] = (bf16)((k0 + j < 7901) ? xp[j] : 0.f);
    *(bf16x4*)(Wf2 + pk_off(n, k0, 128)) = o;
    return;
  }
  b -= 16384;
  {  // phoc -> packed CC cols [2048,8192) hi/lo
    int i = b * 256 + tid;
    if (i >= 256 * 6144) return;
    int k = i % 6144, r = i / 6144;
    int col = 2048 + k;
    float v = (col < 7901) ? phoc[(size_t)r * 5853 + (col - 2048)] : 0.f;
    bf16 h, l; split2(v, h, l);
    size_t o = pk_off(r, col, 128);
    cch[o] = h;
    ccl[o] = l;
  }
}

// ---------------- conv1 pass 2: conv+BN+ReLU+pool+pad (8 ch/group) ---------
__global__ __launch_bounds__(256) void conv1_apply_k(const float* __restrict__ x,
                                                     const float* __restrict__ wt,
                                                     const float* __restrict__ scale,
                                                     const float* __restrict__ shift,
                                                     bf16* __restrict__ yh,
                                                     bf16* __restrict__ yl) {
  int i = blockIdx.x * 256 + threadIdx.x;  // padded pixel slots
  if (i >= 64 * 28 * 68) return;
  int owp = i % 68; int t = i / 68; int ohp = t % 28; int n = t / 28;
  int co0 = blockIdx.y * 8;
  int oh = ohp - 2, ow = owp - 2;
  bf16x8 hv, lv;
#pragma unroll
  for (int j = 0; j < 8; j++) { hv[j] = (bf16)0.f; lv[j] = (bf16)0.f; }
  if (oh >= 0 && oh < 24 && ow >= 0 && ow < 64) {
    const float* ip = x + (size_t)n * 48 * 128;
    int shr[6], swc[6];
#pragma unroll
    for (int k = 0; k < 6; k++) {
      shr[k] = iclamp(2 * oh + k - 2, 0, 47);
      swc[k] = iclamp(2 * ow + k - 2, 0, 127);
    }
    float win[36];
#pragma unroll
    for (int r = 0; r < 6; r++)
#pragma unroll
      for (int c = 0; c < 6; c++) win[r * 6 + c] = ip[shr[r] * 128 + swc[c]];
#pragma unroll
    for (int j = 0; j < 8; j++) {
      const float* wp = wt + (size_t)(co0 + j) * 25;
      float sc = scale[co0 + j], sh = shift[co0 + j];
      float m = -1e30f;
#pragma unroll
      for (int dy = 0; dy < 2; dy++)
#pragma unroll
        for (int dx = 0; dx < 2; dx++) {
          float acc = 0.f;
#pragma unroll
          for (int kh = 0; kh < 5; kh++)
#pragma unroll
            for (int kw = 0; kw < 5; kw++)
              acc += win[(kh + dy) * 6 + kw + dx] * wp[kh * 5 + kw];
          m = fmaxf(m, acc * sc + sh);
        }
      float v = fmaxf(m, 0.f);
      bf16 h, l; split2(v, h, l);
      hv[j] = h; lv[j] = l;
    }
  }
  size_t o = (size_t)i * 64 + co0;
  *(bf16x8*)(yh + o) = hv;
  *(bf16x8*)(yl + o) = lv;
}

// ---------------- conv2 specialized: A-resident + fused pool (max/min) -----
__global__ __launch_bounds__(256) void conv2_gemm_k(const bf16* __restrict__ Ahi,
                                                    const bf16* __restrict__ Bhi,
                                                    float* __restrict__ Wmax,
                                                    float* __restrict__ Wmin,
                                                    float* __restrict__ part) {
  __shared__ bf16 Ash[416 * 64];      // 52 KB (reused as exchange post-loop)
  __shared__ bf16 Bsh[128 * 64];      // 16 KB
  __shared__ float red[2][128][8];    // 8 KB
  const int t = threadIdx.x;
  const int lane = t & 63, w = t >> 6;
  const int m0 = blockIdx.x * 128;
  const int img = m0 / 1536;
  const int oh0 = (m0 % 1536) >> 6;   // even
  const size_t abase = ((size_t)(img * 28 + oh0) * 68) * 64;

#pragma unroll
  for (int i = 0; i < 13; i++) {
    int f = i * 256 + t;
    int p = f >> 3; if (p > 407) p = 407;
    int s = f & 7;
    int ss = s ^ (p & 7);
    gld_lds16(Ahi + abase + (size_t)p * 64 + ss * 8,
              (char*)Ash + (size_t)(i * 256 + w * 64) * 16);
  }

  size_t boff[4];
#pragma unroll
  for (int i = 0; i < 4; i++) {
    int f = (i * 4 + w) * 64 + lane;
    int row = f >> 3, slot = f & 7;
    int ss = slot ^ (row & 7);
    boff[i] = (size_t)row * 1600 + ss * 8;
  }

  const int wrow = w >> 1, wcol = w & 1;
  const int kg = lane >> 4, l15 = lane & 15;
  int pixb[4];
#pragma unroll
  for (int q = 0; q < 4; q++) pixb[q] = wrow * 68 + q * 16 + l15;
  int brb[4], bmk[4];
#pragma unroll
  for (int q = 0; q < 4; q++) {
    int rb = wcol * 64 + q * 16 + l15;
    brb[q] = rb * 128; bmk[q] = rb & 7;
  }
  const char* Ashb = (const char*)Ash;
  const char* Bshb = (const char*)Bsh;

  f32x4 acc[4][4] = {};
  for (int kc = 0; kc < 25; ++kc) {
    const int kh = kc / 5, kw = kc % 5;
    const int kofs = kh * 68 + kw;
    const int k0 = kc * 64;
#pragma unroll
    for (int i = 0; i < 4; i++)
      gld_lds16(Bhi + boff[i] + k0, (char*)Bsh + (i * 4 + w) * 1024);
    __syncthreads();
#pragma unroll
    for (int ks = 0; ks < 2; ks++) {
      const int slot = ks * 4 + kg;
      bf16x8 ah[4], bh[4];
#pragma unroll
      for (int q = 0; q < 4; q++) {
        int pix = pixb[q] + kofs;
        ah[q] = *(const bf16x8*)(Ashb + pix * 128 + ((slot ^ (pix & 7)) << 4));
        bh[q] = *(const bf16x8*)(Bshb + brb[q] + ((slot ^ bmk[q]) << 4));
      }
#pragma unroll
      for (int mi = 0; mi < 4; mi++)
#pragma unroll
        for (int ni = 0; ni < 4; ni++)
          acc[mi][ni] = __builtin_amdgcn_mfma_f32_16x16x32_bf16(ah[mi], bh[ni], acc[mi][ni], 0, 0, 0);
    }
    __syncthreads();  // after this, Ash/Bsh free for reuse
  }

  const int ccol = l15;
  float hmx[4][4][2], hmn[4][4][2];
#pragma unroll
  for (int mi = 0; mi < 4; mi++)
#pragma unroll
    for (int ni = 0; ni < 4; ni++)
#pragma unroll
      for (int jp = 0; jp < 2; jp++) {
        float a = acc[mi][ni][2 * jp], b = acc[mi][ni][2 * jp + 1];
        hmx[mi][ni][jp] = fmaxf(a, b);
        hmn[mi][ni][jp] = fminf(a, b);
      }
  const int contrib = kg * 2 + wrow;
#pragma unroll
  for (int ni = 0; ni < 4; ni++) {
    float s = 0.f, q = 0.f;
#pragma unroll
    for (int mi = 0; mi < 4; mi++)
#pragma unroll
      for (int jj = 0; jj < 4; jj++) {
        float v = acc[mi][ni][jj];
        s += v; q += v * v;
      }
    int coll = wcol * 64 + ni * 16 + ccol;
    red[0][coll][contrib] = s;
    red[1][coll][contrib] = q;
  }
  float* exch = (float*)Ash;
  if (wrow == 1) {
    float* ep = exch + (size_t)(wcol * 64 + lane) * 64;
#pragma unroll
    for (int mi = 0; mi < 4; mi++)
#pragma unroll
      for (int ni = 0; ni < 4; ni++)
#pragma unroll
        for (int jp = 0; jp < 2; jp++) {
          int s = (mi * 8 + ni * 2 + jp) * 2;
          ep[s + 0] = hmx[mi][ni][jp];
          ep[s + 1] = hmn[mi][ni][jp];
        }
  }
  __syncthreads();
  if (wrow == 0) {
    const float* ep = exch + (size_t)(wcol * 64 + lane) * 64;
    const int pmb = img * 384 + (oh0 >> 1) * 32;
#pragma unroll
    for (int mi = 0; mi < 4; mi++)
#pragma unroll
      for (int ni = 0; ni < 4; ni++)
#pragma unroll
        for (int jp = 0; jp < 2; jp++) {
          int s = (mi * 8 + ni * 2 + jp) * 2;
          float mx = fmaxf(hmx[mi][ni][jp], ep[s + 0]);
          float mn = fminf(hmn[mi][ni][jp], ep[s + 1]);
          int pm = pmb + mi * 8 + kg * 2 + jp;
          int ch = wcol * 64 + ni * 16 + ccol;
          Wmax[(size_t)pm * 128 + ch] = mx;
          Wmin[(size_t)pm * 128 + ch] = mn;
        }
  }
  if (t < 128) {
    float s = 0.f, q = 0.f;
#pragma unroll
    for (int j = 0; j < 8; j++) { s += red[0][t][j]; q += red[1][t][j]; }
    size_t c = t;
    part[(c * gridDim.x + blockIdx.x) * 2 + 0] = s;
    part[(c * gridDim.x + blockIdx.x) * 2 + 1] = q;
  }
}

// ---------------- MFMA implicit-GEMM, LDS-staged, optional split-K/pool ----
template<int CI, int KS, int OH, int OW, int CO, bool ALO, bool BLO, int SPLIT, bool FUSEPOOL>
__global__ __launch_bounds__(256) void conv_gemm_k(const bf16* __restrict__ Ahi,
                                                   const bf16* __restrict__ Alo,
                                                   const bf16* __restrict__ Bhi,
                                                   const bf16* __restrict__ Blo,
                                                   float* __restrict__ Cout,
                                                   float* __restrict__ Cmin,
                                                   float* __restrict__ part) {
  static_assert(CI % 64 == 0, "chunk must not straddle ci segments");
  static_assert(!FUSEPOOL || (OW == 32 && SPLIT == 1), "fusepool needs OW=32");
  constexpr int K = KS * KS * CI;
  constexpr int IWP = OW + KS - 1;
  constexpr int NCH = K / 64;
  static_assert(NCH % SPLIT == 0, "split must divide chunk count");
  constexpr int NCHS = NCH / SPLIT;
  constexpr int M = 64 * OH * OW;
  __shared__ bf16 Ash[128 * 64];
  __shared__ bf16 Asl[ALO ? 128 * 64 : 64];
  __shared__ bf16 Bsh[128 * 64];
  __shared__ bf16 Bsl[BLO ? 128 * 64 : 64];
  __shared__ float red[2][128][8];
  const int t = threadIdx.x;
  const int lane = t & 63, w = t >> 6;
  const int m0 = blockIdx.x * 128, n0 = blockIdx.y * 128;
  const int z = (SPLIT > 1) ? blockIdx.z : 0;

  int apix[4]; size_t boff[4];
#pragma unroll
  for (int i = 0; i < 4; i++) {
    int f = (i * 4 + w) * 64 + lane;
    int row = f >> 3, slot = f & 7;
    int ss = slot ^ (row & 7);
    int m = m0 + row;
    int n = m / (OH * OW); int rem = m % (OH * OW);
    int oh = rem / OW, ow_ = rem % OW;
    apix[i] = ((n * (OH + KS - 1) + oh) * IWP + ow_) * CI + ss * 8;
    boff[i] = (size_t)(n0 + row) * K + ss * 8;
  }

  const int wrow = w >> 1, wcol = w & 1;
  const int kg = lane >> 4, l15 = lane & 15;
  int arb[4], amk[4], brb[4], bmk[4];
#pragma unroll
  for (int q = 0; q < 4; q++) {
    int ra = wrow * 64 + q * 16 + l15;
    arb[q] = ra * 128; amk[q] = ra & 7;
    int rb = wcol * 64 + q * 16 + l15;
    brb[q] = rb * 128; bmk[q] = rb & 7;
  }
  const char* Ashb = (const char*)Ash;
  const char* Aslb = (const char*)Asl;
  const char* Bshb = (const char*)Bsh;
  const char* Bslb = (const char*)Bsl;

  f32x4 acc[4][4] = {};
  for (int kc = z * NCHS; kc < (z + 1) * NCHS; ++kc) {
    const int k0 = kc * 64;
    const int seg = k0 / CI;
    const int ci0 = k0 % CI;
    const int kh = seg / KS, kw = seg % KS;
    const int aoff = (kh * IWP + kw) * CI + ci0;   // wave-uniform
#pragma unroll
    for (int i = 0; i < 4; i++) {
      gld_lds16(Ahi + (size_t)apix[i] + aoff, (char*)Ash + (i * 4 + w) * 1024);
      if (ALO)
        gld_lds16(Alo + (size_t)apix[i] + aoff, (char*)Asl + (i * 4 + w) * 1024);
      gld_lds16(Bhi + boff[i] + k0,   (char*)Bsh + (i * 4 + w) * 1024);
      if (BLO)
        gld_lds16(Blo + boff[i] + k0, (char*)Bsl + (i * 4 + w) * 1024);
    }
    __syncthreads();
#pragma unroll
    for (int ks = 0; ks < 2; ks++) {
      const int slot = ks * 4 + kg;
      bf16x8 ah[4], bh[4];
#pragma unroll
      for (int q = 0; q < 4; q++) {
        ah[q] = *(const bf16x8*)(Ashb + arb[q] + ((slot ^ amk[q]) << 4));
        bh[q] = *(const bf16x8*)(Bshb + brb[q] + ((slot ^ bmk[q]) << 4));
      }
#pragma unroll
      for (int mi = 0; mi < 4; mi++)
#pragma unroll
        for (int ni = 0; ni < 4; ni++)
          acc[mi][ni] = __builtin_amdgcn_mfma_f32_16x16x32_bf16(ah[mi], bh[ni], acc[mi][ni], 0, 0, 0);
      if (ALO) {
        bf16x8 al[4];
#pragma unroll
        for (int q = 0; q < 4; q++)
          al[q] = *(const bf16x8*)(Aslb + arb[q] + ((slot ^ amk[q]) << 4));
#pragma unroll
        for (int mi = 0; mi < 4; mi++)
#pragma unroll
          for (int ni = 0; ni < 4; ni++)
            acc[mi][ni] = __builtin_amdgcn_mfma_f32_16x16x32_bf16(al[mi], bh[ni], acc[mi][ni], 0, 0, 0);
      }
      if (BLO) {
        bf16x8 bl[4];
#pragma unroll
        for (int q = 0; q < 4; q++)
          bl[q] = *(const bf16x8*)(Bslb + brb[q] + ((slot ^ bmk[q]) << 4));
#pragma unroll
        for (int mi = 0; mi < 4; mi++)
#pragma unroll
          for (int ni = 0; ni < 4; ni++)
            acc[mi][ni] = __builtin_amdgcn_mfma_f32_16x16x32_bf16(ah[mi], bl[ni], acc[mi][ni], 0, 0, 0);
      }
    }
    __syncthreads();
  }

  const int crow0 = kg * 4, ccol = l15;
  if constexpr (FUSEPOOL) {
    const int n_img = m0 / (OH * OW);
    const int oh0 = (m0 % (OH * OW)) / OW;          // multiple of 4
    const int pmb = n_img * (OH / 2) * (OW / 2) + (oh0 / 2 + wrow) * (OW / 2);
#pragma unroll
    for (int mi = 0; mi < 2; mi++)
#pragma unroll
      for (int ni = 0; ni < 4; ni++)
#pragma unroll
        for (int jp = 0; jp < 2; jp++) {
          float a0 = acc[mi][ni][2 * jp],     a1 = acc[mi][ni][2 * jp + 1];
          float b0 = acc[mi + 2][ni][2 * jp], b1 = acc[mi + 2][ni][2 * jp + 1];
          float mx = fmaxf(fmaxf(a0, a1), fmaxf(b0, b1));
          float mn = fminf(fminf(a0, a1), fminf(b0, b1));
          int pm = pmb + mi * 8 + kg * 2 + jp;
          int ch = n0 + wcol * 64 + ni * 16 + ccol;
          Cout[(size_t)pm * CO + ch] = mx;
          Cmin[(size_t)pm * CO + ch] = mn;
        }
  } else {
    float* Cz = Cout + (size_t)z * M * CO;
#pragma unroll
    for (int mi = 0; mi < 4; mi++) {
      int m = m0 + wrow * 64 + mi * 16 + crow0;
#pragma unroll
      for (int ni = 0; ni < 4; ni++) {
        int nn = n0 + wcol * 64 + ni * 16 + ccol;
        float* cp = Cz + (size_t)m * CO + nn;
#pragma unroll
        for (int jj = 0; jj < 4; jj++) cp[(size_t)jj * CO] = acc[mi][ni][jj];
      }
    }
  }
  if constexpr (SPLIT == 1) {
    const int contrib = kg * 2 + wrow;
#pragma unroll
    for (int ni = 0; ni < 4; ni++) {
      float s = 0.f, q = 0.f;
#pragma unroll
      for (int mi = 0; mi < 4; mi++)
#pragma unroll
        for (int jj = 0; jj < 4; jj++) {
          float v = acc[mi][ni][jj];
          s += v; q += v * v;
        }
      int coll = wcol * 64 + ni * 16 + ccol;
      red[0][coll][contrib] = s;
      red[1][coll][contrib] = q;
    }
    __syncthreads();
    if (t < 128) {
      float s = 0.f, q = 0.f;
#pragma unroll
      for (int j = 0; j < 8; j++) { s += red[0][t][j]; q += red[1][t][j]; }
      size_t c = n0 + t;
      part[(c * gridDim.x + blockIdx.x) * 2 + 0] = s;
      part[(c * gridDim.x + blockIdx.x) * 2 + 1] = q;
    }
  }
}

// ---------------- FC GEMM: packed A (hi/lo) + packed B, zero LDS/barriers --
template<int K, int SPLIT>
__global__ __launch_bounds__(256) void fc_gemm_k(const bf16* __restrict__ Ahp,
                                                 const bf16* __restrict__ Alp,
                                                 const bf16* __restrict__ Bhp,
                                                 float* __restrict__ Cout) {
  constexpr int Kd64 = K / 64;
  constexpr int NCHS = Kd64 / SPLIT;
  constexpr int M = 256, N = 2048;
  const int t = threadIdx.x;
  const int lane = t & 63, w = t >> 6;
  const int m0 = blockIdx.x * 128, n0 = blockIdx.y * 128;
  const int z = blockIdx.z;
  const int wrow = w >> 1, wcol = w & 1;
  const int kg = lane >> 4, l15 = lane & 15;

  size_t ab[4], bb[4];
#pragma unroll
  for (int q = 0; q < 4; q++) {
    int rbA = (m0 >> 4) + wrow * 4 + q;
    ab[q] = (size_t)rbA * Kd64 * 1024 + (size_t)lane * 8;
    int rbB = (n0 >> 4) + wcol * 4 + q;
    bb[q] = (size_t)rbB * Kd64 * 1024 + (size_t)lane * 8;
  }

  f32x4 acc[4][4] = {};
  for (int kc = z * NCHS; kc < (z + 1) * NCHS; ++kc) {
    const size_t bco = (size_t)kc * 1024;
#pragma unroll
    for (int ks = 0; ks < 2; ks++) {
      const size_t soff = bco + ks * 512;
      bf16x8 ah[4], al[4], bh[4];
#pragma unroll
      for (int q = 0; q < 4; q++) {
        ah[q] = *(const bf16x8*)(Ahp + ab[q] + soff);
        al[q] = *(const bf16x8*)(Alp + ab[q] + soff);
        bh[q] = *(const bf16x8*)(Bhp + bb[q] + soff);
      }
#pragma unroll
      for (int mi = 0; mi < 4; mi++)
#pragma unroll
        for (int ni = 0; ni < 4; ni++)
          acc[mi][ni] = __builtin_amdgcn_mfma_f32_16x16x32_bf16(ah[mi], bh[ni], acc[mi][ni], 0, 0, 0);
#pragma unroll
      for (int mi = 0; mi < 4; mi++)
#pragma unroll
        for (int ni = 0; ni < 4; ni++)
          acc[mi][ni] = __builtin_amdgcn_mfma_f32_16x16x32_bf16(al[mi], bh[ni], acc[mi][ni], 0, 0, 0);
    }
  }

  const int crow0 = kg * 4, ccol = l15;
  float* Cz = Cout + (size_t)z * M * N;
#pragma unroll
  for (int mi = 0; mi < 4; mi++) {
    int m = m0 + wrow * 64 + mi * 16 + crow0;
#pragma unroll
    for (int ni = 0; ni < 4; ni++) {
      int nn = n0 + wcol * 64 + ni * 16 + ccol;
      float* cp = Cz + (size_t)m * N + nn;
#pragma unroll
      for (int jj = 0; jj < 4; jj++) cp[(size_t)jj * N] = acc[mi][ni][jj];
    }
  }
}

// ---------------- split-K reduction + BN partials ----------------
template<int M, int CO, int SPLIT, int NS>
__global__ __launch_bounds__(256) void reduce_bn_k(const float* __restrict__ Cp,
                                                   float* __restrict__ Cf,
                                                   float* __restrict__ part) {
  int c = blockIdx.x * 64 + (threadIdx.x & 63);
  int rl = threadIdx.x >> 6;
  constexpr int ROWS = M / NS;
  int r0 = blockIdx.y * ROWS;
  float sum = 0.f, sq = 0.f;
  for (int r = r0 + rl; r < r0 + ROWS; r += 4) {
    float v = 0.f;
#pragma unroll
    for (int s = 0; s < SPLIT; s++) v += Cp[(size_t)s * M * CO + (size_t)r * CO + c];
    Cf[(size_t)r * CO + c] = v;
    sum += v; sq += v * v;
  }
  __shared__ float ls[256], lq[256];
  ls[threadIdx.x] = sum; lq[threadIdx.x] = sq;
  __syncthreads();
  if (threadIdx.x < 64) {
    sum = ls[threadIdx.x] + ls[threadIdx.x + 64] + ls[threadIdx.x + 128] + ls[threadIdx.x + 192];
    sq  = lq[threadIdx.x] + lq[threadIdx.x + 64] + lq[threadIdx.x + 128] + lq[threadIdx.x + 192];
    part[((size_t)c * NS + blockIdx.y) * 2 + 0] = sum;
    part[((size_t)c * NS + blockIdx.y) * 2 + 1] = sq;
  }
}

// ---------------- BN finalize: one block per channel, wave butterfly -------
__global__ __launch_bounds__(64) void bn_finalize(const float* __restrict__ part,
                                                  const float* __restrict__ g,
                                                  const float* __restrict__ b,
                                                  float* __restrict__ scale,
                                                  float* __restrict__ shift,
                                                  int S, float invCount) {
  int c = blockIdx.x;
  int lane = threadIdx.x;
  float sum = 0.f, sq = 0.f;
  for (int s = lane; s < S; s += 64) {
    sum += part[((size_t)c * S + s) * 2 + 0];
    sq  += part[((size_t)c * S + s) * 2 + 1];
  }
#pragma unroll
  for (int o = 32; o > 0; o >>= 1) {
    sum += __shfl_xor(sum, o);
    sq  += __shfl_xor(sq, o);
  }
  if (lane == 0) {
    float m = sum * invCount;
    float var = sq * invCount - m * m;
    float sc = g[c] * rsqrtf(var + 1e-5f);
    scale[c] = sc;
    shift[c] = b[c] - m * sc;
  }
}

// ---------------- fused BN + ReLU + pad (no pool), 8ch/thread --------------
template<int CO, int IH, int IW, int PADO>
__global__ __launch_bounds__(256) void bn_act_pad_k(const float* __restrict__ x,
                                                    const float* __restrict__ scale,
                                                    const float* __restrict__ shift,
                                                    bf16* __restrict__ yh,
                                                    bf16* __restrict__ yl) {
  constexpr int OHP = IH + 2 * PADO, OWP = IW + 2 * PADO;
  constexpr int CO8 = CO / 8;
  int i = blockIdx.x * 256 + threadIdx.x;
  if (i >= 64 * OHP * OWP * CO8) return;
  int c8 = i % CO8; int t = i / CO8; int owp = t % OWP; t /= OWP; int ohp = t % OHP; int n = t / OHP;
  int c0 = c8 * 8;
  int oh = ohp - PADO, ow = owp - PADO;
  bf16x8 hv, lv;
#pragma unroll
  for (int j = 0; j < 8; j++) { hv[j] = (bf16)0.f; lv[j] = (bf16)0.f; }
  if (oh >= 0 && oh < IH && ow >= 0 && ow < IW) {
    float sc[8], sh[8];
    *(f32x4*)(sc)     = *(const f32x4*)(scale + c0);
    *(f32x4*)(sc + 4) = *(const f32x4*)(scale + c0 + 4);
    *(f32x4*)(sh)     = *(const f32x4*)(shift + c0);
    *(f32x4*)(sh + 4) = *(const f32x4*)(shift + c0 + 4);
    const float* p = x + (((size_t)(n * IH) + oh) * IW + ow) * CO + c0;
    float ta[8];
    *(f32x4*)(ta) = *(const f32x4*)(p); *(f32x4*)(ta + 4) = *(const f32x4*)(p + 4);
#pragma unroll
    for (int j = 0; j < 8; j++) {
      float vv = fmaxf(ta[j] * sc[j] + sh[j], 0.f);
      bf16 h, l; split2(vv, h, l);
      hv[j] = h; lv[j] = l;
    }
  }
  size_t o = (size_t)i * 8;
  *(bf16x8*)(yh + o) = hv;
  *(bf16x8*)(yl + o) = lv;
}

// ---------------- BN + ReLU + pad from pooled (max,min), 8ch/thread --------
template<int CO, int PH, int PW, int PADO>
__global__ __launch_bounds__(256) void act_pool_pad_k(const float* __restrict__ wmax,
                                                      const float* __restrict__ wmin,
                                                      const float* __restrict__ scale,
                                                      const float* __restrict__ shift,
                                                      bf16* __restrict__ yh,
                                                      bf16* __restrict__ yl) {
  constexpr int OHP = PH + 2 * PADO, OWP = PW + 2 * PADO;
  constexpr int CO8 = CO / 8;
  int i = blockIdx.x * 256 + threadIdx.x;
  if (i >= 64 * OHP * OWP * CO8) return;
  int c8 = i % CO8; int t = i / CO8; int owp = t % OWP; t /= OWP; int ohp = t % OHP; int n = t / OHP;
  int c0 = c8 * 8;
  int oh = ohp - PADO, ow = owp - PADO;
  bf16x8 hv, lv;
#pragma unroll
  for (int j = 0; j < 8; j++) { hv[j] = (bf16)0.f; lv[j] = (bf16)0.f; }
  if (oh >= 0 && oh < PH && ow >= 0 && ow < PW) {
    float sc[8], sh[8], mx[8], mn[8];
    *(f32x4*)(sc)     = *(const f32x4*)(scale + c0);
    *(f32x4*)(sc + 4) = *(const f32x4*)(scale + c0 + 4);
    *(f32x4*)(sh)     = *(const f32x4*)(shift + c0);
    *(f32x4*)(sh + 4) = *(const f32x4*)(shift + c0 + 4);
    size_t off = (((size_t)(n * PH) + oh) * PW + ow) * CO + c0;
    *(f32x4*)(mx)     = *(const f32x4*)(wmax + off);
    *(f32x4*)(mx + 4) = *(const f32x4*)(wmax + off + 4);
    *(f32x4*)(mn)     = *(const f32x4*)(wmin + off);
    *(f32x4*)(mn + 4) = *(const f32x4*)(wmin + off + 4);
#pragma unroll
    for (int j = 0; j < 8; j++) {
      float sel = (sc[j] >= 0.f) ? mx[j] : mn[j];
      float vv = fmaxf(sel * sc[j] + sh[j], 0.f);
      bf16 h, l; split2(vv, h, l);
      hv[j] = h; lv[j] = l;
    }
  }
  size_t o = (size_t)i * 8;
  *(bf16x8*)(yh + o) = hv;
  *(bf16x8*)(yl + o) = lv;
}

// ---------------- ROI SPP: conv5 fp32 + inline BN -> PACKED S hi/lo --------
__global__ __launch_bounds__(256) void spp_k(const float* __restrict__ feat,
                                             const float* __restrict__ scale,
                                             const float* __restrict__ shift,
                                             const int* __restrict__ roi,
                                             bf16* __restrict__ oh_,
                                             bf16* __restrict__ ol_) {
  int c = blockIdx.x * 256 + threadIdx.x;  // 0..511
  int r = blockIdx.y;                      // 0..255
  const int* rp = roi + r * 5;
  int im = rp[0];
  int c1 = rp[1] >> 3, r1 = rp[2] >> 3, c2 = rp[3] >> 3, r2 = rp[4] >> 3;
  int w = c2 - c1 + 1;
  int lo[6], hi[6];
  int bi = 0;
#pragma unroll
  for (int l = 1; l <= 3; l++)
    for (int k = 0; k < l; k++) {
      lo[bi] = c1 + (k * w) / l;
      hi[bi] = c1 + ((k + 1) * w + l - 1) / l - 1;
      bi++;
    }
  float mx[6];
#pragma unroll
  for (int b = 0; b < 6; b++) mx[b] = -1e30f;
  float sc = scale[c], sh = shift[c];
  const float* fp = feat + (size_t)im * 96 * 512 + c;
  for (int row = r1; row <= r2; row++)
    for (int col = c1; col <= c2; col++) {
      float v = fp[(size_t)(row * 16 + col) * 512] * sc + sh;
#pragma unroll
      for (int b = 0; b < 6; b++)
        if (col >= lo[b] && col <= hi[b]) mx[b] = fmaxf(mx[b], v);
    }
  int idx[6] = {c, 512 + c * 2, 512 + c * 2 + 1, 1536 + c * 3, 1536 + c * 3 + 1, 1536 + c * 3 + 2};
#pragma unroll
  for (int b = 0; b < 6; b++) {
    float v = fmaxf(mx[b], 0.f);
    bf16 h, l; split2(v, h, l);
    size_t o = pk_off(r, idx[b], 48);
    oh_[o] = h;
    ol_[o] = l;
  }
}

// FC1: BN+ReLU, write hi/lo PACKED into CC[:, 0:2048] (K=8192)
__global__ __launch_bounds__(256) void bn1d_apply_cc_k(const float* __restrict__ x,
                                                       const float* __restrict__ scale,
                                                       const float* __restrict__ shift,
                                                       bf16* __restrict__ ch,
                                                       bf16* __restrict__ cl) {
  int i = blockIdx.x * 256 + threadIdx.x;
  if (i >= 256 * 256) return;
  int f8 = i & 255, r = i >> 8;
  int f0 = f8 * 8;
  float xv[8], sc[8], sh[8];
  *(f32x4*)(xv)     = *(const f32x4*)(x + (size_t)r * 2048 + f0);
  *(f32x4*)(xv + 4) = *(const f32x4*)(x + (size_t)r * 2048 + f0 + 4);
  *(f32x4*)(sc)     = *(const f32x4*)(scale + f0);
  *(f32x4*)(sc + 4) = *(const f32x4*)(scale + f0 + 4);
  *(f32x4*)(sh)     = *(const f32x4*)(shift + f0);
  *(f32x4*)(sh + 4) = *(const f32x4*)(shift + f0 + 4);
  bf16x8 hv, lv;
#pragma unroll
  for (int j = 0; j < 8; j++) {
    float v = fmaxf(xv[j] * sc[j] + sh[j], 0.f);
    bf16 h, l; split2(v, h, l);
    hv[j] = h; lv[j] = l;
  }
  size_t o = pk_off(r, f0, 128);
  *(bf16x8*)(ch + o) = hv;
  *(bf16x8*)(cl + o) = lv;
}

// FC2: BN+ReLU, fp32 out, 4 feat/thread
__global__ __launch_bounds__(256) void bn1d_apply_f32_k(const float* __restrict__ x,
                                                        const float* __restrict__ scale,
                                                        const float* __restrict__ shift,
                                                        float* __restrict__ y) {
  int i = blockIdx.x * 256 + threadIdx.x;
  if (i >= 256 * 512) return;
  int f4 = i & 511, r = i >> 9;
  int f0 = f4 * 4;
  f32x4 xv = *(const f32x4*)(x + (size_t)r * 2048 + f0);
  f32x4 sc = *(const f32x4*)(scale + f0);
  f32x4 sh = *(const f32x4*)(shift + f0);
  f32x4 o;
#pragma unroll
  for (int j = 0; j < 4; j++) o[j] = fmaxf(xv[j] * sc[j] + sh[j], 0.f);
  *(f32x4*)(y + (size_t)r * 2048 + f0) = o;
}

// ============================================================================
extern "C" void kernel_launch(void* const* d_in, const int* in_sizes, int n_in,
                              void* d_out, int out_size, void* d_ws, size_t ws_size,
                              hipStream_t stream) {
  (void)in_sizes; (void)n_in; (void)out_size; (void)ws_size;

  const float* x    = (const float*)d_in[0];
  const int*   roi  = (const int*)  d_in[1];
  const float* phoc = (const float*)d_in[2];
  const float* c1w  = (const float*)d_in[3];
  const float* g1   = (const float*)d_in[5];
  const float* b1   = (const float*)d_in[6];
  const float* c2w  = (const float*)d_in[7];
  const float* g2   = (const float*)d_in[9];
  const float* b2   = (const float*)d_in[10];
  const float* c3w  = (const float*)d_in[11];
  const float* g3   = (const float*)d_in[13];
  const float* b3   = (const float*)d_in[14];
  const float* c4w  = (const float*)d_in[15];
  const float* g4   = (const float*)d_in[17];
  const float* b4   = (const float*)d_in[18];
  const float* c5w  = (const float*)d_in[19];
  const float* g5   = (const float*)d_in[21];
  const float* b5   = (const float*)d_in[22];
  const float* f1w  = (const float*)d_in[23];
  const float* g6   = (const float*)d_in[25];
  const float* b6   = (const float*)d_in[26];
  const float* f2w  = (const float*)d_in[27];
  const float* g7   = (const float*)d_in[29];
  const float* b7   = (const float*)d_in[30];
  float* out = (float*)d_out;

  // ---- workspace layout (total ~168.4 MB) ----
  char* ws = (char*)d_ws;
  bf16*  Ahi  = (bf16*) (ws + 0x0200000);   // 16 MB (padded NHWC activations)
  bf16*  Alo  = (bf16*) (ws + 0x1200000);   // 16 MB
  float* C    = (float*)(ws + 0x2200000);   // GEMM out / split slabs / pooled max
  float* CMIN = (float*)(ws + 0x2E00000);   // pooled min
  float* C5F  = (float*)(ws + 0x4600000);   // conv5 final
  bf16*  Wc2h = (bf16*) (ws + 0x5500000);   // conv weights (row-major [CO][K])
  bf16*  Wc3h = (bf16*) (ws + 0x5570000);
  bf16*  Wc4h = (bf16*) (ws + 0x5600000);
  bf16*  Wc5h = (bf16*) (ws + 0x5840000);
  bf16*  Wf1  = (bf16*) (ws + 0x5CC0000);   // packed FC weights
  bf16*  Wf2  = (bf16*) (ws + 0x68C0000);   // packed [2048][8192] = 32 MB
  bf16*  Wc5l = (bf16*) (ws + 0x8C00000);
  bf16*  Shi  = (bf16*) (ws + 0x9080000);   // packed spp out [256][3072]
  bf16*  Slo  = (bf16*) (ws + 0x9200000);
  float* G6   = (float*)(ws + 0x9380000);   // fc1 out fp32 [256][2048]
  bf16*  CChi = (bf16*) (ws + 0x9580000);   // packed concat [256][8192] = 4 MB
  bf16*  CClo = (bf16*) (ws + 0x9980000);
  float* G7   = (float*)(ws + 0x9D80000);   // fc2 out fp32 [256][2048]
  float* PART = (float*)(ws + 0x9F80000);   // 768 KB
  float* SC   = (float*)(ws + 0xA040000);
  float* SH   = (float*)(ws + 0xA050000);

  // ---- prep: conv1 stats (768 blocks) || all transforms (30080 blocks) ----
  prep_k<<<30848, 256, 0, stream>>>(x, c1w, PART,
                                    c2w, c3w, c4w, c5w, f1w, f2w, phoc,
                                    Wc2h, Wc3h, Wc4h, Wc5h, Wc5l, Wf1, Wf2,
                                    CChi, CClo);

  // ---- conv1 finalize + apply (stats already done inside prep) ----
  bn_finalize<<<64, 64, 0, stream>>>(PART, g1, b1, SC, SH, 96, 1.f / 393216.f);
  conv1_apply_k<<<dim3(476, 8), 256, 0, stream>>>(x, c1w, SC, SH, Ahi, Alo);

  // ---- conv2 (1-pass, A-resident, fused pool): -> pooled max/min [24576][128]
  conv2_gemm_k<<<768, 256, 0, stream>>>(Ahi, Wc2h, C, CMIN, PART);
  bn_finalize<<<128, 64, 0, stream>>>(PART, g2, b2, SC, SH, 768, 1.f / 98304.f);
  act_pool_pad_k<128, 12, 32, 1><<<1904, 256, 0, stream>>>(C, CMIN, SC, SH, Ahi, Alo);

  // ---- conv3 (2-pass: Ah.Bh + Al.Bh, no pool) ----
  conv_gemm_k<128, 3, 12, 32, 256, true, false, 1, false><<<dim3(192, 2), 256, 0, stream>>>(Ahi, Alo, Wc3h, nullptr, C, nullptr, PART);
  bn_finalize<<<256, 64, 0, stream>>>(PART, g3, b3, SC, SH, 192, 1.f / 24576.f);
  bn_act_pad_k<256, 12, 32, 1><<<3808, 256, 0, stream>>>(C, SC, SH, Ahi, Alo);

  // ---- conv4 (1-pass, fused pool): -> pooled max/min [6144][512] ----
  conv_gemm_k<256, 3, 12, 32, 512, false, false, 1, true><<<dim3(192, 4), 256, 0, stream>>>(Ahi, Alo, Wc4h, nullptr, C, CMIN, PART);
  bn_finalize<<<512, 64, 0, stream>>>(PART, g4, b4, SC, SH, 192, 1.f / 24576.f);
  act_pool_pad_k<512, 6, 16, 1><<<2304, 256, 0, stream>>>(C, CMIN, SC, SH, Ahi, Alo);

  // ---- conv5 (3-pass, split-K=2): slabs in C, final in C5F ----
  conv_gemm_k<512, 3, 6, 16, 512, true, true, 2, false><<<dim3(48, 4, 2), 256, 0, stream>>>(Ahi, Alo, Wc5h, Wc5l, C, nullptr, nullptr);
  reduce_bn_k<6144, 512, 2, 16><<<dim3(8, 16), 256, 0, stream>>>(C, C5F, PART);
  bn_finalize<<<512, 64, 0, stream>>>(PART, g5, b5, SC, SH, 16, 1.f / 6144.f);

  // ---- SPP (reads fp32 conv5 out + inline BN, packed output) ----
  spp_k<<<dim3(2, 256), 256, 0, stream>>>(C5F, SC, SH, roi, Shi, Slo);

  // ---- FC1 (packed, LDS-free, split-K=16): [256][3072] x [2048][3072] ----
  fc_gemm_k<3072, 16><<<dim3(2, 16, 16), 256, 0, stream>>>(Shi, Slo, Wf1, C);
  reduce_bn_k<256, 2048, 16, 4><<<dim3(32, 4), 256, 0, stream>>>(C, G6, PART);
  bn_finalize<<<2048, 64, 0, stream>>>(PART, g6, b6, SC, SH, 4, 1.f / 256.f);
  bn1d_apply_cc_k<<<256, 256, 0, stream>>>(G6, SC, SH, CChi, CClo);

  // ---- FC2 (packed, LDS-free, split-K=16): [256][8192] x [2048][8192] ----
  fc_gemm_k<8192, 16><<<dim3(2, 16, 16), 256, 0, stream>>>(CChi, CClo, Wf2, C);
  reduce_bn_k<256, 2048, 16, 4><<<dim3(32, 4), 256, 0, stream>>>(C, G7, PART);
  bn_finalize<<<2048, 64, 0, stream>>>(PART, g7, b7, SC, SH, 4, 1.f / 256.f);
  bn1d_apply_f32_k<<<512, 256, 0, stream>>>(G7, SC, SH, out);
}

// Round 20
// 535.834 us; speedup vs baseline: 1.2890x; 1.0287x over previous
//
#include <hip/hip_runtime.h>
#include <hip/hip_bf16.h>

// ============================================================================
// HWNet-SPP forward, MFMA bf16 implicit-GEMM with selective hi/lo precision.
// conv2: A-resident kernel; conv3/4/5: 128x128 LDS-staged template; FC1/FC2:
// packed fragment-order operands, zero LDS/barriers. Pooled layers (conv2,
// conv4) fuse the 2x2 pool into the GEMM epilogue as (window-max, window-min)
// dual fp32 writes. prep does LDS-transposed conv weights AND conv1 BN stats
// (independent, overlapped: VALU-bound stats || BW-bound transforms).
// Pass config (error budget vs absmax threshold 0.098):
//   conv2: Ah*Bh (1-pass)  conv3: +Al*Bh (2-pass)  conv4: 1-pass
//   conv5: Ah*Bh + Al*Bh (2-pass, split-K=2)  FC1/FC2: 2-pass (split-K=16)
// BN stats fused into GEMM epilogue / split-K reducer; bn_finalize is
// one-block-per-channel wave butterfly. conv1 reads x with edge clamping.
// SPP reads conv5 fp32 out with inline BN. Biases skipped (BN cancels).
// ============================================================================

typedef __bf16 bf16;
using bf16x4 = __attribute__((ext_vector_type(4))) __bf16;
using bf16x8 = __attribute__((ext_vector_type(8))) __bf16;
using f32x4  = __attribute__((ext_vector_type(4))) float;

__device__ __forceinline__ void split2(float v, bf16& h, bf16& l) {
  bf16 hb = (bf16)v;
  h = hb;
  l = (bf16)(v - (float)hb);
}

__device__ __forceinline__ int iclamp(int v, int lo, int hi) {
  return v < lo ? lo : (v > hi ? hi : v);
}

__device__ __forceinline__ size_t pk_off(int row, int k, int Kd64) {
  return ((size_t)(row >> 4) * Kd64 + (k >> 6)) * 1024 +
         (size_t)(((k >> 5) & 1) * 512 + ((k >> 3) & 3) * 128 + ((row & 15) << 3) + (k & 7));
}

__device__ __forceinline__ void gld_lds16(const bf16* g, void* lds) {
  __builtin_amdgcn_global_load_lds(
      (const __attribute__((address_space(1))) unsigned int*)g,
      (__attribute__((address_space(3))) unsigned int*)lds, 16, 0, 0);
}

// ---------------- fused prep: conv1 BN stats + all weight/input transforms --
// blocks [0,768): conv1 stats (seg = b/8, ch-group = b%8), VALU-bound.
// blocks [768,...): LDS-transposed conv weights, packed FC weights, phoc.
__global__ __launch_bounds__(256) void prep_k(const float* __restrict__ x,
                                              const float* __restrict__ c1w,
                                              float* __restrict__ part,
                                              const float* __restrict__ c2w,
                                              const float* __restrict__ c3w,
                                              const float* __restrict__ c4w,
                                              const float* __restrict__ c5w,
                                              const float* __restrict__ f1w,
                                              const float* __restrict__ f2w,
                                              const float* __restrict__ phoc,
                                              bf16* __restrict__ Wc2h,
                                              bf16* __restrict__ Wc3h,
                                              bf16* __restrict__ Wc4h,
                                              bf16* __restrict__ Wc5h,
                                              bf16* __restrict__ Wf1,
                                              bf16* __restrict__ Wf2,
                                              bf16* __restrict__ cch,
                                              bf16* __restrict__ ccl) {
  __shared__ float buf[4608];
  __shared__ float ls[256], lq[256];
  int b = blockIdx.x;
  int tid = threadIdx.x;
  if (b < 768) {
    // ---- conv1 BN stats (8 ch/group, edge-clamped reads of x) ----
    int seg = b >> 3;          // 0..95
    int co0 = (b & 7) * 8;     // channel group
    float sums[8] = {0.f}, sqs[8] = {0.f};
    for (int r = 0; r < 16; r++) {
      int pix = seg * 4096 + r * 256 + tid;  // 0..393215
      int w = pix & 127; int t = pix >> 7; int h = t % 48; int n = t / 48;
      const float* ip = x + (size_t)n * 48 * 128;
      int ihs[5], iws[5];
#pragma unroll
      for (int k = 0; k < 5; k++) {
        ihs[k] = iclamp(h + k - 2, 0, 47);
        iws[k] = iclamp(w + k - 2, 0, 127);
      }
      float win[25];
#pragma unroll
      for (int kh = 0; kh < 5; kh++)
#pragma unroll
        for (int kw = 0; kw < 5; kw++) win[kh * 5 + kw] = ip[ihs[kh] * 128 + iws[kw]];
#pragma unroll
      for (int j = 0; j < 8; j++) {
        const float* wp = c1w + (size_t)(co0 + j) * 25;
        float acc = 0.f;
#pragma unroll
        for (int k = 0; k < 25; k++) acc += win[k] * wp[k];
        sums[j] += acc; sqs[j] += acc * acc;
      }
    }
    for (int j = 0; j < 8; j++) {
      ls[tid] = sums[j]; lq[tid] = sqs[j];
      __syncthreads();
      for (int o = 128; o > 0; o >>= 1) {
        if (tid < o) { ls[tid] += ls[tid + o]; lq[tid] += lq[tid + o]; }
        __syncthreads();
      }
      if (tid == 0) {
        int c = co0 + j;
        part[((size_t)c * 96 + seg) * 2 + 0] = ls[0];
        part[((size_t)c * 96 + seg) * 2 + 1] = lq[0];
      }
      __syncthreads();
    }
    return;
  }
  b -= 768;
  const float* src = nullptr;
  bf16 *dsth = nullptr;
  int CI = 0, KK = 0, co = 0;
  if (b < 128)        { src = c2w; dsth = Wc2h; CI = 64;  KK = 25; co = b; }
  else if (b < 384)   { src = c3w; dsth = Wc3h; CI = 128; KK = 9;  co = b - 128; }
  else if (b < 896)   { src = c4w; dsth = Wc4h; CI = 256; KK = 9;  co = b - 384; }
  else if (b < 1408)  { src = c5w; dsth = Wc5h; CI = 512; KK = 9; co = b - 896; }
  if (src) {
    const int n = CI * KK;
    const float* sp = src + (size_t)co * n;
    for (int i = tid; i < n; i += 256) buf[i] = sp[i];
    __syncthreads();
    bf16* oh = dsth + (size_t)co * n;
    for (int o = tid; o < n; o += 256) {
      int ci = o & (CI - 1), kk = o / CI;
      float v = buf[ci * KK + kk];
      bf16 h, l; split2(v, h, l);
      oh[o] = h;
    }
    return;
  }
  b -= 1408;
  if (b < 6144) {  // f1w [2048][3072] -> packed hi, 4 elems/thread
    int i = b * 256 + tid;
    int k0 = (i % 768) * 4, n = i / 768;
    const float4 v = *(const float4*)(f1w + (size_t)n * 3072 + k0);
    bf16x4 o = { (bf16)v.x, (bf16)v.y, (bf16)v.z, (bf16)v.w };
    *(bf16x4*)(Wf1 + pk_off(n, k0, 48)) = o;
    return;
  }
  b -= 6144;
  if (b < 16384) {  // f2w [2048][7901] -> packed hi [2048][8192], 4/thread
    int i = b * 256 + tid;
    int k0 = (i & 2047) * 4, n = i >> 11;
    const float* xp = f2w + (size_t)n * 7901 + k0;
    bf16x4 o;
#pragma unroll
    for (int j = 0; j < 4; j++) o[j] = (bf16)((k0 + j < 7901) ? xp[j] : 0.f);
    *(bf16x4*)(Wf2 + pk_off(n, k0, 128)) = o;
    return;
  }
  b -= 16384;
  {  // phoc -> packed CC cols [2048,8192) hi/lo
    int i = b * 256 + tid;
    if (i >= 256 * 6144) return;
    int k = i % 6144, r = i / 6144;
    int col = 2048 + k;
    float v = (col < 7901) ? phoc[(size_t)r * 5853 + (col - 2048)] : 0.f;
    bf16 h, l; split2(v, h, l);
    size_t o = pk_off(r, col, 128);
    cch[o] = h;
    ccl[o] = l;
  }
}

// ---------------- conv1 pass 2: conv+BN+ReLU+pool+pad (8 ch/group) ---------
__global__ __launch_bounds__(256) void conv1_apply_k(const float* __restrict__ x,
                                                     const float* __restrict__ wt,
                                                     const float* __restrict__ scale,
                                                     const float* __restrict__ shift,
                                                     bf16* __restrict__ yh,
                                                     bf16* __restrict__ yl) {
  int i = blockIdx.x * 256 + threadIdx.x;  // padded pixel slots
  if (i >= 64 * 28 * 68) return;
  int owp = i % 68; int t = i / 68; int ohp = t % 28; int n = t / 28;
  int co0 = blockIdx.y * 8;
  int oh = ohp - 2, ow = owp - 2;
  bf16x8 hv, lv;
#pragma unroll
  for (int j = 0; j < 8; j++) { hv[j] = (bf16)0.f; lv[j] = (bf16)0.f; }
  if (oh >= 0 && oh < 24 && ow >= 0 && ow < 64) {
    const float* ip = x + (size_t)n * 48 * 128;
    int shr[6], swc[6];
#pragma unroll
    for (int k = 0; k < 6; k++) {
      shr[k] = iclamp(2 * oh + k - 2, 0, 47);
      swc[k] = iclamp(2 * ow + k - 2, 0, 127);
    }
    float win[36];
#pragma unroll
    for (int r = 0; r < 6; r++)
#pragma unroll
      for (int c = 0; c < 6; c++) win[r * 6 + c] = ip[shr[r] * 128 + swc[c]];
#pragma unroll
    for (int j = 0; j < 8; j++) {
      const float* wp = wt + (size_t)(co0 + j) * 25;
      float sc = scale[co0 + j], sh = shift[co0 + j];
      float m = -1e30f;
#pragma unroll
      for (int dy = 0; dy < 2; dy++)
#pragma unroll
        for (int dx = 0; dx < 2; dx++) {
          float acc = 0.f;
#pragma unroll
          for (int kh = 0; kh < 5; kh++)
#pragma unroll
            for (int kw = 0; kw < 5; kw++)
              acc += win[(kh + dy) * 6 + kw + dx] * wp[kh * 5 + kw];
          m = fmaxf(m, acc * sc + sh);
        }
      float v = fmaxf(m, 0.f);
      bf16 h, l; split2(v, h, l);
      hv[j] = h; lv[j] = l;
    }
  }
  size_t o = (size_t)i * 64 + co0;
  *(bf16x8*)(yh + o) = hv;
  *(bf16x8*)(yl + o) = lv;
}

// ---------------- conv2 specialized: A-resident + fused pool (max/min) -----
__global__ __launch_bounds__(256) void conv2_gemm_k(const bf16* __restrict__ Ahi,
                                                    const bf16* __restrict__ Bhi,
                                                    float* __restrict__ Wmax,
                                                    float* __restrict__ Wmin,
                                                    float* __restrict__ part) {
  __shared__ bf16 Ash[416 * 64];      // 52 KB (reused as exchange post-loop)
  __shared__ bf16 Bsh[128 * 64];      // 16 KB
  __shared__ float red[2][128][8];    // 8 KB
  const int t = threadIdx.x;
  const int lane = t & 63, w = t >> 6;
  const int m0 = blockIdx.x * 128;
  const int img = m0 / 1536;
  const int oh0 = (m0 % 1536) >> 6;   // even
  const size_t abase = ((size_t)(img * 28 + oh0) * 68) * 64;

#pragma unroll
  for (int i = 0; i < 13; i++) {
    int f = i * 256 + t;
    int p = f >> 3; if (p > 407) p = 407;
    int s = f & 7;
    int ss = s ^ (p & 7);
    gld_lds16(Ahi + abase + (size_t)p * 64 + ss * 8,
              (char*)Ash + (size_t)(i * 256 + w * 64) * 16);
  }

  size_t boff[4];
#pragma unroll
  for (int i = 0; i < 4; i++) {
    int f = (i * 4 + w) * 64 + lane;
    int row = f >> 3, slot = f & 7;
    int ss = slot ^ (row & 7);
    boff[i] = (size_t)row * 1600 + ss * 8;
  }

  const int wrow = w >> 1, wcol = w & 1;
  const int kg = lane >> 4, l15 = lane & 15;
  int pixb[4];
#pragma unroll
  for (int q = 0; q < 4; q++) pixb[q] = wrow * 68 + q * 16 + l15;
  int brb[4], bmk[4];
#pragma unroll
  for (int q = 0; q < 4; q++) {
    int rb = wcol * 64 + q * 16 + l15;
    brb[q] = rb * 128; bmk[q] = rb & 7;
  }
  const char* Ashb = (const char*)Ash;
  const char* Bshb = (const char*)Bsh;

  f32x4 acc[4][4] = {};
  for (int kc = 0; kc < 25; ++kc) {
    const int kh = kc / 5, kw = kc % 5;
    const int kofs = kh * 68 + kw;
    const int k0 = kc * 64;
#pragma unroll
    for (int i = 0; i < 4; i++)
      gld_lds16(Bhi + boff[i] + k0, (char*)Bsh + (i * 4 + w) * 1024);
    __syncthreads();
#pragma unroll
    for (int ks = 0; ks < 2; ks++) {
      const int slot = ks * 4 + kg;
      bf16x8 ah[4], bh[4];
#pragma unroll
      for (int q = 0; q < 4; q++) {
        int pix = pixb[q] + kofs;
        ah[q] = *(const bf16x8*)(Ashb + pix * 128 + ((slot ^ (pix & 7)) << 4));
        bh[q] = *(const bf16x8*)(Bshb + brb[q] + ((slot ^ bmk[q]) << 4));
      }
#pragma unroll
      for (int mi = 0; mi < 4; mi++)
#pragma unroll
        for (int ni = 0; ni < 4; ni++)
          acc[mi][ni] = __builtin_amdgcn_mfma_f32_16x16x32_bf16(ah[mi], bh[ni], acc[mi][ni], 0, 0, 0);
    }
    __syncthreads();  // after this, Ash/Bsh free for reuse
  }

  const int ccol = l15;
  float hmx[4][4][2], hmn[4][4][2];
#pragma unroll
  for (int mi = 0; mi < 4; mi++)
#pragma unroll
    for (int ni = 0; ni < 4; ni++)
#pragma unroll
      for (int jp = 0; jp < 2; jp++) {
        float a = acc[mi][ni][2 * jp], b = acc[mi][ni][2 * jp + 1];
        hmx[mi][ni][jp] = fmaxf(a, b);
        hmn[mi][ni][jp] = fminf(a, b);
      }
  const int contrib = kg * 2 + wrow;
#pragma unroll
  for (int ni = 0; ni < 4; ni++) {
    float s = 0.f, q = 0.f;
#pragma unroll
    for (int mi = 0; mi < 4; mi++)
#pragma unroll
      for (int jj = 0; jj < 4; jj++) {
        float v = acc[mi][ni][jj];
        s += v; q += v * v;
      }
    int coll = wcol * 64 + ni * 16 + ccol;
    red[0][coll][contrib] = s;
    red[1][coll][contrib] = q;
  }
  float* exch = (float*)Ash;
  if (wrow == 1) {
    float* ep = exch + (size_t)(wcol * 64 + lane) * 64;
#pragma unroll
    for (int mi = 0; mi < 4; mi++)
#pragma unroll
      for (int ni = 0; ni < 4; ni++)
#pragma unroll
        for (int jp = 0; jp < 2; jp++) {
          int s = (mi * 8 + ni * 2 + jp) * 2;
          ep[s + 0] = hmx[mi][ni][jp];
          ep[s + 1] = hmn[mi][ni][jp];
        }
  }
  __syncthreads();
  if (wrow == 0) {
    const float* ep = exch + (size_t)(wcol * 64 + lane) * 64;
    const int pmb = img * 384 + (oh0 >> 1) * 32;
#pragma unroll
    for (int mi = 0; mi < 4; mi++)
#pragma unroll
      for (int ni = 0; ni < 4; ni++)
#pragma unroll
        for (int jp = 0; jp < 2; jp++) {
          int s = (mi * 8 + ni * 2 + jp) * 2;
          float mx = fmaxf(hmx[mi][ni][jp], ep[s + 0]);
          float mn = fminf(hmn[mi][ni][jp], ep[s + 1]);
          int pm = pmb + mi * 8 + kg * 2 + jp;
          int ch = wcol * 64 + ni * 16 + ccol;
          Wmax[(size_t)pm * 128 + ch] = mx;
          Wmin[(size_t)pm * 128 + ch] = mn;
        }
  }
  if (t < 128) {
    float s = 0.f, q = 0.f;
#pragma unroll
    for (int j = 0; j < 8; j++) { s += red[0][t][j]; q += red[1][t][j]; }
    size_t c = t;
    part[(c * gridDim.x + blockIdx.x) * 2 + 0] = s;
    part[(c * gridDim.x + blockIdx.x) * 2 + 1] = q;
  }
}

// ---------------- MFMA implicit-GEMM, LDS-staged, optional split-K/pool ----
template<int CI, int KS, int OH, int OW, int CO, bool ALO, bool BLO, int SPLIT, bool FUSEPOOL>
__global__ __launch_bounds__(256) void conv_gemm_k(const bf16* __restrict__ Ahi,
                                                   const bf16* __restrict__ Alo,
                                                   const bf16* __restrict__ Bhi,
                                                   const bf16* __restrict__ Blo,
                                                   float* __restrict__ Cout,
                                                   float* __restrict__ Cmin,
                                                   float* __restrict__ part) {
  static_assert(CI % 64 == 0, "chunk must not straddle ci segments");
  static_assert(!FUSEPOOL || (OW == 32 && SPLIT == 1), "fusepool needs OW=32");
  constexpr int K = KS * KS * CI;
  constexpr int IWP = OW + KS - 1;
  constexpr int NCH = K / 64;
  static_assert(NCH % SPLIT == 0, "split must divide chunk count");
  constexpr int NCHS = NCH / SPLIT;
  constexpr int M = 64 * OH * OW;
  __shared__ bf16 Ash[128 * 64];
  __shared__ bf16 Asl[ALO ? 128 * 64 : 64];
  __shared__ bf16 Bsh[128 * 64];
  __shared__ bf16 Bsl[BLO ? 128 * 64 : 64];
  __shared__ float red[2][128][8];
  const int t = threadIdx.x;
  const int lane = t & 63, w = t >> 6;
  const int m0 = blockIdx.x * 128, n0 = blockIdx.y * 128;
  const int z = (SPLIT > 1) ? blockIdx.z : 0;

  int apix[4]; size_t boff[4];
#pragma unroll
  for (int i = 0; i < 4; i++) {
    int f = (i * 4 + w) * 64 + lane;
    int row = f >> 3, slot = f & 7;
    int ss = slot ^ (row & 7);
    int m = m0 + row;
    int n = m / (OH * OW); int rem = m % (OH * OW);
    int oh = rem / OW, ow_ = rem % OW;
    apix[i] = ((n * (OH + KS - 1) + oh) * IWP + ow_) * CI + ss * 8;
    boff[i] = (size_t)(n0 + row) * K + ss * 8;
  }

  const int wrow = w >> 1, wcol = w & 1;
  const int kg = lane >> 4, l15 = lane & 15;
  int arb[4], amk[4], brb[4], bmk[4];
#pragma unroll
  for (int q = 0; q < 4; q++) {
    int ra = wrow * 64 + q * 16 + l15;
    arb[q] = ra * 128; amk[q] = ra & 7;
    int rb = wcol * 64 + q * 16 + l15;
    brb[q] = rb * 128; bmk[q] = rb & 7;
  }
  const char* Ashb = (const char*)Ash;
  const char* Aslb = (const char*)Asl;
  const char* Bshb = (const char*)Bsh;
  const char* Bslb = (const char*)Bsl;

  f32x4 acc[4][4] = {};
  for (int kc = z * NCHS; kc < (z + 1) * NCHS; ++kc) {
    const int k0 = kc * 64;
    const int seg = k0 / CI;
    const int ci0 = k0 % CI;
    const int kh = seg / KS, kw = seg % KS;
    const int aoff = (kh * IWP + kw) * CI + ci0;   // wave-uniform
#pragma unroll
    for (int i = 0; i < 4; i++) {
      gld_lds16(Ahi + (size_t)apix[i] + aoff, (char*)Ash + (i * 4 + w) * 1024);
      if (ALO)
        gld_lds16(Alo + (size_t)apix[i] + aoff, (char*)Asl + (i * 4 + w) * 1024);
      gld_lds16(Bhi + boff[i] + k0,   (char*)Bsh + (i * 4 + w) * 1024);
      if (BLO)
        gld_lds16(Blo + boff[i] + k0, (char*)Bsl + (i * 4 + w) * 1024);
    }
    __syncthreads();
#pragma unroll
    for (int ks = 0; ks < 2; ks++) {
      const int slot = ks * 4 + kg;
      bf16x8 ah[4], bh[4];
#pragma unroll
      for (int q = 0; q < 4; q++) {
        ah[q] = *(const bf16x8*)(Ashb + arb[q] + ((slot ^ amk[q]) << 4));
        bh[q] = *(const bf16x8*)(Bshb + brb[q] + ((slot ^ bmk[q]) << 4));
      }
#pragma unroll
      for (int mi = 0; mi < 4; mi++)
#pragma unroll
        for (int ni = 0; ni < 4; ni++)
          acc[mi][ni] = __builtin_amdgcn_mfma_f32_16x16x32_bf16(ah[mi], bh[ni], acc[mi][ni], 0, 0, 0);
      if (ALO) {
        bf16x8 al[4];
#pragma unroll
        for (int q = 0; q < 4; q++)
          al[q] = *(const bf16x8*)(Aslb + arb[q] + ((slot ^ amk[q]) << 4));
#pragma unroll
        for (int mi = 0; mi < 4; mi++)
#pragma unroll
          for (int ni = 0; ni < 4; ni++)
            acc[mi][ni] = __builtin_amdgcn_mfma_f32_16x16x32_bf16(al[mi], bh[ni], acc[mi][ni], 0, 0, 0);
      }
      if (BLO) {
        bf16x8 bl[4];
#pragma unroll
        for (int q = 0; q < 4; q++)
          bl[q] = *(const bf16x8*)(Bslb + brb[q] + ((slot ^ bmk[q]) << 4));
#pragma unroll
        for (int mi = 0; mi < 4; mi++)
#pragma unroll
          for (int ni = 0; ni < 4; ni++)
            acc[mi][ni] = __builtin_amdgcn_mfma_f32_16x16x32_bf16(ah[mi], bl[ni], acc[mi][ni], 0, 0, 0);
      }
    }
    __syncthreads();
  }

  const int crow0 = kg * 4, ccol = l15;
  if constexpr (FUSEPOOL) {
    const int n_img = m0 / (OH * OW);
    const int oh0 = (m0 % (OH * OW)) / OW;          // multiple of 4
    const int pmb = n_img * (OH / 2) * (OW / 2) + (oh0 / 2 + wrow) * (OW / 2);
#pragma unroll
    for (int mi = 0; mi < 2; mi++)
#pragma unroll
      for (int ni = 0; ni < 4; ni++)
#pragma unroll
        for (int jp = 0; jp < 2; jp++) {
          float a0 = acc[mi][ni][2 * jp],     a1 = acc[mi][ni][2 * jp + 1];
          float b0 = acc[mi + 2][ni][2 * jp], b1 = acc[mi + 2][ni][2 * jp + 1];
          float mx = fmaxf(fmaxf(a0, a1), fmaxf(b0, b1));
          float mn = fminf(fminf(a0, a1), fminf(b0, b1));
          int pm = pmb + mi * 8 + kg * 2 + jp;
          int ch = n0 + wcol * 64 + ni * 16 + ccol;
          Cout[(size_t)pm * CO + ch] = mx;
          Cmin[(size_t)pm * CO + ch] = mn;
        }
  } else {
    float* Cz = Cout + (size_t)z * M * CO;
#pragma unroll
    for (int mi = 0; mi < 4; mi++) {
      int m = m0 + wrow * 64 + mi * 16 + crow0;
#pragma unroll
      for (int ni = 0; ni < 4; ni++) {
        int nn = n0 + wcol * 64 + ni * 16 + ccol;
        float* cp = Cz + (size_t)m * CO + nn;
#pragma unroll
        for (int jj = 0; jj < 4; jj++) cp[(size_t)jj * CO] = acc[mi][ni][jj];
      }
    }
  }
  if constexpr (SPLIT == 1) {
    const int contrib = kg * 2 + wrow;
#pragma unroll
    for (int ni = 0; ni < 4; ni++) {
      float s = 0.f, q = 0.f;
#pragma unroll
      for (int mi = 0; mi < 4; mi++)
#pragma unroll
        for (int jj = 0; jj < 4; jj++) {
          float v = acc[mi][ni][jj];
          s += v; q += v * v;
        }
      int coll = wcol * 64 + ni * 16 + ccol;
      red[0][coll][contrib] = s;
      red[1][coll][contrib] = q;
    }
    __syncthreads();
    if (t < 128) {
      float s = 0.f, q = 0.f;
#pragma unroll
      for (int j = 0; j < 8; j++) { s += red[0][t][j]; q += red[1][t][j]; }
      size_t c = n0 + t;
      part[(c * gridDim.x + blockIdx.x) * 2 + 0] = s;
      part[(c * gridDim.x + blockIdx.x) * 2 + 1] = q;
    }
  }
}

// ---------------- FC GEMM: packed A (hi/lo) + packed B, zero LDS/barriers --
template<int K, int SPLIT>
__global__ __launch_bounds__(256) void fc_gemm_k(const bf16* __restrict__ Ahp,
                                                 const bf16* __restrict__ Alp,
                                                 const bf16* __restrict__ Bhp,
                                                 float* __restrict__ Cout) {
  constexpr int Kd64 = K / 64;
  constexpr int NCHS = Kd64 / SPLIT;
  constexpr int M = 256, N = 2048;
  const int t = threadIdx.x;
  const int lane = t & 63, w = t >> 6;
  const int m0 = blockIdx.x * 128, n0 = blockIdx.y * 128;
  const int z = blockIdx.z;
  const int wrow = w >> 1, wcol = w & 1;
  const int kg = lane >> 4, l15 = lane & 15;

  size_t ab[4], bb[4];
#pragma unroll
  for (int q = 0; q < 4; q++) {
    int rbA = (m0 >> 4) + wrow * 4 + q;
    ab[q] = (size_t)rbA * Kd64 * 1024 + (size_t)lane * 8;
    int rbB = (n0 >> 4) + wcol * 4 + q;
    bb[q] = (size_t)rbB * Kd64 * 1024 + (size_t)lane * 8;
  }

  f32x4 acc[4][4] = {};
  for (int kc = z * NCHS; kc < (z + 1) * NCHS; ++kc) {
    const size_t bco = (size_t)kc * 1024;
#pragma unroll
    for (int ks = 0; ks < 2; ks++) {
      const size_t soff = bco + ks * 512;
      bf16x8 ah[4], al[4], bh[4];
#pragma unroll
      for (int q = 0; q < 4; q++) {
        ah[q] = *(const bf16x8*)(Ahp + ab[q] + soff);
        al[q] = *(const bf16x8*)(Alp + ab[q] + soff);
        bh[q] = *(const bf16x8*)(Bhp + bb[q] + soff);
      }
#pragma unroll
      for (int mi = 0; mi < 4; mi++)
#pragma unroll
        for (int ni = 0; ni < 4; ni++)
          acc[mi][ni] = __builtin_amdgcn_mfma_f32_16x16x32_bf16(ah[mi], bh[ni], acc[mi][ni], 0, 0, 0);
#pragma unroll
      for (int mi = 0; mi < 4; mi++)
#pragma unroll
        for (int ni = 0; ni < 4; ni++)
          acc[mi][ni] = __builtin_amdgcn_mfma_f32_16x16x32_bf16(al[mi], bh[ni], acc[mi][ni], 0, 0, 0);
    }
  }

  const int crow0 = kg * 4, ccol = l15;
  float* Cz = Cout + (size_t)z * M * N;
#pragma unroll
  for (int mi = 0; mi < 4; mi++) {
    int m = m0 + wrow * 64 + mi * 16 + crow0;
#pragma unroll
    for (int ni = 0; ni < 4; ni++) {
      int nn = n0 + wcol * 64 + ni * 16 + ccol;
      float* cp = Cz + (size_t)m * N + nn;
#pragma unroll
      for (int jj = 0; jj < 4; jj++) cp[(size_t)jj * N] = acc[mi][ni][jj];
    }
  }
}

// ---------------- split-K reduction + BN partials ----------------
template<int M, int CO, int SPLIT, int NS>
__global__ __launch_bounds__(256) void reduce_bn_k(const float* __restrict__ Cp,
                                                   float* __restrict__ Cf,
                                                   float* __restrict__ part) {
  int c = blockIdx.x * 64 + (threadIdx.x & 63);
  int rl = threadIdx.x >> 6;
  constexpr int ROWS = M / NS;
  int r0 = blockIdx.y * ROWS;
  float sum = 0.f, sq = 0.f;
  for (int r = r0 + rl; r < r0 + ROWS; r += 4) {
    float v = 0.f;
#pragma unroll
    for (int s = 0; s < SPLIT; s++) v += Cp[(size_t)s * M * CO + (size_t)r * CO + c];
    Cf[(size_t)r * CO + c] = v;
    sum += v; sq += v * v;
  }
  __shared__ float ls[256], lq[256];
  ls[threadIdx.x] = sum; lq[threadIdx.x] = sq;
  __syncthreads();
  if (threadIdx.x < 64) {
    sum = ls[threadIdx.x] + ls[threadIdx.x + 64] + ls[threadIdx.x + 128] + ls[threadIdx.x + 192];
    sq  = lq[threadIdx.x] + lq[threadIdx.x + 64] + lq[threadIdx.x + 128] + lq[threadIdx.x + 192];
    part[((size_t)c * NS + blockIdx.y) * 2 + 0] = sum;
    part[((size_t)c * NS + blockIdx.y) * 2 + 1] = sq;
  }
}

// ---------------- BN finalize: one block per channel, wave butterfly -------
__global__ __launch_bounds__(64) void bn_finalize(const float* __restrict__ part,
                                                  const float* __restrict__ g,
                                                  const float* __restrict__ b,
                                                  float* __restrict__ scale,
                                                  float* __restrict__ shift,
                                                  int S, float invCount) {
  int c = blockIdx.x;
  int lane = threadIdx.x;
  float sum = 0.f, sq = 0.f;
  for (int s = lane; s < S; s += 64) {
    sum += part[((size_t)c * S + s) * 2 + 0];
    sq  += part[((size_t)c * S + s) * 2 + 1];
  }
#pragma unroll
  for (int o = 32; o > 0; o >>= 1) {
    sum += __shfl_xor(sum, o);
    sq  += __shfl_xor(sq, o);
  }
  if (lane == 0) {
    float m = sum * invCount;
    float var = sq * invCount - m * m;
    float sc = g[c] * rsqrtf(var + 1e-5f);
    scale[c] = sc;
    shift[c] = b[c] - m * sc;
  }
}

// ---------------- fused BN + ReLU + pad (no pool), 8ch/thread --------------
template<int CO, int IH, int IW, int PADO>
__global__ __launch_bounds__(256) void bn_act_pad_k(const float* __restrict__ x,
                                                    const float* __restrict__ scale,
                                                    const float* __restrict__ shift,
                                                    bf16* __restrict__ yh,
                                                    bf16* __restrict__ yl) {
  constexpr int OHP = IH + 2 * PADO, OWP = IW + 2 * PADO;
  constexpr int CO8 = CO / 8;
  int i = blockIdx.x * 256 + threadIdx.x;
  if (i >= 64 * OHP * OWP * CO8) return;
  int c8 = i % CO8; int t = i / CO8; int owp = t % OWP; t /= OWP; int ohp = t % OHP; int n = t / OHP;
  int c0 = c8 * 8;
  int oh = ohp - PADO, ow = owp - PADO;
  bf16x8 hv, lv;
#pragma unroll
  for (int j = 0; j < 8; j++) { hv[j] = (bf16)0.f; lv[j] = (bf16)0.f; }
  if (oh >= 0 && oh < IH && ow >= 0 && ow < IW) {
    float sc[8], sh[8];
    *(f32x4*)(sc)     = *(const f32x4*)(scale + c0);
    *(f32x4*)(sc + 4) = *(const f32x4*)(scale + c0 + 4);
    *(f32x4*)(sh)     = *(const f32x4*)(shift + c0);
    *(f32x4*)(sh + 4) = *(const f32x4*)(shift + c0 + 4);
    const float* p = x + (((size_t)(n * IH) + oh) * IW + ow) * CO + c0;
    float ta[8];
    *(f32x4*)(ta) = *(const f32x4*)(p); *(f32x4*)(ta + 4) = *(const f32x4*)(p + 4);
#pragma unroll
    for (int j = 0; j < 8; j++) {
      float vv = fmaxf(ta[j] * sc[j] + sh[j], 0.f);
      bf16 h, l; split2(vv, h, l);
      hv[j] = h; lv[j] = l;
    }
  }
  size_t o = (size_t)i * 8;
  *(bf16x8*)(yh + o) = hv;
  *(bf16x8*)(yl + o) = lv;
}

// ---------------- BN + ReLU + pad from pooled (max,min), 8ch/thread --------
template<int CO, int PH, int PW, int PADO>
__global__ __launch_bounds__(256) void act_pool_pad_k(const float* __restrict__ wmax,
                                                      const float* __restrict__ wmin,
                                                      const float* __restrict__ scale,
                                                      const float* __restrict__ shift,
                                                      bf16* __restrict__ yh,
                                                      bf16* __restrict__ yl) {
  constexpr int OHP = PH + 2 * PADO, OWP = PW + 2 * PADO;
  constexpr int CO8 = CO / 8;
  int i = blockIdx.x * 256 + threadIdx.x;
  if (i >= 64 * OHP * OWP * CO8) return;
  int c8 = i % CO8; int t = i / CO8; int owp = t % OWP; t /= OWP; int ohp = t % OHP; int n = t / OHP;
  int c0 = c8 * 8;
  int oh = ohp - PADO, ow = owp - PADO;
  bf16x8 hv, lv;
#pragma unroll
  for (int j = 0; j < 8; j++) { hv[j] = (bf16)0.f; lv[j] = (bf16)0.f; }
  if (oh >= 0 && oh < PH && ow >= 0 && ow < PW) {
    float sc[8], sh[8], mx[8], mn[8];
    *(f32x4*)(sc)     = *(const f32x4*)(scale + c0);
    *(f32x4*)(sc + 4) = *(const f32x4*)(scale + c0 + 4);
    *(f32x4*)(sh)     = *(const f32x4*)(shift + c0);
    *(f32x4*)(sh + 4) = *(const f32x4*)(shift + c0 + 4);
    size_t off = (((size_t)(n * PH) + oh) * PW + ow) * CO + c0;
    *(f32x4*)(mx)     = *(const f32x4*)(wmax + off);
    *(f32x4*)(mx + 4) = *(const f32x4*)(wmax + off + 4);
    *(f32x4*)(mn)     = *(const f32x4*)(wmin + off);
    *(f32x4*)(mn + 4) = *(const f32x4*)(wmin + off + 4);
#pragma unroll
    for (int j = 0; j < 8; j++) {
      float sel = (sc[j] >= 0.f) ? mx[j] : mn[j];
      float vv = fmaxf(sel * sc[j] + sh[j], 0.f);
      bf16 h, l; split2(vv, h, l);
      hv[j] = h; lv[j] = l;
    }
  }
  size_t o = (size_t)i * 8;
  *(bf16x8*)(yh + o) = hv;
  *(bf16x8*)(yl + o) = lv;
}

// ---------------- ROI SPP: conv5 fp32 + inline BN -> PACKED S hi/lo --------
__global__ __launch_bounds__(256) void spp_k(const float* __restrict__ feat,
                                             const float* __restrict__ scale,
                                             const float* __restrict__ shift,
                                             const int* __restrict__ roi,
                                             bf16* __restrict__ oh_,
                                             bf16* __restrict__ ol_) {
  int c = blockIdx.x * 256 + threadIdx.x;  // 0..511
  int r = blockIdx.y;                      // 0..255
  const int* rp = roi + r * 5;
  int im = rp[0];
  int c1 = rp[1] >> 3, r1 = rp[2] >> 3, c2 = rp[3] >> 3, r2 = rp[4] >> 3;
  int w = c2 - c1 + 1;
  int lo[6], hi[6];
  int bi = 0;
#pragma unroll
  for (int l = 1; l <= 3; l++)
    for (int k = 0; k < l; k++) {
      lo[bi] = c1 + (k * w) / l;
      hi[bi] = c1 + ((k + 1) * w + l - 1) / l - 1;
      bi++;
    }
  float mx[6];
#pragma unroll
  for (int b = 0; b < 6; b++) mx[b] = -1e30f;
  float sc = scale[c], sh = shift[c];
  const float* fp = feat + (size_t)im * 96 * 512 + c;
  for (int row = r1; row <= r2; row++)
    for (int col = c1; col <= c2; col++) {
      float v = fp[(size_t)(row * 16 + col) * 512] * sc + sh;
#pragma unroll
      for (int b = 0; b < 6; b++)
        if (col >= lo[b] && col <= hi[b]) mx[b] = fmaxf(mx[b], v);
    }
  int idx[6] = {c, 512 + c * 2, 512 + c * 2 + 1, 1536 + c * 3, 1536 + c * 3 + 1, 1536 + c * 3 + 2};
#pragma unroll
  for (int b = 0; b < 6; b++) {
    float v = fmaxf(mx[b], 0.f);
    bf16 h, l; split2(v, h, l);
    size_t o = pk_off(r, idx[b], 48);
    oh_[o] = h;
    ol_[o] = l;
  }
}

// FC1: BN+ReLU, write hi/lo PACKED into CC[:, 0:2048] (K=8192)
__global__ __launch_bounds__(256) void bn1d_apply_cc_k(const float* __restrict__ x,
                                                       const float* __restrict__ scale,
                                                       const float* __restrict__ shift,
                                                       bf16* __restrict__ ch,
                                                       bf16* __restrict__ cl) {
  int i = blockIdx.x * 256 + threadIdx.x;
  if (i >= 256 * 256) return;
  int f8 = i & 255, r = i >> 8;
  int f0 = f8 * 8;
  float xv[8], sc[8], sh[8];
  *(f32x4*)(xv)     = *(const f32x4*)(x + (size_t)r * 2048 + f0);
  *(f32x4*)(xv + 4) = *(const f32x4*)(x + (size_t)r * 2048 + f0 + 4);
  *(f32x4*)(sc)     = *(const f32x4*)(scale + f0);
  *(f32x4*)(sc + 4) = *(const f32x4*)(scale + f0 + 4);
  *(f32x4*)(sh)     = *(const f32x4*)(shift + f0);
  *(f32x4*)(sh + 4) = *(const f32x4*)(shift + f0 + 4);
  bf16x8 hv, lv;
#pragma unroll
  for (int j = 0; j < 8; j++) {
    float v = fmaxf(xv[j] * sc[j] + sh[j], 0.f);
    bf16 h, l; split2(v, h, l);
    hv[j] = h; lv[j] = l;
  }
  size_t o = pk_off(r, f0, 128);
  *(bf16x8*)(ch + o) = hv;
  *(bf16x8*)(cl + o) = lv;
}

// FC2: BN+ReLU, fp32 out, 4 feat/thread
__global__ __launch_bounds__(256) void bn1d_apply_f32_k(const float* __restrict__ x,
                                                        const float* __restrict__ scale,
                                                        const float* __restrict__ shift,
                                                        float* __restrict__ y) {
  int i = blockIdx.x * 256 + threadIdx.x;
  if (i >= 256 * 512) return;
  int f4 = i & 511, r = i >> 9;
  int f0 = f4 * 4;
  f32x4 xv = *(const f32x4*)(x + (size_t)r * 2048 + f0);
  f32x4 sc = *(const f32x4*)(scale + f0);
  f32x4 sh = *(const f32x4*)(shift + f0);
  f32x4 o;
#pragma unroll
  for (int j = 0; j < 4; j++) o[j] = fmaxf(xv[j] * sc[j] + sh[j], 0.f);
  *(f32x4*)(y + (size_t)r * 2048 + f0) = o;
}

// ============================================================================
extern "C" void kernel_launch(void* const* d_in, const int* in_sizes, int n_in,
                              void* d_out, int out_size, void* d_ws, size_t ws_size,
                              hipStream_t stream) {
  (void)in_sizes; (void)n_in; (void)out_size; (void)ws_size;

  const float* x    = (const float*)d_in[0];
  const int*   roi  = (const int*)  d_in[1];
  const float* phoc = (const float*)d_in[2];
  const float* c1w  = (const float*)d_in[3];
  const float* g1   = (const float*)d_in[5];
  const float* b1   = (const float*)d_in[6];
  const float* c2w  = (const float*)d_in[7];
  const float* g2   = (const float*)d_in[9];
  const float* b2   = (const float*)d_in[10];
  const float* c3w  = (const float*)d_in[11];
  const float* g3   = (const float*)d_in[13];
  const float* b3   = (const float*)d_in[14];
  const float* c4w  = (const float*)d_in[15];
  const float* g4   = (const float*)d_in[17];
  const float* b4   = (const float*)d_in[18];
  const float* c5w  = (const float*)d_in[19];
  const float* g5   = (const float*)d_in[21];
  const float* b5   = (const float*)d_in[22];
  const float* f1w  = (const float*)d_in[23];
  const float* g6   = (const float*)d_in[25];
  const float* b6   = (const float*)d_in[26];
  const float* f2w  = (const float*)d_in[27];
  const float* g7   = (const float*)d_in[29];
  const float* b7   = (const float*)d_in[30];
  float* out = (float*)d_out;

  // ---- workspace layout (total ~168.4 MB) ----
  char* ws = (char*)d_ws;
  bf16*  Ahi  = (bf16*) (ws + 0x0200000);   // 16 MB (padded NHWC activations)
  bf16*  Alo  = (bf16*) (ws + 0x1200000);   // 16 MB
  float* C    = (float*)(ws + 0x2200000);   // GEMM out / split slabs / pooled max
  float* CMIN = (float*)(ws + 0x2E00000);   // pooled min
  float* C5F  = (float*)(ws + 0x4600000);   // conv5 final
  bf16*  Wc2h = (bf16*) (ws + 0x5500000);   // conv weights (row-major [CO][K])
  bf16*  Wc3h = (bf16*) (ws + 0x5570000);
  bf16*  Wc4h = (bf16*) (ws + 0x5600000);
  bf16*  Wc5h = (bf16*) (ws + 0x5840000);
  bf16*  Wf1  = (bf16*) (ws + 0x5CC0000);   // packed FC weights
  bf16*  Wf2  = (bf16*) (ws + 0x68C0000);   // packed [2048][8192] = 32 MB
  bf16*  Shi  = (bf16*) (ws + 0x9080000);   // packed spp out [256][3072]
  bf16*  Slo  = (bf16*) (ws + 0x9200000);
  float* G6   = (float*)(ws + 0x9380000);   // fc1 out fp32 [256][2048]
  bf16*  CChi = (bf16*) (ws + 0x9580000);   // packed concat [256][8192] = 4 MB
  bf16*  CClo = (bf16*) (ws + 0x9980000);
  float* G7   = (float*)(ws + 0x9D80000);   // fc2 out fp32 [256][2048]
  float* PART = (float*)(ws + 0x9F80000);   // 768 KB
  float* SC   = (float*)(ws + 0xA040000);
  float* SH   = (float*)(ws + 0xA050000);

  // ---- prep: conv1 stats (768 blocks) || all transforms (30080 blocks) ----
  prep_k<<<30848, 256, 0, stream>>>(x, c1w, PART,
                                    c2w, c3w, c4w, c5w, f1w, f2w, phoc,
                                    Wc2h, Wc3h, Wc4h, Wc5h, Wf1, Wf2,
                                    CChi, CClo);

  // ---- conv1 finalize + apply (stats already done inside prep) ----
  bn_finalize<<<64, 64, 0, stream>>>(PART, g1, b1, SC, SH, 96, 1.f / 393216.f);
  conv1_apply_k<<<dim3(476, 8), 256, 0, stream>>>(x, c1w, SC, SH, Ahi, Alo);

  // ---- conv2 (1-pass, A-resident, fused pool): -> pooled max/min [24576][128]
  conv2_gemm_k<<<768, 256, 0, stream>>>(Ahi, Wc2h, C, CMIN, PART);
  bn_finalize<<<128, 64, 0, stream>>>(PART, g2, b2, SC, SH, 768, 1.f / 98304.f);
  act_pool_pad_k<128, 12, 32, 1><<<1904, 256, 0, stream>>>(C, CMIN, SC, SH, Ahi, Alo);

  // ---- conv3 (2-pass: Ah.Bh + Al.Bh, no pool) ----
  conv_gemm_k<128, 3, 12, 32, 256, true, false, 1, false><<<dim3(192, 2), 256, 0, stream>>>(Ahi, Alo, Wc3h, nullptr, C, nullptr, PART);
  bn_finalize<<<256, 64, 0, stream>>>(PART, g3, b3, SC, SH, 192, 1.f / 24576.f);
  bn_act_pad_k<256, 12, 32, 1><<<3808, 256, 0, stream>>>(C, SC, SH, Ahi, Alo);

  // ---- conv4 (1-pass, fused pool): -> pooled max/min [6144][512] ----
  conv_gemm_k<256, 3, 12, 32, 512, false, false, 1, true><<<dim3(192, 4), 256, 0, stream>>>(Ahi, Alo, Wc4h, nullptr, C, CMIN, PART);
  bn_finalize<<<512, 64, 0, stream>>>(PART, g4, b4, SC, SH, 192, 1.f / 24576.f);
  act_pool_pad_k<512, 6, 16, 1><<<2304, 256, 0, stream>>>(C, CMIN, SC, SH, Ahi, Alo);

  // ---- conv5 (2-pass: Ah.Bh + Al.Bh, split-K=2): slabs in C, final in C5F --
  conv_gemm_k<512, 3, 6, 16, 512, true, false, 2, false><<<dim3(48, 4, 2), 256, 0, stream>>>(Ahi, Alo, Wc5h, nullptr, C, nullptr, nullptr);
  reduce_bn_k<6144, 512, 2, 16><<<dim3(8, 16), 256, 0, stream>>>(C, C5F, PART);
  bn_finalize<<<512, 64, 0, stream>>>(PART, g5, b5, SC, SH, 16, 1.f / 6144.f);

  // ---- SPP (reads fp32 conv5 out + inline BN, packed output) ----
  spp_k<<<dim3(2, 256), 256, 0, stream>>>(C5F, SC, SH, roi, Shi, Slo);

  // ---- FC1 (packed, LDS-free, split-K=16): [256][3072] x [2048][3072] ----
  fc_gemm_k<3072, 16><<<dim3(2, 16, 16), 256, 0, stream>>>(Shi, Slo, Wf1, C);
  reduce_bn_k<256, 2048, 16, 4><<<dim3(32, 4), 256, 0, stream>>>(C, G6, PART);
  bn_finalize<<<2048, 64, 0, stream>>>(PART, g6, b6, SC, SH, 4, 1.f / 256.f);
  bn1d_apply_cc_k<<<256, 256, 0, stream>>>(G6, SC, SH, CChi, CClo);

  // ---- FC2 (packed, LDS-free, split-K=16): [256][8192] x [2048][8192] ----
  fc_gemm_k<8192, 16><<<dim3(2, 16, 16), 256, 0, stream>>>(CChi, CClo, Wf2, C);
  reduce_bn_k<256, 2048, 16, 4><<<dim3(32, 4), 256, 0, stream>>>(C, G7, PART);
  bn_finalize<<<2048, 64, 0, stream>>>(PART, g7, b7, SC, SH, 4, 1.f / 256.f);
  bn1d_apply_f32_k<<<512, 256, 0, stream>>>(G7, SC, SH, out);
}

// Round 21
// 516.078 us; speedup vs baseline: 1.3383x; 1.0383x over previous
//
#include <hip/hip_runtime.h>
#include <hip/hip_bf16.h>

// ============================================================================
// HWNet-SPP forward, MFMA bf16 implicit-GEMM with selective hi/lo precision.
// conv2: A-resident kernel; conv3/4/5: 128x128 LDS-staged template; FC1/FC2:
// packed fragment-order operands, zero LDS/barriers. Pooled layers (conv2,
// conv4) fuse the 2x2 pool into the GEMM epilogue as (window-max, window-min)
// dual fp32 writes. prep does LDS-transposed conv weights AND conv1 BN stats
// (independent, overlapped: VALU-bound stats || BW-bound transforms).
// Pass config (error budget vs absmax threshold 0.098):
//   conv2: Ah*Bh (1-pass)  conv3: +Al*Bh (2-pass)  conv4: 1-pass
//   conv5: Ah*Bh (1-pass, split-K=2)  FC1/FC2: 2-pass (split-K=16)
// BN stats fused into GEMM epilogue / split-K reducer; bn_finalize is
// one-block-per-channel wave butterfly. conv1 reads x with edge clamping.
// SPP reads conv5 fp32 out with inline BN. Biases skipped (BN cancels).
// ============================================================================

typedef __bf16 bf16;
using bf16x4 = __attribute__((ext_vector_type(4))) __bf16;
using bf16x8 = __attribute__((ext_vector_type(8))) __bf16;
using f32x4  = __attribute__((ext_vector_type(4))) float;

__device__ __forceinline__ void split2(float v, bf16& h, bf16& l) {
  bf16 hb = (bf16)v;
  h = hb;
  l = (bf16)(v - (float)hb);
}

__device__ __forceinline__ int iclamp(int v, int lo, int hi) {
  return v < lo ? lo : (v > hi ? hi : v);
}

__device__ __forceinline__ size_t pk_off(int row, int k, int Kd64) {
  return ((size_t)(row >> 4) * Kd64 + (k >> 6)) * 1024 +
         (size_t)(((k >> 5) & 1) * 512 + ((k >> 3) & 3) * 128 + ((row & 15) << 3) + (k & 7));
}

__device__ __forceinline__ void gld_lds16(const bf16* g, void* lds) {
  __builtin_amdgcn_global_load_lds(
      (const __attribute__((address_space(1))) unsigned int*)g,
      (__attribute__((address_space(3))) unsigned int*)lds, 16, 0, 0);
}

// ---------------- fused prep: conv1 BN stats + all weight/input transforms --
// blocks [0,768): conv1 stats (seg = b/8, ch-group = b%8), VALU-bound.
// blocks [768,...): LDS-transposed conv weights, packed FC weights, phoc.
__global__ __launch_bounds__(256) void prep_k(const float* __restrict__ x,
                                              const float* __restrict__ c1w,
                                              float* __restrict__ part,
                                              const float* __restrict__ c2w,
                                              const float* __restrict__ c3w,
                                              const float* __restrict__ c4w,
                                              const float* __restrict__ c5w,
                                              const float* __restrict__ f1w,
                                              const float* __restrict__ f2w,
                                              const float* __restrict__ phoc,
                                              bf16* __restrict__ Wc2h,
                                              bf16* __restrict__ Wc3h,
                                              bf16* __restrict__ Wc4h,
                                              bf16* __restrict__ Wc5h,
                                              bf16* __restrict__ Wf1,
                                              bf16* __restrict__ Wf2,
                                              bf16* __restrict__ cch,
                                              bf16* __restrict__ ccl) {
  __shared__ float buf[4608];
  __shared__ float ls[256], lq[256];
  int b = blockIdx.x;
  int tid = threadIdx.x;
  if (b < 768) {
    // ---- conv1 BN stats (8 ch/group, edge-clamped reads of x) ----
    int seg = b >> 3;          // 0..95
    int co0 = (b & 7) * 8;     // channel group
    float sums[8] = {0.f}, sqs[8] = {0.f};
    for (int r = 0; r < 16; r++) {
      int pix = seg * 4096 + r * 256 + tid;  // 0..393215
      int w = pix & 127; int t = pix >> 7; int h = t % 48; int n = t / 48;
      const float* ip = x + (size_t)n * 48 * 128;
      int ihs[5], iws[5];
#pragma unroll
      for (int k = 0; k < 5; k++) {
        ihs[k] = iclamp(h + k - 2, 0, 47);
        iws[k] = iclamp(w + k - 2, 0, 127);
      }
      float win[25];
#pragma unroll
      for (int kh = 0; kh < 5; kh++)
#pragma unroll
        for (int kw = 0; kw < 5; kw++) win[kh * 5 + kw] = ip[ihs[kh] * 128 + iws[kw]];
#pragma unroll
      for (int j = 0; j < 8; j++) {
        const float* wp = c1w + (size_t)(co0 + j) * 25;
        float acc = 0.f;
#pragma unroll
        for (int k = 0; k < 25; k++) acc += win[k] * wp[k];
        sums[j] += acc; sqs[j] += acc * acc;
      }
    }
    for (int j = 0; j < 8; j++) {
      ls[tid] = sums[j]; lq[tid] = sqs[j];
      __syncthreads();
      for (int o = 128; o > 0; o >>= 1) {
        if (tid < o) { ls[tid] += ls[tid + o]; lq[tid] += lq[tid + o]; }
        __syncthreads();
      }
      if (tid == 0) {
        int c = co0 + j;
        part[((size_t)c * 96 + seg) * 2 + 0] = ls[0];
        part[((size_t)c * 96 + seg) * 2 + 1] = lq[0];
      }
      __syncthreads();
    }
    return;
  }
  b -= 768;
  const float* src = nullptr;
  bf16 *dsth = nullptr;
  int CI = 0, KK = 0, co = 0;
  if (b < 128)        { src = c2w; dsth = Wc2h; CI = 64;  KK = 25; co = b; }
  else if (b < 384)   { src = c3w; dsth = Wc3h; CI = 128; KK = 9;  co = b - 128; }
  else if (b < 896)   { src = c4w; dsth = Wc4h; CI = 256; KK = 9;  co = b - 384; }
  else if (b < 1408)  { src = c5w; dsth = Wc5h; CI = 512; KK = 9; co = b - 896; }
  if (src) {
    const int n = CI * KK;
    const float* sp = src + (size_t)co * n;
    for (int i = tid; i < n; i += 256) buf[i] = sp[i];
    __syncthreads();
    bf16* oh = dsth + (size_t)co * n;
    for (int o = tid; o < n; o += 256) {
      int ci = o & (CI - 1), kk = o / CI;
      float v = buf[ci * KK + kk];
      bf16 h, l; split2(v, h, l);
      oh[o] = h;
    }
    return;
  }
  b -= 1408;
  if (b < 6144) {  // f1w [2048][3072] -> packed hi, 4 elems/thread
    int i = b * 256 + tid;
    int k0 = (i % 768) * 4, n = i / 768;
    const float4 v = *(const float4*)(f1w + (size_t)n * 3072 + k0);
    bf16x4 o = { (bf16)v.x, (bf16)v.y, (bf16)v.z, (bf16)v.w };
    *(bf16x4*)(Wf1 + pk_off(n, k0, 48)) = o;
    return;
  }
  b -= 6144;
  if (b < 16384) {  // f2w [2048][7901] -> packed hi [2048][8192], 4/thread
    int i = b * 256 + tid;
    int k0 = (i & 2047) * 4, n = i >> 11;
    const float* xp = f2w + (size_t)n * 7901 + k0;
    bf16x4 o;
#pragma unroll
    for (int j = 0; j < 4; j++) o[j] = (bf16)((k0 + j < 7901) ? xp[j] : 0.f);
    *(bf16x4*)(Wf2 + pk_off(n, k0, 128)) = o;
    return;
  }
  b -= 16384;
  {  // phoc -> packed CC cols [2048,8192) hi/lo
    int i = b * 256 + tid;
    if (i >= 256 * 6144) return;
    int k = i % 6144, r = i / 6144;
    int col = 2048 + k;
    float v = (col < 7901) ? phoc[(size_t)r * 5853 + (col - 2048)] : 0.f;
    bf16 h, l; split2(v, h, l);
    size_t o = pk_off(r, col, 128);
    cch[o] = h;
    ccl[o] = l;
  }
}

// ---------------- conv1 pass 2: conv+BN+ReLU+pool+pad (8 ch/group) ---------
__global__ __launch_bounds__(256) void conv1_apply_k(const float* __restrict__ x,
                                                     const float* __restrict__ wt,
                                                     const float* __restrict__ scale,
                                                     const float* __restrict__ shift,
                                                     bf16* __restrict__ yh,
                                                     bf16* __restrict__ yl) {
  int i = blockIdx.x * 256 + threadIdx.x;  // padded pixel slots
  if (i >= 64 * 28 * 68) return;
  int owp = i % 68; int t = i / 68; int ohp = t % 28; int n = t / 28;
  int co0 = blockIdx.y * 8;
  int oh = ohp - 2, ow = owp - 2;
  bf16x8 hv, lv;
#pragma unroll
  for (int j = 0; j < 8; j++) { hv[j] = (bf16)0.f; lv[j] = (bf16)0.f; }
  if (oh >= 0 && oh < 24 && ow >= 0 && ow < 64) {
    const float* ip = x + (size_t)n * 48 * 128;
    int shr[6], swc[6];
#pragma unroll
    for (int k = 0; k < 6; k++) {
      shr[k] = iclamp(2 * oh + k - 2, 0, 47);
      swc[k] = iclamp(2 * ow + k - 2, 0, 127);
    }
    float win[36];
#pragma unroll
    for (int r = 0; r < 6; r++)
#pragma unroll
      for (int c = 0; c < 6; c++) win[r * 6 + c] = ip[shr[r] * 128 + swc[c]];
#pragma unroll
    for (int j = 0; j < 8; j++) {
      const float* wp = wt + (size_t)(co0 + j) * 25;
      float sc = scale[co0 + j], sh = shift[co0 + j];
      float m = -1e30f;
#pragma unroll
      for (int dy = 0; dy < 2; dy++)
#pragma unroll
        for (int dx = 0; dx < 2; dx++) {
          float acc = 0.f;
#pragma unroll
          for (int kh = 0; kh < 5; kh++)
#pragma unroll
            for (int kw = 0; kw < 5; kw++)
              acc += win[(kh + dy) * 6 + kw + dx] * wp[kh * 5 + kw];
          m = fmaxf(m, acc * sc + sh);
        }
      float v = fmaxf(m, 0.f);
      bf16 h, l; split2(v, h, l);
      hv[j] = h; lv[j] = l;
    }
  }
  size_t o = (size_t)i * 64 + co0;
  *(bf16x8*)(yh + o) = hv;
  *(bf16x8*)(yl + o) = lv;
}

// ---------------- conv2 specialized: A-resident + fused pool (max/min) -----
__global__ __launch_bounds__(256) void conv2_gemm_k(const bf16* __restrict__ Ahi,
                                                    const bf16* __restrict__ Bhi,
                                                    float* __restrict__ Wmax,
                                                    float* __restrict__ Wmin,
                                                    float* __restrict__ part) {
  __shared__ bf16 Ash[416 * 64];      // 52 KB (reused as exchange post-loop)
  __shared__ bf16 Bsh[128 * 64];      // 16 KB
  __shared__ float red[2][128][8];    // 8 KB
  const int t = threadIdx.x;
  const int lane = t & 63, w = t >> 6;
  const int m0 = blockIdx.x * 128;
  const int img = m0 / 1536;
  const int oh0 = (m0 % 1536) >> 6;   // even
  const size_t abase = ((size_t)(img * 28 + oh0) * 68) * 64;

#pragma unroll
  for (int i = 0; i < 13; i++) {
    int f = i * 256 + t;
    int p = f >> 3; if (p > 407) p = 407;
    int s = f & 7;
    int ss = s ^ (p & 7);
    gld_lds16(Ahi + abase + (size_t)p * 64 + ss * 8,
              (char*)Ash + (size_t)(i * 256 + w * 64) * 16);
  }

  size_t boff[4];
#pragma unroll
  for (int i = 0; i < 4; i++) {
    int f = (i * 4 + w) * 64 + lane;
    int row = f >> 3, slot = f & 7;
    int ss = slot ^ (row & 7);
    boff[i] = (size_t)row * 1600 + ss * 8;
  }

  const int wrow = w >> 1, wcol = w & 1;
  const int kg = lane >> 4, l15 = lane & 15;
  int pixb[4];
#pragma unroll
  for (int q = 0; q < 4; q++) pixb[q] = wrow * 68 + q * 16 + l15;
  int brb[4], bmk[4];
#pragma unroll
  for (int q = 0; q < 4; q++) {
    int rb = wcol * 64 + q * 16 + l15;
    brb[q] = rb * 128; bmk[q] = rb & 7;
  }
  const char* Ashb = (const char*)Ash;
  const char* Bshb = (const char*)Bsh;

  f32x4 acc[4][4] = {};
  for (int kc = 0; kc < 25; ++kc) {
    const int kh = kc / 5, kw = kc % 5;
    const int kofs = kh * 68 + kw;
    const int k0 = kc * 64;
#pragma unroll
    for (int i = 0; i < 4; i++)
      gld_lds16(Bhi + boff[i] + k0, (char*)Bsh + (i * 4 + w) * 1024);
    __syncthreads();
#pragma unroll
    for (int ks = 0; ks < 2; ks++) {
      const int slot = ks * 4 + kg;
      bf16x8 ah[4], bh[4];
#pragma unroll
      for (int q = 0; q < 4; q++) {
        int pix = pixb[q] + kofs;
        ah[q] = *(const bf16x8*)(Ashb + pix * 128 + ((slot ^ (pix & 7)) << 4));
        bh[q] = *(const bf16x8*)(Bshb + brb[q] + ((slot ^ bmk[q]) << 4));
      }
#pragma unroll
      for (int mi = 0; mi < 4; mi++)
#pragma unroll
        for (int ni = 0; ni < 4; ni++)
          acc[mi][ni] = __builtin_amdgcn_mfma_f32_16x16x32_bf16(ah[mi], bh[ni], acc[mi][ni], 0, 0, 0);
    }
    __syncthreads();  // after this, Ash/Bsh free for reuse
  }

  const int ccol = l15;
  float hmx[4][4][2], hmn[4][4][2];
#pragma unroll
  for (int mi = 0; mi < 4; mi++)
#pragma unroll
    for (int ni = 0; ni < 4; ni++)
#pragma unroll
      for (int jp = 0; jp < 2; jp++) {
        float a = acc[mi][ni][2 * jp], b = acc[mi][ni][2 * jp + 1];
        hmx[mi][ni][jp] = fmaxf(a, b);
        hmn[mi][ni][jp] = fminf(a, b);
      }
  const int contrib = kg * 2 + wrow;
#pragma unroll
  for (int ni = 0; ni < 4; ni++) {
    float s = 0.f, q = 0.f;
#pragma unroll
    for (int mi = 0; mi < 4; mi++)
#pragma unroll
      for (int jj = 0; jj < 4; jj++) {
        float v = acc[mi][ni][jj];
        s += v; q += v * v;
      }
    int coll = wcol * 64 + ni * 16 + ccol;
    red[0][coll][contrib] = s;
    red[1][coll][contrib] = q;
  }
  float* exch = (float*)Ash;
  if (wrow == 1) {
    float* ep = exch + (size_t)(wcol * 64 + lane) * 64;
#pragma unroll
    for (int mi = 0; mi < 4; mi++)
#pragma unroll
      for (int ni = 0; ni < 4; ni++)
#pragma unroll
        for (int jp = 0; jp < 2; jp++) {
          int s = (mi * 8 + ni * 2 + jp) * 2;
          ep[s + 0] = hmx[mi][ni][jp];
          ep[s + 1] = hmn[mi][ni][jp];
        }
  }
  __syncthreads();
  if (wrow == 0) {
    const float* ep = exch + (size_t)(wcol * 64 + lane) * 64;
    const int pmb = img * 384 + (oh0 >> 1) * 32;
#pragma unroll
    for (int mi = 0; mi < 4; mi++)
#pragma unroll
      for (int ni = 0; ni < 4; ni++)
#pragma unroll
        for (int jp = 0; jp < 2; jp++) {
          int s = (mi * 8 + ni * 2 + jp) * 2;
          float mx = fmaxf(hmx[mi][ni][jp], ep[s + 0]);
          float mn = fminf(hmn[mi][ni][jp], ep[s + 1]);
          int pm = pmb + mi * 8 + kg * 2 + jp;
          int ch = wcol * 64 + ni * 16 + ccol;
          Wmax[(size_t)pm * 128 + ch] = mx;
          Wmin[(size_t)pm * 128 + ch] = mn;
        }
  }
  if (t < 128) {
    float s = 0.f, q = 0.f;
#pragma unroll
    for (int j = 0; j < 8; j++) { s += red[0][t][j]; q += red[1][t][j]; }
    size_t c = t;
    part[(c * gridDim.x + blockIdx.x) * 2 + 0] = s;
    part[(c * gridDim.x + blockIdx.x) * 2 + 1] = q;
  }
}

// ---------------- MFMA implicit-GEMM, LDS-staged, optional split-K/pool ----
template<int CI, int KS, int OH, int OW, int CO, bool ALO, bool BLO, int SPLIT, bool FUSEPOOL>
__global__ __launch_bounds__(256) void conv_gemm_k(const bf16* __restrict__ Ahi,
                                                   const bf16* __restrict__ Alo,
                                                   const bf16* __restrict__ Bhi,
                                                   const bf16* __restrict__ Blo,
                                                   float* __restrict__ Cout,
                                                   float* __restrict__ Cmin,
                                                   float* __restrict__ part) {
  static_assert(CI % 64 == 0, "chunk must not straddle ci segments");
  static_assert(!FUSEPOOL || (OW == 32 && SPLIT == 1), "fusepool needs OW=32");
  constexpr int K = KS * KS * CI;
  constexpr int IWP = OW + KS - 1;
  constexpr int NCH = K / 64;
  static_assert(NCH % SPLIT == 0, "split must divide chunk count");
  constexpr int NCHS = NCH / SPLIT;
  constexpr int M = 64 * OH * OW;
  __shared__ bf16 Ash[128 * 64];
  __shared__ bf16 Asl[ALO ? 128 * 64 : 64];
  __shared__ bf16 Bsh[128 * 64];
  __shared__ bf16 Bsl[BLO ? 128 * 64 : 64];
  __shared__ float red[2][128][8];
  const int t = threadIdx.x;
  const int lane = t & 63, w = t >> 6;
  const int m0 = blockIdx.x * 128, n0 = blockIdx.y * 128;
  const int z = (SPLIT > 1) ? blockIdx.z : 0;

  int apix[4]; size_t boff[4];
#pragma unroll
  for (int i = 0; i < 4; i++) {
    int f = (i * 4 + w) * 64 + lane;
    int row = f >> 3, slot = f & 7;
    int ss = slot ^ (row & 7);
    int m = m0 + row;
    int n = m / (OH * OW); int rem = m % (OH * OW);
    int oh = rem / OW, ow_ = rem % OW;
    apix[i] = ((n * (OH + KS - 1) + oh) * IWP + ow_) * CI + ss * 8;
    boff[i] = (size_t)(n0 + row) * K + ss * 8;
  }

  const int wrow = w >> 1, wcol = w & 1;
  const int kg = lane >> 4, l15 = lane & 15;
  int arb[4], amk[4], brb[4], bmk[4];
#pragma unroll
  for (int q = 0; q < 4; q++) {
    int ra = wrow * 64 + q * 16 + l15;
    arb[q] = ra * 128; amk[q] = ra & 7;
    int rb = wcol * 64 + q * 16 + l15;
    brb[q] = rb * 128; bmk[q] = rb & 7;
  }
  const char* Ashb = (const char*)Ash;
  const char* Aslb = (const char*)Asl;
  const char* Bshb = (const char*)Bsh;
  const char* Bslb = (const char*)Bsl;

  f32x4 acc[4][4] = {};
  for (int kc = z * NCHS; kc < (z + 1) * NCHS; ++kc) {
    const int k0 = kc * 64;
    const int seg = k0 / CI;
    const int ci0 = k0 % CI;
    const int kh = seg / KS, kw = seg % KS;
    const int aoff = (kh * IWP + kw) * CI + ci0;   // wave-uniform
#pragma unroll
    for (int i = 0; i < 4; i++) {
      gld_lds16(Ahi + (size_t)apix[i] + aoff, (char*)Ash + (i * 4 + w) * 1024);
      if (ALO)
        gld_lds16(Alo + (size_t)apix[i] + aoff, (char*)Asl + (i * 4 + w) * 1024);
      gld_lds16(Bhi + boff[i] + k0,   (char*)Bsh + (i * 4 + w) * 1024);
      if (BLO)
        gld_lds16(Blo + boff[i] + k0, (char*)Bsl + (i * 4 + w) * 1024);
    }
    __syncthreads();
#pragma unroll
    for (int ks = 0; ks < 2; ks++) {
      const int slot = ks * 4 + kg;
      bf16x8 ah[4], bh[4];
#pragma unroll
      for (int q = 0; q < 4; q++) {
        ah[q] = *(const bf16x8*)(Ashb + arb[q] + ((slot ^ amk[q]) << 4));
        bh[q] = *(const bf16x8*)(Bshb + brb[q] + ((slot ^ bmk[q]) << 4));
      }
#pragma unroll
      for (int mi = 0; mi < 4; mi++)
#pragma unroll
        for (int ni = 0; ni < 4; ni++)
          acc[mi][ni] = __builtin_amdgcn_mfma_f32_16x16x32_bf16(ah[mi], bh[ni], acc[mi][ni], 0, 0, 0);
      if (ALO) {
        bf16x8 al[4];
#pragma unroll
        for (int q = 0; q < 4; q++)
          al[q] = *(const bf16x8*)(Aslb + arb[q] + ((slot ^ amk[q]) << 4));
#pragma unroll
        for (int mi = 0; mi < 4; mi++)
#pragma unroll
          for (int ni = 0; ni < 4; ni++)
            acc[mi][ni] = __builtin_amdgcn_mfma_f32_16x16x32_bf16(al[mi], bh[ni], acc[mi][ni], 0, 0, 0);
      }
      if (BLO) {
        bf16x8 bl[4];
#pragma unroll
        for (int q = 0; q < 4; q++)
          bl[q] = *(const bf16x8*)(Bslb + brb[q] + ((slot ^ bmk[q]) << 4));
#pragma unroll
        for (int mi = 0; mi < 4; mi++)
#pragma unroll
          for (int ni = 0; ni < 4; ni++)
            acc[mi][ni] = __builtin_amdgcn_mfma_f32_16x16x32_bf16(ah[mi], bl[ni], acc[mi][ni], 0, 0, 0);
      }
    }
    __syncthreads();
  }

  const int crow0 = kg * 4, ccol = l15;
  if constexpr (FUSEPOOL) {
    const int n_img = m0 / (OH * OW);
    const int oh0 = (m0 % (OH * OW)) / OW;          // multiple of 4
    const int pmb = n_img * (OH / 2) * (OW / 2) + (oh0 / 2 + wrow) * (OW / 2);
#pragma unroll
    for (int mi = 0; mi < 2; mi++)
#pragma unroll
      for (int ni = 0; ni < 4; ni++)
#pragma unroll
        for (int jp = 0; jp < 2; jp++) {
          float a0 = acc[mi][ni][2 * jp],     a1 = acc[mi][ni][2 * jp + 1];
          float b0 = acc[mi + 2][ni][2 * jp], b1 = acc[mi + 2][ni][2 * jp + 1];
          float mx = fmaxf(fmaxf(a0, a1), fmaxf(b0, b1));
          float mn = fminf(fminf(a0, a1), fminf(b0, b1));
          int pm = pmb + mi * 8 + kg * 2 + jp;
          int ch = n0 + wcol * 64 + ni * 16 + ccol;
          Cout[(size_t)pm * CO + ch] = mx;
          Cmin[(size_t)pm * CO + ch] = mn;
        }
  } else {
    float* Cz = Cout + (size_t)z * M * CO;
#pragma unroll
    for (int mi = 0; mi < 4; mi++) {
      int m = m0 + wrow * 64 + mi * 16 + crow0;
#pragma unroll
      for (int ni = 0; ni < 4; ni++) {
        int nn = n0 + wcol * 64 + ni * 16 + ccol;
        float* cp = Cz + (size_t)m * CO + nn;
#pragma unroll
        for (int jj = 0; jj < 4; jj++) cp[(size_t)jj * CO] = acc[mi][ni][jj];
      }
    }
  }
  if constexpr (SPLIT == 1) {
    const int contrib = kg * 2 + wrow;
#pragma unroll
    for (int ni = 0; ni < 4; ni++) {
      float s = 0.f, q = 0.f;
#pragma unroll
      for (int mi = 0; mi < 4; mi++)
#pragma unroll
        for (int jj = 0; jj < 4; jj++) {
          float v = acc[mi][ni][jj];
          s += v; q += v * v;
        }
      int coll = wcol * 64 + ni * 16 + ccol;
      red[0][coll][contrib] = s;
      red[1][coll][contrib] = q;
    }
    __syncthreads();
    if (t < 128) {
      float s = 0.f, q = 0.f;
#pragma unroll
      for (int j = 0; j < 8; j++) { s += red[0][t][j]; q += red[1][t][j]; }
      size_t c = n0 + t;
      part[(c * gridDim.x + blockIdx.x) * 2 + 0] = s;
      part[(c * gridDim.x + blockIdx.x) * 2 + 1] = q;
    }
  }
}

// ---------------- FC GEMM: packed A (hi/lo) + packed B, zero LDS/barriers --
template<int K, int SPLIT>
__global__ __launch_bounds__(256) void fc_gemm_k(const bf16* __restrict__ Ahp,
                                                 const bf16* __restrict__ Alp,
                                                 const bf16* __restrict__ Bhp,
                                                 float* __restrict__ Cout) {
  constexpr int Kd64 = K / 64;
  constexpr int NCHS = Kd64 / SPLIT;
  constexpr int M = 256, N = 2048;
  const int t = threadIdx.x;
  const int lane = t & 63, w = t >> 6;
  const int m0 = blockIdx.x * 128, n0 = blockIdx.y * 128;
  const int z = blockIdx.z;
  const int wrow = w >> 1, wcol = w & 1;
  const int kg = lane >> 4, l15 = lane & 15;

  size_t ab[4], bb[4];
#pragma unroll
  for (int q = 0; q < 4; q++) {
    int rbA = (m0 >> 4) + wrow * 4 + q;
    ab[q] = (size_t)rbA * Kd64 * 1024 + (size_t)lane * 8;
    int rbB = (n0 >> 4) + wcol * 4 + q;
    bb[q] = (size_t)rbB * Kd64 * 1024 + (size_t)lane * 8;
  }

  f32x4 acc[4][4] = {};
  for (int kc = z * NCHS; kc < (z + 1) * NCHS; ++kc) {
    const size_t bco = (size_t)kc * 1024;
#pragma unroll
    for (int ks = 0; ks < 2; ks++) {
      const size_t soff = bco + ks * 512;
      bf16x8 ah[4], al[4], bh[4];
#pragma unroll
      for (int q = 0; q < 4; q++) {
        ah[q] = *(const bf16x8*)(Ahp + ab[q] + soff);
        al[q] = *(const bf16x8*)(Alp + ab[q] + soff);
        bh[q] = *(const bf16x8*)(Bhp + bb[q] + soff);
      }
#pragma unroll
      for (int mi = 0; mi < 4; mi++)
#pragma unroll
        for (int ni = 0; ni < 4; ni++)
          acc[mi][ni] = __builtin_amdgcn_mfma_f32_16x16x32_bf16(ah[mi], bh[ni], acc[mi][ni], 0, 0, 0);
#pragma unroll
      for (int mi = 0; mi < 4; mi++)
#pragma unroll
        for (int ni = 0; ni < 4; ni++)
          acc[mi][ni] = __builtin_amdgcn_mfma_f32_16x16x32_bf16(al[mi], bh[ni], acc[mi][ni], 0, 0, 0);
    }
  }

  const int crow0 = kg * 4, ccol = l15;
  float* Cz = Cout + (size_t)z * M * N;
#pragma unroll
  for (int mi = 0; mi < 4; mi++) {
    int m = m0 + wrow * 64 + mi * 16 + crow0;
#pragma unroll
    for (int ni = 0; ni < 4; ni++) {
      int nn = n0 + wcol * 64 + ni * 16 + ccol;
      float* cp = Cz + (size_t)m * N + nn;
#pragma unroll
      for (int jj = 0; jj < 4; jj++) cp[(size_t)jj * N] = acc[mi][ni][jj];
    }
  }
}

// ---------------- split-K reduction + BN partials ----------------
template<int M, int CO, int SPLIT, int NS>
__global__ __launch_bounds__(256) void reduce_bn_k(const float* __restrict__ Cp,
                                                   float* __restrict__ Cf,
                                                   float* __restrict__ part) {
  int c = blockIdx.x * 64 + (threadIdx.x & 63);
  int rl = threadIdx.x >> 6;
  constexpr int ROWS = M / NS;
  int r0 = blockIdx.y * ROWS;
  float sum = 0.f, sq = 0.f;
  for (int r = r0 + rl; r < r0 + ROWS; r += 4) {
    float v = 0.f;
#pragma unroll
    for (int s = 0; s < SPLIT; s++) v += Cp[(size_t)s * M * CO + (size_t)r * CO + c];
    Cf[(size_t)r * CO + c] = v;
    sum += v; sq += v * v;
  }
  __shared__ float ls[256], lq[256];
  ls[threadIdx.x] = sum; lq[threadIdx.x] = sq;
  __syncthreads();
  if (threadIdx.x < 64) {
    sum = ls[threadIdx.x] + ls[threadIdx.x + 64] + ls[threadIdx.x + 128] + ls[threadIdx.x + 192];
    sq  = lq[threadIdx.x] + lq[threadIdx.x + 64] + lq[threadIdx.x + 128] + lq[threadIdx.x + 192];
    part[((size_t)c * NS + blockIdx.y) * 2 + 0] = sum;
    part[((size_t)c * NS + blockIdx.y) * 2 + 1] = sq;
  }
}

// ---------------- BN finalize: one block per channel, wave butterfly -------
__global__ __launch_bounds__(64) void bn_finalize(const float* __restrict__ part,
                                                  const float* __restrict__ g,
                                                  const float* __restrict__ b,
                                                  float* __restrict__ scale,
                                                  float* __restrict__ shift,
                                                  int S, float invCount) {
  int c = blockIdx.x;
  int lane = threadIdx.x;
  float sum = 0.f, sq = 0.f;
  for (int s = lane; s < S; s += 64) {
    sum += part[((size_t)c * S + s) * 2 + 0];
    sq  += part[((size_t)c * S + s) * 2 + 1];
  }
#pragma unroll
  for (int o = 32; o > 0; o >>= 1) {
    sum += __shfl_xor(sum, o);
    sq  += __shfl_xor(sq, o);
  }
  if (lane == 0) {
    float m = sum * invCount;
    float var = sq * invCount - m * m;
    float sc = g[c] * rsqrtf(var + 1e-5f);
    scale[c] = sc;
    shift[c] = b[c] - m * sc;
  }
}

// ---------------- fused BN + ReLU + pad (no pool), 8ch/thread --------------
template<int CO, int IH, int IW, int PADO>
__global__ __launch_bounds__(256) void bn_act_pad_k(const float* __restrict__ x,
                                                    const float* __restrict__ scale,
                                                    const float* __restrict__ shift,
                                                    bf16* __restrict__ yh,
                                                    bf16* __restrict__ yl) {
  constexpr int OHP = IH + 2 * PADO, OWP = IW + 2 * PADO;
  constexpr int CO8 = CO / 8;
  int i = blockIdx.x * 256 + threadIdx.x;
  if (i >= 64 * OHP * OWP * CO8) return;
  int c8 = i % CO8; int t = i / CO8; int owp = t % OWP; t /= OWP; int ohp = t % OHP; int n = t / OHP;
  int c0 = c8 * 8;
  int oh = ohp - PADO, ow = owp - PADO;
  bf16x8 hv, lv;
#pragma unroll
  for (int j = 0; j < 8; j++) { hv[j] = (bf16)0.f; lv[j] = (bf16)0.f; }
  if (oh >= 0 && oh < IH && ow >= 0 && ow < IW) {
    float sc[8], sh[8];
    *(f32x4*)(sc)     = *(const f32x4*)(scale + c0);
    *(f32x4*)(sc + 4) = *(const f32x4*)(scale + c0 + 4);
    *(f32x4*)(sh)     = *(const f32x4*)(shift + c0);
    *(f32x4*)(sh + 4) = *(const f32x4*)(shift + c0 + 4);
    const float* p = x + (((size_t)(n * IH) + oh) * IW + ow) * CO + c0;
    float ta[8];
    *(f32x4*)(ta) = *(const f32x4*)(p); *(f32x4*)(ta + 4) = *(const f32x4*)(p + 4);
#pragma unroll
    for (int j = 0; j < 8; j++) {
      float vv = fmaxf(ta[j] * sc[j] + sh[j], 0.f);
      bf16 h, l; split2(vv, h, l);
      hv[j] = h; lv[j] = l;
    }
  }
  size_t o = (size_t)i * 8;
  *(bf16x8*)(yh + o) = hv;
  *(bf16x8*)(yl + o) = lv;
}

// ---------------- BN + ReLU + pad from pooled (max,min), 8ch/thread --------
template<int CO, int PH, int PW, int PADO>
__global__ __launch_bounds__(256) void act_pool_pad_k(const float* __restrict__ wmax,
                                                      const float* __restrict__ wmin,
                                                      const float* __restrict__ scale,
                                                      const float* __restrict__ shift,
                                                      bf16* __restrict__ yh,
                                                      bf16* __restrict__ yl) {
  constexpr int OHP = PH + 2 * PADO, OWP = PW + 2 * PADO;
  constexpr int CO8 = CO / 8;
  int i = blockIdx.x * 256 + threadIdx.x;
  if (i >= 64 * OHP * OWP * CO8) return;
  int c8 = i % CO8; int t = i / CO8; int owp = t % OWP; t /= OWP; int ohp = t % OHP; int n = t / OHP;
  int c0 = c8 * 8;
  int oh = ohp - PADO, ow = owp - PADO;
  bf16x8 hv, lv;
#pragma unroll
  for (int j = 0; j < 8; j++) { hv[j] = (bf16)0.f; lv[j] = (bf16)0.f; }
  if (oh >= 0 && oh < PH && ow >= 0 && ow < PW) {
    float sc[8], sh[8], mx[8], mn[8];
    *(f32x4*)(sc)     = *(const f32x4*)(scale + c0);
    *(f32x4*)(sc + 4) = *(const f32x4*)(scale + c0 + 4);
    *(f32x4*)(sh)     = *(const f32x4*)(shift + c0);
    *(f32x4*)(sh + 4) = *(const f32x4*)(shift + c0 + 4);
    size_t off = (((size_t)(n * PH) + oh) * PW + ow) * CO + c0;
    *(f32x4*)(mx)     = *(const f32x4*)(wmax + off);
    *(f32x4*)(mx + 4) = *(const f32x4*)(wmax + off + 4);
    *(f32x4*)(mn)     = *(const f32x4*)(wmin + off);
    *(f32x4*)(mn + 4) = *(const f32x4*)(wmin + off + 4);
#pragma unroll
    for (int j = 0; j < 8; j++) {
      float sel = (sc[j] >= 0.f) ? mx[j] : mn[j];
      float vv = fmaxf(sel * sc[j] + sh[j], 0.f);
      bf16 h, l; split2(vv, h, l);
      hv[j] = h; lv[j] = l;
    }
  }
  size_t o = (size_t)i * 8;
  *(bf16x8*)(yh + o) = hv;
  *(bf16x8*)(yl + o) = lv;
}

// ---------------- ROI SPP: conv5 fp32 + inline BN -> PACKED S hi/lo --------
__global__ __launch_bounds__(256) void spp_k(const float* __restrict__ feat,
                                             const float* __restrict__ scale,
                                             const float* __restrict__ shift,
                                             const int* __restrict__ roi,
                                             bf16* __restrict__ oh_,
                                             bf16* __restrict__ ol_) {
  int c = blockIdx.x * 256 + threadIdx.x;  // 0..511
  int r = blockIdx.y;                      // 0..255
  const int* rp = roi + r * 5;
  int im = rp[0];
  int c1 = rp[1] >> 3, r1 = rp[2] >> 3, c2 = rp[3] >> 3, r2 = rp[4] >> 3;
  int w = c2 - c1 + 1;
  int lo[6], hi[6];
  int bi = 0;
#pragma unroll
  for (int l = 1; l <= 3; l++)
    for (int k = 0; k < l; k++) {
      lo[bi] = c1 + (k * w) / l;
      hi[bi] = c1 + ((k + 1) * w + l - 1) / l - 1;
      bi++;
    }
  float mx[6];
#pragma unroll
  for (int b = 0; b < 6; b++) mx[b] = -1e30f;
  float sc = scale[c], sh = shift[c];
  const float* fp = feat + (size_t)im * 96 * 512 + c;
  for (int row = r1; row <= r2; row++)
    for (int col = c1; col <= c2; col++) {
      float v = fp[(size_t)(row * 16 + col) * 512] * sc + sh;
#pragma unroll
      for (int b = 0; b < 6; b++)
        if (col >= lo[b] && col <= hi[b]) mx[b] = fmaxf(mx[b], v);
    }
  int idx[6] = {c, 512 + c * 2, 512 + c * 2 + 1, 1536 + c * 3, 1536 + c * 3 + 1, 1536 + c * 3 + 2};
#pragma unroll
  for (int b = 0; b < 6; b++) {
    float v = fmaxf(mx[b], 0.f);
    bf16 h, l; split2(v, h, l);
    size_t o = pk_off(r, idx[b], 48);
    oh_[o] = h;
    ol_[o] = l;
  }
}

// FC1: BN+ReLU, write hi/lo PACKED into CC[:, 0:2048] (K=8192)
__global__ __launch_bounds__(256) void bn1d_apply_cc_k(const float* __restrict__ x,
                                                       const float* __restrict__ scale,
                                                       const float* __restrict__ shift,
                                                       bf16* __restrict__ ch,
                                                       bf16* __restrict__ cl) {
  int i = blockIdx.x * 256 + threadIdx.x;
  if (i >= 256 * 256) return;
  int f8 = i & 255, r = i >> 8;
  int f0 = f8 * 8;
  float xv[8], sc[8], sh[8];
  *(f32x4*)(xv)     = *(const f32x4*)(x + (size_t)r * 2048 + f0);
  *(f32x4*)(xv + 4) = *(const f32x4*)(x + (size_t)r * 2048 + f0 + 4);
  *(f32x4*)(sc)     = *(const f32x4*)(scale + f0);
  *(f32x4*)(sc + 4) = *(const f32x4*)(scale + f0 + 4);
  *(f32x4*)(sh)     = *(const f32x4*)(shift + f0);
  *(f32x4*)(sh + 4) = *(const f32x4*)(shift + f0 + 4);
  bf16x8 hv, lv;
#pragma unroll
  for (int j = 0; j < 8; j++) {
    float v = fmaxf(xv[j] * sc[j] + sh[j], 0.f);
    bf16 h, l; split2(v, h, l);
    hv[j] = h; lv[j] = l;
  }
  size_t o = pk_off(r, f0, 128);
  *(bf16x8*)(ch + o) = hv;
  *(bf16x8*)(cl + o) = lv;
}

// FC2: BN+ReLU, fp32 out, 4 feat/thread
__global__ __launch_bounds__(256) void bn1d_apply_f32_k(const float* __restrict__ x,
                                                        const float* __restrict__ scale,
                                                        const float* __restrict__ shift,
                                                        float* __restrict__ y) {
  int i = blockIdx.x * 256 + threadIdx.x;
  if (i >= 256 * 512) return;
  int f4 = i & 511, r = i >> 9;
  int f0 = f4 * 4;
  f32x4 xv = *(const f32x4*)(x + (size_t)r * 2048 + f0);
  f32x4 sc = *(const f32x4*)(scale + f0);
  f32x4 sh = *(const f32x4*)(shift + f0);
  f32x4 o;
#pragma unroll
  for (int j = 0; j < 4; j++) o[j] = fmaxf(xv[j] * sc[j] + sh[j], 0.f);
  *(f32x4*)(y + (size_t)r * 2048 + f0) = o;
}

// ============================================================================
extern "C" void kernel_launch(void* const* d_in, const int* in_sizes, int n_in,
                              void* d_out, int out_size, void* d_ws, size_t ws_size,
                              hipStream_t stream) {
  (void)in_sizes; (void)n_in; (void)out_size; (void)ws_size;

  const float* x    = (const float*)d_in[0];
  const int*   roi  = (const int*)  d_in[1];
  const float* phoc = (const float*)d_in[2];
  const float* c1w  = (const float*)d_in[3];
  const float* g1   = (const float*)d_in[5];
  const float* b1   = (const float*)d_in[6];
  const float* c2w  = (const float*)d_in[7];
  const float* g2   = (const float*)d_in[9];
  const float* b2   = (const float*)d_in[10];
  const float* c3w  = (const float*)d_in[11];
  const float* g3   = (const float*)d_in[13];
  const float* b3   = (const float*)d_in[14];
  const float* c4w  = (const float*)d_in[15];
  const float* g4   = (const float*)d_in[17];
  const float* b4   = (const float*)d_in[18];
  const float* c5w  = (const float*)d_in[19];
  const float* g5   = (const float*)d_in[21];
  const float* b5   = (const float*)d_in[22];
  const float* f1w  = (const float*)d_in[23];
  const float* g6   = (const float*)d_in[25];
  const float* b6   = (const float*)d_in[26];
  const float* f2w  = (const float*)d_in[27];
  const float* g7   = (const float*)d_in[29];
  const float* b7   = (const float*)d_in[30];
  float* out = (float*)d_out;

  // ---- workspace layout (total ~168.4 MB) ----
  char* ws = (char*)d_ws;
  bf16*  Ahi  = (bf16*) (ws + 0x0200000);   // 16 MB (padded NHWC activations)
  bf16*  Alo  = (bf16*) (ws + 0x1200000);   // 16 MB
  float* C    = (float*)(ws + 0x2200000);   // GEMM out / split slabs / pooled max
  float* CMIN = (float*)(ws + 0x2E00000);   // pooled min
  float* C5F  = (float*)(ws + 0x4600000);   // conv5 final
  bf16*  Wc2h = (bf16*) (ws + 0x5500000);   // conv weights (row-major [CO][K])
  bf16*  Wc3h = (bf16*) (ws + 0x5570000);
  bf16*  Wc4h = (bf16*) (ws + 0x5600000);
  bf16*  Wc5h = (bf16*) (ws + 0x5840000);
  bf16*  Wf1  = (bf16*) (ws + 0x5CC0000);   // packed FC weights
  bf16*  Wf2  = (bf16*) (ws + 0x68C0000);   // packed [2048][8192] = 32 MB
  bf16*  Shi  = (bf16*) (ws + 0x9080000);   // packed spp out [256][3072]
  bf16*  Slo  = (bf16*) (ws + 0x9200000);
  float* G6   = (float*)(ws + 0x9380000);   // fc1 out fp32 [256][2048]
  bf16*  CChi = (bf16*) (ws + 0x9580000);   // packed concat [256][8192] = 4 MB
  bf16*  CClo = (bf16*) (ws + 0x9980000);
  float* G7   = (float*)(ws + 0x9D80000);   // fc2 out fp32 [256][2048]
  float* PART = (float*)(ws + 0x9F80000);   // 768 KB
  float* SC   = (float*)(ws + 0xA040000);
  float* SH   = (float*)(ws + 0xA050000);

  // ---- prep: conv1 stats (768 blocks) || all transforms (30080 blocks) ----
  prep_k<<<30848, 256, 0, stream>>>(x, c1w, PART,
                                    c2w, c3w, c4w, c5w, f1w, f2w, phoc,
                                    Wc2h, Wc3h, Wc4h, Wc5h, Wf1, Wf2,
                                    CChi, CClo);

  // ---- conv1 finalize + apply (stats already done inside prep) ----
  bn_finalize<<<64, 64, 0, stream>>>(PART, g1, b1, SC, SH, 96, 1.f / 393216.f);
  conv1_apply_k<<<dim3(476, 8), 256, 0, stream>>>(x, c1w, SC, SH, Ahi, Alo);

  // ---- conv2 (1-pass, A-resident, fused pool): -> pooled max/min [24576][128]
  conv2_gemm_k<<<768, 256, 0, stream>>>(Ahi, Wc2h, C, CMIN, PART);
  bn_finalize<<<128, 64, 0, stream>>>(PART, g2, b2, SC, SH, 768, 1.f / 98304.f);
  act_pool_pad_k<128, 12, 32, 1><<<1904, 256, 0, stream>>>(C, CMIN, SC, SH, Ahi, Alo);

  // ---- conv3 (2-pass: Ah.Bh + Al.Bh, no pool) ----
  conv_gemm_k<128, 3, 12, 32, 256, true, false, 1, false><<<dim3(192, 2), 256, 0, stream>>>(Ahi, Alo, Wc3h, nullptr, C, nullptr, PART);
  bn_finalize<<<256, 64, 0, stream>>>(PART, g3, b3, SC, SH, 192, 1.f / 24576.f);
  bn_act_pad_k<256, 12, 32, 1><<<3808, 256, 0, stream>>>(C, SC, SH, Ahi, Alo);

  // ---- conv4 (1-pass, fused pool): -> pooled max/min [6144][512] ----
  conv_gemm_k<256, 3, 12, 32, 512, false, false, 1, true><<<dim3(192, 4), 256, 0, stream>>>(Ahi, Alo, Wc4h, nullptr, C, CMIN, PART);
  bn_finalize<<<512, 64, 0, stream>>>(PART, g4, b4, SC, SH, 192, 1.f / 24576.f);
  act_pool_pad_k<512, 6, 16, 1><<<2304, 256, 0, stream>>>(C, CMIN, SC, SH, Ahi, Alo);

  // ---- conv5 (1-pass: Ah.Bh, split-K=2): slabs in C, final in C5F ----
  conv_gemm_k<512, 3, 6, 16, 512, false, false, 2, false><<<dim3(48, 4, 2), 256, 0, stream>>>(Ahi, Alo, Wc5h, nullptr, C, nullptr, nullptr);
  reduce_bn_k<6144, 512, 2, 16><<<dim3(8, 16), 256, 0, stream>>>(C, C5F, PART);
  bn_finalize<<<512, 64, 0, stream>>>(PART, g5, b5, SC, SH, 16, 1.f / 6144.f);

  // ---- SPP (reads fp32 conv5 out + inline BN, packed output) ----
  spp_k<<<dim3(2, 256), 256, 0, stream>>>(C5F, SC, SH, roi, Shi, Slo);

  // ---- FC1 (packed, LDS-free, split-K=16): [256][3072] x [2048][3072] ----
  fc_gemm_k<3072, 16><<<dim3(2, 16, 16), 256, 0, stream>>>(Shi, Slo, Wf1, C);
  reduce_bn_k<256, 2048, 16, 4><<<dim3(32, 4), 256, 0, stream>>>(C, G6, PART);
  bn_finalize<<<2048, 64, 0, stream>>>(PART, g6, b6, SC, SH, 4, 1.f / 256.f);
  bn1d_apply_cc_k<<<256, 256, 0, stream>>>(G6, SC, SH, CChi, CClo);

  // ---- FC2 (packed, LDS-free, split-K=16): [256][8192] x [2048][8192] ----
  fc_gemm_k<8192, 16><<<dim3(2, 16, 16), 256, 0, stream>>>(CChi, CClo, Wf2, C);
  reduce_bn_k<256, 2048, 16, 4><<<dim3(32, 4), 256, 0, stream>>>(C, G7, PART);
  bn_finalize<<<2048, 64, 0, stream>>>(PART, g7, b7, SC, SH, 4, 1.f / 256.f);
  bn1d_apply_f32_k<<<512, 256, 0, stream>>>(G7, SC, SH, out);
}

// Round 22
// 505.166 us; speedup vs baseline: 1.3672x; 1.0216x over previous
//
#include <hip/hip_runtime.h>
#include <hip/hip_bf16.h>

// ============================================================================
// HWNet-SPP forward, MFMA bf16 implicit-GEMM with selective hi/lo precision.
// conv2: A-resident kernel; conv3/4/5: 128x128 LDS-staged template; FC1/FC2:
// packed fragment-order operands, zero LDS/barriers. Pooled layers (conv2,
// conv4) fuse the 2x2 pool into the GEMM epilogue as (window-max, window-min)
// dual fp32 writes. prep does LDS-transposed conv weights AND conv1 BN stats.
// Pass config (error budget vs absmax threshold 0.098):
//   conv2: Ah*Bh (1-pass)  conv3: +Al*Bh (2-pass)  conv4: 1-pass
//   conv5: Ah*Bh (1-pass, split-K=2)  FC1: 2-pass  FC2: 1-pass (split-K=16)
// BN stats fused into GEMM epilogue / split-K reducer; bn_finalize is
// one-block-per-channel wave butterfly. conv1 reads x with edge clamping.
// SPP reads conv5 fp32 out with inline BN. Biases skipped (BN cancels).
// ============================================================================

typedef __bf16 bf16;
using bf16x4 = __attribute__((ext_vector_type(4))) __bf16;
using bf16x8 = __attribute__((ext_vector_type(8))) __bf16;
using f32x4  = __attribute__((ext_vector_type(4))) float;

__device__ __forceinline__ void split2(float v, bf16& h, bf16& l) {
  bf16 hb = (bf16)v;
  h = hb;
  l = (bf16)(v - (float)hb);
}

__device__ __forceinline__ int iclamp(int v, int lo, int hi) {
  return v < lo ? lo : (v > hi ? hi : v);
}

__device__ __forceinline__ size_t pk_off(int row, int k, int Kd64) {
  return ((size_t)(row >> 4) * Kd64 + (k >> 6)) * 1024 +
         (size_t)(((k >> 5) & 1) * 512 + ((k >> 3) & 3) * 128 + ((row & 15) << 3) + (k & 7));
}

__device__ __forceinline__ void gld_lds16(const bf16* g, void* lds) {
  __builtin_amdgcn_global_load_lds(
      (const __attribute__((address_space(1))) unsigned int*)g,
      (__attribute__((address_space(3))) unsigned int*)lds, 16, 0, 0);
}

// ---------------- fused prep: conv1 BN stats + all weight/input transforms --
__global__ __launch_bounds__(256) void prep_k(const float* __restrict__ x,
                                              const float* __restrict__ c1w,
                                              float* __restrict__ part,
                                              const float* __restrict__ c2w,
                                              const float* __restrict__ c3w,
                                              const float* __restrict__ c4w,
                                              const float* __restrict__ c5w,
                                              const float* __restrict__ f1w,
                                              const float* __restrict__ f2w,
                                              const float* __restrict__ phoc,
                                              bf16* __restrict__ Wc2h,
                                              bf16* __restrict__ Wc3h,
                                              bf16* __restrict__ Wc4h,
                                              bf16* __restrict__ Wc5h,
                                              bf16* __restrict__ Wf1,
                                              bf16* __restrict__ Wf2,
                                              bf16* __restrict__ cch) {
  __shared__ float buf[4608];
  __shared__ float ls[256], lq[256];
  int b = blockIdx.x;
  int tid = threadIdx.x;
  if (b < 768) {
    // ---- conv1 BN stats (8 ch/group, edge-clamped reads of x) ----
    int seg = b >> 3;          // 0..95
    int co0 = (b & 7) * 8;     // channel group
    float sums[8] = {0.f}, sqs[8] = {0.f};
    for (int r = 0; r < 16; r++) {
      int pix = seg * 4096 + r * 256 + tid;  // 0..393215
      int w = pix & 127; int t = pix >> 7; int h = t % 48; int n = t / 48;
      const float* ip = x + (size_t)n * 48 * 128;
      int ihs[5], iws[5];
#pragma unroll
      for (int k = 0; k < 5; k++) {
        ihs[k] = iclamp(h + k - 2, 0, 47);
        iws[k] = iclamp(w + k - 2, 0, 127);
      }
      float win[25];
#pragma unroll
      for (int kh = 0; kh < 5; kh++)
#pragma unroll
        for (int kw = 0; kw < 5; kw++) win[kh * 5 + kw] = ip[ihs[kh] * 128 + iws[kw]];
#pragma unroll
      for (int j = 0; j < 8; j++) {
        const float* wp = c1w + (size_t)(co0 + j) * 25;
        float acc = 0.f;
#pragma unroll
        for (int k = 0; k < 25; k++) acc += win[k] * wp[k];
        sums[j] += acc; sqs[j] += acc * acc;
      }
    }
    for (int j = 0; j < 8; j++) {
      ls[tid] = sums[j]; lq[tid] = sqs[j];
      __syncthreads();
      for (int o = 128; o > 0; o >>= 1) {
        if (tid < o) { ls[tid] += ls[tid + o]; lq[tid] += lq[tid + o]; }
        __syncthreads();
      }
      if (tid == 0) {
        int c = co0 + j;
        part[((size_t)c * 96 + seg) * 2 + 0] = ls[0];
        part[((size_t)c * 96 + seg) * 2 + 1] = lq[0];
      }
      __syncthreads();
    }
    return;
  }
  b -= 768;
  const float* src = nullptr;
  bf16 *dsth = nullptr;
  int CI = 0, KK = 0, co = 0;
  if (b < 128)        { src = c2w; dsth = Wc2h; CI = 64;  KK = 25; co = b; }
  else if (b < 384)   { src = c3w; dsth = Wc3h; CI = 128; KK = 9;  co = b - 128; }
  else if (b < 896)   { src = c4w; dsth = Wc4h; CI = 256; KK = 9;  co = b - 384; }
  else if (b < 1408)  { src = c5w; dsth = Wc5h; CI = 512; KK = 9; co = b - 896; }
  if (src) {
    const int n = CI * KK;
    const float* sp = src + (size_t)co * n;
    for (int i = tid; i < n; i += 256) buf[i] = sp[i];
    __syncthreads();
    bf16* oh = dsth + (size_t)co * n;
    for (int o = tid; o < n; o += 256) {
      int ci = o & (CI - 1), kk = o / CI;
      float v = buf[ci * KK + kk];
      bf16 h, l; split2(v, h, l);
      oh[o] = h;
    }
    return;
  }
  b -= 1408;
  if (b < 6144) {  // f1w [2048][3072] -> packed hi, 4 elems/thread
    int i = b * 256 + tid;
    int k0 = (i % 768) * 4, n = i / 768;
    const float4 v = *(const float4*)(f1w + (size_t)n * 3072 + k0);
    bf16x4 o = { (bf16)v.x, (bf16)v.y, (bf16)v.z, (bf16)v.w };
    *(bf16x4*)(Wf1 + pk_off(n, k0, 48)) = o;
    return;
  }
  b -= 6144;
  if (b < 16384) {  // f2w [2048][7901] -> packed hi [2048][8192], 4/thread
    int i = b * 256 + tid;
    int k0 = (i & 2047) * 4, n = i >> 11;
    const float* xp = f2w + (size_t)n * 7901 + k0;
    bf16x4 o;
#pragma unroll
    for (int j = 0; j < 4; j++) o[j] = (bf16)((k0 + j < 7901) ? xp[j] : 0.f);
    *(bf16x4*)(Wf2 + pk_off(n, k0, 128)) = o;
    return;
  }
  b -= 16384;
  {  // phoc -> packed CC cols [2048,8192) hi only
    int i = b * 256 + tid;
    if (i >= 256 * 6144) return;
    int k = i % 6144, r = i / 6144;
    int col = 2048 + k;
    float v = (col < 7901) ? phoc[(size_t)r * 5853 + (col - 2048)] : 0.f;
    cch[pk_off(r, col, 128)] = (bf16)v;
  }
}

// ---------------- conv1 pass 2: conv+BN+ReLU+pool+pad (8 ch/group) ---------
__global__ __launch_bounds__(256) void conv1_apply_k(const float* __restrict__ x,
                                                     const float* __restrict__ wt,
                                                     const float* __restrict__ scale,
                                                     const float* __restrict__ shift,
                                                     bf16* __restrict__ yh,
                                                     bf16* __restrict__ yl) {
  int i = blockIdx.x * 256 + threadIdx.x;  // padded pixel slots
  if (i >= 64 * 28 * 68) return;
  int owp = i % 68; int t = i / 68; int ohp = t % 28; int n = t / 28;
  int co0 = blockIdx.y * 8;
  int oh = ohp - 2, ow = owp - 2;
  bf16x8 hv, lv;
#pragma unroll
  for (int j = 0; j < 8; j++) { hv[j] = (bf16)0.f; lv[j] = (bf16)0.f; }
  if (oh >= 0 && oh < 24 && ow >= 0 && ow < 64) {
    const float* ip = x + (size_t)n * 48 * 128;
    int shr[6], swc[6];
#pragma unroll
    for (int k = 0; k < 6; k++) {
      shr[k] = iclamp(2 * oh + k - 2, 0, 47);
      swc[k] = iclamp(2 * ow + k - 2, 0, 127);
    }
    float win[36];
#pragma unroll
    for (int r = 0; r < 6; r++)
#pragma unroll
      for (int c = 0; c < 6; c++) win[r * 6 + c] = ip[shr[r] * 128 + swc[c]];
#pragma unroll
    for (int j = 0; j < 8; j++) {
      const float* wp = wt + (size_t)(co0 + j) * 25;
      float sc = scale[co0 + j], sh = shift[co0 + j];
      float m = -1e30f;
#pragma unroll
      for (int dy = 0; dy < 2; dy++)
#pragma unroll
        for (int dx = 0; dx < 2; dx++) {
          float acc = 0.f;
#pragma unroll
          for (int kh = 0; kh < 5; kh++)
#pragma unroll
            for (int kw = 0; kw < 5; kw++)
              acc += win[(kh + dy) * 6 + kw + dx] * wp[kh * 5 + kw];
          m = fmaxf(m, acc * sc + sh);
        }
      float v = fmaxf(m, 0.f);
      bf16 h, l; split2(v, h, l);
      hv[j] = h; lv[j] = l;
    }
  }
  size_t o = (size_t)i * 64 + co0;
  *(bf16x8*)(yh + o) = hv;
  *(bf16x8*)(yl + o) = lv;
}

// ---------------- conv2 specialized: A-resident + fused pool (max/min) -----
__global__ __launch_bounds__(256) void conv2_gemm_k(const bf16* __restrict__ Ahi,
                                                    const bf16* __restrict__ Bhi,
                                                    float* __restrict__ Wmax,
                                                    float* __restrict__ Wmin,
                                                    float* __restrict__ part) {
  __shared__ bf16 Ash[416 * 64];      // 52 KB (reused as exchange post-loop)
  __shared__ bf16 Bsh[128 * 64];      // 16 KB
  __shared__ float red[2][128][8];    // 8 KB
  const int t = threadIdx.x;
  const int lane = t & 63, w = t >> 6;
  const int m0 = blockIdx.x * 128;
  const int img = m0 / 1536;
  const int oh0 = (m0 % 1536) >> 6;   // even
  const size_t abase = ((size_t)(img * 28 + oh0) * 68) * 64;

#pragma unroll
  for (int i = 0; i < 13; i++) {
    int f = i * 256 + t;
    int p = f >> 3; if (p > 407) p = 407;
    int s = f & 7;
    int ss = s ^ (p & 7);
    gld_lds16(Ahi + abase + (size_t)p * 64 + ss * 8,
              (char*)Ash + (size_t)(i * 256 + w * 64) * 16);
  }

  size_t boff[4];
#pragma unroll
  for (int i = 0; i < 4; i++) {
    int f = (i * 4 + w) * 64 + lane;
    int row = f >> 3, slot = f & 7;
    int ss = slot ^ (row & 7);
    boff[i] = (size_t)row * 1600 + ss * 8;
  }

  const int wrow = w >> 1, wcol = w & 1;
  const int kg = lane >> 4, l15 = lane & 15;
  int pixb[4];
#pragma unroll
  for (int q = 0; q < 4; q++) pixb[q] = wrow * 68 + q * 16 + l15;
  int brb[4], bmk[4];
#pragma unroll
  for (int q = 0; q < 4; q++) {
    int rb = wcol * 64 + q * 16 + l15;
    brb[q] = rb * 128; bmk[q] = rb & 7;
  }
  const char* Ashb = (const char*)Ash;
  const char* Bshb = (const char*)Bsh;

  f32x4 acc[4][4] = {};
  for (int kc = 0; kc < 25; ++kc) {
    const int kh = kc / 5, kw = kc % 5;
    const int kofs = kh * 68 + kw;
    const int k0 = kc * 64;
#pragma unroll
    for (int i = 0; i < 4; i++)
      gld_lds16(Bhi + boff[i] + k0, (char*)Bsh + (i * 4 + w) * 1024);
    __syncthreads();
#pragma unroll
    for (int ks = 0; ks < 2; ks++) {
      const int slot = ks * 4 + kg;
      bf16x8 ah[4], bh[4];
#pragma unroll
      for (int q = 0; q < 4; q++) {
        int pix = pixb[q] + kofs;
        ah[q] = *(const bf16x8*)(Ashb + pix * 128 + ((slot ^ (pix & 7)) << 4));
        bh[q] = *(const bf16x8*)(Bshb + brb[q] + ((slot ^ bmk[q]) << 4));
      }
#pragma unroll
      for (int mi = 0; mi < 4; mi++)
#pragma unroll
        for (int ni = 0; ni < 4; ni++)
          acc[mi][ni] = __builtin_amdgcn_mfma_f32_16x16x32_bf16(ah[mi], bh[ni], acc[mi][ni], 0, 0, 0);
    }
    __syncthreads();  // after this, Ash/Bsh free for reuse
  }

  const int ccol = l15;
  float hmx[4][4][2], hmn[4][4][2];
#pragma unroll
  for (int mi = 0; mi < 4; mi++)
#pragma unroll
    for (int ni = 0; ni < 4; ni++)
#pragma unroll
      for (int jp = 0; jp < 2; jp++) {
        float a = acc[mi][ni][2 * jp], b = acc[mi][ni][2 * jp + 1];
        hmx[mi][ni][jp] = fmaxf(a, b);
        hmn[mi][ni][jp] = fminf(a, b);
      }
  const int contrib = kg * 2 + wrow;
#pragma unroll
  for (int ni = 0; ni < 4; ni++) {
    float s = 0.f, q = 0.f;
#pragma unroll
    for (int mi = 0; mi < 4; mi++)
#pragma unroll
      for (int jj = 0; jj < 4; jj++) {
        float v = acc[mi][ni][jj];
        s += v; q += v * v;
      }
    int coll = wcol * 64 + ni * 16 + ccol;
    red[0][coll][contrib] = s;
    red[1][coll][contrib] = q;
  }
  float* exch = (float*)Ash;
  if (wrow == 1) {
    float* ep = exch + (size_t)(wcol * 64 + lane) * 64;
#pragma unroll
    for (int mi = 0; mi < 4; mi++)
#pragma unroll
      for (int ni = 0; ni < 4; ni++)
#pragma unroll
        for (int jp = 0; jp < 2; jp++) {
          int s = (mi * 8 + ni * 2 + jp) * 2;
          ep[s + 0] = hmx[mi][ni][jp];
          ep[s + 1] = hmn[mi][ni][jp];
        }
  }
  __syncthreads();
  if (wrow == 0) {
    const float* ep = exch + (size_t)(wcol * 64 + lane) * 64;
    const int pmb = img * 384 + (oh0 >> 1) * 32;
#pragma unroll
    for (int mi = 0; mi < 4; mi++)
#pragma unroll
      for (int ni = 0; ni < 4; ni++)
#pragma unroll
        for (int jp = 0; jp < 2; jp++) {
          int s = (mi * 8 + ni * 2 + jp) * 2;
          float mx = fmaxf(hmx[mi][ni][jp], ep[s + 0]);
          float mn = fminf(hmn[mi][ni][jp], ep[s + 1]);
          int pm = pmb + mi * 8 + kg * 2 + jp;
          int ch = wcol * 64 + ni * 16 + ccol;
          Wmax[(size_t)pm * 128 + ch] = mx;
          Wmin[(size_t)pm * 128 + ch] = mn;
        }
  }
  if (t < 128) {
    float s = 0.f, q = 0.f;
#pragma unroll
    for (int j = 0; j < 8; j++) { s += red[0][t][j]; q += red[1][t][j]; }
    size_t c = t;
    part[(c * gridDim.x + blockIdx.x) * 2 + 0] = s;
    part[(c * gridDim.x + blockIdx.x) * 2 + 1] = q;
  }
}

// ---------------- MFMA implicit-GEMM, LDS-staged, optional split-K/pool ----
template<int CI, int KS, int OH, int OW, int CO, bool ALO, bool BLO, int SPLIT, bool FUSEPOOL>
__global__ __launch_bounds__(256) void conv_gemm_k(const bf16* __restrict__ Ahi,
                                                   const bf16* __restrict__ Alo,
                                                   const bf16* __restrict__ Bhi,
                                                   const bf16* __restrict__ Blo,
                                                   float* __restrict__ Cout,
                                                   float* __restrict__ Cmin,
                                                   float* __restrict__ part) {
  static_assert(CI % 64 == 0, "chunk must not straddle ci segments");
  static_assert(!FUSEPOOL || (OW == 32 && SPLIT == 1), "fusepool needs OW=32");
  constexpr int K = KS * KS * CI;
  constexpr int IWP = OW + KS - 1;
  constexpr int NCH = K / 64;
  static_assert(NCH % SPLIT == 0, "split must divide chunk count");
  constexpr int NCHS = NCH / SPLIT;
  constexpr int M = 64 * OH * OW;
  __shared__ bf16 Ash[128 * 64];
  __shared__ bf16 Asl[ALO ? 128 * 64 : 64];
  __shared__ bf16 Bsh[128 * 64];
  __shared__ bf16 Bsl[BLO ? 128 * 64 : 64];
  __shared__ float red[2][128][8];
  const int t = threadIdx.x;
  const int lane = t & 63, w = t >> 6;
  const int m0 = blockIdx.x * 128, n0 = blockIdx.y * 128;
  const int z = (SPLIT > 1) ? blockIdx.z : 0;

  int apix[4]; size_t boff[4];
#pragma unroll
  for (int i = 0; i < 4; i++) {
    int f = (i * 4 + w) * 64 + lane;
    int row = f >> 3, slot = f & 7;
    int ss = slot ^ (row & 7);
    int m = m0 + row;
    int n = m / (OH * OW); int rem = m % (OH * OW);
    int oh = rem / OW, ow_ = rem % OW;
    apix[i] = ((n * (OH + KS - 1) + oh) * IWP + ow_) * CI + ss * 8;
    boff[i] = (size_t)(n0 + row) * K + ss * 8;
  }

  const int wrow = w >> 1, wcol = w & 1;
  const int kg = lane >> 4, l15 = lane & 15;
  int arb[4], amk[4], brb[4], bmk[4];
#pragma unroll
  for (int q = 0; q < 4; q++) {
    int ra = wrow * 64 + q * 16 + l15;
    arb[q] = ra * 128; amk[q] = ra & 7;
    int rb = wcol * 64 + q * 16 + l15;
    brb[q] = rb * 128; bmk[q] = rb & 7;
  }
  const char* Ashb = (const char*)Ash;
  const char* Aslb = (const char*)Asl;
  const char* Bshb = (const char*)Bsh;
  const char* Bslb = (const char*)Bsl;

  f32x4 acc[4][4] = {};
  for (int kc = z * NCHS; kc < (z + 1) * NCHS; ++kc) {
    const int k0 = kc * 64;
    const int seg = k0 / CI;
    const int ci0 = k0 % CI;
    const int kh = seg / KS, kw = seg % KS;
    const int aoff = (kh * IWP + kw) * CI + ci0;   // wave-uniform
#pragma unroll
    for (int i = 0; i < 4; i++) {
      gld_lds16(Ahi + (size_t)apix[i] + aoff, (char*)Ash + (i * 4 + w) * 1024);
      if (ALO)
        gld_lds16(Alo + (size_t)apix[i] + aoff, (char*)Asl + (i * 4 + w) * 1024);
      gld_lds16(Bhi + boff[i] + k0,   (char*)Bsh + (i * 4 + w) * 1024);
      if (BLO)
        gld_lds16(Blo + boff[i] + k0, (char*)Bsl + (i * 4 + w) * 1024);
    }
    __syncthreads();
#pragma unroll
    for (int ks = 0; ks < 2; ks++) {
      const int slot = ks * 4 + kg;
      bf16x8 ah[4], bh[4];
#pragma unroll
      for (int q = 0; q < 4; q++) {
        ah[q] = *(const bf16x8*)(Ashb + arb[q] + ((slot ^ amk[q]) << 4));
        bh[q] = *(const bf16x8*)(Bshb + brb[q] + ((slot ^ bmk[q]) << 4));
      }
#pragma unroll
      for (int mi = 0; mi < 4; mi++)
#pragma unroll
        for (int ni = 0; ni < 4; ni++)
          acc[mi][ni] = __builtin_amdgcn_mfma_f32_16x16x32_bf16(ah[mi], bh[ni], acc[mi][ni], 0, 0, 0);
      if (ALO) {
        bf16x8 al[4];
#pragma unroll
        for (int q = 0; q < 4; q++)
          al[q] = *(const bf16x8*)(Aslb + arb[q] + ((slot ^ amk[q]) << 4));
#pragma unroll
        for (int mi = 0; mi < 4; mi++)
#pragma unroll
          for (int ni = 0; ni < 4; ni++)
            acc[mi][ni] = __builtin_amdgcn_mfma_f32_16x16x32_bf16(al[mi], bh[ni], acc[mi][ni], 0, 0, 0);
      }
      if (BLO) {
        bf16x8 bl[4];
#pragma unroll
        for (int q = 0; q < 4; q++)
          bl[q] = *(const bf16x8*)(Bslb + brb[q] + ((slot ^ bmk[q]) << 4));
#pragma unroll
        for (int mi = 0; mi < 4; mi++)
#pragma unroll
          for (int ni = 0; ni < 4; ni++)
            acc[mi][ni] = __builtin_amdgcn_mfma_f32_16x16x32_bf16(ah[mi], bl[ni], acc[mi][ni], 0, 0, 0);
      }
    }
    __syncthreads();
  }

  const int crow0 = kg * 4, ccol = l15;
  if constexpr (FUSEPOOL) {
    const int n_img = m0 / (OH * OW);
    const int oh0 = (m0 % (OH * OW)) / OW;          // multiple of 4
    const int pmb = n_img * (OH / 2) * (OW / 2) + (oh0 / 2 + wrow) * (OW / 2);
#pragma unroll
    for (int mi = 0; mi < 2; mi++)
#pragma unroll
      for (int ni = 0; ni < 4; ni++)
#pragma unroll
        for (int jp = 0; jp < 2; jp++) {
          float a0 = acc[mi][ni][2 * jp],     a1 = acc[mi][ni][2 * jp + 1];
          float b0 = acc[mi + 2][ni][2 * jp], b1 = acc[mi + 2][ni][2 * jp + 1];
          float mx = fmaxf(fmaxf(a0, a1), fmaxf(b0, b1));
          float mn = fminf(fminf(a0, a1), fminf(b0, b1));
          int pm = pmb + mi * 8 + kg * 2 + jp;
          int ch = n0 + wcol * 64 + ni * 16 + ccol;
          Cout[(size_t)pm * CO + ch] = mx;
          Cmin[(size_t)pm * CO + ch] = mn;
        }
  } else {
    float* Cz = Cout + (size_t)z * M * CO;
#pragma unroll
    for (int mi = 0; mi < 4; mi++) {
      int m = m0 + wrow * 64 + mi * 16 + crow0;
#pragma unroll
      for (int ni = 0; ni < 4; ni++) {
        int nn = n0 + wcol * 64 + ni * 16 + ccol;
        float* cp = Cz + (size_t)m * CO + nn;
#pragma unroll
        for (int jj = 0; jj < 4; jj++) cp[(size_t)jj * CO] = acc[mi][ni][jj];
      }
    }
  }
  if constexpr (SPLIT == 1) {
    const int contrib = kg * 2 + wrow;
#pragma unroll
    for (int ni = 0; ni < 4; ni++) {
      float s = 0.f, q = 0.f;
#pragma unroll
      for (int mi = 0; mi < 4; mi++)
#pragma unroll
        for (int jj = 0; jj < 4; jj++) {
          float v = acc[mi][ni][jj];
          s += v; q += v * v;
        }
      int coll = wcol * 64 + ni * 16 + ccol;
      red[0][coll][contrib] = s;
      red[1][coll][contrib] = q;
    }
    __syncthreads();
    if (t < 128) {
      float s = 0.f, q = 0.f;
#pragma unroll
      for (int j = 0; j < 8; j++) { s += red[0][t][j]; q += red[1][t][j]; }
      size_t c = n0 + t;
      part[(c * gridDim.x + blockIdx.x) * 2 + 0] = s;
      part[(c * gridDim.x + blockIdx.x) * 2 + 1] = q;
    }
  }
}

// ---------------- FC GEMM: packed A (hi,+lo if ALO) + packed B, zero LDS ---
template<int K, int SPLIT, bool ALO>
__global__ __launch_bounds__(256) void fc_gemm_k(const bf16* __restrict__ Ahp,
                                                 const bf16* __restrict__ Alp,
                                                 const bf16* __restrict__ Bhp,
                                                 float* __restrict__ Cout) {
  constexpr int Kd64 = K / 64;
  constexpr int NCHS = Kd64 / SPLIT;
  constexpr int M = 256, N = 2048;
  const int t = threadIdx.x;
  const int lane = t & 63, w = t >> 6;
  const int m0 = blockIdx.x * 128, n0 = blockIdx.y * 128;
  const int z = blockIdx.z;
  const int wrow = w >> 1, wcol = w & 1;
  const int kg = lane >> 4, l15 = lane & 15;

  size_t ab[4], bb[4];
#pragma unroll
  for (int q = 0; q < 4; q++) {
    int rbA = (m0 >> 4) + wrow * 4 + q;
    ab[q] = (size_t)rbA * Kd64 * 1024 + (size_t)lane * 8;
    int rbB = (n0 >> 4) + wcol * 4 + q;
    bb[q] = (size_t)rbB * Kd64 * 1024 + (size_t)lane * 8;
  }

  f32x4 acc[4][4] = {};
  for (int kc = z * NCHS; kc < (z + 1) * NCHS; ++kc) {
    const size_t bco = (size_t)kc * 1024;
#pragma unroll
    for (int ks = 0; ks < 2; ks++) {
      const size_t soff = bco + ks * 512;
      bf16x8 ah[4], bh[4];
#pragma unroll
      for (int q = 0; q < 4; q++) {
        ah[q] = *(const bf16x8*)(Ahp + ab[q] + soff);
        bh[q] = *(const bf16x8*)(Bhp + bb[q] + soff);
      }
#pragma unroll
      for (int mi = 0; mi < 4; mi++)
#pragma unroll
        for (int ni = 0; ni < 4; ni++)
          acc[mi][ni] = __builtin_amdgcn_mfma_f32_16x16x32_bf16(ah[mi], bh[ni], acc[mi][ni], 0, 0, 0);
      if (ALO) {
        bf16x8 al[4];
#pragma unroll
        for (int q = 0; q < 4; q++)
          al[q] = *(const bf16x8*)(Alp + ab[q] + soff);
#pragma unroll
        for (int mi = 0; mi < 4; mi++)
#pragma unroll
          for (int ni = 0; ni < 4; ni++)
            acc[mi][ni] = __builtin_amdgcn_mfma_f32_16x16x32_bf16(al[mi], bh[ni], acc[mi][ni], 0, 0, 0);
      }
    }
  }

  const int crow0 = kg * 4, ccol = l15;
  float* Cz = Cout + (size_t)z * M * N;
#pragma unroll
  for (int mi = 0; mi < 4; mi++) {
    int m = m0 + wrow * 64 + mi * 16 + crow0;
#pragma unroll
    for (int ni = 0; ni < 4; ni++) {
      int nn = n0 + wcol * 64 + ni * 16 + ccol;
      float* cp = Cz + (size_t)m * N + nn;
#pragma unroll
      for (int jj = 0; jj < 4; jj++) cp[(size_t)jj * N] = acc[mi][ni][jj];
    }
  }
}

// ---------------- split-K reduction + BN partials ----------------
template<int M, int CO, int SPLIT, int NS>
__global__ __launch_bounds__(256) void reduce_bn_k(const float* __restrict__ Cp,
                                                   float* __restrict__ Cf,
                                                   float* __restrict__ part) {
  int c = blockIdx.x * 64 + (threadIdx.x & 63);
  int rl = threadIdx.x >> 6;
  constexpr int ROWS = M / NS;
  int r0 = blockIdx.y * ROWS;
  float sum = 0.f, sq = 0.f;
  for (int r = r0 + rl; r < r0 + ROWS; r += 4) {
    float v = 0.f;
#pragma unroll
    for (int s = 0; s < SPLIT; s++) v += Cp[(size_t)s * M * CO + (size_t)r * CO + c];
    Cf[(size_t)r * CO + c] = v;
    sum += v; sq += v * v;
  }
  __shared__ float ls[256], lq[256];
  ls[threadIdx.x] = sum; lq[threadIdx.x] = sq;
  __syncthreads();
  if (threadIdx.x < 64) {
    sum = ls[threadIdx.x] + ls[threadIdx.x + 64] + ls[threadIdx.x + 128] + ls[threadIdx.x + 192];
    sq  = lq[threadIdx.x] + lq[threadIdx.x + 64] + lq[threadIdx.x + 128] + lq[threadIdx.x + 192];
    part[((size_t)c * NS + blockIdx.y) * 2 + 0] = sum;
    part[((size_t)c * NS + blockIdx.y) * 2 + 1] = sq;
  }
}

// ---------------- BN finalize: one block per channel, wave butterfly -------
__global__ __launch_bounds__(64) void bn_finalize(const float* __restrict__ part,
                                                  const float* __restrict__ g,
                                                  const float* __restrict__ b,
                                                  float* __restrict__ scale,
                                                  float* __restrict__ shift,
                                                  int S, float invCount) {
  int c = blockIdx.x;
  int lane = threadIdx.x;
  float sum = 0.f, sq = 0.f;
  for (int s = lane; s < S; s += 64) {
    sum += part[((size_t)c * S + s) * 2 + 0];
    sq  += part[((size_t)c * S + s) * 2 + 1];
  }
#pragma unroll
  for (int o = 32; o > 0; o >>= 1) {
    sum += __shfl_xor(sum, o);
    sq  += __shfl_xor(sq, o);
  }
  if (lane == 0) {
    float m = sum * invCount;
    float var = sq * invCount - m * m;
    float sc = g[c] * rsqrtf(var + 1e-5f);
    scale[c] = sc;
    shift[c] = b[c] - m * sc;
  }
}

// ---------------- fused BN + ReLU + pad (no pool), 8ch/thread --------------
template<int CO, int IH, int IW, int PADO>
__global__ __launch_bounds__(256) void bn_act_pad_k(const float* __restrict__ x,
                                                    const float* __restrict__ scale,
                                                    const float* __restrict__ shift,
                                                    bf16* __restrict__ yh,
                                                    bf16* __restrict__ yl) {
  constexpr int OHP = IH + 2 * PADO, OWP = IW + 2 * PADO;
  constexpr int CO8 = CO / 8;
  int i = blockIdx.x * 256 + threadIdx.x;
  if (i >= 64 * OHP * OWP * CO8) return;
  int c8 = i % CO8; int t = i / CO8; int owp = t % OWP; t /= OWP; int ohp = t % OHP; int n = t / OHP;
  int c0 = c8 * 8;
  int oh = ohp - PADO, ow = owp - PADO;
  bf16x8 hv, lv;
#pragma unroll
  for (int j = 0; j < 8; j++) { hv[j] = (bf16)0.f; lv[j] = (bf16)0.f; }
  if (oh >= 0 && oh < IH && ow >= 0 && ow < IW) {
    float sc[8], sh[8];
    *(f32x4*)(sc)     = *(const f32x4*)(scale + c0);
    *(f32x4*)(sc + 4) = *(const f32x4*)(scale + c0 + 4);
    *(f32x4*)(sh)     = *(const f32x4*)(shift + c0);
    *(f32x4*)(sh + 4) = *(const f32x4*)(shift + c0 + 4);
    const float* p = x + (((size_t)(n * IH) + oh) * IW + ow) * CO + c0;
    float ta[8];
    *(f32x4*)(ta) = *(const f32x4*)(p); *(f32x4*)(ta + 4) = *(const f32x4*)(p + 4);
#pragma unroll
    for (int j = 0; j < 8; j++) {
      float vv = fmaxf(ta[j] * sc[j] + sh[j], 0.f);
      bf16 h, l; split2(vv, h, l);
      hv[j] = h; lv[j] = l;
    }
  }
  size_t o = (size_t)i * 8;
  *(bf16x8*)(yh + o) = hv;
  *(bf16x8*)(yl + o) = lv;
}

// ---------------- BN + ReLU + pad from pooled (max,min), 8ch/thread --------
template<int CO, int PH, int PW, int PADO>
__global__ __launch_bounds__(256) void act_pool_pad_k(const float* __restrict__ wmax,
                                                      const float* __restrict__ wmin,
                                                      const float* __restrict__ scale,
                                                      const float* __restrict__ shift,
                                                      bf16* __restrict__ yh,
                                                      bf16* __restrict__ yl) {
  constexpr int OHP = PH + 2 * PADO, OWP = PW + 2 * PADO;
  constexpr int CO8 = CO / 8;
  int i = blockIdx.x * 256 + threadIdx.x;
  if (i >= 64 * OHP * OWP * CO8) return;
  int c8 = i % CO8; int t = i / CO8; int owp = t % OWP; t /= OWP; int ohp = t % OHP; int n = t / OHP;
  int c0 = c8 * 8;
  int oh = ohp - PADO, ow = owp - PADO;
  bf16x8 hv, lv;
#pragma unroll
  for (int j = 0; j < 8; j++) { hv[j] = (bf16)0.f; lv[j] = (bf16)0.f; }
  if (oh >= 0 && oh < PH && ow >= 0 && ow < PW) {
    float sc[8], sh[8], mx[8], mn[8];
    *(f32x4*)(sc)     = *(const f32x4*)(scale + c0);
    *(f32x4*)(sc + 4) = *(const f32x4*)(scale + c0 + 4);
    *(f32x4*)(sh)     = *(const f32x4*)(shift + c0);
    *(f32x4*)(sh + 4) = *(const f32x4*)(shift + c0 + 4);
    size_t off = (((size_t)(n * PH) + oh) * PW + ow) * CO + c0;
    *(f32x4*)(mx)     = *(const f32x4*)(wmax + off);
    *(f32x4*)(mx + 4) = *(const f32x4*)(wmax + off + 4);
    *(f32x4*)(mn)     = *(const f32x4*)(wmin + off);
    *(f32x4*)(mn + 4) = *(const f32x4*)(wmin + off + 4);
#pragma unroll
    for (int j = 0; j < 8; j++) {
      float sel = (sc[j] >= 0.f) ? mx[j] : mn[j];
      float vv = fmaxf(sel * sc[j] + sh[j], 0.f);
      bf16 h, l; split2(vv, h, l);
      hv[j] = h; lv[j] = l;
    }
  }
  size_t o = (size_t)i * 8;
  *(bf16x8*)(yh + o) = hv;
  *(bf16x8*)(yl + o) = lv;
}

// ---------------- ROI SPP: conv5 fp32 + inline BN -> PACKED S hi/lo --------
__global__ __launch_bounds__(256) void spp_k(const float* __restrict__ feat,
                                             const float* __restrict__ scale,
                                             const float* __restrict__ shift,
                                             const int* __restrict__ roi,
                                             bf16* __restrict__ oh_,
                                             bf16* __restrict__ ol_) {
  int c = blockIdx.x * 256 + threadIdx.x;  // 0..511
  int r = blockIdx.y;                      // 0..255
  const int* rp = roi + r * 5;
  int im = rp[0];
  int c1 = rp[1] >> 3, r1 = rp[2] >> 3, c2 = rp[3] >> 3, r2 = rp[4] >> 3;
  int w = c2 - c1 + 1;
  int lo[6], hi[6];
  int bi = 0;
#pragma unroll
  for (int l = 1; l <= 3; l++)
    for (int k = 0; k < l; k++) {
      lo[bi] = c1 + (k * w) / l;
      hi[bi] = c1 + ((k + 1) * w + l - 1) / l - 1;
      bi++;
    }
  float mx[6];
#pragma unroll
  for (int b = 0; b < 6; b++) mx[b] = -1e30f;
  float sc = scale[c], sh = shift[c];
  const float* fp = feat + (size_t)im * 96 * 512 + c;
  for (int row = r1; row <= r2; row++)
    for (int col = c1; col <= c2; col++) {
      float v = fp[(size_t)(row * 16 + col) * 512] * sc + sh;
#pragma unroll
      for (int b = 0; b < 6; b++)
        if (col >= lo[b] && col <= hi[b]) mx[b] = fmaxf(mx[b], v);
    }
  int idx[6] = {c, 512 + c * 2, 512 + c * 2 + 1, 1536 + c * 3, 1536 + c * 3 + 1, 1536 + c * 3 + 2};
#pragma unroll
  for (int b = 0; b < 6; b++) {
    float v = fmaxf(mx[b], 0.f);
    bf16 h, l; split2(v, h, l);
    size_t o = pk_off(r, idx[b], 48);
    oh_[o] = h;
    ol_[o] = l;
  }
}

// FC1: BN+ReLU, write hi PACKED into CC[:, 0:2048] (K=8192); FC2 is 1-pass.
__global__ __launch_bounds__(256) void bn1d_apply_cc_k(const float* __restrict__ x,
                                                       const float* __restrict__ scale,
                                                       const float* __restrict__ shift,
                                                       bf16* __restrict__ ch) {
  int i = blockIdx.x * 256 + threadIdx.x;
  if (i >= 256 * 256) return;
  int f8 = i & 255, r = i >> 8;
  int f0 = f8 * 8;
  float xv[8], sc[8], sh[8];
  *(f32x4*)(xv)     = *(const f32x4*)(x + (size_t)r * 2048 + f0);
  *(f32x4*)(xv + 4) = *(const f32x4*)(x + (size_t)r * 2048 + f0 + 4);
  *(f32x4*)(sc)     = *(const f32x4*)(scale + f0);
  *(f32x4*)(sc + 4) = *(const f32x4*)(scale + f0 + 4);
  *(f32x4*)(sh)     = *(const f32x4*)(shift + f0);
  *(f32x4*)(sh + 4) = *(const f32x4*)(shift + f0 + 4);
  bf16x8 hv;
#pragma unroll
  for (int j = 0; j < 8; j++) {
    float v = fmaxf(xv[j] * sc[j] + sh[j], 0.f);
    hv[j] = (bf16)v;
  }
  *(bf16x8*)(ch + pk_off(r, f0, 128)) = hv;
}

// FC2: BN+ReLU, fp32 out, 4 feat/thread
__global__ __launch_bounds__(256) void bn1d_apply_f32_k(const float* __restrict__ x,
                                                        const float* __restrict__ scale,
                                                        const float* __restrict__ shift,
                                                        float* __restrict__ y) {
  int i = blockIdx.x * 256 + threadIdx.x;
  if (i >= 256 * 512) return;
  int f4 = i & 511, r = i >> 9;
  int f0 = f4 * 4;
  f32x4 xv = *(const f32x4*)(x + (size_t)r * 2048 + f0);
  f32x4 sc = *(const f32x4*)(scale + f0);
  f32x4 sh = *(const f32x4*)(shift + f0);
  f32x4 o;
#pragma unroll
  for (int j = 0; j < 4; j++) o[j] = fmaxf(xv[j] * sc[j] + sh[j], 0.f);
  *(f32x4*)(y + (size_t)r * 2048 + f0) = o;
}

// ============================================================================
extern "C" void kernel_launch(void* const* d_in, const int* in_sizes, int n_in,
                              void* d_out, int out_size, void* d_ws, size_t ws_size,
                              hipStream_t stream) {
  (void)in_sizes; (void)n_in; (void)out_size; (void)ws_size;

  const float* x    = (const float*)d_in[0];
  const int*   roi  = (const int*)  d_in[1];
  const float* phoc = (const float*)d_in[2];
  const float* c1w  = (const float*)d_in[3];
  const float* g1   = (const float*)d_in[5];
  const float* b1   = (const float*)d_in[6];
  const float* c2w  = (const float*)d_in[7];
  const float* g2   = (const float*)d_in[9];
  const float* b2   = (const float*)d_in[10];
  const float* c3w  = (const float*)d_in[11];
  const float* g3   = (const float*)d_in[13];
  const float* b3   = (const float*)d_in[14];
  const float* c4w  = (const float*)d_in[15];
  const float* g4   = (const float*)d_in[17];
  const float* b4   = (const float*)d_in[18];
  const float* c5w  = (const float*)d_in[19];
  const float* g5   = (const float*)d_in[21];
  const float* b5   = (const float*)d_in[22];
  const float* f1w  = (const float*)d_in[23];
  const float* g6   = (const float*)d_in[25];
  const float* b6   = (const float*)d_in[26];
  const float* f2w  = (const float*)d_in[27];
  const float* g7   = (const float*)d_in[29];
  const float* b7   = (const float*)d_in[30];
  float* out = (float*)d_out;

  // ---- workspace layout (total ~168.4 MB) ----
  char* ws = (char*)d_ws;
  bf16*  Ahi  = (bf16*) (ws + 0x0200000);   // 16 MB (padded NHWC activations)
  bf16*  Alo  = (bf16*) (ws + 0x1200000);   // 16 MB
  float* C    = (float*)(ws + 0x2200000);   // GEMM out / split slabs / pooled max
  float* CMIN = (float*)(ws + 0x2E00000);   // pooled min
  float* C5F  = (float*)(ws + 0x4600000);   // conv5 final
  bf16*  Wc2h = (bf16*) (ws + 0x5500000);   // conv weights (row-major [CO][K])
  bf16*  Wc3h = (bf16*) (ws + 0x5570000);
  bf16*  Wc4h = (bf16*) (ws + 0x5600000);
  bf16*  Wc5h = (bf16*) (ws + 0x5840000);
  bf16*  Wf1  = (bf16*) (ws + 0x5CC0000);   // packed FC weights
  bf16*  Wf2  = (bf16*) (ws + 0x68C0000);   // packed [2048][8192] = 32 MB
  bf16*  Shi  = (bf16*) (ws + 0x9080000);   // packed spp out [256][3072]
  bf16*  Slo  = (bf16*) (ws + 0x9200000);
  float* G6   = (float*)(ws + 0x9380000);   // fc1 out fp32 [256][2048]
  bf16*  CChi = (bf16*) (ws + 0x9580000);   // packed concat hi [256][8192] = 4 MB
  float* G7   = (float*)(ws + 0x9D80000);   // fc2 out fp32 [256][2048]
  float* PART = (float*)(ws + 0x9F80000);   // 768 KB
  float* SC   = (float*)(ws + 0xA040000);
  float* SH   = (float*)(ws + 0xA050000);

  // ---- prep: conv1 stats (768 blocks) || all transforms (30080 blocks) ----
  prep_k<<<30848, 256, 0, stream>>>(x, c1w, PART,
                                    c2w, c3w, c4w, c5w, f1w, f2w, phoc,
                                    Wc2h, Wc3h, Wc4h, Wc5h, Wf1, Wf2,
                                    CChi);

  // ---- conv1 finalize + apply (stats already done inside prep) ----
  bn_finalize<<<64, 64, 0, stream>>>(PART, g1, b1, SC, SH, 96, 1.f / 393216.f);
  conv1_apply_k<<<dim3(476, 8), 256, 0, stream>>>(x, c1w, SC, SH, Ahi, Alo);

  // ---- conv2 (1-pass, A-resident, fused pool): -> pooled max/min [24576][128]
  conv2_gemm_k<<<768, 256, 0, stream>>>(Ahi, Wc2h, C, CMIN, PART);
  bn_finalize<<<128, 64, 0, stream>>>(PART, g2, b2, SC, SH, 768, 1.f / 98304.f);
  act_pool_pad_k<128, 12, 32, 1><<<1904, 256, 0, stream>>>(C, CMIN, SC, SH, Ahi, Alo);

  // ---- conv3 (2-pass: Ah.Bh + Al.Bh, no pool) ----
  conv_gemm_k<128, 3, 12, 32, 256, true, false, 1, false><<<dim3(192, 2), 256, 0, stream>>>(Ahi, Alo, Wc3h, nullptr, C, nullptr, PART);
  bn_finalize<<<256, 64, 0, stream>>>(PART, g3, b3, SC, SH, 192, 1.f / 24576.f);
  bn_act_pad_k<256, 12, 32, 1><<<3808, 256, 0, stream>>>(C, SC, SH, Ahi, Alo);

  // ---- conv4 (1-pass, fused pool): -> pooled max/min [6144][512] ----
  conv_gemm_k<256, 3, 12, 32, 512, false, false, 1, true><<<dim3(192, 4), 256, 0, stream>>>(Ahi, Alo, Wc4h, nullptr, C, CMIN, PART);
  bn_finalize<<<512, 64, 0, stream>>>(PART, g4, b4, SC, SH, 192, 1.f / 24576.f);
  act_pool_pad_k<512, 6, 16, 1><<<2304, 256, 0, stream>>>(C, CMIN, SC, SH, Ahi, Alo);

  // ---- conv5 (1-pass: Ah.Bh, split-K=2): slabs in C, final in C5F ----
  conv_gemm_k<512, 3, 6, 16, 512, false, false, 2, false><<<dim3(48, 4, 2), 256, 0, stream>>>(Ahi, Alo, Wc5h, nullptr, C, nullptr, nullptr);
  reduce_bn_k<6144, 512, 2, 16><<<dim3(8, 16), 256, 0, stream>>>(C, C5F, PART);
  bn_finalize<<<512, 64, 0, stream>>>(PART, g5, b5, SC, SH, 16, 1.f / 6144.f);

  // ---- SPP (reads fp32 conv5 out + inline BN, packed output) ----
  spp_k<<<dim3(2, 256), 256, 0, stream>>>(C5F, SC, SH, roi, Shi, Slo);

  // ---- FC1 (packed, LDS-free, 2-pass, split-K=16): [256][3072] x [2048][3072]
  fc_gemm_k<3072, 16, true><<<dim3(2, 16, 16), 256, 0, stream>>>(Shi, Slo, Wf1, C);
  reduce_bn_k<256, 2048, 16, 4><<<dim3(32, 4), 256, 0, stream>>>(C, G6, PART);
  bn_finalize<<<2048, 64, 0, stream>>>(PART, g6, b6, SC, SH, 4, 1.f / 256.f);
  bn1d_apply_cc_k<<<256, 256, 0, stream>>>(G6, SC, SH, CChi);

  // ---- FC2 (packed, LDS-free, 1-pass, split-K=16): [256][8192] x [2048][8192]
  fc_gemm_k<8192, 16, false><<<dim3(2, 16, 16), 256, 0, stream>>>(CChi, nullptr, Wf2, C);
  reduce_bn_k<256, 2048, 16, 4><<<dim3(32, 4), 256, 0, stream>>>(C, G7, PART);
  bn_finalize<<<2048, 64, 0, stream>>>(PART, g7, b7, SC, SH, 4, 1.f / 256.f);
  bn1d_apply_f32_k<<<512, 256, 0, stream>>>(G7, SC, SH, out);
}

// Round 23
// 498.183 us; speedup vs baseline: 1.3864x; 1.0140x over previous
//
#include <hip/hip_runtime.h>
#include <hip/hip_bf16.h>

// ============================================================================
// HWNet-SPP forward, MFMA bf16 implicit-GEMM with selective hi/lo precision.
// conv2: A-resident kernel; conv3/4/5: 128x128 LDS-staged template; FC1/FC2:
// packed fragment-order operands, zero LDS/barriers. Pooled layers (conv2,
// conv4) fuse the 2x2 pool into the GEMM epilogue as (window-max, window-min)
// dual fp32 writes. prep does conv1 BN stats + LDS-transposed conv weights +
// TILE-BASED packed FC-weight repack (one block per 1024-elem packed tile:
// coalesced fp32 tile read -> LDS -> coalesced 2KB contiguous packed write).
// Pass config (error budget vs absmax threshold 0.098):
//   conv2: Ah*Bh (1-pass)  conv3: +Al*Bh (2-pass)  conv4: 1-pass
//   conv5: Ah*Bh (1-pass, split-K=2)  FC1: 2-pass  FC2: 1-pass (split-K=16)
// BN stats fused into GEMM epilogue / split-K reducer; bn_finalize is
// one-block-per-channel wave butterfly. conv1 reads x with edge clamping.
// SPP reads conv5 fp32 out with inline BN. Biases skipped (BN cancels).
// ============================================================================

typedef __bf16 bf16;
using bf16x4 = __attribute__((ext_vector_type(4))) __bf16;
using bf16x8 = __attribute__((ext_vector_type(8))) __bf16;
using f32x4  = __attribute__((ext_vector_type(4))) float;

__device__ __forceinline__ void split2(float v, bf16& h, bf16& l) {
  bf16 hb = (bf16)v;
  h = hb;
  l = (bf16)(v - (float)hb);
}

__device__ __forceinline__ int iclamp(int v, int lo, int hi) {
  return v < lo ? lo : (v > hi ? hi : v);
}

__device__ __forceinline__ size_t pk_off(int row, int k, int Kd64) {
  return ((size_t)(row >> 4) * Kd64 + (k >> 6)) * 1024 +
         (size_t)(((k >> 5) & 1) * 512 + ((k >> 3) & 3) * 128 + ((row & 15) << 3) + (k & 7));
}

__device__ __forceinline__ void gld_lds16(const bf16* g, void* lds) {
  __builtin_amdgcn_global_load_lds(
      (const __attribute__((address_space(1))) unsigned int*)g,
      (__attribute__((address_space(3))) unsigned int*)lds, 16, 0, 0);
}

// ---------------- fused prep: conv1 BN stats + all weight/input transforms --
// blocks [0,768): conv1 stats. [768,2176): conv weights (LDS transpose).
// [2176,8320): f1w tiles. [8320,24704): f2w tiles. [24704,26240): phoc tiles.
__global__ __launch_bounds__(256) void prep_k(const float* __restrict__ x,
                                              const float* __restrict__ c1w,
                                              float* __restrict__ part,
                                              const float* __restrict__ c2w,
                                              const float* __restrict__ c3w,
                                              const float* __restrict__ c4w,
                                              const float* __restrict__ c5w,
                                              const float* __restrict__ f1w,
                                              const float* __restrict__ f2w,
                                              const float* __restrict__ phoc,
                                              bf16* __restrict__ Wc2h,
                                              bf16* __restrict__ Wc3h,
                                              bf16* __restrict__ Wc4h,
                                              bf16* __restrict__ Wc5h,
                                              bf16* __restrict__ Wf1,
                                              bf16* __restrict__ Wf2,
                                              bf16* __restrict__ cch) {
  __shared__ float buf[4608];
  __shared__ float ls[256], lq[256];
  int b = blockIdx.x;
  int tid = threadIdx.x;
  if (b < 768) {
    // ---- conv1 BN stats (8 ch/group, edge-clamped reads of x) ----
    int seg = b >> 3;          // 0..95
    int co0 = (b & 7) * 8;     // channel group
    float sums[8] = {0.f}, sqs[8] = {0.f};
    for (int r = 0; r < 16; r++) {
      int pix = seg * 4096 + r * 256 + tid;  // 0..393215
      int w = pix & 127; int t = pix >> 7; int h = t % 48; int n = t / 48;
      const float* ip = x + (size_t)n * 48 * 128;
      int ihs[5], iws[5];
#pragma unroll
      for (int k = 0; k < 5; k++) {
        ihs[k] = iclamp(h + k - 2, 0, 47);
        iws[k] = iclamp(w + k - 2, 0, 127);
      }
      float win[25];
#pragma unroll
      for (int kh = 0; kh < 5; kh++)
#pragma unroll
        for (int kw = 0; kw < 5; kw++) win[kh * 5 + kw] = ip[ihs[kh] * 128 + iws[kw]];
#pragma unroll
      for (int j = 0; j < 8; j++) {
        const float* wp = c1w + (size_t)(co0 + j) * 25;
        float acc = 0.f;
#pragma unroll
        for (int k = 0; k < 25; k++) acc += win[k] * wp[k];
        sums[j] += acc; sqs[j] += acc * acc;
      }
    }
    for (int j = 0; j < 8; j++) {
      ls[tid] = sums[j]; lq[tid] = sqs[j];
      __syncthreads();
      for (int o = 128; o > 0; o >>= 1) {
        if (tid < o) { ls[tid] += ls[tid + o]; lq[tid] += lq[tid + o]; }
        __syncthreads();
      }
      if (tid == 0) {
        int c = co0 + j;
        part[((size_t)c * 96 + seg) * 2 + 0] = ls[0];
        part[((size_t)c * 96 + seg) * 2 + 1] = lq[0];
      }
      __syncthreads();
    }
    return;
  }
  b -= 768;
  const float* src = nullptr;
  bf16 *dsth = nullptr;
  int CI = 0, KK = 0, co = 0;
  if (b < 128)        { src = c2w; dsth = Wc2h; CI = 64;  KK = 25; co = b; }
  else if (b < 384)   { src = c3w; dsth = Wc3h; CI = 128; KK = 9;  co = b - 128; }
  else if (b < 896)   { src = c4w; dsth = Wc4h; CI = 256; KK = 9;  co = b - 384; }
  else if (b < 1408)  { src = c5w; dsth = Wc5h; CI = 512; KK = 9; co = b - 896; }
  if (src) {
    const int n = CI * KK;
    const float* sp = src + (size_t)co * n;
    for (int i = tid; i < n; i += 256) buf[i] = sp[i];
    __syncthreads();
    bf16* oh = dsth + (size_t)co * n;
    for (int o = tid; o < n; o += 256) {
      int ci = o & (CI - 1), kk = o / CI;
      oh[o] = (bf16)buf[ci * KK + kk];
    }
    return;
  }
  b -= 1408;
  if (b < 6144) {  // f1w [2048][3072] -> one packed 16x64 tile per block
    int rb = b / 48, kb = b % 48;
    int row0 = rb * 16, k0 = kb * 64;
    {
      int r = tid >> 4, c = (tid & 15) * 4;
      const float4 v = *(const float4*)(f1w + (size_t)(row0 + r) * 3072 + k0 + c);
      buf[r * 64 + c + 0] = v.x; buf[r * 64 + c + 1] = v.y;
      buf[r * 64 + c + 2] = v.z; buf[r * 64 + c + 3] = v.w;
    }
    __syncthreads();
    bf16x4 o4;
#pragma unroll
    for (int j = 0; j < 4; j++) {
      int o = tid * 4 + j;
      int r = (o >> 3) & 15;
      int kl = (o >> 9) * 32 + ((o >> 7) & 3) * 8 + (o & 7);
      o4[j] = (bf16)buf[r * 64 + kl];
    }
    *(bf16x4*)(Wf1 + (size_t)b * 1024 + tid * 4) = o4;
    return;
  }
  b -= 6144;
  if (b < 16384) {  // f2w [2048][7901] -> packed [2048][8192] tiles, guarded
    int rb = b >> 7, kb = b & 127;
    int row0 = rb * 16, k0 = kb * 64;
    {
      int r = tid >> 4, c = (tid & 15) * 4;
      const float* sp = f2w + (size_t)(row0 + r) * 7901 + k0 + c;
#pragma unroll
      for (int j = 0; j < 4; j++)
        buf[r * 64 + c + j] = (k0 + c + j < 7901) ? sp[j] : 0.f;
    }
    __syncthreads();
    bf16x4 o4;
#pragma unroll
    for (int j = 0; j < 4; j++) {
      int o = tid * 4 + j;
      int r = (o >> 3) & 15;
      int kl = (o >> 9) * 32 + ((o >> 7) & 3) * 8 + (o & 7);
      o4[j] = (bf16)buf[r * 64 + kl];
    }
    *(bf16x4*)(Wf2 + (size_t)b * 1024 + tid * 4) = o4;
    return;
  }
  b -= 16384;
  {  // phoc [256][5853] -> packed CC cols [2048,8192) tiles, guarded
    if (b >= 1536) return;
    int rb = b / 96, kb = b % 96;
    int row0 = rb * 16;
    {
      int r = tid >> 4, c = (tid & 15) * 4;
      const float* sp = phoc + (size_t)(row0 + r) * 5853 + kb * 64 + c;
#pragma unroll
      for (int j = 0; j < 4; j++)
        buf[r * 64 + c + j] = (kb * 64 + c + j < 5853) ? sp[j] : 0.f;
    }
    __syncthreads();
    bf16x4 o4;
#pragma unroll
    for (int j = 0; j < 4; j++) {
      int o = tid * 4 + j;
      int r = (o >> 3) & 15;
      int kl = (o >> 9) * 32 + ((o >> 7) & 3) * 8 + (o & 7);
      o4[j] = (bf16)buf[r * 64 + kl];
    }
    *(bf16x4*)(cch + ((size_t)rb * 128 + 32 + kb) * 1024 + tid * 4) = o4;
  }
}

// ---------------- conv1 pass 2: conv+BN+ReLU+pool+pad (8 ch/group) ---------
__global__ __launch_bounds__(256) void conv1_apply_k(const float* __restrict__ x,
                                                     const float* __restrict__ wt,
                                                     const float* __restrict__ scale,
                                                     const float* __restrict__ shift,
                                                     bf16* __restrict__ yh,
                                                     bf16* __restrict__ yl) {
  int i = blockIdx.x * 256 + threadIdx.x;  // padded pixel slots
  if (i >= 64 * 28 * 68) return;
  int owp = i % 68; int t = i / 68; int ohp = t % 28; int n = t / 28;
  int co0 = blockIdx.y * 8;
  int oh = ohp - 2, ow = owp - 2;
  bf16x8 hv, lv;
#pragma unroll
  for (int j = 0; j < 8; j++) { hv[j] = (bf16)0.f; lv[j] = (bf16)0.f; }
  if (oh >= 0 && oh < 24 && ow >= 0 && ow < 64) {
    const float* ip = x + (size_t)n * 48 * 128;
    int shr[6], swc[6];
#pragma unroll
    for (int k = 0; k < 6; k++) {
      shr[k] = iclamp(2 * oh + k - 2, 0, 47);
      swc[k] = iclamp(2 * ow + k - 2, 0, 127);
    }
    float win[36];
#pragma unroll
    for (int r = 0; r < 6; r++)
#pragma unroll
      for (int c = 0; c < 6; c++) win[r * 6 + c] = ip[shr[r] * 128 + swc[c]];
#pragma unroll
    for (int j = 0; j < 8; j++) {
      const float* wp = wt + (size_t)(co0 + j) * 25;
      float sc = scale[co0 + j], sh = shift[co0 + j];
      float m = -1e30f;
#pragma unroll
      for (int dy = 0; dy < 2; dy++)
#pragma unroll
        for (int dx = 0; dx < 2; dx++) {
          float acc = 0.f;
#pragma unroll
          for (int kh = 0; kh < 5; kh++)
#pragma unroll
            for (int kw = 0; kw < 5; kw++)
              acc += win[(kh + dy) * 6 + kw + dx] * wp[kh * 5 + kw];
          m = fmaxf(m, acc * sc + sh);
        }
      float v = fmaxf(m, 0.f);
      bf16 h, l; split2(v, h, l);
      hv[j] = h; lv[j] = l;
    }
  }
  size_t o = (size_t)i * 64 + co0;
  *(bf16x8*)(yh + o) = hv;
  *(bf16x8*)(yl + o) = lv;
}

// ---------------- conv2 specialized: A-resident + fused pool (max/min) -----
__global__ __launch_bounds__(256) void conv2_gemm_k(const bf16* __restrict__ Ahi,
                                                    const bf16* __restrict__ Bhi,
                                                    float* __restrict__ Wmax,
                                                    float* __restrict__ Wmin,
                                                    float* __restrict__ part) {
  __shared__ bf16 Ash[416 * 64];      // 52 KB (reused as exchange post-loop)
  __shared__ bf16 Bsh[128 * 64];      // 16 KB
  __shared__ float red[2][128][8];    // 8 KB
  const int t = threadIdx.x;
  const int lane = t & 63, w = t >> 6;
  const int m0 = blockIdx.x * 128;
  const int img = m0 / 1536;
  const int oh0 = (m0 % 1536) >> 6;   // even
  const size_t abase = ((size_t)(img * 28 + oh0) * 68) * 64;

#pragma unroll
  for (int i = 0; i < 13; i++) {
    int f = i * 256 + t;
    int p = f >> 3; if (p > 407) p = 407;
    int s = f & 7;
    int ss = s ^ (p & 7);
    gld_lds16(Ahi + abase + (size_t)p * 64 + ss * 8,
              (char*)Ash + (size_t)(i * 256 + w * 64) * 16);
  }

  size_t boff[4];
#pragma unroll
  for (int i = 0; i < 4; i++) {
    int f = (i * 4 + w) * 64 + lane;
    int row = f >> 3, slot = f & 7;
    int ss = slot ^ (row & 7);
    boff[i] = (size_t)row * 1600 + ss * 8;
  }

  const int wrow = w >> 1, wcol = w & 1;
  const int kg = lane >> 4, l15 = lane & 15;
  int pixb[4];
#pragma unroll
  for (int q = 0; q < 4; q++) pixb[q] = wrow * 68 + q * 16 + l15;
  int brb[4], bmk[4];
#pragma unroll
  for (int q = 0; q < 4; q++) {
    int rb = wcol * 64 + q * 16 + l15;
    brb[q] = rb * 128; bmk[q] = rb & 7;
  }
  const char* Ashb = (const char*)Ash;
  const char* Bshb = (const char*)Bsh;

  f32x4 acc[4][4] = {};
  for (int kc = 0; kc < 25; ++kc) {
    const int kh = kc / 5, kw = kc % 5;
    const int kofs = kh * 68 + kw;
    const int k0 = kc * 64;
#pragma unroll
    for (int i = 0; i < 4; i++)
      gld_lds16(Bhi + boff[i] + k0, (char*)Bsh + (i * 4 + w) * 1024);
    __syncthreads();
#pragma unroll
    for (int ks = 0; ks < 2; ks++) {
      const int slot = ks * 4 + kg;
      bf16x8 ah[4], bh[4];
#pragma unroll
      for (int q = 0; q < 4; q++) {
        int pix = pixb[q] + kofs;
        ah[q] = *(const bf16x8*)(Ashb + pix * 128 + ((slot ^ (pix & 7)) << 4));
        bh[q] = *(const bf16x8*)(Bshb + brb[q] + ((slot ^ bmk[q]) << 4));
      }
#pragma unroll
      for (int mi = 0; mi < 4; mi++)
#pragma unroll
        for (int ni = 0; ni < 4; ni++)
          acc[mi][ni] = __builtin_amdgcn_mfma_f32_16x16x32_bf16(ah[mi], bh[ni], acc[mi][ni], 0, 0, 0);
    }
    __syncthreads();  // after this, Ash/Bsh free for reuse
  }

  const int ccol = l15;
  float hmx[4][4][2], hmn[4][4][2];
#pragma unroll
  for (int mi = 0; mi < 4; mi++)
#pragma unroll
    for (int ni = 0; ni < 4; ni++)
#pragma unroll
      for (int jp = 0; jp < 2; jp++) {
        float a = acc[mi][ni][2 * jp], b = acc[mi][ni][2 * jp + 1];
        hmx[mi][ni][jp] = fmaxf(a, b);
        hmn[mi][ni][jp] = fminf(a, b);
      }
  const int contrib = kg * 2 + wrow;
#pragma unroll
  for (int ni = 0; ni < 4; ni++) {
    float s = 0.f, q = 0.f;
#pragma unroll
    for (int mi = 0; mi < 4; mi++)
#pragma unroll
      for (int jj = 0; jj < 4; jj++) {
        float v = acc[mi][ni][jj];
        s += v; q += v * v;
      }
    int coll = wcol * 64 + ni * 16 + ccol;
    red[0][coll][contrib] = s;
    red[1][coll][contrib] = q;
  }
  float* exch = (float*)Ash;
  if (wrow == 1) {
    float* ep = exch + (size_t)(wcol * 64 + lane) * 64;
#pragma unroll
    for (int mi = 0; mi < 4; mi++)
#pragma unroll
      for (int ni = 0; ni < 4; ni++)
#pragma unroll
        for (int jp = 0; jp < 2; jp++) {
          int s = (mi * 8 + ni * 2 + jp) * 2;
          ep[s + 0] = hmx[mi][ni][jp];
          ep[s + 1] = hmn[mi][ni][jp];
        }
  }
  __syncthreads();
  if (wrow == 0) {
    const float* ep = exch + (size_t)(wcol * 64 + lane) * 64;
    const int pmb = img * 384 + (oh0 >> 1) * 32;
#pragma unroll
    for (int mi = 0; mi < 4; mi++)
#pragma unroll
      for (int ni = 0; ni < 4; ni++)
#pragma unroll
        for (int jp = 0; jp < 2; jp++) {
          int s = (mi * 8 + ni * 2 + jp) * 2;
          float mx = fmaxf(hmx[mi][ni][jp], ep[s + 0]);
          float mn = fminf(hmn[mi][ni][jp], ep[s + 1]);
          int pm = pmb + mi * 8 + kg * 2 + jp;
          int ch = wcol * 64 + ni * 16 + ccol;
          Wmax[(size_t)pm * 128 + ch] = mx;
          Wmin[(size_t)pm * 128 + ch] = mn;
        }
  }
  if (t < 128) {
    float s = 0.f, q = 0.f;
#pragma unroll
    for (int j = 0; j < 8; j++) { s += red[0][t][j]; q += red[1][t][j]; }
    size_t c = t;
    part[(c * gridDim.x + blockIdx.x) * 2 + 0] = s;
    part[(c * gridDim.x + blockIdx.x) * 2 + 1] = q;
  }
}

// ---------------- MFMA implicit-GEMM, LDS-staged, optional split-K/pool ----
template<int CI, int KS, int OH, int OW, int CO, bool ALO, bool BLO, int SPLIT, bool FUSEPOOL>
__global__ __launch_bounds__(256) void conv_gemm_k(const bf16* __restrict__ Ahi,
                                                   const bf16* __restrict__ Alo,
                                                   const bf16* __restrict__ Bhi,
                                                   const bf16* __restrict__ Blo,
                                                   float* __restrict__ Cout,
                                                   float* __restrict__ Cmin,
                                                   float* __restrict__ part) {
  static_assert(CI % 64 == 0, "chunk must not straddle ci segments");
  static_assert(!FUSEPOOL || (OW == 32 && SPLIT == 1), "fusepool needs OW=32");
  constexpr int K = KS * KS * CI;
  constexpr int IWP = OW + KS - 1;
  constexpr int NCH = K / 64;
  static_assert(NCH % SPLIT == 0, "split must divide chunk count");
  constexpr int NCHS = NCH / SPLIT;
  constexpr int M = 64 * OH * OW;
  __shared__ bf16 Ash[128 * 64];
  __shared__ bf16 Asl[ALO ? 128 * 64 : 64];
  __shared__ bf16 Bsh[128 * 64];
  __shared__ bf16 Bsl[BLO ? 128 * 64 : 64];
  __shared__ float red[2][128][8];
  const int t = threadIdx.x;
  const int lane = t & 63, w = t >> 6;
  const int m0 = blockIdx.x * 128, n0 = blockIdx.y * 128;
  const int z = (SPLIT > 1) ? blockIdx.z : 0;

  int apix[4]; size_t boff[4];
#pragma unroll
  for (int i = 0; i < 4; i++) {
    int f = (i * 4 + w) * 64 + lane;
    int row = f >> 3, slot = f & 7;
    int ss = slot ^ (row & 7);
    int m = m0 + row;
    int n = m / (OH * OW); int rem = m % (OH * OW);
    int oh = rem / OW, ow_ = rem % OW;
    apix[i] = ((n * (OH + KS - 1) + oh) * IWP + ow_) * CI + ss * 8;
    boff[i] = (size_t)(n0 + row) * K + ss * 8;
  }

  const int wrow = w >> 1, wcol = w & 1;
  const int kg = lane >> 4, l15 = lane & 15;
  int arb[4], amk[4], brb[4], bmk[4];
#pragma unroll
  for (int q = 0; q < 4; q++) {
    int ra = wrow * 64 + q * 16 + l15;
    arb[q] = ra * 128; amk[q] = ra & 7;
    int rb = wcol * 64 + q * 16 + l15;
    brb[q] = rb * 128; bmk[q] = rb & 7;
  }
  const char* Ashb = (const char*)Ash;
  const char* Aslb = (const char*)Asl;
  const char* Bshb = (const char*)Bsh;
  const char* Bslb = (const char*)Bsl;

  f32x4 acc[4][4] = {};
  for (int kc = z * NCHS; kc < (z + 1) * NCHS; ++kc) {
    const int k0 = kc * 64;
    const int seg = k0 / CI;
    const int ci0 = k0 % CI;
    const int kh = seg / KS, kw = seg % KS;
    const int aoff = (kh * IWP + kw) * CI + ci0;   // wave-uniform
#pragma unroll
    for (int i = 0; i < 4; i++) {
      gld_lds16(Ahi + (size_t)apix[i] + aoff, (char*)Ash + (i * 4 + w) * 1024);
      if (ALO)
        gld_lds16(Alo + (size_t)apix[i] + aoff, (char*)Asl + (i * 4 + w) * 1024);
      gld_lds16(Bhi + boff[i] + k0,   (char*)Bsh + (i * 4 + w) * 1024);
      if (BLO)
        gld_lds16(Blo + boff[i] + k0, (char*)Bsl + (i * 4 + w) * 1024);
    }
    __syncthreads();
#pragma unroll
    for (int ks = 0; ks < 2; ks++) {
      const int slot = ks * 4 + kg;
      bf16x8 ah[4], bh[4];
#pragma unroll
      for (int q = 0; q < 4; q++) {
        ah[q] = *(const bf16x8*)(Ashb + arb[q] + ((slot ^ amk[q]) << 4));
        bh[q] = *(const bf16x8*)(Bshb + brb[q] + ((slot ^ bmk[q]) << 4));
      }
#pragma unroll
      for (int mi = 0; mi < 4; mi++)
#pragma unroll
        for (int ni = 0; ni < 4; ni++)
          acc[mi][ni] = __builtin_amdgcn_mfma_f32_16x16x32_bf16(ah[mi], bh[ni], acc[mi][ni], 0, 0, 0);
      if (ALO) {
        bf16x8 al[4];
#pragma unroll
        for (int q = 0; q < 4; q++)
          al[q] = *(const bf16x8*)(Aslb + arb[q] + ((slot ^ amk[q]) << 4));
#pragma unroll
        for (int mi = 0; mi < 4; mi++)
#pragma unroll
          for (int ni = 0; ni < 4; ni++)
            acc[mi][ni] = __builtin_amdgcn_mfma_f32_16x16x32_bf16(al[mi], bh[ni], acc[mi][ni], 0, 0, 0);
      }
      if (BLO) {
        bf16x8 bl[4];
#pragma unroll
        for (int q = 0; q < 4; q++)
          bl[q] = *(const bf16x8*)(Bslb + brb[q] + ((slot ^ bmk[q]) << 4));
#pragma unroll
        for (int mi = 0; mi < 4; mi++)
#pragma unroll
          for (int ni = 0; ni < 4; ni++)
            acc[mi][ni] = __builtin_amdgcn_mfma_f32_16x16x32_bf16(ah[mi], bl[ni], acc[mi][ni], 0, 0, 0);
      }
    }
    __syncthreads();
  }

  const int crow0 = kg * 4, ccol = l15;
  if constexpr (FUSEPOOL) {
    const int n_img = m0 / (OH * OW);
    const int oh0 = (m0 % (OH * OW)) / OW;          // multiple of 4
    const int pmb = n_img * (OH / 2) * (OW / 2) + (oh0 / 2 + wrow) * (OW / 2);
#pragma unroll
    for (int mi = 0; mi < 2; mi++)
#pragma unroll
      for (int ni = 0; ni < 4; ni++)
#pragma unroll
        for (int jp = 0; jp < 2; jp++) {
          float a0 = acc[mi][ni][2 * jp],     a1 = acc[mi][ni][2 * jp + 1];
          float b0 = acc[mi + 2][ni][2 * jp], b1 = acc[mi + 2][ni][2 * jp + 1];
          float mx = fmaxf(fmaxf(a0, a1), fmaxf(b0, b1));
          float mn = fminf(fminf(a0, a1), fminf(b0, b1));
          int pm = pmb + mi * 8 + kg * 2 + jp;
          int ch = n0 + wcol * 64 + ni * 16 + ccol;
          Cout[(size_t)pm * CO + ch] = mx;
          Cmin[(size_t)pm * CO + ch] = mn;
        }
  } else {
    float* Cz = Cout + (size_t)z * M * CO;
#pragma unroll
    for (int mi = 0; mi < 4; mi++) {
      int m = m0 + wrow * 64 + mi * 16 + crow0;
#pragma unroll
      for (int ni = 0; ni < 4; ni++) {
        int nn = n0 + wcol * 64 + ni * 16 + ccol;
        float* cp = Cz + (size_t)m * CO + nn;
#pragma unroll
        for (int jj = 0; jj < 4; jj++) cp[(size_t)jj * CO] = acc[mi][ni][jj];
      }
    }
  }
  if constexpr (SPLIT == 1) {
    const int contrib = kg * 2 + wrow;
#pragma unroll
    for (int ni = 0; ni < 4; ni++) {
      float s = 0.f, q = 0.f;
#pragma unroll
      for (int mi = 0; mi < 4; mi++)
#pragma unroll
        for (int jj = 0; jj < 4; jj++) {
          float v = acc[mi][ni][jj];
          s += v; q += v * v;
        }
      int coll = wcol * 64 + ni * 16 + ccol;
      red[0][coll][contrib] = s;
      red[1][coll][contrib] = q;
    }
    __syncthreads();
    if (t < 128) {
      float s = 0.f, q = 0.f;
#pragma unroll
      for (int j = 0; j < 8; j++) { s += red[0][t][j]; q += red[1][t][j]; }
      size_t c = n0 + t;
      part[(c * gridDim.x + blockIdx.x) * 2 + 0] = s;
      part[(c * gridDim.x + blockIdx.x) * 2 + 1] = q;
    }
  }
}

// ---------------- FC GEMM: packed A (hi,+lo if ALO) + packed B, zero LDS ---
template<int K, int SPLIT, bool ALO>
__global__ __launch_bounds__(256) void fc_gemm_k(const bf16* __restrict__ Ahp,
                                                 const bf16* __restrict__ Alp,
                                                 const bf16* __restrict__ Bhp,
                                                 float* __restrict__ Cout) {
  constexpr int Kd64 = K / 64;
  constexpr int NCHS = Kd64 / SPLIT;
  constexpr int M = 256, N = 2048;
  const int t = threadIdx.x;
  const int lane = t & 63, w = t >> 6;
  const int m0 = blockIdx.x * 128, n0 = blockIdx.y * 128;
  const int z = blockIdx.z;
  const int wrow = w >> 1, wcol = w & 1;
  const int kg = lane >> 4, l15 = lane & 15;

  size_t ab[4], bb[4];
#pragma unroll
  for (int q = 0; q < 4; q++) {
    int rbA = (m0 >> 4) + wrow * 4 + q;
    ab[q] = (size_t)rbA * Kd64 * 1024 + (size_t)lane * 8;
    int rbB = (n0 >> 4) + wcol * 4 + q;
    bb[q] = (size_t)rbB * Kd64 * 1024 + (size_t)lane * 8;
  }

  f32x4 acc[4][4] = {};
  for (int kc = z * NCHS; kc < (z + 1) * NCHS; ++kc) {
    const size_t bco = (size_t)kc * 1024;
#pragma unroll
    for (int ks = 0; ks < 2; ks++) {
      const size_t soff = bco + ks * 512;
      bf16x8 ah[4], bh[4];
#pragma unroll
      for (int q = 0; q < 4; q++) {
        ah[q] = *(const bf16x8*)(Ahp + ab[q] + soff);
        bh[q] = *(const bf16x8*)(Bhp + bb[q] + soff);
      }
#pragma unroll
      for (int mi = 0; mi < 4; mi++)
#pragma unroll
        for (int ni = 0; ni < 4; ni++)
          acc[mi][ni] = __builtin_amdgcn_mfma_f32_16x16x32_bf16(ah[mi], bh[ni], acc[mi][ni], 0, 0, 0);
      if (ALO) {
        bf16x8 al[4];
#pragma unroll
        for (int q = 0; q < 4; q++)
          al[q] = *(const bf16x8*)(Alp + ab[q] + soff);
#pragma unroll
        for (int mi = 0; mi < 4; mi++)
#pragma unroll
          for (int ni = 0; ni < 4; ni++)
            acc[mi][ni] = __builtin_amdgcn_mfma_f32_16x16x32_bf16(al[mi], bh[ni], acc[mi][ni], 0, 0, 0);
      }
    }
  }

  const int crow0 = kg * 4, ccol = l15;
  float* Cz = Cout + (size_t)z * M * N;
#pragma unroll
  for (int mi = 0; mi < 4; mi++) {
    int m = m0 + wrow * 64 + mi * 16 + crow0;
#pragma unroll
    for (int ni = 0; ni < 4; ni++) {
      int nn = n0 + wcol * 64 + ni * 16 + ccol;
      float* cp = Cz + (size_t)m * N + nn;
#pragma unroll
      for (int jj = 0; jj < 4; jj++) cp[(size_t)jj * N] = acc[mi][ni][jj];
    }
  }
}

// ---------------- split-K reduction + BN partials ----------------
template<int M, int CO, int SPLIT, int NS>
__global__ __launch_bounds__(256) void reduce_bn_k(const float* __restrict__ Cp,
                                                   float* __restrict__ Cf,
                                                   float* __restrict__ part) {
  int c = blockIdx.x * 64 + (threadIdx.x & 63);
  int rl = threadIdx.x >> 6;
  constexpr int ROWS = M / NS;
  int r0 = blockIdx.y * ROWS;
  float sum = 0.f, sq = 0.f;
  for (int r = r0 + rl; r < r0 + ROWS; r += 4) {
    float v = 0.f;
#pragma unroll
    for (int s = 0; s < SPLIT; s++) v += Cp[(size_t)s * M * CO + (size_t)r * CO + c];
    Cf[(size_t)r * CO + c] = v;
    sum += v; sq += v * v;
  }
  __shared__ float ls[256], lq[256];
  ls[threadIdx.x] = sum; lq[threadIdx.x] = sq;
  __syncthreads();
  if (threadIdx.x < 64) {
    sum = ls[threadIdx.x] + ls[threadIdx.x + 64] + ls[threadIdx.x + 128] + ls[threadIdx.x + 192];
    sq  = lq[threadIdx.x] + lq[threadIdx.x + 64] + lq[threadIdx.x + 128] + lq[threadIdx.x + 192];
    part[((size_t)c * NS + blockIdx.y) * 2 + 0] = sum;
    part[((size_t)c * NS + blockIdx.y) * 2 + 1] = sq;
  }
}

// ---------------- BN finalize: one block per channel, wave butterfly -------
__global__ __launch_bounds__(64) void bn_finalize(const float* __restrict__ part,
                                                  const float* __restrict__ g,
                                                  const float* __restrict__ b,
                                                  float* __restrict__ scale,
                                                  float* __restrict__ shift,
                                                  int S, float invCount) {
  int c = blockIdx.x;
  int lane = threadIdx.x;
  float sum = 0.f, sq = 0.f;
  for (int s = lane; s < S; s += 64) {
    sum += part[((size_t)c * S + s) * 2 + 0];
    sq  += part[((size_t)c * S + s) * 2 + 1];
  }
#pragma unroll
  for (int o = 32; o > 0; o >>= 1) {
    sum += __shfl_xor(sum, o);
    sq  += __shfl_xor(sq, o);
  }
  if (lane == 0) {
    float m = sum * invCount;
    float var = sq * invCount - m * m;
    float sc = g[c] * rsqrtf(var + 1e-5f);
    scale[c] = sc;
    shift[c] = b[c] - m * sc;
  }
}

// ---------------- fused BN + ReLU + pad (no pool), 8ch/thread --------------
template<int CO, int IH, int IW, int PADO>
__global__ __launch_bounds__(256) void bn_act_pad_k(const float* __restrict__ x,
                                                    const float* __restrict__ scale,
                                                    const float* __restrict__ shift,
                                                    bf16* __restrict__ yh,
                                                    bf16* __restrict__ yl) {
  constexpr int OHP = IH + 2 * PADO, OWP = IW + 2 * PADO;
  constexpr int CO8 = CO / 8;
  int i = blockIdx.x * 256 + threadIdx.x;
  if (i >= 64 * OHP * OWP * CO8) return;
  int c8 = i % CO8; int t = i / CO8; int owp = t % OWP; t /= OWP; int ohp = t % OHP; int n = t / OHP;
  int c0 = c8 * 8;
  int oh = ohp - PADO, ow = owp - PADO;
  bf16x8 hv, lv;
#pragma unroll
  for (int j = 0; j < 8; j++) { hv[j] = (bf16)0.f; lv[j] = (bf16)0.f; }
  if (oh >= 0 && oh < IH && ow >= 0 && ow < IW) {
    float sc[8], sh[8];
    *(f32x4*)(sc)     = *(const f32x4*)(scale + c0);
    *(f32x4*)(sc + 4) = *(const f32x4*)(scale + c0 + 4);
    *(f32x4*)(sh)     = *(const f32x4*)(shift + c0);
    *(f32x4*)(sh + 4) = *(const f32x4*)(shift + c0 + 4);
    const float* p = x + (((size_t)(n * IH) + oh) * IW + ow) * CO + c0;
    float ta[8];
    *(f32x4*)(ta) = *(const f32x4*)(p); *(f32x4*)(ta + 4) = *(const f32x4*)(p + 4);
#pragma unroll
    for (int j = 0; j < 8; j++) {
      float vv = fmaxf(ta[j] * sc[j] + sh[j], 0.f);
      bf16 h, l; split2(vv, h, l);
      hv[j] = h; lv[j] = l;
    }
  }
  size_t o = (size_t)i * 8;
  *(bf16x8*)(yh + o) = hv;
  *(bf16x8*)(yl + o) = lv;
}

// ---------------- BN + ReLU + pad from pooled (max,min), 8ch/thread --------
template<int CO, int PH, int PW, int PADO>
__global__ __launch_bounds__(256) void act_pool_pad_k(const float* __restrict__ wmax,
                                                      const float* __restrict__ wmin,
                                                      const float* __restrict__ scale,
                                                      const float* __restrict__ shift,
                                                      bf16* __restrict__ yh,
                                                      bf16* __restrict__ yl) {
  constexpr int OHP = PH + 2 * PADO, OWP = PW + 2 * PADO;
  constexpr int CO8 = CO / 8;
  int i = blockIdx.x * 256 + threadIdx.x;
  if (i >= 64 * OHP * OWP * CO8) return;
  int c8 = i % CO8; int t = i / CO8; int owp = t % OWP; t /= OWP; int ohp = t % OHP; int n = t / OHP;
  int c0 = c8 * 8;
  int oh = ohp - PADO, ow = owp - PADO;
  bf16x8 hv, lv;
#pragma unroll
  for (int j = 0; j < 8; j++) { hv[j] = (bf16)0.f; lv[j] = (bf16)0.f; }
  if (oh >= 0 && oh < PH && ow >= 0 && ow < PW) {
    float sc[8], sh[8], mx[8], mn[8];
    *(f32x4*)(sc)     = *(const f32x4*)(scale + c0);
    *(f32x4*)(sc + 4) = *(const f32x4*)(scale + c0 + 4);
    *(f32x4*)(sh)     = *(const f32x4*)(shift + c0);
    *(f32x4*)(sh + 4) = *(const f32x4*)(shift + c0 + 4);
    size_t off = (((size_t)(n * PH) + oh) * PW + ow) * CO + c0;
    *(f32x4*)(mx)     = *(const f32x4*)(wmax + off);
    *(f32x4*)(mx + 4) = *(const f32x4*)(wmax + off + 4);
    *(f32x4*)(mn)     = *(const f32x4*)(wmin + off);
    *(f32x4*)(mn + 4) = *(const f32x4*)(wmin + off + 4);
#pragma unroll
    for (int j = 0; j < 8; j++) {
      float sel = (sc[j] >= 0.f) ? mx[j] : mn[j];
      float vv = fmaxf(sel * sc[j] + sh[j], 0.f);
      bf16 h, l; split2(vv, h, l);
      hv[j] = h; lv[j] = l;
    }
  }
  size_t o = (size_t)i * 8;
  *(bf16x8*)(yh + o) = hv;
  *(bf16x8*)(yl + o) = lv;
}

// ---------------- ROI SPP: conv5 fp32 + inline BN -> PACKED S hi/lo --------
__global__ __launch_bounds__(256) void spp_k(const float* __restrict__ feat,
                                             const float* __restrict__ scale,
                                             const float* __restrict__ shift,
                                             const int* __restrict__ roi,
                                             bf16* __restrict__ oh_,
                                             bf16* __restrict__ ol_) {
  int c = blockIdx.x * 256 + threadIdx.x;  // 0..511
  int r = blockIdx.y;                      // 0..255
  const int* rp = roi + r * 5;
  int im = rp[0];
  int c1 = rp[1] >> 3, r1 = rp[2] >> 3, c2 = rp[3] >> 3, r2 = rp[4] >> 3;
  int w = c2 - c1 + 1;
  int lo[6], hi[6];
  int bi = 0;
#pragma unroll
  for (int l = 1; l <= 3; l++)
    for (int k = 0; k < l; k++) {
      lo[bi] = c1 + (k * w) / l;
      hi[bi] = c1 + ((k + 1) * w + l - 1) / l - 1;
      bi++;
    }
  float mx[6];
#pragma unroll
  for (int b = 0; b < 6; b++) mx[b] = -1e30f;
  float sc = scale[c], sh = shift[c];
  const float* fp = feat + (size_t)im * 96 * 512 + c;
  for (int row = r1; row <= r2; row++)
    for (int col = c1; col <= c2; col++) {
      float v = fp[(size_t)(row * 16 + col) * 512] * sc + sh;
#pragma unroll
      for (int b = 0; b < 6; b++)
        if (col >= lo[b] && col <= hi[b]) mx[b] = fmaxf(mx[b], v);
    }
  int idx[6] = {c, 512 + c * 2, 512 + c * 2 + 1, 1536 + c * 3, 1536 + c * 3 + 1, 1536 + c * 3 + 2};
#pragma unroll
  for (int b = 0; b < 6; b++) {
    float v = fmaxf(mx[b], 0.f);
    bf16 h, l; split2(v, h, l);
    size_t o = pk_off(r, idx[b], 48);
    oh_[o] = h;
    ol_[o] = l;
  }
}

// FC1: BN+ReLU, write hi PACKED into CC[:, 0:2048] (K=8192); FC2 is 1-pass.
__global__ __launch_bounds__(256) void bn1d_apply_cc_k(const float* __restrict__ x,
                                                       const float* __restrict__ scale,
                                                       const float* __restrict__ shift,
                                                       bf16* __restrict__ ch) {
  int i = blockIdx.x * 256 + threadIdx.x;
  if (i >= 256 * 256) return;
  int f8 = i & 255, r = i >> 8;
  int f0 = f8 * 8;
  float xv[8], sc[8], sh[8];
  *(f32x4*)(xv)     = *(const f32x4*)(x + (size_t)r * 2048 + f0);
  *(f32x4*)(xv + 4) = *(const f32x4*)(x + (size_t)r * 2048 + f0 + 4);
  *(f32x4*)(sc)     = *(const f32x4*)(scale + f0);
  *(f32x4*)(sc + 4) = *(const f32x4*)(scale + f0 + 4);
  *(f32x4*)(sh)     = *(const f32x4*)(shift + f0);
  *(f32x4*)(sh + 4) = *(const f32x4*)(shift + f0 + 4);
  bf16x8 hv;
#pragma unroll
  for (int j = 0; j < 8; j++) {
    float v = fmaxf(xv[j] * sc[j] + sh[j], 0.f);
    hv[j] = (bf16)v;
  }
  *(bf16x8*)(ch + pk_off(r, f0, 128)) = hv;
}

// FC2: BN+ReLU, fp32 out, 4 feat/thread
__global__ __launch_bounds__(256) void bn1d_apply_f32_k(const float* __restrict__ x,
                                                        const float* __restrict__ scale,
                                                        const float* __restrict__ shift,
                                                        float* __restrict__ y) {
  int i = blockIdx.x * 256 + threadIdx.x;
  if (i >= 256 * 512) return;
  int f4 = i & 511, r = i >> 9;
  int f0 = f4 * 4;
  f32x4 xv = *(const f32x4*)(x + (size_t)r * 2048 + f0);
  f32x4 sc = *(const f32x4*)(scale + f0);
  f32x4 sh = *(const f32x4*)(shift + f0);
  f32x4 o;
#pragma unroll
  for (int j = 0; j < 4; j++) o[j] = fmaxf(xv[j] * sc[j] + sh[j], 0.f);
  *(f32x4*)(y + (size_t)r * 2048 + f0) = o;
}

// ============================================================================
extern "C" void kernel_launch(void* const* d_in, const int* in_sizes, int n_in,
                              void* d_out, int out_size, void* d_ws, size_t ws_size,
                              hipStream_t stream) {
  (void)in_sizes; (void)n_in; (void)out_size; (void)ws_size;

  const float* x    = (const float*)d_in[0];
  const int*   roi  = (const int*)  d_in[1];
  const float* phoc = (const float*)d_in[2];
  const float* c1w  = (const float*)d_in[3];
  const float* g1   = (const float*)d_in[5];
  const float* b1   = (const float*)d_in[6];
  const float* c2w  = (const float*)d_in[7];
  const float* g2   = (const float*)d_in[9];
  const float* b2   = (const float*)d_in[10];
  const float* c3w  = (const float*)d_in[11];
  const float* g3   = (const float*)d_in[13];
  const float* b3   = (const float*)d_in[14];
  const float* c4w  = (const float*)d_in[15];
  const float* g4   = (const float*)d_in[17];
  const float* b4   = (const float*)d_in[18];
  const float* c5w  = (const float*)d_in[19];
  const float* g5   = (const float*)d_in[21];
  const float* b5   = (const float*)d_in[22];
  const float* f1w  = (const float*)d_in[23];
  const float* g6   = (const float*)d_in[25];
  const float* b6   = (const float*)d_in[26];
  const float* f2w  = (const float*)d_in[27];
  const float* g7   = (const float*)d_in[29];
  const float* b7   = (const float*)d_in[30];
  float* out = (float*)d_out;

  // ---- workspace layout (total ~168.4 MB) ----
  char* ws = (char*)d_ws;
  bf16*  Ahi  = (bf16*) (ws + 0x0200000);   // 16 MB (padded NHWC activations)
  bf16*  Alo  = (bf16*) (ws + 0x1200000);   // 16 MB
  float* C    = (float*)(ws + 0x2200000);   // GEMM out / split slabs / pooled max
  float* CMIN = (float*)(ws + 0x2E00000);   // pooled min
  float* C5F  = (float*)(ws + 0x4600000);   // conv5 final
  bf16*  Wc2h = (bf16*) (ws + 0x5500000);   // conv weights (row-major [CO][K])
  bf16*  Wc3h = (bf16*) (ws + 0x5570000);
  bf16*  Wc4h = (bf16*) (ws + 0x5600000);
  bf16*  Wc5h = (bf16*) (ws + 0x5840000);
  bf16*  Wf1  = (bf16*) (ws + 0x5CC0000);   // packed FC weights
  bf16*  Wf2  = (bf16*) (ws + 0x68C0000);   // packed [2048][8192] = 32 MB
  bf16*  Shi  = (bf16*) (ws + 0x9080000);   // packed spp out [256][3072]
  bf16*  Slo  = (bf16*) (ws + 0x9200000);
  float* G6   = (float*)(ws + 0x9380000);   // fc1 out fp32 [256][2048]
  bf16*  CChi = (bf16*) (ws + 0x9580000);   // packed concat hi [256][8192] = 4 MB
  float* G7   = (float*)(ws + 0x9D80000);   // fc2 out fp32 [256][2048]
  float* PART = (float*)(ws + 0x9F80000);   // 768 KB
  float* SC   = (float*)(ws + 0xA040000);
  float* SH   = (float*)(ws + 0xA050000);

  // ---- prep: conv1 stats (768) || conv weights (1408) || FC tiles (24064) --
  prep_k<<<26240, 256, 0, stream>>>(x, c1w, PART,
                                    c2w, c3w, c4w, c5w, f1w, f2w, phoc,
                                    Wc2h, Wc3h, Wc4h, Wc5h, Wf1, Wf2,
                                    CChi);

  // ---- conv1 finalize + apply (stats already done inside prep) ----
  bn_finalize<<<64, 64, 0, stream>>>(PART, g1, b1, SC, SH, 96, 1.f / 393216.f);
  conv1_apply_k<<<dim3(476, 8), 256, 0, stream>>>(x, c1w, SC, SH, Ahi, Alo);

  // ---- conv2 (1-pass, A-resident, fused pool): -> pooled max/min [24576][128]
  conv2_gemm_k<<<768, 256, 0, stream>>>(Ahi, Wc2h, C, CMIN, PART);
  bn_finalize<<<128, 64, 0, stream>>>(PART, g2, b2, SC, SH, 768, 1.f / 98304.f);
  act_pool_pad_k<128, 12, 32, 1><<<1904, 256, 0, stream>>>(C, CMIN, SC, SH, Ahi, Alo);

  // ---- conv3 (2-pass: Ah.Bh + Al.Bh, no pool) ----
  conv_gemm_k<128, 3, 12, 32, 256, true, false, 1, false><<<dim3(192, 2), 256, 0, stream>>>(Ahi, Alo, Wc3h, nullptr, C, nullptr, PART);
  bn_finalize<<<256, 64, 0, stream>>>(PART, g3, b3, SC, SH, 192, 1.f / 24576.f);
  bn_act_pad_k<256, 12, 32, 1><<<3808, 256, 0, stream>>>(C, SC, SH, Ahi, Alo);

  // ---- conv4 (1-pass, fused pool): -> pooled max/min [6144][512] ----
  conv_gemm_k<256, 3, 12, 32, 512, false, false, 1, true><<<dim3(192, 4), 256, 0, stream>>>(Ahi, Alo, Wc4h, nullptr, C, CMIN, PART);
  bn_finalize<<<512, 64, 0, stream>>>(PART, g4, b4, SC, SH, 192, 1.f / 24576.f);
  act_pool_pad_k<512, 6, 16, 1><<<2304, 256, 0, stream>>>(C, CMIN, SC, SH, Ahi, Alo);

  // ---- conv5 (1-pass: Ah.Bh, split-K=2): slabs in C, final in C5F ----
  conv_gemm_k<512, 3, 6, 16, 512, false, false, 2, false><<<dim3(48, 4, 2), 256, 0, stream>>>(Ahi, Alo, Wc5h, nullptr, C, nullptr, nullptr);
  reduce_bn_k<6144, 512, 2, 16><<<dim3(8, 16), 256, 0, stream>>>(C, C5F, PART);
  bn_finalize<<<512, 64, 0, stream>>>(PART, g5, b5, SC, SH, 16, 1.f / 6144.f);

  // ---- SPP (reads fp32 conv5 out + inline BN, packed output) ----
  spp_k<<<dim3(2, 256), 256, 0, stream>>>(C5F, SC, SH, roi, Shi, Slo);

  // ---- FC1 (packed, LDS-free, 2-pass, split-K=16): [256][3072] x [2048][3072]
  fc_gemm_k<3072, 16, true><<<dim3(2, 16, 16), 256, 0, stream>>>(Shi, Slo, Wf1, C);
  reduce_bn_k<256, 2048, 16, 4><<<dim3(32, 4), 256, 0, stream>>>(C, G6, PART);
  bn_finalize<<<2048, 64, 0, stream>>>(PART, g6, b6, SC, SH, 4, 1.f / 256.f);
  bn1d_apply_cc_k<<<256, 256, 0, stream>>>(G6, SC, SH, CChi);

  // ---- FC2 (packed, LDS-free, 1-pass, split-K=16): [256][8192] x [2048][8192]
  fc_gemm_k<8192, 16, false><<<dim3(2, 16, 16), 256, 0, stream>>>(CChi, nullptr, Wf2, C);
  reduce_bn_k<256, 2048, 16, 4><<<dim3(32, 4), 256, 0, stream>>>(C, G7, PART);
  bn_finalize<<<2048, 64, 0, stream>>>(PART, g7, b7, SC, SH, 4, 1.f / 256.f);
  bn1d_apply_f32_k<<<512, 256, 0, stream>>>(G7, SC, SH, out);
}

// Round 24
// 486.558 us; speedup vs baseline: 1.4195x; 1.0239x over previous
//
#include <hip/hip_runtime.h>
#include <hip/hip_bf16.h>

// ============================================================================
// HWNet-SPP forward, MFMA bf16 implicit-GEMM with selective hi/lo precision.
// conv2: A-resident kernel; conv3/4/5: 128x128 LDS-staged template; FC1/FC2:
// packed fragment-order operands, zero LDS/barriers. Pooled layers (conv2,
// conv4) fuse the 2x2 pool into the GEMM epilogue as (window-max, window-min)
// dual fp32 writes. prep does conv1 BN stats + LDS-transposed conv weights +
// tile-based packed FC-weight repack (coalesced both sides).
// Pass config (error budget vs absmax threshold 0.098):
//   conv2: Ah*Bh (1-pass)  conv3: +Al*Bh (2-pass)  conv4: 1-pass
//   conv5: Ah*Bh (1-pass, split-K=2)  FC1/FC2: 1-pass (split-K=16)
// lo-activation surfaces are written ONLY where consumed (conv3's input);
// all other lo-writes eliminated as dead traffic. BN stats fused into GEMM
// epilogue / split-K reducer; bn_finalize is one-block-per-channel butterfly.
// conv1 reads x with edge clamping. SPP reads conv5 fp32 out with inline BN.
// Biases skipped (BN cancels).
// ============================================================================

typedef __bf16 bf16;
using bf16x4 = __attribute__((ext_vector_type(4))) __bf16;
using bf16x8 = __attribute__((ext_vector_type(8))) __bf16;
using f32x4  = __attribute__((ext_vector_type(4))) float;

__device__ __forceinline__ void split2(float v, bf16& h, bf16& l) {
  bf16 hb = (bf16)v;
  h = hb;
  l = (bf16)(v - (float)hb);
}

__device__ __forceinline__ int iclamp(int v, int lo, int hi) {
  return v < lo ? lo : (v > hi ? hi : v);
}

__device__ __forceinline__ size_t pk_off(int row, int k, int Kd64) {
  return ((size_t)(row >> 4) * Kd64 + (k >> 6)) * 1024 +
         (size_t)(((k >> 5) & 1) * 512 + ((k >> 3) & 3) * 128 + ((row & 15) << 3) + (k & 7));
}

__device__ __forceinline__ void gld_lds16(const bf16* g, void* lds) {
  __builtin_amdgcn_global_load_lds(
      (const __attribute__((address_space(1))) unsigned int*)g,
      (__attribute__((address_space(3))) unsigned int*)lds, 16, 0, 0);
}

// ---------------- fused prep: conv1 BN stats + all weight/input transforms --
// blocks [0,768): conv1 stats. [768,2176): conv weights (LDS transpose).
// [2176,8320): f1w tiles. [8320,24704): f2w tiles. [24704,26240): phoc tiles.
__global__ __launch_bounds__(256) void prep_k(const float* __restrict__ x,
                                              const float* __restrict__ c1w,
                                              float* __restrict__ part,
                                              const float* __restrict__ c2w,
                                              const float* __restrict__ c3w,
                                              const float* __restrict__ c4w,
                                              const float* __restrict__ c5w,
                                              const float* __restrict__ f1w,
                                              const float* __restrict__ f2w,
                                              const float* __restrict__ phoc,
                                              bf16* __restrict__ Wc2h,
                                              bf16* __restrict__ Wc3h,
                                              bf16* __restrict__ Wc4h,
                                              bf16* __restrict__ Wc5h,
                                              bf16* __restrict__ Wf1,
                                              bf16* __restrict__ Wf2,
                                              bf16* __restrict__ cch) {
  __shared__ float buf[4608];
  __shared__ float ls[256], lq[256];
  int b = blockIdx.x;
  int tid = threadIdx.x;
  if (b < 768) {
    // ---- conv1 BN stats (8 ch/group, edge-clamped reads of x) ----
    int seg = b >> 3;          // 0..95
    int co0 = (b & 7) * 8;     // channel group
    float sums[8] = {0.f}, sqs[8] = {0.f};
    for (int r = 0; r < 16; r++) {
      int pix = seg * 4096 + r * 256 + tid;  // 0..393215
      int w = pix & 127; int t = pix >> 7; int h = t % 48; int n = t / 48;
      const float* ip = x + (size_t)n * 48 * 128;
      int ihs[5], iws[5];
#pragma unroll
      for (int k = 0; k < 5; k++) {
        ihs[k] = iclamp(h + k - 2, 0, 47);
        iws[k] = iclamp(w + k - 2, 0, 127);
      }
      float win[25];
#pragma unroll
      for (int kh = 0; kh < 5; kh++)
#pragma unroll
        for (int kw = 0; kw < 5; kw++) win[kh * 5 + kw] = ip[ihs[kh] * 128 + iws[kw]];
#pragma unroll
      for (int j = 0; j < 8; j++) {
        const float* wp = c1w + (size_t)(co0 + j) * 25;
        float acc = 0.f;
#pragma unroll
        for (int k = 0; k < 25; k++) acc += win[k] * wp[k];
        sums[j] += acc; sqs[j] += acc * acc;
      }
    }
    for (int j = 0; j < 8; j++) {
      ls[tid] = sums[j]; lq[tid] = sqs[j];
      __syncthreads();
      for (int o = 128; o > 0; o >>= 1) {
        if (tid < o) { ls[tid] += ls[tid + o]; lq[tid] += lq[tid + o]; }
        __syncthreads();
      }
      if (tid == 0) {
        int c = co0 + j;
        part[((size_t)c * 96 + seg) * 2 + 0] = ls[0];
        part[((size_t)c * 96 + seg) * 2 + 1] = lq[0];
      }
      __syncthreads();
    }
    return;
  }
  b -= 768;
  const float* src = nullptr;
  bf16 *dsth = nullptr;
  int CI = 0, KK = 0, co = 0;
  if (b < 128)        { src = c2w; dsth = Wc2h; CI = 64;  KK = 25; co = b; }
  else if (b < 384)   { src = c3w; dsth = Wc3h; CI = 128; KK = 9;  co = b - 128; }
  else if (b < 896)   { src = c4w; dsth = Wc4h; CI = 256; KK = 9;  co = b - 384; }
  else if (b < 1408)  { src = c5w; dsth = Wc5h; CI = 512; KK = 9; co = b - 896; }
  if (src) {
    const int n = CI * KK;
    const float* sp = src + (size_t)co * n;
    for (int i = tid; i < n; i += 256) buf[i] = sp[i];
    __syncthreads();
    bf16* oh = dsth + (size_t)co * n;
    for (int o = tid; o < n; o += 256) {
      int ci = o & (CI - 1), kk = o / CI;
      oh[o] = (bf16)buf[ci * KK + kk];
    }
    return;
  }
  b -= 1408;
  if (b < 6144) {  // f1w [2048][3072] -> one packed 16x64 tile per block
    int rb = b / 48, kb = b % 48;
    int row0 = rb * 16, k0 = kb * 64;
    {
      int r = tid >> 4, c = (tid & 15) * 4;
      const float4 v = *(const float4*)(f1w + (size_t)(row0 + r) * 3072 + k0 + c);
      buf[r * 64 + c + 0] = v.x; buf[r * 64 + c + 1] = v.y;
      buf[r * 64 + c + 2] = v.z; buf[r * 64 + c + 3] = v.w;
    }
    __syncthreads();
    bf16x4 o4;
#pragma unroll
    for (int j = 0; j < 4; j++) {
      int o = tid * 4 + j;
      int r = (o >> 3) & 15;
      int kl = (o >> 9) * 32 + ((o >> 7) & 3) * 8 + (o & 7);
      o4[j] = (bf16)buf[r * 64 + kl];
    }
    *(bf16x4*)(Wf1 + (size_t)b * 1024 + tid * 4) = o4;
    return;
  }
  b -= 6144;
  if (b < 16384) {  // f2w [2048][7901] -> packed [2048][8192] tiles, guarded
    int rb = b >> 7, kb = b & 127;
    int row0 = rb * 16, k0 = kb * 64;
    {
      int r = tid >> 4, c = (tid & 15) * 4;
      const float* sp = f2w + (size_t)(row0 + r) * 7901 + k0 + c;
#pragma unroll
      for (int j = 0; j < 4; j++)
        buf[r * 64 + c + j] = (k0 + c + j < 7901) ? sp[j] : 0.f;
    }
    __syncthreads();
    bf16x4 o4;
#pragma unroll
    for (int j = 0; j < 4; j++) {
      int o = tid * 4 + j;
      int r = (o >> 3) & 15;
      int kl = (o >> 9) * 32 + ((o >> 7) & 3) * 8 + (o & 7);
      o4[j] = (bf16)buf[r * 64 + kl];
    }
    *(bf16x4*)(Wf2 + (size_t)b * 1024 + tid * 4) = o4;
    return;
  }
  b -= 16384;
  {  // phoc [256][5853] -> packed CC cols [2048,8192) tiles, guarded
    if (b >= 1536) return;
    int rb = b / 96, kb = b % 96;
    int row0 = rb * 16;
    {
      int r = tid >> 4, c = (tid & 15) * 4;
      const float* sp = phoc + (size_t)(row0 + r) * 5853 + kb * 64 + c;
#pragma unroll
      for (int j = 0; j < 4; j++)
        buf[r * 64 + c + j] = (kb * 64 + c + j < 5853) ? sp[j] : 0.f;
    }
    __syncthreads();
    bf16x4 o4;
#pragma unroll
    for (int j = 0; j < 4; j++) {
      int o = tid * 4 + j;
      int r = (o >> 3) & 15;
      int kl = (o >> 9) * 32 + ((o >> 7) & 3) * 8 + (o & 7);
      o4[j] = (bf16)buf[r * 64 + kl];
    }
    *(bf16x4*)(cch + ((size_t)rb * 128 + 32 + kb) * 1024 + tid * 4) = o4;
  }
}

// ---------------- conv1 pass 2: conv+BN+ReLU+pool+pad, hi-only -------------
__global__ __launch_bounds__(256) void conv1_apply_k(const float* __restrict__ x,
                                                     const float* __restrict__ wt,
                                                     const float* __restrict__ scale,
                                                     const float* __restrict__ shift,
                                                     bf16* __restrict__ yh) {
  int i = blockIdx.x * 256 + threadIdx.x;  // padded pixel slots
  if (i >= 64 * 28 * 68) return;
  int owp = i % 68; int t = i / 68; int ohp = t % 28; int n = t / 28;
  int co0 = blockIdx.y * 8;
  int oh = ohp - 2, ow = owp - 2;
  bf16x8 hv;
#pragma unroll
  for (int j = 0; j < 8; j++) hv[j] = (bf16)0.f;
  if (oh >= 0 && oh < 24 && ow >= 0 && ow < 64) {
    const float* ip = x + (size_t)n * 48 * 128;
    int shr[6], swc[6];
#pragma unroll
    for (int k = 0; k < 6; k++) {
      shr[k] = iclamp(2 * oh + k - 2, 0, 47);
      swc[k] = iclamp(2 * ow + k - 2, 0, 127);
    }
    float win[36];
#pragma unroll
    for (int r = 0; r < 6; r++)
#pragma unroll
      for (int c = 0; c < 6; c++) win[r * 6 + c] = ip[shr[r] * 128 + swc[c]];
#pragma unroll
    for (int j = 0; j < 8; j++) {
      const float* wp = wt + (size_t)(co0 + j) * 25;
      float sc = scale[co0 + j], sh = shift[co0 + j];
      float m = -1e30f;
#pragma unroll
      for (int dy = 0; dy < 2; dy++)
#pragma unroll
        for (int dx = 0; dx < 2; dx++) {
          float acc = 0.f;
#pragma unroll
          for (int kh = 0; kh < 5; kh++)
#pragma unroll
            for (int kw = 0; kw < 5; kw++)
              acc += win[(kh + dy) * 6 + kw + dx] * wp[kh * 5 + kw];
          m = fmaxf(m, acc * sc + sh);
        }
      hv[j] = (bf16)fmaxf(m, 0.f);
    }
  }
  *(bf16x8*)(yh + (size_t)i * 64 + co0) = hv;
}

// ---------------- conv2 specialized: A-resident + fused pool (max/min) -----
__global__ __launch_bounds__(256) void conv2_gemm_k(const bf16* __restrict__ Ahi,
                                                    const bf16* __restrict__ Bhi,
                                                    float* __restrict__ Wmax,
                                                    float* __restrict__ Wmin,
                                                    float* __restrict__ part) {
  __shared__ bf16 Ash[416 * 64];      // 52 KB (reused as exchange post-loop)
  __shared__ bf16 Bsh[128 * 64];      // 16 KB
  __shared__ float red[2][128][8];    // 8 KB
  const int t = threadIdx.x;
  const int lane = t & 63, w = t >> 6;
  const int m0 = blockIdx.x * 128;
  const int img = m0 / 1536;
  const int oh0 = (m0 % 1536) >> 6;   // even
  const size_t abase = ((size_t)(img * 28 + oh0) * 68) * 64;

#pragma unroll
  for (int i = 0; i < 13; i++) {
    int f = i * 256 + t;
    int p = f >> 3; if (p > 407) p = 407;
    int s = f & 7;
    int ss = s ^ (p & 7);
    gld_lds16(Ahi + abase + (size_t)p * 64 + ss * 8,
              (char*)Ash + (size_t)(i * 256 + w * 64) * 16);
  }

  size_t boff[4];
#pragma unroll
  for (int i = 0; i < 4; i++) {
    int f = (i * 4 + w) * 64 + lane;
    int row = f >> 3, slot = f & 7;
    int ss = slot ^ (row & 7);
    boff[i] = (size_t)row * 1600 + ss * 8;
  }

  const int wrow = w >> 1, wcol = w & 1;
  const int kg = lane >> 4, l15 = lane & 15;
  int pixb[4];
#pragma unroll
  for (int q = 0; q < 4; q++) pixb[q] = wrow * 68 + q * 16 + l15;
  int brb[4], bmk[4];
#pragma unroll
  for (int q = 0; q < 4; q++) {
    int rb = wcol * 64 + q * 16 + l15;
    brb[q] = rb * 128; bmk[q] = rb & 7;
  }
  const char* Ashb = (const char*)Ash;
  const char* Bshb = (const char*)Bsh;

  f32x4 acc[4][4] = {};
  for (int kc = 0; kc < 25; ++kc) {
    const int kh = kc / 5, kw = kc % 5;
    const int kofs = kh * 68 + kw;
    const int k0 = kc * 64;
#pragma unroll
    for (int i = 0; i < 4; i++)
      gld_lds16(Bhi + boff[i] + k0, (char*)Bsh + (i * 4 + w) * 1024);
    __syncthreads();
#pragma unroll
    for (int ks = 0; ks < 2; ks++) {
      const int slot = ks * 4 + kg;
      bf16x8 ah[4], bh[4];
#pragma unroll
      for (int q = 0; q < 4; q++) {
        int pix = pixb[q] + kofs;
        ah[q] = *(const bf16x8*)(Ashb + pix * 128 + ((slot ^ (pix & 7)) << 4));
        bh[q] = *(const bf16x8*)(Bshb + brb[q] + ((slot ^ bmk[q]) << 4));
      }
#pragma unroll
      for (int mi = 0; mi < 4; mi++)
#pragma unroll
        for (int ni = 0; ni < 4; ni++)
          acc[mi][ni] = __builtin_amdgcn_mfma_f32_16x16x32_bf16(ah[mi], bh[ni], acc[mi][ni], 0, 0, 0);
    }
    __syncthreads();  // after this, Ash/Bsh free for reuse
  }

  const int ccol = l15;
  float hmx[4][4][2], hmn[4][4][2];
#pragma unroll
  for (int mi = 0; mi < 4; mi++)
#pragma unroll
    for (int ni = 0; ni < 4; ni++)
#pragma unroll
      for (int jp = 0; jp < 2; jp++) {
        float a = acc[mi][ni][2 * jp], b = acc[mi][ni][2 * jp + 1];
        hmx[mi][ni][jp] = fmaxf(a, b);
        hmn[mi][ni][jp] = fminf(a, b);
      }
  const int contrib = kg * 2 + wrow;
#pragma unroll
  for (int ni = 0; ni < 4; ni++) {
    float s = 0.f, q = 0.f;
#pragma unroll
    for (int mi = 0; mi < 4; mi++)
#pragma unroll
      for (int jj = 0; jj < 4; jj++) {
        float v = acc[mi][ni][jj];
        s += v; q += v * v;
      }
    int coll = wcol * 64 + ni * 16 + ccol;
    red[0][coll][contrib] = s;
    red[1][coll][contrib] = q;
  }
  float* exch = (float*)Ash;
  if (wrow == 1) {
    float* ep = exch + (size_t)(wcol * 64 + lane) * 64;
#pragma unroll
    for (int mi = 0; mi < 4; mi++)
#pragma unroll
      for (int ni = 0; ni < 4; ni++)
#pragma unroll
        for (int jp = 0; jp < 2; jp++) {
          int s = (mi * 8 + ni * 2 + jp) * 2;
          ep[s + 0] = hmx[mi][ni][jp];
          ep[s + 1] = hmn[mi][ni][jp];
        }
  }
  __syncthreads();
  if (wrow == 0) {
    const float* ep = exch + (size_t)(wcol * 64 + lane) * 64;
    const int pmb = img * 384 + (oh0 >> 1) * 32;
#pragma unroll
    for (int mi = 0; mi < 4; mi++)
#pragma unroll
      for (int ni = 0; ni < 4; ni++)
#pragma unroll
        for (int jp = 0; jp < 2; jp++) {
          int s = (mi * 8 + ni * 2 + jp) * 2;
          float mx = fmaxf(hmx[mi][ni][jp], ep[s + 0]);
          float mn = fminf(hmn[mi][ni][jp], ep[s + 1]);
          int pm = pmb + mi * 8 + kg * 2 + jp;
          int ch = wcol * 64 + ni * 16 + ccol;
          Wmax[(size_t)pm * 128 + ch] = mx;
          Wmin[(size_t)pm * 128 + ch] = mn;
        }
  }
  if (t < 128) {
    float s = 0.f, q = 0.f;
#pragma unroll
    for (int j = 0; j < 8; j++) { s += red[0][t][j]; q += red[1][t][j]; }
    size_t c = t;
    part[(c * gridDim.x + blockIdx.x) * 2 + 0] = s;
    part[(c * gridDim.x + blockIdx.x) * 2 + 1] = q;
  }
}

// ---------------- MFMA implicit-GEMM, LDS-staged, optional split-K/pool ----
template<int CI, int KS, int OH, int OW, int CO, bool ALO, bool BLO, int SPLIT, bool FUSEPOOL>
__global__ __launch_bounds__(256) void conv_gemm_k(const bf16* __restrict__ Ahi,
                                                   const bf16* __restrict__ Alo,
                                                   const bf16* __restrict__ Bhi,
                                                   const bf16* __restrict__ Blo,
                                                   float* __restrict__ Cout,
                                                   float* __restrict__ Cmin,
                                                   float* __restrict__ part) {
  static_assert(CI % 64 == 0, "chunk must not straddle ci segments");
  static_assert(!FUSEPOOL || (OW == 32 && SPLIT == 1), "fusepool needs OW=32");
  constexpr int K = KS * KS * CI;
  constexpr int IWP = OW + KS - 1;
  constexpr int NCH = K / 64;
  static_assert(NCH % SPLIT == 0, "split must divide chunk count");
  constexpr int NCHS = NCH / SPLIT;
  constexpr int M = 64 * OH * OW;
  __shared__ bf16 Ash[128 * 64];
  __shared__ bf16 Asl[ALO ? 128 * 64 : 64];
  __shared__ bf16 Bsh[128 * 64];
  __shared__ bf16 Bsl[BLO ? 128 * 64 : 64];
  __shared__ float red[2][128][8];
  const int t = threadIdx.x;
  const int lane = t & 63, w = t >> 6;
  const int m0 = blockIdx.x * 128, n0 = blockIdx.y * 128;
  const int z = (SPLIT > 1) ? blockIdx.z : 0;

  int apix[4]; size_t boff[4];
#pragma unroll
  for (int i = 0; i < 4; i++) {
    int f = (i * 4 + w) * 64 + lane;
    int row = f >> 3, slot = f & 7;
    int ss = slot ^ (row & 7);
    int m = m0 + row;
    int n = m / (OH * OW); int rem = m % (OH * OW);
    int oh = rem / OW, ow_ = rem % OW;
    apix[i] = ((n * (OH + KS - 1) + oh) * IWP + ow_) * CI + ss * 8;
    boff[i] = (size_t)(n0 + row) * K + ss * 8;
  }

  const int wrow = w >> 1, wcol = w & 1;
  const int kg = lane >> 4, l15 = lane & 15;
  int arb[4], amk[4], brb[4], bmk[4];
#pragma unroll
  for (int q = 0; q < 4; q++) {
    int ra = wrow * 64 + q * 16 + l15;
    arb[q] = ra * 128; amk[q] = ra & 7;
    int rb = wcol * 64 + q * 16 + l15;
    brb[q] = rb * 128; bmk[q] = rb & 7;
  }
  const char* Ashb = (const char*)Ash;
  const char* Aslb = (const char*)Asl;
  const char* Bshb = (const char*)Bsh;
  const char* Bslb = (const char*)Bsl;

  f32x4 acc[4][4] = {};
  for (int kc = z * NCHS; kc < (z + 1) * NCHS; ++kc) {
    const int k0 = kc * 64;
    const int seg = k0 / CI;
    const int ci0 = k0 % CI;
    const int kh = seg / KS, kw = seg % KS;
    const int aoff = (kh * IWP + kw) * CI + ci0;   // wave-uniform
#pragma unroll
    for (int i = 0; i < 4; i++) {
      gld_lds16(Ahi + (size_t)apix[i] + aoff, (char*)Ash + (i * 4 + w) * 1024);
      if (ALO)
        gld_lds16(Alo + (size_t)apix[i] + aoff, (char*)Asl + (i * 4 + w) * 1024);
      gld_lds16(Bhi + boff[i] + k0,   (char*)Bsh + (i * 4 + w) * 1024);
      if (BLO)
        gld_lds16(Blo + boff[i] + k0, (char*)Bsl + (i * 4 + w) * 1024);
    }
    __syncthreads();
#pragma unroll
    for (int ks = 0; ks < 2; ks++) {
      const int slot = ks * 4 + kg;
      bf16x8 ah[4], bh[4];
#pragma unroll
      for (int q = 0; q < 4; q++) {
        ah[q] = *(const bf16x8*)(Ashb + arb[q] + ((slot ^ amk[q]) << 4));
        bh[q] = *(const bf16x8*)(Bshb + brb[q] + ((slot ^ bmk[q]) << 4));
      }
#pragma unroll
      for (int mi = 0; mi < 4; mi++)
#pragma unroll
        for (int ni = 0; ni < 4; ni++)
          acc[mi][ni] = __builtin_amdgcn_mfma_f32_16x16x32_bf16(ah[mi], bh[ni], acc[mi][ni], 0, 0, 0);
      if (ALO) {
        bf16x8 al[4];
#pragma unroll
        for (int q = 0; q < 4; q++)
          al[q] = *(const bf16x8*)(Aslb + arb[q] + ((slot ^ amk[q]) << 4));
#pragma unroll
        for (int mi = 0; mi < 4; mi++)
#pragma unroll
          for (int ni = 0; ni < 4; ni++)
            acc[mi][ni] = __builtin_amdgcn_mfma_f32_16x16x32_bf16(al[mi], bh[ni], acc[mi][ni], 0, 0, 0);
      }
      if (BLO) {
        bf16x8 bl[4];
#pragma unroll
        for (int q = 0; q < 4; q++)
          bl[q] = *(const bf16x8*)(Bslb + brb[q] + ((slot ^ bmk[q]) << 4));
#pragma unroll
        for (int mi = 0; mi < 4; mi++)
#pragma unroll
          for (int ni = 0; ni < 4; ni++)
            acc[mi][ni] = __builtin_amdgcn_mfma_f32_16x16x32_bf16(ah[mi], bl[ni], acc[mi][ni], 0, 0, 0);
      }
    }
    __syncthreads();
  }

  const int crow0 = kg * 4, ccol = l15;
  if constexpr (FUSEPOOL) {
    const int n_img = m0 / (OH * OW);
    const int oh0 = (m0 % (OH * OW)) / OW;          // multiple of 4
    const int pmb = n_img * (OH / 2) * (OW / 2) + (oh0 / 2 + wrow) * (OW / 2);
#pragma unroll
    for (int mi = 0; mi < 2; mi++)
#pragma unroll
      for (int ni = 0; ni < 4; ni++)
#pragma unroll
        for (int jp = 0; jp < 2; jp++) {
          float a0 = acc[mi][ni][2 * jp],     a1 = acc[mi][ni][2 * jp + 1];
          float b0 = acc[mi + 2][ni][2 * jp], b1 = acc[mi + 2][ni][2 * jp + 1];
          float mx = fmaxf(fmaxf(a0, a1), fmaxf(b0, b1));
          float mn = fminf(fminf(a0, a1), fminf(b0, b1));
          int pm = pmb + mi * 8 + kg * 2 + jp;
          int ch = n0 + wcol * 64 + ni * 16 + ccol;
          Cout[(size_t)pm * CO + ch] = mx;
          Cmin[(size_t)pm * CO + ch] = mn;
        }
  } else {
    float* Cz = Cout + (size_t)z * M * CO;
#pragma unroll
    for (int mi = 0; mi < 4; mi++) {
      int m = m0 + wrow * 64 + mi * 16 + crow0;
#pragma unroll
      for (int ni = 0; ni < 4; ni++) {
        int nn = n0 + wcol * 64 + ni * 16 + ccol;
        float* cp = Cz + (size_t)m * CO + nn;
#pragma unroll
        for (int jj = 0; jj < 4; jj++) cp[(size_t)jj * CO] = acc[mi][ni][jj];
      }
    }
  }
  if constexpr (SPLIT == 1) {
    const int contrib = kg * 2 + wrow;
#pragma unroll
    for (int ni = 0; ni < 4; ni++) {
      float s = 0.f, q = 0.f;
#pragma unroll
      for (int mi = 0; mi < 4; mi++)
#pragma unroll
        for (int jj = 0; jj < 4; jj++) {
          float v = acc[mi][ni][jj];
          s += v; q += v * v;
        }
      int coll = wcol * 64 + ni * 16 + ccol;
      red[0][coll][contrib] = s;
      red[1][coll][contrib] = q;
    }
    __syncthreads();
    if (t < 128) {
      float s = 0.f, q = 0.f;
#pragma unroll
      for (int j = 0; j < 8; j++) { s += red[0][t][j]; q += red[1][t][j]; }
      size_t c = n0 + t;
      part[(c * gridDim.x + blockIdx.x) * 2 + 0] = s;
      part[(c * gridDim.x + blockIdx.x) * 2 + 1] = q;
    }
  }
}

// ---------------- FC GEMM: packed A (hi,+lo if ALO) + packed B, zero LDS ---
template<int K, int SPLIT, bool ALO>
__global__ __launch_bounds__(256) void fc_gemm_k(const bf16* __restrict__ Ahp,
                                                 const bf16* __restrict__ Alp,
                                                 const bf16* __restrict__ Bhp,
                                                 float* __restrict__ Cout) {
  constexpr int Kd64 = K / 64;
  constexpr int NCHS = Kd64 / SPLIT;
  constexpr int M = 256, N = 2048;
  const int t = threadIdx.x;
  const int lane = t & 63, w = t >> 6;
  const int m0 = blockIdx.x * 128, n0 = blockIdx.y * 128;
  const int z = blockIdx.z;
  const int wrow = w >> 1, wcol = w & 1;
  const int kg = lane >> 4, l15 = lane & 15;

  size_t ab[4], bb[4];
#pragma unroll
  for (int q = 0; q < 4; q++) {
    int rbA = (m0 >> 4) + wrow * 4 + q;
    ab[q] = (size_t)rbA * Kd64 * 1024 + (size_t)lane * 8;
    int rbB = (n0 >> 4) + wcol * 4 + q;
    bb[q] = (size_t)rbB * Kd64 * 1024 + (size_t)lane * 8;
  }

  f32x4 acc[4][4] = {};
  for (int kc = z * NCHS; kc < (z + 1) * NCHS; ++kc) {
    const size_t bco = (size_t)kc * 1024;
#pragma unroll
    for (int ks = 0; ks < 2; ks++) {
      const size_t soff = bco + ks * 512;
      bf16x8 ah[4], bh[4];
#pragma unroll
      for (int q = 0; q < 4; q++) {
        ah[q] = *(const bf16x8*)(Ahp + ab[q] + soff);
        bh[q] = *(const bf16x8*)(Bhp + bb[q] + soff);
      }
#pragma unroll
      for (int mi = 0; mi < 4; mi++)
#pragma unroll
        for (int ni = 0; ni < 4; ni++)
          acc[mi][ni] = __builtin_amdgcn_mfma_f32_16x16x32_bf16(ah[mi], bh[ni], acc[mi][ni], 0, 0, 0);
      if (ALO) {
        bf16x8 al[4];
#pragma unroll
        for (int q = 0; q < 4; q++)
          al[q] = *(const bf16x8*)(Alp + ab[q] + soff);
#pragma unroll
        for (int mi = 0; mi < 4; mi++)
#pragma unroll
          for (int ni = 0; ni < 4; ni++)
            acc[mi][ni] = __builtin_amdgcn_mfma_f32_16x16x32_bf16(al[mi], bh[ni], acc[mi][ni], 0, 0, 0);
      }
    }
  }

  const int crow0 = kg * 4, ccol = l15;
  float* Cz = Cout + (size_t)z * M * N;
#pragma unroll
  for (int mi = 0; mi < 4; mi++) {
    int m = m0 + wrow * 64 + mi * 16 + crow0;
#pragma unroll
    for (int ni = 0; ni < 4; ni++) {
      int nn = n0 + wcol * 64 + ni * 16 + ccol;
      float* cp = Cz + (size_t)m * N + nn;
#pragma unroll
      for (int jj = 0; jj < 4; jj++) cp[(size_t)jj * N] = acc[mi][ni][jj];
    }
  }
}

// ---------------- split-K reduction + BN partials ----------------
template<int M, int CO, int SPLIT, int NS>
__global__ __launch_bounds__(256) void reduce_bn_k(const float* __restrict__ Cp,
                                                   float* __restrict__ Cf,
                                                   float* __restrict__ part) {
  int c = blockIdx.x * 64 + (threadIdx.x & 63);
  int rl = threadIdx.x >> 6;
  constexpr int ROWS = M / NS;
  int r0 = blockIdx.y * ROWS;
  float sum = 0.f, sq = 0.f;
  for (int r = r0 + rl; r < r0 + ROWS; r += 4) {
    float v = 0.f;
#pragma unroll
    for (int s = 0; s < SPLIT; s++) v += Cp[(size_t)s * M * CO + (size_t)r * CO + c];
    Cf[(size_t)r * CO + c] = v;
    sum += v; sq += v * v;
  }
  __shared__ float ls[256], lq[256];
  ls[threadIdx.x] = sum; lq[threadIdx.x] = sq;
  __syncthreads();
  if (threadIdx.x < 64) {
    sum = ls[threadIdx.x] + ls[threadIdx.x + 64] + ls[threadIdx.x + 128] + ls[threadIdx.x + 192];
    sq  = lq[threadIdx.x] + lq[threadIdx.x + 64] + lq[threadIdx.x + 128] + lq[threadIdx.x + 192];
    part[((size_t)c * NS + blockIdx.y) * 2 + 0] = sum;
    part[((size_t)c * NS + blockIdx.y) * 2 + 1] = sq;
  }
}

// ---------------- BN finalize: one block per channel, wave butterfly -------
__global__ __launch_bounds__(64) void bn_finalize(const float* __restrict__ part,
                                                  const float* __restrict__ g,
                                                  const float* __restrict__ b,
                                                  float* __restrict__ scale,
                                                  float* __restrict__ shift,
                                                  int S, float invCount) {
  int c = blockIdx.x;
  int lane = threadIdx.x;
  float sum = 0.f, sq = 0.f;
  for (int s = lane; s < S; s += 64) {
    sum += part[((size_t)c * S + s) * 2 + 0];
    sq  += part[((size_t)c * S + s) * 2 + 1];
  }
#pragma unroll
  for (int o = 32; o > 0; o >>= 1) {
    sum += __shfl_xor(sum, o);
    sq  += __shfl_xor(sq, o);
  }
  if (lane == 0) {
    float m = sum * invCount;
    float var = sq * invCount - m * m;
    float sc = g[c] * rsqrtf(var + 1e-5f);
    scale[c] = sc;
    shift[c] = b[c] - m * sc;
  }
}

// ---------------- fused BN + ReLU + pad (no pool), hi-only, 8ch/thread -----
template<int CO, int IH, int IW, int PADO>
__global__ __launch_bounds__(256) void bn_act_pad_k(const float* __restrict__ x,
                                                    const float* __restrict__ scale,
                                                    const float* __restrict__ shift,
                                                    bf16* __restrict__ yh) {
  constexpr int OHP = IH + 2 * PADO, OWP = IW + 2 * PADO;
  constexpr int CO8 = CO / 8;
  int i = blockIdx.x * 256 + threadIdx.x;
  if (i >= 64 * OHP * OWP * CO8) return;
  int c8 = i % CO8; int t = i / CO8; int owp = t % OWP; t /= OWP; int ohp = t % OHP; int n = t / OHP;
  int c0 = c8 * 8;
  int oh = ohp - PADO, ow = owp - PADO;
  bf16x8 hv;
#pragma unroll
  for (int j = 0; j < 8; j++) hv[j] = (bf16)0.f;
  if (oh >= 0 && oh < IH && ow >= 0 && ow < IW) {
    float sc[8], sh[8];
    *(f32x4*)(sc)     = *(const f32x4*)(scale + c0);
    *(f32x4*)(sc + 4) = *(const f32x4*)(scale + c0 + 4);
    *(f32x4*)(sh)     = *(const f32x4*)(shift + c0);
    *(f32x4*)(sh + 4) = *(const f32x4*)(shift + c0 + 4);
    const float* p = x + (((size_t)(n * IH) + oh) * IW + ow) * CO + c0;
    float ta[8];
    *(f32x4*)(ta) = *(const f32x4*)(p); *(f32x4*)(ta + 4) = *(const f32x4*)(p + 4);
#pragma unroll
    for (int j = 0; j < 8; j++)
      hv[j] = (bf16)fmaxf(ta[j] * sc[j] + sh[j], 0.f);
  }
  *(bf16x8*)(yh + (size_t)i * 8) = hv;
}

// ---------------- BN + ReLU + pad from pooled (max,min), 8ch/thread --------
template<int CO, int PH, int PW, int PADO, bool WRLO>
__global__ __launch_bounds__(256) void act_pool_pad_k(const float* __restrict__ wmax,
                                                      const float* __restrict__ wmin,
                                                      const float* __restrict__ scale,
                                                      const float* __restrict__ shift,
                                                      bf16* __restrict__ yh,
                                                      bf16* __restrict__ yl) {
  constexpr int OHP = PH + 2 * PADO, OWP = PW + 2 * PADO;
  constexpr int CO8 = CO / 8;
  int i = blockIdx.x * 256 + threadIdx.x;
  if (i >= 64 * OHP * OWP * CO8) return;
  int c8 = i % CO8; int t = i / CO8; int owp = t % OWP; t /= OWP; int ohp = t % OHP; int n = t / OHP;
  int c0 = c8 * 8;
  int oh = ohp - PADO, ow = owp - PADO;
  bf16x8 hv, lv;
#pragma unroll
  for (int j = 0; j < 8; j++) { hv[j] = (bf16)0.f; lv[j] = (bf16)0.f; }
  if (oh >= 0 && oh < PH && ow >= 0 && ow < PW) {
    float sc[8], sh[8], mx[8], mn[8];
    *(f32x4*)(sc)     = *(const f32x4*)(scale + c0);
    *(f32x4*)(sc + 4) = *(const f32x4*)(scale + c0 + 4);
    *(f32x4*)(sh)     = *(const f32x4*)(shift + c0);
    *(f32x4*)(sh + 4) = *(const f32x4*)(shift + c0 + 4);
    size_t off = (((size_t)(n * PH) + oh) * PW + ow) * CO + c0;
    *(f32x4*)(mx)     = *(const f32x4*)(wmax + off);
    *(f32x4*)(mx + 4) = *(const f32x4*)(wmax + off + 4);
    *(f32x4*)(mn)     = *(const f32x4*)(wmin + off);
    *(f32x4*)(mn + 4) = *(const f32x4*)(wmin + off + 4);
#pragma unroll
    for (int j = 0; j < 8; j++) {
      float sel = (sc[j] >= 0.f) ? mx[j] : mn[j];
      float vv = fmaxf(sel * sc[j] + sh[j], 0.f);
      if (WRLO) {
        bf16 h, l; split2(vv, h, l);
        hv[j] = h; lv[j] = l;
      } else {
        hv[j] = (bf16)vv;
      }
    }
  }
  size_t o = (size_t)i * 8;
  *(bf16x8*)(yh + o) = hv;
  if (WRLO) *(bf16x8*)(yl + o) = lv;
}

// ---------------- ROI SPP: conv5 fp32 + inline BN -> PACKED S hi ----------
__global__ __launch_bounds__(256) void spp_k(const float* __restrict__ feat,
                                             const float* __restrict__ scale,
                                             const float* __restrict__ shift,
                                             const int* __restrict__ roi,
                                             bf16* __restrict__ oh_) {
  int c = blockIdx.x * 256 + threadIdx.x;  // 0..511
  int r = blockIdx.y;                      // 0..255
  const int* rp = roi + r * 5;
  int im = rp[0];
  int c1 = rp[1] >> 3, r1 = rp[2] >> 3, c2 = rp[3] >> 3, r2 = rp[4] >> 3;
  int w = c2 - c1 + 1;
  int lo[6], hi[6];
  int bi = 0;
#pragma unroll
  for (int l = 1; l <= 3; l++)
    for (int k = 0; k < l; k++) {
      lo[bi] = c1 + (k * w) / l;
      hi[bi] = c1 + ((k + 1) * w + l - 1) / l - 1;
      bi++;
    }
  float mx[6];
#pragma unroll
  for (int b = 0; b < 6; b++) mx[b] = -1e30f;
  float sc = scale[c], sh = shift[c];
  const float* fp = feat + (size_t)im * 96 * 512 + c;
  for (int row = r1; row <= r2; row++)
    for (int col = c1; col <= c2; col++) {
      float v = fp[(size_t)(row * 16 + col) * 512] * sc + sh;
#pragma unroll
      for (int b = 0; b < 6; b++)
        if (col >= lo[b] && col <= hi[b]) mx[b] = fmaxf(mx[b], v);
    }
  int idx[6] = {c, 512 + c * 2, 512 + c * 2 + 1, 1536 + c * 3, 1536 + c * 3 + 1, 1536 + c * 3 + 2};
#pragma unroll
  for (int b = 0; b < 6; b++)
    oh_[pk_off(r, idx[b], 48)] = (bf16)fmaxf(mx[b], 0.f);
}

// FC1: BN+ReLU, write hi PACKED into CC[:, 0:2048] (K=8192); FC2 is 1-pass.
__global__ __launch_bounds__(256) void bn1d_apply_cc_k(const float* __restrict__ x,
                                                       const float* __restrict__ scale,
                                                       const float* __restrict__ shift,
                                                       bf16* __restrict__ ch) {
  int i = blockIdx.x * 256 + threadIdx.x;
  if (i >= 256 * 256) return;
  int f8 = i & 255, r = i >> 8;
  int f0 = f8 * 8;
  float xv[8], sc[8], sh[8];
  *(f32x4*)(xv)     = *(const f32x4*)(x + (size_t)r * 2048 + f0);
  *(f32x4*)(xv + 4) = *(const f32x4*)(x + (size_t)r * 2048 + f0 + 4);
  *(f32x4*)(sc)     = *(const f32x4*)(scale + f0);
  *(f32x4*)(sc + 4) = *(const f32x4*)(scale + f0 + 4);
  *(f32x4*)(sh)     = *(const f32x4*)(shift + f0);
  *(f32x4*)(sh + 4) = *(const f32x4*)(shift + f0 + 4);
  bf16x8 hv;
#pragma unroll
  for (int j = 0; j < 8; j++) {
    float v = fmaxf(xv[j] * sc[j] + sh[j], 0.f);
    hv[j] = (bf16)v;
  }
  *(bf16x8*)(ch + pk_off(r, f0, 128)) = hv;
}

// FC2: BN+ReLU, fp32 out, 4 feat/thread
__global__ __launch_bounds__(256) void bn1d_apply_f32_k(const float* __restrict__ x,
                                                        const float* __restrict__ scale,
                                                        const float* __restrict__ shift,
                                                        float* __restrict__ y) {
  int i = blockIdx.x * 256 + threadIdx.x;
  if (i >= 256 * 512) return;
  int f4 = i & 511, r = i >> 9;
  int f0 = f4 * 4;
  f32x4 xv = *(const f32x4*)(x + (size_t)r * 2048 + f0);
  f32x4 sc = *(const f32x4*)(scale + f0);
  f32x4 sh = *(const f32x4*)(shift + f0);
  f32x4 o;
#pragma unroll
  for (int j = 0; j < 4; j++) o[j] = fmaxf(xv[j] * sc[j] + sh[j], 0.f);
  *(f32x4*)(y + (size_t)r * 2048 + f0) = o;
}

// ============================================================================
extern "C" void kernel_launch(void* const* d_in, const int* in_sizes, int n_in,
                              void* d_out, int out_size, void* d_ws, size_t ws_size,
                              hipStream_t stream) {
  (void)in_sizes; (void)n_in; (void)out_size; (void)ws_size;

  const float* x    = (const float*)d_in[0];
  const int*   roi  = (const int*)  d_in[1];
  const float* phoc = (const float*)d_in[2];
  const float* c1w  = (const float*)d_in[3];
  const float* g1   = (const float*)d_in[5];
  const float* b1   = (const float*)d_in[6];
  const float* c2w  = (const float*)d_in[7];
  const float* g2   = (const float*)d_in[9];
  const float* b2   = (const float*)d_in[10];
  const float* c3w  = (const float*)d_in[11];
  const float* g3   = (const float*)d_in[13];
  const float* b3   = (const float*)d_in[14];
  const float* c4w  = (const float*)d_in[15];
  const float* g4   = (const float*)d_in[17];
  const float* b4   = (const float*)d_in[18];
  const float* c5w  = (const float*)d_in[19];
  const float* g5   = (const float*)d_in[21];
  const float* b5   = (const float*)d_in[22];
  const float* f1w  = (const float*)d_in[23];
  const float* g6   = (const float*)d_in[25];
  const float* b6   = (const float*)d_in[26];
  const float* f2w  = (const float*)d_in[27];
  const float* g7   = (const float*)d_in[29];
  const float* b7   = (const float*)d_in[30];
  float* out = (float*)d_out;

  // ---- workspace layout (total ~168.4 MB) ----
  char* ws = (char*)d_ws;
  bf16*  Ahi  = (bf16*) (ws + 0x0200000);   // 16 MB (padded NHWC activations)
  bf16*  Alo  = (bf16*) (ws + 0x1200000);   // 16 MB (only conv3's input live)
  float* C    = (float*)(ws + 0x2200000);   // GEMM out / split slabs / pooled max
  float* CMIN = (float*)(ws + 0x2E00000);   // pooled min
  float* C5F  = (float*)(ws + 0x4600000);   // conv5 final
  bf16*  Wc2h = (bf16*) (ws + 0x5500000);   // conv weights (row-major [CO][K])
  bf16*  Wc3h = (bf16*) (ws + 0x5570000);
  bf16*  Wc4h = (bf16*) (ws + 0x5600000);
  bf16*  Wc5h = (bf16*) (ws + 0x5840000);
  bf16*  Wf1  = (bf16*) (ws + 0x5CC0000);   // packed FC weights
  bf16*  Wf2  = (bf16*) (ws + 0x68C0000);   // packed [2048][8192] = 32 MB
  bf16*  Shi  = (bf16*) (ws + 0x9080000);   // packed spp out [256][3072]
  float* G6   = (float*)(ws + 0x9380000);   // fc1 out fp32 [256][2048]
  bf16*  CChi = (bf16*) (ws + 0x9580000);   // packed concat hi [256][8192] = 4 MB
  float* G7   = (float*)(ws + 0x9D80000);   // fc2 out fp32 [256][2048]
  float* PART = (float*)(ws + 0x9F80000);   // 768 KB
  float* SC   = (float*)(ws + 0xA040000);
  float* SH   = (float*)(ws + 0xA050000);

  // ---- prep: conv1 stats (768) || conv weights (1408) || FC tiles (24064) --
  prep_k<<<26240, 256, 0, stream>>>(x, c1w, PART,
                                    c2w, c3w, c4w, c5w, f1w, f2w, phoc,
                                    Wc2h, Wc3h, Wc4h, Wc5h, Wf1, Wf2,
                                    CChi);

  // ---- conv1 finalize + apply (stats already done inside prep) ----
  bn_finalize<<<64, 64, 0, stream>>>(PART, g1, b1, SC, SH, 96, 1.f / 393216.f);
  conv1_apply_k<<<dim3(476, 8), 256, 0, stream>>>(x, c1w, SC, SH, Ahi);

  // ---- conv2 (1-pass, A-resident, fused pool): -> pooled max/min [24576][128]
  conv2_gemm_k<<<768, 256, 0, stream>>>(Ahi, Wc2h, C, CMIN, PART);
  bn_finalize<<<128, 64, 0, stream>>>(PART, g2, b2, SC, SH, 768, 1.f / 98304.f);
  act_pool_pad_k<128, 12, 32, 1, true><<<1904, 256, 0, stream>>>(C, CMIN, SC, SH, Ahi, Alo);

  // ---- conv3 (2-pass: Ah.Bh + Al.Bh, no pool) ----
  conv_gemm_k<128, 3, 12, 32, 256, true, false, 1, false><<<dim3(192, 2), 256, 0, stream>>>(Ahi, Alo, Wc3h, nullptr, C, nullptr, PART);
  bn_finalize<<<256, 64, 0, stream>>>(PART, g3, b3, SC, SH, 192, 1.f / 24576.f);
  bn_act_pad_k<256, 12, 32, 1><<<3808, 256, 0, stream>>>(C, SC, SH, Ahi);

  // ---- conv4 (1-pass, fused pool): -> pooled max/min [6144][512] ----
  conv_gemm_k<256, 3, 12, 32, 512, false, false, 1, true><<<dim3(192, 4), 256, 0, stream>>>(Ahi, Alo, Wc4h, nullptr, C, CMIN, PART);
  bn_finalize<<<512, 64, 0, stream>>>(PART, g4, b4, SC, SH, 192, 1.f / 24576.f);
  act_pool_pad_k<512, 6, 16, 1, false><<<2304, 256, 0, stream>>>(C, CMIN, SC, SH, Ahi, nullptr);

  // ---- conv5 (1-pass: Ah.Bh, split-K=2): slabs in C, final in C5F ----
  conv_gemm_k<512, 3, 6, 16, 512, false, false, 2, false><<<dim3(48, 4, 2), 256, 0, stream>>>(Ahi, Alo, Wc5h, nullptr, C, nullptr, nullptr);
  reduce_bn_k<6144, 512, 2, 16><<<dim3(8, 16), 256, 0, stream>>>(C, C5F, PART);
  bn_finalize<<<512, 64, 0, stream>>>(PART, g5, b5, SC, SH, 16, 1.f / 6144.f);

  // ---- SPP (reads fp32 conv5 out + inline BN, packed hi output) ----
  spp_k<<<dim3(2, 256), 256, 0, stream>>>(C5F, SC, SH, roi, Shi);

  // ---- FC1 (packed, LDS-free, 1-pass, split-K=16): [256][3072] x [2048][3072]
  fc_gemm_k<3072, 16, false><<<dim3(2, 16, 16), 256, 0, stream>>>(Shi, nullptr, Wf1, C);
  reduce_bn_k<256, 2048, 16, 4><<<dim3(32, 4), 256, 0, stream>>>(C, G6, PART);
  bn_finalize<<<2048, 64, 0, stream>>>(PART, g6, b6, SC, SH, 4, 1.f / 256.f);
  bn1d_apply_cc_k<<<256, 256, 0, stream>>>(G6, SC, SH, CChi);

  // ---- FC2 (packed, LDS-free, 1-pass, split-K=16): [256][8192] x [2048][8192]
  fc_gemm_k<8192, 16, false><<<dim3(2, 16, 16), 256, 0, stream>>>(CChi, nullptr, Wf2, C);
  reduce_bn_k<256, 2048, 16, 4><<<dim3(32, 4), 256, 0, stream>>>(C, G7, PART);
  bn_finalize<<<2048, 64, 0, stream>>>(PART, g7, b7, SC, SH, 4, 1.f / 256.f);
  bn1d_apply_f32_k<<<512, 256, 0, stream>>>(G7, SC, SH, out);
}

// Round 25
// 478.870 us; speedup vs baseline: 1.4423x; 1.0161x over previous
//
#include <hip/hip_runtime.h>
#include <hip/hip_bf16.h>

// ============================================================================
// HWNet-SPP forward, MFMA bf16 implicit-GEMM. ALL GEMMs now 1-pass bf16
// (error budget measured empirically: absmax pinned ~0.078 by conv2/conv4;
// threshold 0.098). conv2: A-resident kernel; conv3/4/5: 128x128 LDS-staged
// template; FC1/FC2: packed fragment-order operands, zero LDS/barriers.
// Pooled layers (conv2, conv4) fuse the 2x2 pool into the GEMM epilogue as
// (window-max, window-min) dual fp32 writes. prep does conv1 BN stats +
// LDS-transposed conv weights + tile-based packed FC-weight repack.
// No lo-activation surfaces remain (all residual passes dropped).
// BN stats fused into GEMM epilogue / split-K reducer; bn_finalize is
// one-block-per-channel wave butterfly. conv1 reads x with edge clamping.
// SPP reads conv5 fp32 out with inline BN. Biases skipped (BN cancels).
// ============================================================================

typedef __bf16 bf16;
using bf16x4 = __attribute__((ext_vector_type(4))) __bf16;
using bf16x8 = __attribute__((ext_vector_type(8))) __bf16;
using f32x4  = __attribute__((ext_vector_type(4))) float;

__device__ __forceinline__ int iclamp(int v, int lo, int hi) {
  return v < lo ? lo : (v > hi ? hi : v);
}

__device__ __forceinline__ size_t pk_off(int row, int k, int Kd64) {
  return ((size_t)(row >> 4) * Kd64 + (k >> 6)) * 1024 +
         (size_t)(((k >> 5) & 1) * 512 + ((k >> 3) & 3) * 128 + ((row & 15) << 3) + (k & 7));
}

__device__ __forceinline__ void gld_lds16(const bf16* g, void* lds) {
  __builtin_amdgcn_global_load_lds(
      (const __attribute__((address_space(1))) unsigned int*)g,
      (__attribute__((address_space(3))) unsigned int*)lds, 16, 0, 0);
}

// ---------------- fused prep: conv1 BN stats + all weight/input transforms --
// blocks [0,768): conv1 stats. [768,2176): conv weights (LDS transpose).
// [2176,8320): f1w tiles. [8320,24704): f2w tiles. [24704,26240): phoc tiles.
__global__ __launch_bounds__(256) void prep_k(const float* __restrict__ x,
                                              const float* __restrict__ c1w,
                                              float* __restrict__ part,
                                              const float* __restrict__ c2w,
                                              const float* __restrict__ c3w,
                                              const float* __restrict__ c4w,
                                              const float* __restrict__ c5w,
                                              const float* __restrict__ f1w,
                                              const float* __restrict__ f2w,
                                              const float* __restrict__ phoc,
                                              bf16* __restrict__ Wc2h,
                                              bf16* __restrict__ Wc3h,
                                              bf16* __restrict__ Wc4h,
                                              bf16* __restrict__ Wc5h,
                                              bf16* __restrict__ Wf1,
                                              bf16* __restrict__ Wf2,
                                              bf16* __restrict__ cch) {
  __shared__ float buf[4608];
  __shared__ float ls[256], lq[256];
  int b = blockIdx.x;
  int tid = threadIdx.x;
  if (b < 768) {
    // ---- conv1 BN stats (8 ch/group, edge-clamped reads of x) ----
    int seg = b >> 3;          // 0..95
    int co0 = (b & 7) * 8;     // channel group
    float sums[8] = {0.f}, sqs[8] = {0.f};
    for (int r = 0; r < 16; r++) {
      int pix = seg * 4096 + r * 256 + tid;  // 0..393215
      int w = pix & 127; int t = pix >> 7; int h = t % 48; int n = t / 48;
      const float* ip = x + (size_t)n * 48 * 128;
      int ihs[5], iws[5];
#pragma unroll
      for (int k = 0; k < 5; k++) {
        ihs[k] = iclamp(h + k - 2, 0, 47);
        iws[k] = iclamp(w + k - 2, 0, 127);
      }
      float win[25];
#pragma unroll
      for (int kh = 0; kh < 5; kh++)
#pragma unroll
        for (int kw = 0; kw < 5; kw++) win[kh * 5 + kw] = ip[ihs[kh] * 128 + iws[kw]];
#pragma unroll
      for (int j = 0; j < 8; j++) {
        const float* wp = c1w + (size_t)(co0 + j) * 25;
        float acc = 0.f;
#pragma unroll
        for (int k = 0; k < 25; k++) acc += win[k] * wp[k];
        sums[j] += acc; sqs[j] += acc * acc;
      }
    }
    for (int j = 0; j < 8; j++) {
      ls[tid] = sums[j]; lq[tid] = sqs[j];
      __syncthreads();
      for (int o = 128; o > 0; o >>= 1) {
        if (tid < o) { ls[tid] += ls[tid + o]; lq[tid] += lq[tid + o]; }
        __syncthreads();
      }
      if (tid == 0) {
        int c = co0 + j;
        part[((size_t)c * 96 + seg) * 2 + 0] = ls[0];
        part[((size_t)c * 96 + seg) * 2 + 1] = lq[0];
      }
      __syncthreads();
    }
    return;
  }
  b -= 768;
  const float* src = nullptr;
  bf16 *dsth = nullptr;
  int CI = 0, KK = 0, co = 0;
  if (b < 128)        { src = c2w; dsth = Wc2h; CI = 64;  KK = 25; co = b; }
  else if (b < 384)   { src = c3w; dsth = Wc3h; CI = 128; KK = 9;  co = b - 128; }
  else if (b < 896)   { src = c4w; dsth = Wc4h; CI = 256; KK = 9;  co = b - 384; }
  else if (b < 1408)  { src = c5w; dsth = Wc5h; CI = 512; KK = 9; co = b - 896; }
  if (src) {
    const int n = CI * KK;
    const float* sp = src + (size_t)co * n;
    for (int i = tid; i < n; i += 256) buf[i] = sp[i];
    __syncthreads();
    bf16* oh = dsth + (size_t)co * n;
    for (int o = tid; o < n; o += 256) {
      int ci = o & (CI - 1), kk = o / CI;
      oh[o] = (bf16)buf[ci * KK + kk];
    }
    return;
  }
  b -= 1408;
  if (b < 6144) {  // f1w [2048][3072] -> one packed 16x64 tile per block
    int rb = b / 48, kb = b % 48;
    int row0 = rb * 16, k0 = kb * 64;
    {
      int r = tid >> 4, c = (tid & 15) * 4;
      const float4 v = *(const float4*)(f1w + (size_t)(row0 + r) * 3072 + k0 + c);
      buf[r * 64 + c + 0] = v.x; buf[r * 64 + c + 1] = v.y;
      buf[r * 64 + c + 2] = v.z; buf[r * 64 + c + 3] = v.w;
    }
    __syncthreads();
    bf16x4 o4;
#pragma unroll
    for (int j = 0; j < 4; j++) {
      int o = tid * 4 + j;
      int r = (o >> 3) & 15;
      int kl = (o >> 9) * 32 + ((o >> 7) & 3) * 8 + (o & 7);
      o4[j] = (bf16)buf[r * 64 + kl];
    }
    *(bf16x4*)(Wf1 + (size_t)b * 1024 + tid * 4) = o4;
    return;
  }
  b -= 6144;
  if (b < 16384) {  // f2w [2048][7901] -> packed [2048][8192] tiles, guarded
    int rb = b >> 7, kb = b & 127;
    int row0 = rb * 16, k0 = kb * 64;
    {
      int r = tid >> 4, c = (tid & 15) * 4;
      const float* sp = f2w + (size_t)(row0 + r) * 7901 + k0 + c;
#pragma unroll
      for (int j = 0; j < 4; j++)
        buf[r * 64 + c + j] = (k0 + c + j < 7901) ? sp[j] : 0.f;
    }
    __syncthreads();
    bf16x4 o4;
#pragma unroll
    for (int j = 0; j < 4; j++) {
      int o = tid * 4 + j;
      int r = (o >> 3) & 15;
      int kl = (o >> 9) * 32 + ((o >> 7) & 3) * 8 + (o & 7);
      o4[j] = (bf16)buf[r * 64 + kl];
    }
    *(bf16x4*)(Wf2 + (size_t)b * 1024 + tid * 4) = o4;
    return;
  }
  b -= 16384;
  {  // phoc [256][5853] -> packed CC cols [2048,8192) tiles, guarded
    if (b >= 1536) return;
    int rb = b / 96, kb = b % 96;
    int row0 = rb * 16;
    {
      int r = tid >> 4, c = (tid & 15) * 4;
      const float* sp = phoc + (size_t)(row0 + r) * 5853 + kb * 64 + c;
#pragma unroll
      for (int j = 0; j < 4; j++)
        buf[r * 64 + c + j] = (kb * 64 + c + j < 5853) ? sp[j] : 0.f;
    }
    __syncthreads();
    bf16x4 o4;
#pragma unroll
    for (int j = 0; j < 4; j++) {
      int o = tid * 4 + j;
      int r = (o >> 3) & 15;
      int kl = (o >> 9) * 32 + ((o >> 7) & 3) * 8 + (o & 7);
      o4[j] = (bf16)buf[r * 64 + kl];
    }
    *(bf16x4*)(cch + ((size_t)rb * 128 + 32 + kb) * 1024 + tid * 4) = o4;
  }
}

// ---------------- conv1 pass 2: conv+BN+ReLU+pool+pad, hi-only -------------
__global__ __launch_bounds__(256) void conv1_apply_k(const float* __restrict__ x,
                                                     const float* __restrict__ wt,
                                                     const float* __restrict__ scale,
                                                     const float* __restrict__ shift,
                                                     bf16* __restrict__ yh) {
  int i = blockIdx.x * 256 + threadIdx.x;  // padded pixel slots
  if (i >= 64 * 28 * 68) return;
  int owp = i % 68; int t = i / 68; int ohp = t % 28; int n = t / 28;
  int co0 = blockIdx.y * 8;
  int oh = ohp - 2, ow = owp - 2;
  bf16x8 hv;
#pragma unroll
  for (int j = 0; j < 8; j++) hv[j] = (bf16)0.f;
  if (oh >= 0 && oh < 24 && ow >= 0 && ow < 64) {
    const float* ip = x + (size_t)n * 48 * 128;
    int shr[6], swc[6];
#pragma unroll
    for (int k = 0; k < 6; k++) {
      shr[k] = iclamp(2 * oh + k - 2, 0, 47);
      swc[k] = iclamp(2 * ow + k - 2, 0, 127);
    }
    float win[36];
#pragma unroll
    for (int r = 0; r < 6; r++)
#pragma unroll
      for (int c = 0; c < 6; c++) win[r * 6 + c] = ip[shr[r] * 128 + swc[c]];
#pragma unroll
    for (int j = 0; j < 8; j++) {
      const float* wp = wt + (size_t)(co0 + j) * 25;
      float sc = scale[co0 + j], sh = shift[co0 + j];
      float m = -1e30f;
#pragma unroll
      for (int dy = 0; dy < 2; dy++)
#pragma unroll
        for (int dx = 0; dx < 2; dx++) {
          float acc = 0.f;
#pragma unroll
          for (int kh = 0; kh < 5; kh++)
#pragma unroll
            for (int kw = 0; kw < 5; kw++)
              acc += win[(kh + dy) * 6 + kw + dx] * wp[kh * 5 + kw];
          m = fmaxf(m, acc * sc + sh);
        }
      hv[j] = (bf16)fmaxf(m, 0.f);
    }
  }
  *(bf16x8*)(yh + (size_t)i * 64 + co0) = hv;
}

// ---------------- conv2 specialized: A-resident + fused pool (max/min) -----
__global__ __launch_bounds__(256) void conv2_gemm_k(const bf16* __restrict__ Ahi,
                                                    const bf16* __restrict__ Bhi,
                                                    float* __restrict__ Wmax,
                                                    float* __restrict__ Wmin,
                                                    float* __restrict__ part) {
  __shared__ bf16 Ash[416 * 64];      // 52 KB (reused as exchange post-loop)
  __shared__ bf16 Bsh[128 * 64];      // 16 KB
  __shared__ float red[2][128][8];    // 8 KB
  const int t = threadIdx.x;
  const int lane = t & 63, w = t >> 6;
  const int m0 = blockIdx.x * 128;
  const int img = m0 / 1536;
  const int oh0 = (m0 % 1536) >> 6;   // even
  const size_t abase = ((size_t)(img * 28 + oh0) * 68) * 64;

#pragma unroll
  for (int i = 0; i < 13; i++) {
    int f = i * 256 + t;
    int p = f >> 3; if (p > 407) p = 407;
    int s = f & 7;
    int ss = s ^ (p & 7);
    gld_lds16(Ahi + abase + (size_t)p * 64 + ss * 8,
              (char*)Ash + (size_t)(i * 256 + w * 64) * 16);
  }

  size_t boff[4];
#pragma unroll
  for (int i = 0; i < 4; i++) {
    int f = (i * 4 + w) * 64 + lane;
    int row = f >> 3, slot = f & 7;
    int ss = slot ^ (row & 7);
    boff[i] = (size_t)row * 1600 + ss * 8;
  }

  const int wrow = w >> 1, wcol = w & 1;
  const int kg = lane >> 4, l15 = lane & 15;
  int pixb[4];
#pragma unroll
  for (int q = 0; q < 4; q++) pixb[q] = wrow * 68 + q * 16 + l15;
  int brb[4], bmk[4];
#pragma unroll
  for (int q = 0; q < 4; q++) {
    int rb = wcol * 64 + q * 16 + l15;
    brb[q] = rb * 128; bmk[q] = rb & 7;
  }
  const char* Ashb = (const char*)Ash;
  const char* Bshb = (const char*)Bsh;

  f32x4 acc[4][4] = {};
  for (int kc = 0; kc < 25; ++kc) {
    const int kh = kc / 5, kw = kc % 5;
    const int kofs = kh * 68 + kw;
    const int k0 = kc * 64;
#pragma unroll
    for (int i = 0; i < 4; i++)
      gld_lds16(Bhi + boff[i] + k0, (char*)Bsh + (i * 4 + w) * 1024);
    __syncthreads();
#pragma unroll
    for (int ks = 0; ks < 2; ks++) {
      const int slot = ks * 4 + kg;
      bf16x8 ah[4], bh[4];
#pragma unroll
      for (int q = 0; q < 4; q++) {
        int pix = pixb[q] + kofs;
        ah[q] = *(const bf16x8*)(Ashb + pix * 128 + ((slot ^ (pix & 7)) << 4));
        bh[q] = *(const bf16x8*)(Bshb + brb[q] + ((slot ^ bmk[q]) << 4));
      }
#pragma unroll
      for (int mi = 0; mi < 4; mi++)
#pragma unroll
        for (int ni = 0; ni < 4; ni++)
          acc[mi][ni] = __builtin_amdgcn_mfma_f32_16x16x32_bf16(ah[mi], bh[ni], acc[mi][ni], 0, 0, 0);
    }
    __syncthreads();  // after this, Ash/Bsh free for reuse
  }

  const int ccol = l15;
  float hmx[4][4][2], hmn[4][4][2];
#pragma unroll
  for (int mi = 0; mi < 4; mi++)
#pragma unroll
    for (int ni = 0; ni < 4; ni++)
#pragma unroll
      for (int jp = 0; jp < 2; jp++) {
        float a = acc[mi][ni][2 * jp], b = acc[mi][ni][2 * jp + 1];
        hmx[mi][ni][jp] = fmaxf(a, b);
        hmn[mi][ni][jp] = fminf(a, b);
      }
  const int contrib = kg * 2 + wrow;
#pragma unroll
  for (int ni = 0; ni < 4; ni++) {
    float s = 0.f, q = 0.f;
#pragma unroll
    for (int mi = 0; mi < 4; mi++)
#pragma unroll
      for (int jj = 0; jj < 4; jj++) {
        float v = acc[mi][ni][jj];
        s += v; q += v * v;
      }
    int coll = wcol * 64 + ni * 16 + ccol;
    red[0][coll][contrib] = s;
    red[1][coll][contrib] = q;
  }
  float* exch = (float*)Ash;
  if (wrow == 1) {
    float* ep = exch + (size_t)(wcol * 64 + lane) * 64;
#pragma unroll
    for (int mi = 0; mi < 4; mi++)
#pragma unroll
      for (int ni = 0; ni < 4; ni++)
#pragma unroll
        for (int jp = 0; jp < 2; jp++) {
          int s = (mi * 8 + ni * 2 + jp) * 2;
          ep[s + 0] = hmx[mi][ni][jp];
          ep[s + 1] = hmn[mi][ni][jp];
        }
  }
  __syncthreads();
  if (wrow == 0) {
    const float* ep = exch + (size_t)(wcol * 64 + lane) * 64;
    const int pmb = img * 384 + (oh0 >> 1) * 32;
#pragma unroll
    for (int mi = 0; mi < 4; mi++)
#pragma unroll
      for (int ni = 0; ni < 4; ni++)
#pragma unroll
        for (int jp = 0; jp < 2; jp++) {
          int s = (mi * 8 + ni * 2 + jp) * 2;
          float mx = fmaxf(hmx[mi][ni][jp], ep[s + 0]);
          float mn = fminf(hmn[mi][ni][jp], ep[s + 1]);
          int pm = pmb + mi * 8 + kg * 2 + jp;
          int ch = wcol * 64 + ni * 16 + ccol;
          Wmax[(size_t)pm * 128 + ch] = mx;
          Wmin[(size_t)pm * 128 + ch] = mn;
        }
  }
  if (t < 128) {
    float s = 0.f, q = 0.f;
#pragma unroll
    for (int j = 0; j < 8; j++) { s += red[0][t][j]; q += red[1][t][j]; }
    size_t c = t;
    part[(c * gridDim.x + blockIdx.x) * 2 + 0] = s;
    part[(c * gridDim.x + blockIdx.x) * 2 + 1] = q;
  }
}

// ---------------- MFMA implicit-GEMM, LDS-staged, optional split-K/pool ----
template<int CI, int KS, int OH, int OW, int CO, bool ALO, bool BLO, int SPLIT, bool FUSEPOOL>
__global__ __launch_bounds__(256) void conv_gemm_k(const bf16* __restrict__ Ahi,
                                                   const bf16* __restrict__ Alo,
                                                   const bf16* __restrict__ Bhi,
                                                   const bf16* __restrict__ Blo,
                                                   float* __restrict__ Cout,
                                                   float* __restrict__ Cmin,
                                                   float* __restrict__ part) {
  static_assert(CI % 64 == 0, "chunk must not straddle ci segments");
  static_assert(!FUSEPOOL || (OW == 32 && SPLIT == 1), "fusepool needs OW=32");
  constexpr int K = KS * KS * CI;
  constexpr int IWP = OW + KS - 1;
  constexpr int NCH = K / 64;
  static_assert(NCH % SPLIT == 0, "split must divide chunk count");
  constexpr int NCHS = NCH / SPLIT;
  constexpr int M = 64 * OH * OW;
  __shared__ bf16 Ash[128 * 64];
  __shared__ bf16 Asl[ALO ? 128 * 64 : 64];
  __shared__ bf16 Bsh[128 * 64];
  __shared__ bf16 Bsl[BLO ? 128 * 64 : 64];
  __shared__ float red[2][128][8];
  const int t = threadIdx.x;
  const int lane = t & 63, w = t >> 6;
  const int m0 = blockIdx.x * 128, n0 = blockIdx.y * 128;
  const int z = (SPLIT > 1) ? blockIdx.z : 0;

  int apix[4]; size_t boff[4];
#pragma unroll
  for (int i = 0; i < 4; i++) {
    int f = (i * 4 + w) * 64 + lane;
    int row = f >> 3, slot = f & 7;
    int ss = slot ^ (row & 7);
    int m = m0 + row;
    int n = m / (OH * OW); int rem = m % (OH * OW);
    int oh = rem / OW, ow_ = rem % OW;
    apix[i] = ((n * (OH + KS - 1) + oh) * IWP + ow_) * CI + ss * 8;
    boff[i] = (size_t)(n0 + row) * K + ss * 8;
  }

  const int wrow = w >> 1, wcol = w & 1;
  const int kg = lane >> 4, l15 = lane & 15;
  int arb[4], amk[4], brb[4], bmk[4];
#pragma unroll
  for (int q = 0; q < 4; q++) {
    int ra = wrow * 64 + q * 16 + l15;
    arb[q] = ra * 128; amk[q] = ra & 7;
    int rb = wcol * 64 + q * 16 + l15;
    brb[q] = rb * 128; bmk[q] = rb & 7;
  }
  const char* Ashb = (const char*)Ash;
  const char* Aslb = (const char*)Asl;
  const char* Bshb = (const char*)Bsh;
  const char* Bslb = (const char*)Bsl;

  f32x4 acc[4][4] = {};
  for (int kc = z * NCHS; kc < (z + 1) * NCHS; ++kc) {
    const int k0 = kc * 64;
    const int seg = k0 / CI;
    const int ci0 = k0 % CI;
    const int kh = seg / KS, kw = seg % KS;
    const int aoff = (kh * IWP + kw) * CI + ci0;   // wave-uniform
#pragma unroll
    for (int i = 0; i < 4; i++) {
      gld_lds16(Ahi + (size_t)apix[i] + aoff, (char*)Ash + (i * 4 + w) * 1024);
      if (ALO)
        gld_lds16(Alo + (size_t)apix[i] + aoff, (char*)Asl + (i * 4 + w) * 1024);
      gld_lds16(Bhi + boff[i] + k0,   (char*)Bsh + (i * 4 + w) * 1024);
      if (BLO)
        gld_lds16(Blo + boff[i] + k0, (char*)Bsl + (i * 4 + w) * 1024);
    }
    __syncthreads();
#pragma unroll
    for (int ks = 0; ks < 2; ks++) {
      const int slot = ks * 4 + kg;
      bf16x8 ah[4], bh[4];
#pragma unroll
      for (int q = 0; q < 4; q++) {
        ah[q] = *(const bf16x8*)(Ashb + arb[q] + ((slot ^ amk[q]) << 4));
        bh[q] = *(const bf16x8*)(Bshb + brb[q] + ((slot ^ bmk[q]) << 4));
      }
#pragma unroll
      for (int mi = 0; mi < 4; mi++)
#pragma unroll
        for (int ni = 0; ni < 4; ni++)
          acc[mi][ni] = __builtin_amdgcn_mfma_f32_16x16x32_bf16(ah[mi], bh[ni], acc[mi][ni], 0, 0, 0);
      if (ALO) {
        bf16x8 al[4];
#pragma unroll
        for (int q = 0; q < 4; q++)
          al[q] = *(const bf16x8*)(Aslb + arb[q] + ((slot ^ amk[q]) << 4));
#pragma unroll
        for (int mi = 0; mi < 4; mi++)
#pragma unroll
          for (int ni = 0; ni < 4; ni++)
            acc[mi][ni] = __builtin_amdgcn_mfma_f32_16x16x32_bf16(al[mi], bh[ni], acc[mi][ni], 0, 0, 0);
      }
      if (BLO) {
        bf16x8 bl[4];
#pragma unroll
        for (int q = 0; q < 4; q++)
          bl[q] = *(const bf16x8*)(Bslb + brb[q] + ((slot ^ bmk[q]) << 4));
#pragma unroll
        for (int mi = 0; mi < 4; mi++)
#pragma unroll
          for (int ni = 0; ni < 4; ni++)
            acc[mi][ni] = __builtin_amdgcn_mfma_f32_16x16x32_bf16(ah[mi], bl[ni], acc[mi][ni], 0, 0, 0);
      }
    }
    __syncthreads();
  }

  const int crow0 = kg * 4, ccol = l15;
  if constexpr (FUSEPOOL) {
    const int n_img = m0 / (OH * OW);
    const int oh0 = (m0 % (OH * OW)) / OW;          // multiple of 4
    const int pmb = n_img * (OH / 2) * (OW / 2) + (oh0 / 2 + wrow) * (OW / 2);
#pragma unroll
    for (int mi = 0; mi < 2; mi++)
#pragma unroll
      for (int ni = 0; ni < 4; ni++)
#pragma unroll
        for (int jp = 0; jp < 2; jp++) {
          float a0 = acc[mi][ni][2 * jp],     a1 = acc[mi][ni][2 * jp + 1];
          float b0 = acc[mi + 2][ni][2 * jp], b1 = acc[mi + 2][ni][2 * jp + 1];
          float mx = fmaxf(fmaxf(a0, a1), fmaxf(b0, b1));
          float mn = fminf(fminf(a0, a1), fminf(b0, b1));
          int pm = pmb + mi * 8 + kg * 2 + jp;
          int ch = n0 + wcol * 64 + ni * 16 + ccol;
          Cout[(size_t)pm * CO + ch] = mx;
          Cmin[(size_t)pm * CO + ch] = mn;
        }
  } else {
    float* Cz = Cout + (size_t)z * M * CO;
#pragma unroll
    for (int mi = 0; mi < 4; mi++) {
      int m = m0 + wrow * 64 + mi * 16 + crow0;
#pragma unroll
      for (int ni = 0; ni < 4; ni++) {
        int nn = n0 + wcol * 64 + ni * 16 + ccol;
        float* cp = Cz + (size_t)m * CO + nn;
#pragma unroll
        for (int jj = 0; jj < 4; jj++) cp[(size_t)jj * CO] = acc[mi][ni][jj];
      }
    }
  }
  if constexpr (SPLIT == 1) {
    const int contrib = kg * 2 + wrow;
#pragma unroll
    for (int ni = 0; ni < 4; ni++) {
      float s = 0.f, q = 0.f;
#pragma unroll
      for (int mi = 0; mi < 4; mi++)
#pragma unroll
        for (int jj = 0; jj < 4; jj++) {
          float v = acc[mi][ni][jj];
          s += v; q += v * v;
        }
      int coll = wcol * 64 + ni * 16 + ccol;
      red[0][coll][contrib] = s;
      red[1][coll][contrib] = q;
    }
    __syncthreads();
    if (t < 128) {
      float s = 0.f, q = 0.f;
#pragma unroll
      for (int j = 0; j < 8; j++) { s += red[0][t][j]; q += red[1][t][j]; }
      size_t c = n0 + t;
      part[(c * gridDim.x + blockIdx.x) * 2 + 0] = s;
      part[(c * gridDim.x + blockIdx.x) * 2 + 1] = q;
    }
  }
}

// ---------------- FC GEMM: packed A (hi,+lo if ALO) + packed B, zero LDS ---
template<int K, int SPLIT, bool ALO>
__global__ __launch_bounds__(256) void fc_gemm_k(const bf16* __restrict__ Ahp,
                                                 const bf16* __restrict__ Alp,
                                                 const bf16* __restrict__ Bhp,
                                                 float* __restrict__ Cout) {
  constexpr int Kd64 = K / 64;
  constexpr int NCHS = Kd64 / SPLIT;
  constexpr int M = 256, N = 2048;
  const int t = threadIdx.x;
  const int lane = t & 63, w = t >> 6;
  const int m0 = blockIdx.x * 128, n0 = blockIdx.y * 128;
  const int z = blockIdx.z;
  const int wrow = w >> 1, wcol = w & 1;
  const int kg = lane >> 4, l15 = lane & 15;

  size_t ab[4], bb[4];
#pragma unroll
  for (int q = 0; q < 4; q++) {
    int rbA = (m0 >> 4) + wrow * 4 + q;
    ab[q] = (size_t)rbA * Kd64 * 1024 + (size_t)lane * 8;
    int rbB = (n0 >> 4) + wcol * 4 + q;
    bb[q] = (size_t)rbB * Kd64 * 1024 + (size_t)lane * 8;
  }

  f32x4 acc[4][4] = {};
  for (int kc = z * NCHS; kc < (z + 1) * NCHS; ++kc) {
    const size_t bco = (size_t)kc * 1024;
#pragma unroll
    for (int ks = 0; ks < 2; ks++) {
      const size_t soff = bco + ks * 512;
      bf16x8 ah[4], bh[4];
#pragma unroll
      for (int q = 0; q < 4; q++) {
        ah[q] = *(const bf16x8*)(Ahp + ab[q] + soff);
        bh[q] = *(const bf16x8*)(Bhp + bb[q] + soff);
      }
#pragma unroll
      for (int mi = 0; mi < 4; mi++)
#pragma unroll
        for (int ni = 0; ni < 4; ni++)
          acc[mi][ni] = __builtin_amdgcn_mfma_f32_16x16x32_bf16(ah[mi], bh[ni], acc[mi][ni], 0, 0, 0);
      if (ALO) {
        bf16x8 al[4];
#pragma unroll
        for (int q = 0; q < 4; q++)
          al[q] = *(const bf16x8*)(Alp + ab[q] + soff);
#pragma unroll
        for (int mi = 0; mi < 4; mi++)
#pragma unroll
          for (int ni = 0; ni < 4; ni++)
            acc[mi][ni] = __builtin_amdgcn_mfma_f32_16x16x32_bf16(al[mi], bh[ni], acc[mi][ni], 0, 0, 0);
      }
    }
  }

  const int crow0 = kg * 4, ccol = l15;
  float* Cz = Cout + (size_t)z * M * N;
#pragma unroll
  for (int mi = 0; mi < 4; mi++) {
    int m = m0 + wrow * 64 + mi * 16 + crow0;
#pragma unroll
    for (int ni = 0; ni < 4; ni++) {
      int nn = n0 + wcol * 64 + ni * 16 + ccol;
      float* cp = Cz + (size_t)m * N + nn;
#pragma unroll
      for (int jj = 0; jj < 4; jj++) cp[(size_t)jj * N] = acc[mi][ni][jj];
    }
  }
}

// ---------------- split-K reduction + BN partials ----------------
template<int M, int CO, int SPLIT, int NS>
__global__ __launch_bounds__(256) void reduce_bn_k(const float* __restrict__ Cp,
                                                   float* __restrict__ Cf,
                                                   float* __restrict__ part) {
  int c = blockIdx.x * 64 + (threadIdx.x & 63);
  int rl = threadIdx.x >> 6;
  constexpr int ROWS = M / NS;
  int r0 = blockIdx.y * ROWS;
  float sum = 0.f, sq = 0.f;
  for (int r = r0 + rl; r < r0 + ROWS; r += 4) {
    float v = 0.f;
#pragma unroll
    for (int s = 0; s < SPLIT; s++) v += Cp[(size_t)s * M * CO + (size_t)r * CO + c];
    Cf[(size_t)r * CO + c] = v;
    sum += v; sq += v * v;
  }
  __shared__ float ls[256], lq[256];
  ls[threadIdx.x] = sum; lq[threadIdx.x] = sq;
  __syncthreads();
  if (threadIdx.x < 64) {
    sum = ls[threadIdx.x] + ls[threadIdx.x + 64] + ls[threadIdx.x + 128] + ls[threadIdx.x + 192];
    sq  = lq[threadIdx.x] + lq[threadIdx.x + 64] + lq[threadIdx.x + 128] + lq[threadIdx.x + 192];
    part[((size_t)c * NS + blockIdx.y) * 2 + 0] = sum;
    part[((size_t)c * NS + blockIdx.y) * 2 + 1] = sq;
  }
}

// ---------------- BN finalize: one block per channel, wave butterfly -------
__global__ __launch_bounds__(64) void bn_finalize(const float* __restrict__ part,
                                                  const float* __restrict__ g,
                                                  const float* __restrict__ b,
                                                  float* __restrict__ scale,
                                                  float* __restrict__ shift,
                                                  int S, float invCount) {
  int c = blockIdx.x;
  int lane = threadIdx.x;
  float sum = 0.f, sq = 0.f;
  for (int s = lane; s < S; s += 64) {
    sum += part[((size_t)c * S + s) * 2 + 0];
    sq  += part[((size_t)c * S + s) * 2 + 1];
  }
#pragma unroll
  for (int o = 32; o > 0; o >>= 1) {
    sum += __shfl_xor(sum, o);
    sq  += __shfl_xor(sq, o);
  }
  if (lane == 0) {
    float m = sum * invCount;
    float var = sq * invCount - m * m;
    float sc = g[c] * rsqrtf(var + 1e-5f);
    scale[c] = sc;
    shift[c] = b[c] - m * sc;
  }
}

// ---------------- fused BN + ReLU + pad (no pool), hi-only, 8ch/thread -----
template<int CO, int IH, int IW, int PADO>
__global__ __launch_bounds__(256) void bn_act_pad_k(const float* __restrict__ x,
                                                    const float* __restrict__ scale,
                                                    const float* __restrict__ shift,
                                                    bf16* __restrict__ yh) {
  constexpr int OHP = IH + 2 * PADO, OWP = IW + 2 * PADO;
  constexpr int CO8 = CO / 8;
  int i = blockIdx.x * 256 + threadIdx.x;
  if (i >= 64 * OHP * OWP * CO8) return;
  int c8 = i % CO8; int t = i / CO8; int owp = t % OWP; t /= OWP; int ohp = t % OHP; int n = t / OHP;
  int c0 = c8 * 8;
  int oh = ohp - PADO, ow = owp - PADO;
  bf16x8 hv;
#pragma unroll
  for (int j = 0; j < 8; j++) hv[j] = (bf16)0.f;
  if (oh >= 0 && oh < IH && ow >= 0 && ow < IW) {
    float sc[8], sh[8];
    *(f32x4*)(sc)     = *(const f32x4*)(scale + c0);
    *(f32x4*)(sc + 4) = *(const f32x4*)(scale + c0 + 4);
    *(f32x4*)(sh)     = *(const f32x4*)(shift + c0);
    *(f32x4*)(sh + 4) = *(const f32x4*)(shift + c0 + 4);
    const float* p = x + (((size_t)(n * IH) + oh) * IW + ow) * CO + c0;
    float ta[8];
    *(f32x4*)(ta) = *(const f32x4*)(p); *(f32x4*)(ta + 4) = *(const f32x4*)(p + 4);
#pragma unroll
    for (int j = 0; j < 8; j++)
      hv[j] = (bf16)fmaxf(ta[j] * sc[j] + sh[j], 0.f);
  }
  *(bf16x8*)(yh + (size_t)i * 8) = hv;
}

// ---------------- BN + ReLU + pad from pooled (max,min), hi-only, 8ch/thr --
template<int CO, int PH, int PW, int PADO>
__global__ __launch_bounds__(256) void act_pool_pad_k(const float* __restrict__ wmax,
                                                      const float* __restrict__ wmin,
                                                      const float* __restrict__ scale,
                                                      const float* __restrict__ shift,
                                                      bf16* __restrict__ yh) {
  constexpr int OHP = PH + 2 * PADO, OWP = PW + 2 * PADO;
  constexpr int CO8 = CO / 8;
  int i = blockIdx.x * 256 + threadIdx.x;
  if (i >= 64 * OHP * OWP * CO8) return;
  int c8 = i % CO8; int t = i / CO8; int owp = t % OWP; t /= OWP; int ohp = t % OHP; int n = t / OHP;
  int c0 = c8 * 8;
  int oh = ohp - PADO, ow = owp - PADO;
  bf16x8 hv;
#pragma unroll
  for (int j = 0; j < 8; j++) hv[j] = (bf16)0.f;
  if (oh >= 0 && oh < PH && ow >= 0 && ow < PW) {
    float sc[8], sh[8], mx[8], mn[8];
    *(f32x4*)(sc)     = *(const f32x4*)(scale + c0);
    *(f32x4*)(sc + 4) = *(const f32x4*)(scale + c0 + 4);
    *(f32x4*)(sh)     = *(const f32x4*)(shift + c0);
    *(f32x4*)(sh + 4) = *(const f32x4*)(shift + c0 + 4);
    size_t off = (((size_t)(n * PH) + oh) * PW + ow) * CO + c0;
    *(f32x4*)(mx)     = *(const f32x4*)(wmax + off);
    *(f32x4*)(mx + 4) = *(const f32x4*)(wmax + off + 4);
    *(f32x4*)(mn)     = *(const f32x4*)(wmin + off);
    *(f32x4*)(mn + 4) = *(const f32x4*)(wmin + off + 4);
#pragma unroll
    for (int j = 0; j < 8; j++) {
      float sel = (sc[j] >= 0.f) ? mx[j] : mn[j];
      hv[j] = (bf16)fmaxf(sel * sc[j] + sh[j], 0.f);
    }
  }
  *(bf16x8*)(yh + (size_t)i * 8) = hv;
}

// ---------------- ROI SPP: conv5 fp32 + inline BN -> PACKED S hi ----------
__global__ __launch_bounds__(256) void spp_k(const float* __restrict__ feat,
                                             const float* __restrict__ scale,
                                             const float* __restrict__ shift,
                                             const int* __restrict__ roi,
                                             bf16* __restrict__ oh_) {
  int c = blockIdx.x * 256 + threadIdx.x;  // 0..511
  int r = blockIdx.y;                      // 0..255
  const int* rp = roi + r * 5;
  int im = rp[0];
  int c1 = rp[1] >> 3, r1 = rp[2] >> 3, c2 = rp[3] >> 3, r2 = rp[4] >> 3;
  int w = c2 - c1 + 1;
  int lo[6], hi[6];
  int bi = 0;
#pragma unroll
  for (int l = 1; l <= 3; l++)
    for (int k = 0; k < l; k++) {
      lo[bi] = c1 + (k * w) / l;
      hi[bi] = c1 + ((k + 1) * w + l - 1) / l - 1;
      bi++;
    }
  float mx[6];
#pragma unroll
  for (int b = 0; b < 6; b++) mx[b] = -1e30f;
  float sc = scale[c], sh = shift[c];
  const float* fp = feat + (size_t)im * 96 * 512 + c;
  for (int row = r1; row <= r2; row++)
    for (int col = c1; col <= c2; col++) {
      float v = fp[(size_t)(row * 16 + col) * 512] * sc + sh;
#pragma unroll
      for (int b = 0; b < 6; b++)
        if (col >= lo[b] && col <= hi[b]) mx[b] = fmaxf(mx[b], v);
    }
  int idx[6] = {c, 512 + c * 2, 512 + c * 2 + 1, 1536 + c * 3, 1536 + c * 3 + 1, 1536 + c * 3 + 2};
#pragma unroll
  for (int b = 0; b < 6; b++)
    oh_[pk_off(r, idx[b], 48)] = (bf16)fmaxf(mx[b], 0.f);
}

// FC1: BN+ReLU, write hi PACKED into CC[:, 0:2048] (K=8192); FC2 is 1-pass.
__global__ __launch_bounds__(256) void bn1d_apply_cc_k(const float* __restrict__ x,
                                                       const float* __restrict__ scale,
                                                       const float* __restrict__ shift,
                                                       bf16* __restrict__ ch) {
  int i = blockIdx.x * 256 + threadIdx.x;
  if (i >= 256 * 256) return;
  int f8 = i & 255, r = i >> 8;
  int f0 = f8 * 8;
  float xv[8], sc[8], sh[8];
  *(f32x4*)(xv)     = *(const f32x4*)(x + (size_t)r * 2048 + f0);
  *(f32x4*)(xv + 4) = *(const f32x4*)(x + (size_t)r * 2048 + f0 + 4);
  *(f32x4*)(sc)     = *(const f32x4*)(scale + f0);
  *(f32x4*)(sc + 4) = *(const f32x4*)(scale + f0 + 4);
  *(f32x4*)(sh)     = *(const f32x4*)(shift + f0);
  *(f32x4*)(sh + 4) = *(const f32x4*)(shift + f0 + 4);
  bf16x8 hv;
#pragma unroll
  for (int j = 0; j < 8; j++) {
    float v = fmaxf(xv[j] * sc[j] + sh[j], 0.f);
    hv[j] = (bf16)v;
  }
  *(bf16x8*)(ch + pk_off(r, f0, 128)) = hv;
}

// FC2: BN+ReLU, fp32 out, 4 feat/thread
__global__ __launch_bounds__(256) void bn1d_apply_f32_k(const float* __restrict__ x,
                                                        const float* __restrict__ scale,
                                                        const float* __restrict__ shift,
                                                        float* __restrict__ y) {
  int i = blockIdx.x * 256 + threadIdx.x;
  if (i >= 256 * 512) return;
  int f4 = i & 511, r = i >> 9;
  int f0 = f4 * 4;
  f32x4 xv = *(const f32x4*)(x + (size_t)r * 2048 + f0);
  f32x4 sc = *(const f32x4*)(scale + f0);
  f32x4 sh = *(const f32x4*)(shift + f0);
  f32x4 o;
#pragma unroll
  for (int j = 0; j < 4; j++) o[j] = fmaxf(xv[j] * sc[j] + sh[j], 0.f);
  *(f32x4*)(y + (size_t)r * 2048 + f0) = o;
}

// ============================================================================
extern "C" void kernel_launch(void* const* d_in, const int* in_sizes, int n_in,
                              void* d_out, int out_size, void* d_ws, size_t ws_size,
                              hipStream_t stream) {
  (void)in_sizes; (void)n_in; (void)out_size; (void)ws_size;

  const float* x    = (const float*)d_in[0];
  const int*   roi  = (const int*)  d_in[1];
  const float* phoc = (const float*)d_in[2];
  const float* c1w  = (const float*)d_in[3];
  const float* g1   = (const float*)d_in[5];
  const float* b1   = (const float*)d_in[6];
  const float* c2w  = (const float*)d_in[7];
  const float* g2   = (const float*)d_in[9];
  const float* b2   = (const float*)d_in[10];
  const float* c3w  = (const float*)d_in[11];
  const float* g3   = (const float*)d_in[13];
  const float* b3   = (const float*)d_in[14];
  const float* c4w  = (const float*)d_in[15];
  const float* g4   = (const float*)d_in[17];
  const float* b4   = (const float*)d_in[18];
  const float* c5w  = (const float*)d_in[19];
  const float* g5   = (const float*)d_in[21];
  const float* b5   = (const float*)d_in[22];
  const float* f1w  = (const float*)d_in[23];
  const float* g6   = (const float*)d_in[25];
  const float* b6   = (const float*)d_in[26];
  const float* f2w  = (const float*)d_in[27];
  const float* g7   = (const float*)d_in[29];
  const float* b7   = (const float*)d_in[30];
  float* out = (float*)d_out;

  // ---- workspace layout ----
  char* ws = (char*)d_ws;
  bf16*  Ahi  = (bf16*) (ws + 0x0200000);   // 16 MB (padded NHWC activations)
  float* C    = (float*)(ws + 0x2200000);   // GEMM out / split slabs / pooled max
  float* CMIN = (float*)(ws + 0x2E00000);   // pooled min
  float* C5F  = (float*)(ws + 0x4600000);   // conv5 final
  bf16*  Wc2h = (bf16*) (ws + 0x5500000);   // conv weights (row-major [CO][K])
  bf16*  Wc3h = (bf16*) (ws + 0x5570000);
  bf16*  Wc4h = (bf16*) (ws + 0x5600000);
  bf16*  Wc5h = (bf16*) (ws + 0x5840000);
  bf16*  Wf1  = (bf16*) (ws + 0x5CC0000);   // packed FC weights
  bf16*  Wf2  = (bf16*) (ws + 0x68C0000);   // packed [2048][8192] = 32 MB
  bf16*  Shi  = (bf16*) (ws + 0x9080000);   // packed spp out [256][3072]
  float* G6   = (float*)(ws + 0x9380000);   // fc1 out fp32 [256][2048]
  bf16*  CChi = (bf16*) (ws + 0x9580000);   // packed concat hi [256][8192] = 4 MB
  float* G7   = (float*)(ws + 0x9D80000);   // fc2 out fp32 [256][2048]
  float* PART = (float*)(ws + 0x9F80000);   // 768 KB
  float* SC   = (float*)(ws + 0xA040000);
  float* SH   = (float*)(ws + 0xA050000);

  // ---- prep: conv1 stats (768) || conv weights (1408) || FC tiles (24064) --
  prep_k<<<26240, 256, 0, stream>>>(x, c1w, PART,
                                    c2w, c3w, c4w, c5w, f1w, f2w, phoc,
                                    Wc2h, Wc3h, Wc4h, Wc5h, Wf1, Wf2,
                                    CChi);

  // ---- conv1 finalize + apply (stats already done inside prep) ----
  bn_finalize<<<64, 64, 0, stream>>>(PART, g1, b1, SC, SH, 96, 1.f / 393216.f);
  conv1_apply_k<<<dim3(476, 8), 256, 0, stream>>>(x, c1w, SC, SH, Ahi);

  // ---- conv2 (1-pass, A-resident, fused pool): -> pooled max/min [24576][128]
  conv2_gemm_k<<<768, 256, 0, stream>>>(Ahi, Wc2h, C, CMIN, PART);
  bn_finalize<<<128, 64, 0, stream>>>(PART, g2, b2, SC, SH, 768, 1.f / 98304.f);
  act_pool_pad_k<128, 12, 32, 1><<<1904, 256, 0, stream>>>(C, CMIN, SC, SH, Ahi);

  // ---- conv3 (1-pass: Ah.Bh, no pool) ----
  conv_gemm_k<128, 3, 12, 32, 256, false, false, 1, false><<<dim3(192, 2), 256, 0, stream>>>(Ahi, nullptr, Wc3h, nullptr, C, nullptr, PART);
  bn_finalize<<<256, 64, 0, stream>>>(PART, g3, b3, SC, SH, 192, 1.f / 24576.f);
  bn_act_pad_k<256, 12, 32, 1><<<3808, 256, 0, stream>>>(C, SC, SH, Ahi);

  // ---- conv4 (1-pass, fused pool): -> pooled max/min [6144][512] ----
  conv_gemm_k<256, 3, 12, 32, 512, false, false, 1, true><<<dim3(192, 4), 256, 0, stream>>>(Ahi, nullptr, Wc4h, nullptr, C, CMIN, PART);
  bn_finalize<<<512, 64, 0, stream>>>(PART, g4, b4, SC, SH, 192, 1.f / 24576.f);
  act_pool_pad_k<512, 6, 16, 1><<<2304, 256, 0, stream>>>(C, CMIN, SC, SH, Ahi);

  // ---- conv5 (1-pass: Ah.Bh, split-K=2): slabs in C, final in C5F ----
  conv_gemm_k<512, 3, 6, 16, 512, false, false, 2, false><<<dim3(48, 4, 2), 256, 0, stream>>>(Ahi, nullptr, Wc5h, nullptr, C, nullptr, nullptr);
  reduce_bn_k<6144, 512, 2, 16><<<dim3(8, 16), 256, 0, stream>>>(C, C5F, PART);
  bn_finalize<<<512, 64, 0, stream>>>(PART, g5, b5, SC, SH, 16, 1.f / 6144.f);

  // ---- SPP (reads fp32 conv5 out + inline BN, packed hi output) ----
  spp_k<<<dim3(2, 256), 256, 0, stream>>>(C5F, SC, SH, roi, Shi);

  // ---- FC1 (packed, LDS-free, 1-pass, split-K=16): [256][3072] x [2048][3072]
  fc_gemm_k<3072, 16, false><<<dim3(2, 16, 16), 256, 0, stream>>>(Shi, nullptr, Wf1, C);
  reduce_bn_k<256, 2048, 16, 4><<<dim3(32, 4), 256, 0, stream>>>(C, G6, PART);
  bn_finalize<<<2048, 64, 0, stream>>>(PART, g6, b6, SC, SH, 4, 1.f / 256.f);
  bn1d_apply_cc_k<<<256, 256, 0, stream>>>(G6, SC, SH, CChi);

  // ---- FC2 (packed, LDS-free, 1-pass, split-K=16): [256][8192] x [2048][8192]
  fc_gemm_k<8192, 16, false><<<dim3(2, 16, 16), 256, 0, stream>>>(CChi, nullptr, Wf2, C);
  reduce_bn_k<256, 2048, 16, 4><<<dim3(32, 4), 256, 0, stream>>>(C, G7, PART);
  bn_finalize<<<2048, 64, 0, stream>>>(PART, g7, b7, SC, SH, 4, 1.f / 256.f);
  bn1d_apply_f32_k<<<512, 256, 0, stream>>>(G7, SC, SH, out);
}